// Round 8
// baseline (753.967 us; speedup 1.0000x reference)
//
#include <hip/hip_runtime.h>
#include <hip/hip_bf16.h>
#include <math.h>

#define N_NODES 50000
#define N_EDGES 800000
#define FDIM 53
#define BATCH 128
#define HF 212   /* H*F */
#define F2 106   /* 2F  */
#define POOLW 424 /* 212+106+106 */
#define NPK2 220 /* 106 + 106 + 8: U | V | alS | alD */
#define PSTR 32  /* padded bin stride (ints) = 128 B: one L2 line per node */
#define ECS 128  /* U/V bf16 row stride (shorts) = 256 B = 4 L2 lines */

typedef __attribute__((ext_vector_type(8))) short short8;
typedef __attribute__((ext_vector_type(4))) float f32x4;

__device__ __forceinline__ float leaky02(float x){ return x >= 0.f ? x : 0.2f * x; }

__device__ __forceinline__ short f2bf(float x) {
  unsigned u = __float_as_uint(x);
  unsigned r = (u + 0x7fffu + ((u >> 16) & 1u)) >> 16;
  return (short)r;
}
__device__ __forceinline__ float bf2f(short b) {
  return __uint_as_float(((unsigned)(unsigned short)b) << 16);
}
// packed pair f32x2 -> bf16x2 (v_cvt_pk_bf16_f32, RNE)
__device__ __forceinline__ unsigned pk2(float a, float b) {
  union { __hip_bfloat162 h; unsigned u; } c;
  c.h = __float22bfloat162_rn(make_float2(a, b));
  return c.u;
}
// wave-uniform scalarization helpers: move provably-uniform values to SGPRs
// so loop control / addressing compiles to SALU + saddr loads.
__device__ __forceinline__ int rfl(int v) { return __builtin_amdgcn_readfirstlane(v); }
__device__ __forceinline__ int rlanei(int v, int l) { return __builtin_amdgcn_readlane(v, l); }
__device__ __forceinline__ float rlanef(float v, int l) {
  return __uint_as_float((unsigned)__builtin_amdgcn_readlane((int)__float_as_uint(v), l));
}
// LDS-only barrier: waits lgkmcnt(0) (ds ops) but leaves global loads in flight
__device__ __forceinline__ void ldsbar() {
  __builtin_amdgcn_s_waitcnt(0xC07F);   // vmcnt(63) expcnt(7) lgkmcnt(0)
  __builtin_amdgcn_s_barrier();
}

// ---------------------------------------------------------------------------
// cAl[k*8 + sd*4 + h] = sum_f gat_w[k, h*53+f] * (sd? a_dst : a_src)[h,f]
// ---------------------------------------------------------------------------
__global__ void k_cal(const float* __restrict__ gat_w, const float* __restrict__ asrc,
                      const float* __restrict__ adst, float* __restrict__ cAl) {
  int t = threadIdx.x;
  if (t >= FDIM * 8) return;
  int k = t >> 3, r = t & 7, sd = r >> 2, h = r & 3;
  const float* av = sd ? adst : asrc;
  float acc = 0.f;
  for (int f = 0; f < FDIM; ++f) acc += gat_w[k * HF + h * FDIM + f] * av[h * FDIM + f];
  cAl[t] = acc;
}

// ---------------------------------------------------------------------------
// Pack Wp[53][220] = [W1top-W1bot | W1bot | cAl] and bias bp[220]
// ---------------------------------------------------------------------------
__global__ void k_prep(const float* __restrict__ ec_w1, const float* __restrict__ ec_b1,
                       const float* __restrict__ cAl,
                       float* __restrict__ Wp, float* __restrict__ bp) {
  int idx = blockIdx.x * blockDim.x + threadIdx.x;
  if (idx < FDIM * NPK2) {
    int k = idx / NPK2, j = idx % NPK2;
    float v;
    if (j < F2)            v = ec_w1[k * F2 + j] - ec_w1[(FDIM + k) * F2 + j];
    else if (j < 2 * F2)   v = ec_w1[(FDIM + k) * F2 + (j - F2)];
    else                   v = cAl[k * 8 + (j - 2 * F2)];
    Wp[idx] = v;
  }
  if (idx < NPK2) {
    bp[idx] = (idx < F2) ? ec_b1[idx] : 0.f;
  }
}

// ---------------------------------------------------------------------------
// Node-linear GEMM: x[50000x53] @ Wp[53x220] + bp -> U | V | alS | alD.
// Also emits xb (bf16 x rows, 64-short stride) during A-tile staging.
// ---------------------------------------------------------------------------
#define GM 64
#define GN 110
#define GNP 112
#define APAD 57
__global__ __launch_bounds__(256) void k_gemm(
    const float* __restrict__ x, const float* __restrict__ Wp, const float* __restrict__ bp,
    short* __restrict__ xb, short* __restrict__ Ub, short* __restrict__ Vb,
    float* __restrict__ alS, float* __restrict__ alD) {
  __shared__ float As[GM * APAD];
  __shared__ float Ws[FDIM * GNP];
  int mb = blockIdx.x >> 1, nc = blockIdx.x & 1;
  int m0 = mb * GM, n0 = nc * GN;
  int t = threadIdx.x;
  for (int idx = t; idx < GM * FDIM; idx += 256) {
    int m = idx / FDIM, k = idx % FDIM;
    int gm = m0 + m;
    float v = (gm < N_NODES) ? x[(size_t)gm * FDIM + k] : 0.f;
    As[m * APAD + k] = v;
    if (nc == 0 && gm < N_NODES) xb[(size_t)gm * 64 + k] = f2bf(v);
  }
  for (int idx = t; idx < FDIM * GNP; idx += 256) {
    int k = idx / GNP, n = idx % GNP;
    Ws[idx] = (n < GN) ? Wp[k * NPK2 + n0 + n] : 0.f;
  }
  __syncthreads();
  int tx = t & 15, ty = t >> 4;
  int ms = tx * 4, ns = ty * 7;
  float acc[4][7];
#pragma unroll
  for (int i = 0; i < 4; i++)
#pragma unroll
    for (int j = 0; j < 7; j++) acc[i][j] = 0.f;
  for (int k = 0; k < FDIM; k++) {
    float a0 = As[(ms + 0) * APAD + k];
    float a1 = As[(ms + 1) * APAD + k];
    float a2 = As[(ms + 2) * APAD + k];
    float a3 = As[(ms + 3) * APAD + k];
    float b[7];
#pragma unroll
    for (int j = 0; j < 7; j++) b[j] = Ws[k * GNP + ns + j];
#pragma unroll
    for (int j = 0; j < 7; j++) {
      acc[0][j] += a0 * b[j];
      acc[1][j] += a1 * b[j];
      acc[2][j] += a2 * b[j];
      acc[3][j] += a3 * b[j];
    }
  }
  float bj[7];
#pragma unroll
  for (int j = 0; j < 7; j++) {
    int g = n0 + ns + j;
    bj[j] = (g < NPK2) ? bp[g] : 0.f;
  }
#pragma unroll
  for (int i = 0; i < 4; i++) {
    int gm = m0 + ms + i;
    if (gm >= N_NODES) break;
#pragma unroll
    for (int j = 0; j < 7; j++) {
      int g = n0 + ns + j;
      float v = acc[i][j] + bj[j];
      if (g < F2)             Ub[(size_t)gm * ECS + g] = f2bf(v);
      else if (g < 2 * F2)    Vb[(size_t)gm * ECS + (g - F2)] = f2bf(v);
      else if (g < 2 * F2 + 4) alS[gm * 4 + (g - 2 * F2)] = v;
      else if (g < NPK2)      alD[gm * 4 + (g - 2 * F2 - 4)] = v;
    }
  }
}

// ---------------------------------------------------------------------------
// CSR build with L2-line-padded bins: hist -> scan (compacts to rp, turns
// padded slot into scatter cursor) -> scatter. Graph counts via sorted-batch
// boundary detection (no atomics).
// ---------------------------------------------------------------------------
#define SCAN_BLOCKS ((N_NODES + 255) / 256)

__global__ void k_hist(const int* __restrict__ ei, int* __restrict__ histP) {
  int t = blockIdx.x * blockDim.x + threadIdx.x;
  if (t < N_EDGES) atomicAdd(&histP[ei[N_EDGES + t] << 5], 1);
}

__global__ void k_bnd(const int* __restrict__ batch, int* __restrict__ start) {
  int t = blockIdx.x * blockDim.x + threadIdx.x;
  if (t >= N_NODES) return;
  int b = batch[t];
  if (t == 0)
    for (int g = 0; g <= b; g++) start[g] = 0;
  int bn = (t + 1 < N_NODES) ? batch[t + 1] : BATCH;
  for (int g = b + 1; g <= bn; g++) start[g] = t + 1;
}

__global__ __launch_bounds__(256) void k_scan1(const int* __restrict__ histP,
                                               int* __restrict__ rp, int* __restrict__ bsum) {
  __shared__ int buf[256];
  int tid = threadIdx.x;
  int idx = blockIdx.x * 256 + tid;
  int v = (idx < N_NODES) ? histP[idx << 5] : 0;
  buf[tid] = v;
  __syncthreads();
  for (int off = 1; off < 256; off <<= 1) {
    int t2 = (tid >= off) ? buf[tid - off] : 0;
    __syncthreads();
    buf[tid] += t2;
    __syncthreads();
  }
  if (idx < N_NODES) rp[idx] = buf[tid] - v;
  if (tid == 255) bsum[blockIdx.x] = buf[255];
}

__global__ __launch_bounds__(256) void k_scan2(int* __restrict__ bsum) {
  __shared__ int buf[256];
  int tid = threadIdx.x;
  int v = (tid < SCAN_BLOCKS) ? bsum[tid] : 0;
  buf[tid] = v;
  __syncthreads();
  for (int off = 1; off < 256; off <<= 1) {
    int t2 = (tid >= off) ? buf[tid - off] : 0;
    __syncthreads();
    buf[tid] += t2;
    __syncthreads();
  }
  if (tid < SCAN_BLOCKS) bsum[tid] = buf[tid] - v;
}

__global__ __launch_bounds__(256) void k_scan3(const int* __restrict__ bsum,
                                               int* __restrict__ rp, int* __restrict__ histP) {
  int idx = blockIdx.x * 256 + threadIdx.x;
  if (idx < N_NODES) {
    int o = rp[idx] + bsum[blockIdx.x];
    rp[idx] = o;
    histP[idx << 5] = o;   // becomes the (padded) scatter cursor
  }
  if (idx == 0) rp[N_NODES] = N_EDGES;
}

__global__ void k_scatter(const int* __restrict__ ei, int* __restrict__ histP,
                          int* __restrict__ colidx) {
  int e = blockIdx.x * blockDim.x + threadIdx.x;
  if (e >= N_EDGES) return;
  int d = ei[N_EDGES + e];
  int pos = atomicAdd(&histP[d << 5], 1);
  colidx[pos] = ei[e];
}

// ---------------------------------------------------------------------------
// Fused GAT-aggregate + GIN-sum, scalarized: node-level state in SGPRs
// (readfirstlane), edge broadcasts via readlane (no ds_bpermute), gather
// bases scalar (saddr form), alS rows loaded as one float4.
// ---------------------------------------------------------------------------
#define GCH 20
__global__ __launch_bounds__(256) void k_gatgin(
    const short* __restrict__ xb, const float* __restrict__ alS, const float* __restrict__ alD,
    const int* __restrict__ rp, const int* __restrict__ colidx,
    short* __restrict__ agg4, float* __restrict__ agg) {
  int wid = threadIdx.x >> 6, lane = threadIdx.x & 63;
  bool fa = lane < FDIM;
  int i0 = blockIdx.x * GCH;
  int iend = min(i0 + GCH, N_NODES);
  __shared__ int rpG[GCH + 1];
  {
    int t = threadIdx.x, nn = iend - i0;
    if (t <= nn) rpG[t] = rp[i0 + t];
  }
  __syncthreads();
  for (int i = i0 + wid; i < iend; i += 4) {
    int iu = rfl(i);                               // scalar node id
    int base = rfl(rpG[iu - i0]);
    int deg = rfl(rpG[iu - i0 + 1]) - base;
    float4 adv = *(const float4*)(alD + (size_t)iu * 4);
    float4 asv = *(const float4*)(alS + (size_t)iu * 4);
    float aldi[4] = {adv.x, adv.y, adv.z, adv.w};
    float exs[4];
    exs[0] = __expf(leaky02(asv.x + aldi[0]));     // self-loop term
    exs[1] = __expf(leaky02(asv.y + aldi[1]));
    exs[2] = __expf(leaky02(asv.z + aldi[2]));
    exs[3] = __expf(leaky02(asv.w + aldi[3]));
    float xiv = fa ? bf2f(xb[(size_t)iu * 64 + lane]) : 0.f;
    float ag0 = exs[0] * xiv, ag1 = exs[1] * xiv, ag2 = exs[2] * xiv, ag3 = exs[3] * xiv;
    float ax = xiv;
    float zl[4] = {0.f, 0.f, 0.f, 0.f};

    for (int c0 = 0; c0 < deg; c0 += 64) {
      int cn = min(64, deg - c0);                  // scalar
      int s = 0;
      float ex0 = 0.f, ex1 = 0.f, ex2 = 0.f, ex3 = 0.f;
      if (lane < cn) {
        s = colidx[base + c0 + lane];
        float4 av = *(const float4*)(alS + (size_t)s * 4);
        ex0 = __expf(leaky02(av.x + aldi[0]));
        ex1 = __expf(leaky02(av.y + aldi[1]));
        ex2 = __expf(leaky02(av.z + aldi[2]));
        ex3 = __expf(leaky02(av.w + aldi[3]));
        zl[0] += ex0; zl[1] += ex1; zl[2] += ex2; zl[3] += ex3;
      }
      for (int jj = 0; jj < cn; jj += 4) {
        int sj[4]; float a0[4], a1[4], a2[4], a3[4]; bool vq[4];
#pragma unroll
        for (int q = 0; q < 4; q++) {
          int j2 = jj + q;                         // scalar
          int jc = (j2 < cn) ? j2 : (cn - 1);      // scalar
          vq[q] = j2 < cn;                         // scalar
          sj[q] = rlanei(s, jc);                   // SGPR broadcast
          a0[q] = vq[q] ? rlanef(ex0, jc) : 0.f;
          a1[q] = vq[q] ? rlanef(ex1, jc) : 0.f;
          a2[q] = vq[q] ? rlanef(ex2, jc) : 0.f;
          a3[q] = vq[q] ? rlanef(ex3, jc) : 0.f;
        }
        float xg[4];
#pragma unroll
        for (int q = 0; q < 4; q++)
          xg[q] = fa ? bf2f(xb[(size_t)sj[q] * 64 + lane]) : 0.f;   // saddr gather
#pragma unroll
        for (int q = 0; q < 4; q++) {
          ag0 += a0[q] * xg[q];
          ag1 += a1[q] * xg[q];
          ag2 += a2[q] * xg[q];
          ag3 += a3[q] * xg[q];
          if (vq[q]) ax += xg[q];
        }
      }
    }
#pragma unroll
    for (int off = 32; off >= 1; off >>= 1)
#pragma unroll
      for (int h = 0; h < 4; h++) zl[h] += __shfl_xor(zl[h], off);
    if (fa) {
      float z0 = zl[0] + exs[0] + 1e-16f;
      float z1 = zl[1] + exs[1] + 1e-16f;
      float z2 = zl[2] + exs[2] + 1e-16f;
      float z3 = zl[3] + exs[3] + 1e-16f;
      short* ar = agg4 + (size_t)iu * HF;
      ar[0 * FDIM + lane] = f2bf(ag0 / z0);
      ar[1 * FDIM + lane] = f2bf(ag1 / z1);
      ar[2 * FDIM + lane] = f2bf(ag2 / z2);
      ar[3 * FDIM + lane] = f2bf(ag3 / z3);
      agg[(size_t)iu * FDIM + lane] = ax;
    }
  }
}

// ---------------------------------------------------------------------------
// GAT transform: grouped (per-head 53x53) GEMM + relu + pooled accumulation
// ---------------------------------------------------------------------------
#define TCOLS 224   /* 4 heads x 56 padded cols */
#define A4S 217     /* As row stride in shorts (odd -> conflict-free) */
__global__ __launch_bounds__(256) void k_gtrans(
    const short* __restrict__ agg4, const float* __restrict__ gat_w,
    const float* __restrict__ bias, const int* __restrict__ batch,
    float* __restrict__ pooled) {
  __shared__ short As[64 * A4S];
  __shared__ float Bs[FDIM * TCOLS];
  __shared__ float psum[4 * TCOLS];
  int m0 = blockIdx.x * 64;
  int t = threadIdx.x;
  for (int idx = t; idx < 4 * TCOLS; idx += 256) psum[idx] = 0.f;
  for (int idx = t; idx < 64 * HF; idx += 256) {
    int m = idx / HF, c = idx % HF;
    int gm = m0 + m;
    As[m * A4S + c] = (gm < N_NODES) ? agg4[(size_t)gm * HF + c] : (short)0;
  }
  for (int idx = t; idx < FDIM * TCOLS; idx += 256) {
    int k = idx / TCOLS, c = idx % TCOLS;
    int h = c / 56, jn = c % 56;
    Bs[idx] = (jn < FDIM) ? gat_w[k * HF + h * FDIM + jn] : 0.f;
  }
  __syncthreads();
  int tx = t & 15, ty = t >> 4;
  int ms = tx * 4, ns = ty * 14;
  int hh = ty >> 2;
  int jnb = (ty & 3) * 14;
  float acc[4][14];
#pragma unroll
  for (int i = 0; i < 4; i++)
#pragma unroll
    for (int j = 0; j < 14; j++) acc[i][j] = 0.f;
  for (int k = 0; k < FDIM; k++) {
    float a0 = bf2f(As[(ms + 0) * A4S + hh * FDIM + k]);
    float a1 = bf2f(As[(ms + 1) * A4S + hh * FDIM + k]);
    float a2 = bf2f(As[(ms + 2) * A4S + hh * FDIM + k]);
    float a3 = bf2f(As[(ms + 3) * A4S + hh * FDIM + k]);
    float b[14];
#pragma unroll
    for (int j = 0; j < 14; j++) b[j] = Bs[k * TCOLS + ns + j];
#pragma unroll
    for (int j = 0; j < 14; j++) {
      acc[0][j] += a0 * b[j];
      acc[1][j] += a1 * b[j];
      acc[2][j] += a2 * b[j];
      acc[3][j] += a3 * b[j];
    }
  }
  float bj[14]; bool jv[14];
#pragma unroll
  for (int j = 0; j < 14; j++) {
    jv[j] = (jnb + j) < FDIM;
    bj[j] = jv[j] ? bias[hh * FDIM + jnb + j] : 0.f;
  }
  int bmin = batch[m0];
  float pj[14];
#pragma unroll
  for (int j = 0; j < 14; j++) pj[j] = 0.f;
  int curb = -1;
#pragma unroll
  for (int i = 0; i < 4; i++) {
    int gm = m0 + ms + i;
    if (gm >= N_NODES) break;
    int b = batch[gm];
    if (b != curb) {
      if (curb >= 0) {
        int slot = curb - bmin;
        if (slot >= 0 && slot < 4) {
#pragma unroll
          for (int j = 0; j < 14; j++)
            if (jv[j]) atomicAdd(&psum[slot * TCOLS + ns + j], pj[j]);
        } else {
          float* pg = pooled + (size_t)curb * POOLW;
#pragma unroll
          for (int j = 0; j < 14; j++)
            if (jv[j]) atomicAdd(&pg[hh * FDIM + jnb + j], pj[j]);
        }
      }
      curb = b;
#pragma unroll
      for (int j = 0; j < 14; j++)
        pj[j] = jv[j] ? fmaxf(acc[i][j] + bj[j], 0.f) : 0.f;
    } else {
#pragma unroll
      for (int j = 0; j < 14; j++)
        if (jv[j]) pj[j] += fmaxf(acc[i][j] + bj[j], 0.f);
    }
  }
  if (curb >= 0) {
    int slot = curb - bmin;
    if (slot >= 0 && slot < 4) {
#pragma unroll
      for (int j = 0; j < 14; j++)
        if (jv[j]) atomicAdd(&psum[slot * TCOLS + ns + j], pj[j]);
    } else {
      float* pg = pooled + (size_t)curb * POOLW;
#pragma unroll
      for (int j = 0; j < 14; j++)
        if (jv[j]) atomicAdd(&pg[hh * FDIM + jnb + j], pj[j]);
    }
  }
  __syncthreads();
  for (int idx = t; idx < 4 * TCOLS; idx += 256) {
    int slot = idx / TCOLS, c = idx % TCOLS;
    int h = c / 56, jn = c % 56;
    float v = psum[idx];
    int b = bmin + slot;
    if (jn < FDIM && b < BATCH && v != 0.f)
      atomicAdd(&pooled[(size_t)b * POOLW + h * FDIM + jn], v);
  }
}

// ---------------------------------------------------------------------------
// GIN (2): h1g = relu(agg @ w1 + b1)
// ---------------------------------------------------------------------------
__global__ __launch_bounds__(256) void k_gin1(
    const float* __restrict__ agg, const float* __restrict__ w1, const float* __restrict__ b1,
    float* __restrict__ h1g) {
  __shared__ float As[64 * APAD];
  __shared__ float Ws[FDIM * 112];
  int m0 = blockIdx.x * 64;
  int t = threadIdx.x;
  for (int idx = t; idx < 64 * FDIM; idx += 256) {
    int m = idx / FDIM, k = idx % FDIM;
    int gm = m0 + m;
    As[m * APAD + k] = (gm < N_NODES) ? agg[(size_t)gm * FDIM + k] : 0.f;
  }
  for (int idx = t; idx < FDIM * 112; idx += 256) {
    int k = idx / 112, n = idx % 112;
    Ws[idx] = (n < F2) ? w1[k * F2 + n] : 0.f;
  }
  __syncthreads();
  int tx = t & 15, ty = t >> 4;
  int ms = tx * 4, ns = ty * 7;
  float acc[4][7];
#pragma unroll
  for (int i = 0; i < 4; i++)
#pragma unroll
    for (int j = 0; j < 7; j++) acc[i][j] = 0.f;
  for (int k = 0; k < FDIM; k++) {
    float a0 = As[(ms + 0) * APAD + k];
    float a1 = As[(ms + 1) * APAD + k];
    float a2 = As[(ms + 2) * APAD + k];
    float a3 = As[(ms + 3) * APAD + k];
    float b[7];
#pragma unroll
    for (int j = 0; j < 7; j++) b[j] = Ws[k * 112 + ns + j];
#pragma unroll
    for (int j = 0; j < 7; j++) {
      acc[0][j] += a0 * b[j];
      acc[1][j] += a1 * b[j];
      acc[2][j] += a2 * b[j];
      acc[3][j] += a3 * b[j];
    }
  }
#pragma unroll
  for (int i = 0; i < 4; i++) {
    int gm = m0 + ms + i;
    if (gm >= N_NODES) break;
#pragma unroll
    for (int j = 0; j < 7; j++) {
      int n = ns + j;
      if (n < F2) h1g[(size_t)gm * F2 + n] = fmaxf(acc[i][j] + b1[n], 0.f);
    }
  }
}

// ---------------------------------------------------------------------------
// GIN (3): h2 = relu(h1g @ w2 + b2) + pooled accumulation (LDS psum)
// ---------------------------------------------------------------------------
#define A2PAD 111
__global__ __launch_bounds__(256) void k_gin2(
    const float* __restrict__ h1g, const float* __restrict__ w2, const float* __restrict__ b2,
    const int* __restrict__ batch, float* __restrict__ pooled) {
  __shared__ float As[64 * A2PAD];
  __shared__ float Ws[F2 * 112];
  __shared__ float psum[4 * 112];
  int m0 = blockIdx.x * 64;
  int t = threadIdx.x;
  for (int idx = t; idx < 4 * 112; idx += 256) psum[idx] = 0.f;
  for (int idx = t; idx < 64 * F2; idx += 256) {
    int m = idx / F2, k = idx % F2;
    int gm = m0 + m;
    As[m * A2PAD + k] = (gm < N_NODES) ? h1g[(size_t)gm * F2 + k] : 0.f;
  }
  for (int idx = t; idx < F2 * 112; idx += 256) {
    int k = idx / 112, n = idx % 112;
    Ws[idx] = (n < F2) ? w2[k * F2 + n] : 0.f;
  }
  __syncthreads();
  int tx = t & 15, ty = t >> 4;
  int ms = tx * 4, ns = ty * 7;
  float acc[4][7];
#pragma unroll
  for (int i = 0; i < 4; i++)
#pragma unroll
    for (int j = 0; j < 7; j++) acc[i][j] = 0.f;
  for (int k = 0; k < F2; k++) {
    float a0 = As[(ms + 0) * A2PAD + k];
    float a1 = As[(ms + 1) * A2PAD + k];
    float a2 = As[(ms + 2) * A2PAD + k];
    float a3 = As[(ms + 3) * A2PAD + k];
    float b[7];
#pragma unroll
    for (int j = 0; j < 7; j++) b[j] = Ws[k * 112 + ns + j];
#pragma unroll
    for (int j = 0; j < 7; j++) {
      acc[0][j] += a0 * b[j];
      acc[1][j] += a1 * b[j];
      acc[2][j] += a2 * b[j];
      acc[3][j] += a3 * b[j];
    }
  }
  float b2n[7];
#pragma unroll
  for (int j = 0; j < 7; j++) {
    int n = ns + j;
    b2n[j] = (n < F2) ? b2[n] : 0.f;
  }
  int bmin = batch[m0];
  float pj[7];
#pragma unroll
  for (int j = 0; j < 7; j++) pj[j] = 0.f;
  int curb = -1;
#pragma unroll
  for (int i = 0; i < 4; i++) {
    int gm = m0 + ms + i;
    if (gm >= N_NODES) break;
    int b = batch[gm];
    if (b != curb) {
      if (curb >= 0) {
        int slot = curb - bmin;
        if (slot >= 0 && slot < 4) {
#pragma unroll
          for (int j = 0; j < 7; j++)
            if (ns + j < F2) atomicAdd(&psum[slot * 112 + ns + j], pj[j]);
        } else {
          float* pg = pooled + (size_t)curb * POOLW + HF;
#pragma unroll
          for (int j = 0; j < 7; j++)
            if (ns + j < F2) atomicAdd(&pg[ns + j], pj[j]);
        }
      }
      curb = b;
#pragma unroll
      for (int j = 0; j < 7; j++)
        pj[j] = (ns + j < F2) ? fmaxf(acc[i][j] + b2n[j], 0.f) : 0.f;
    } else {
#pragma unroll
      for (int j = 0; j < 7; j++)
        if (ns + j < F2) pj[j] += fmaxf(acc[i][j] + b2n[j], 0.f);
    }
  }
  if (curb >= 0) {
    int slot = curb - bmin;
    if (slot >= 0 && slot < 4) {
#pragma unroll
      for (int j = 0; j < 7; j++)
        if (ns + j < F2) atomicAdd(&psum[slot * 112 + ns + j], pj[j]);
    } else {
      float* pg = pooled + (size_t)curb * POOLW + HF;
#pragma unroll
      for (int j = 0; j < 7; j++)
        if (ns + j < F2) atomicAdd(&pg[ns + j], pj[j]);
    }
  }
  __syncthreads();
  for (int idx = t; idx < 4 * 112; idx += 256) {
    int slot = idx / 112, n = idx % 112;
    float v = psum[idx];
    int b = bmin + slot;
    if (n < F2 && b < BATCH && v != 0.f)
      atomicAdd(&pooled[(size_t)b * POOLW + HF + n], v);
  }
}

// ---------------------------------------------------------------------------
// EdgeConv v12: v8 structure (1-deep prefetch, register max, no LDS atomics)
// + wave-uniform scalarization: rpL/batL-derived state via readfirstlane so
// the tile walk / addressing compiles to SALU + saddr loads.
// ---------------------------------------------------------------------------
#define ECH 25
__global__ __launch_bounds__(256) void k_ec(
    const short* __restrict__ Ub, const short* __restrict__ Vb,
    const float* __restrict__ w2, const float* __restrict__ b2,
    const int* __restrict__ rp, const int* __restrict__ colidx,
    const int* __restrict__ batch, float* __restrict__ pooled) {
  const int t = threadIdx.x;
  const int lane = t & 63, wid = t >> 6;
  const int n16 = lane & 15, quad = lane >> 4;
  const int nt = (wid == 3) ? 1 : 2;   // u-tile 7 is all-pad

  const int i0 = blockIdx.x * ECH;
  const int iend = min(i0 + ECH, N_NODES);
  const int nn = iend - i0;

  __shared__ int rpL[ECH + 1];
  __shared__ int batL[ECH];

  short8 Bh[2][4];
  for (int tt = 0; tt < 2; tt++) {
    int ucol = (wid * 2 + tt) * 16 + n16;
    for (int kc = 0; kc < 4; kc++) {
      short8 vh;
#pragma unroll
      for (int jv = 0; jv < 8; jv++) {
        int kk = kc * 32 + quad * 8 + jv;
        float w = (ucol < F2 && kk < F2) ? w2[kk * F2 + ucol] : 0.f;
        vh[jv] = f2bf(w);
      }
      Bh[tt][kc] = vh;
    }
  }
  float b2v[2];
#pragma unroll
  for (int tt = 0; tt < 2; tt++) {
    int u = (wid * 2 + tt) * 16 + n16;
    b2v[tt] = (u < F2) ? b2[u] : 0.f;
  }

  if (t <= nn) rpL[t] = rp[i0 + t];
  if (t < nn) batL[t] = batch[i0 + t];
  __syncthreads();

  __shared__ short hs[2][16 * 16 * 8];
  union SU { short8 s; unsigned u[4]; };
  const int es = t & 15, kg = t >> 4;
  const int k0 = kg * 8;

  float sm0 = 0.f, sm1 = 0.f;
  int curb = -1;
  const int u0 = (wid * 2) * 16 + n16;
  const int u1 = (wid * 2 + 1) * 16 + n16;

  // tile walk (all state SGPR via readfirstlane): (node, tile, base, deg)
  auto advance = [&](int& ii, int& ttb, int& bb, int& dd) -> bool {
    ttb++;
    if (ttb * 16 < dd) return true;
    ttb = 0;
    for (ii = ii + 1; ii < iend; ii++) {
      bb = rfl(rpL[ii - i0]); dd = rfl(rpL[ii - i0 + 1]) - bb;
      if (dd > 0) return true;
    }
    return false;
  };

  // current tile T
  int i = i0, tb = 0, base = 0, deg = 0;
  bool have = false;
  for (; i < iend; i++) {
    base = rfl(rpL[i - i0]); deg = rfl(rpL[i - i0 + 1]) - base;
    if (deg > 0) { have = true; break; }
  }
  short8 pu8{}, pv8{};
  // tile T+1 coords + its colidx value (sc) already fetched
  int i1 = i, tb1 = 0, base1 = base, deg1 = deg;
  bool have1 = false;
  int sc = 0;
  if (have) {
    pu8 = *(const short8*)(Ub + (size_t)i * ECS + k0);
    int s0 = colidx[base + ((es < deg) ? es : 0)];
    pv8 = *(const short8*)(Vb + (size_t)s0 * ECS + k0);
    have1 = advance(i1, tb1, base1, deg1);
    if (have1) {
      int eg = tb1 * 16 + es;
      sc = colidx[base1 + ((eg < deg1) ? eg : 0)];
    }
  }

  float Uc[8];
  float vmax0 = -1e30f, vmax1 = -1e30f;
  int parity = 0;
  while (have) {
    if (tb == 0) {
#pragma unroll
      for (int j = 0; j < 8; j++) Uc[j] = bf2f(pu8[j]);
    }
    SU w;
#pragma unroll
    for (int p = 0; p < 4; p++) {
      bool kv = (k0 + 2 * p) < F2;
      float h0 = kv ? fmaxf(Uc[2 * p]     + bf2f(pv8[2 * p]),     0.f) : 0.f;
      float h1 = kv ? fmaxf(Uc[2 * p + 1] + bf2f(pv8[2 * p + 1]), 0.f) : 0.f;
      w.u[p] = pk2(h0, h1);
    }
    *(short8*)&hs[parity][(kg * 16 + es) * 8] = w.s;

    // prefetch: V (and U) for tile T+1 using sc fetched last iter; colidx for T+2
    int i2 = i1, tb2 = tb1, base2 = base1, deg2 = deg1;
    bool have2 = false;
    int scN = 0;
    if (have1) {
      if (tb1 == 0) pu8 = *(const short8*)(Ub + (size_t)i1 * ECS + k0);
      pv8 = *(const short8*)(Vb + (size_t)sc * ECS + k0);
      have2 = advance(i2, tb2, base2, deg2);
      if (have2) {
        int eg2 = tb2 * 16 + es;
        scN = colidx[base2 + ((eg2 < deg2) ? eg2 : 0)];
      }
    }

    ldsbar();
    f32x4 a0 = {0.f, 0.f, 0.f, 0.f}, a1 = {0.f, 0.f, 0.f, 0.f};
#pragma unroll
    for (int kc = 0; kc < 4; kc++) {
      short8 af = *(const short8*)&hs[parity][((kc * 4 + quad) * 16 + n16) * 8];
      a0 = __builtin_amdgcn_mfma_f32_16x16x32_bf16(af, Bh[0][kc], a0, 0, 0, 0);
      if (nt > 1)
        a1 = __builtin_amdgcn_mfma_f32_16x16x32_bf16(af, Bh[1][kc], a1, 0, 0, 0);
    }
#pragma unroll
    for (int r = 0; r < 4; r++) {
      int er = tb * 16 + quad * 4 + r;
      if (er < deg) { vmax0 = fmaxf(vmax0, a0[r]); vmax1 = fmaxf(vmax1, a1[r]); }
    }
    if (!have1 || i1 != i) {
      // node i finishes with this tile: cross-quad reduce deferred to here
      vmax0 = fmaxf(vmax0, __shfl_xor(vmax0, 16));
      vmax0 = fmaxf(vmax0, __shfl_xor(vmax0, 32));
      vmax1 = fmaxf(vmax1, __shfl_xor(vmax1, 16));
      vmax1 = fmaxf(vmax1, __shfl_xor(vmax1, 32));
      float o0 = fmaxf(vmax0 + b2v[0], 0.f);
      float o1 = fmaxf(vmax1 + b2v[1], 0.f);
      int b = rfl(batL[i - i0]);
      if (b != curb) {
        if (curb >= 0 && quad == 0) {
          float* pg = pooled + (size_t)curb * POOLW + HF + F2;
          if (u0 < F2) atomicAdd(&pg[u0], sm0);
          if (nt > 1 && u1 < F2) atomicAdd(&pg[u1], sm1);
        }
        curb = b; sm0 = o0; sm1 = o1;
      } else {
        sm0 += o0; sm1 += o1;
      }
      vmax0 = -1e30f; vmax1 = -1e30f;
    }
    i = i1; tb = tb1; base = base1; deg = deg1; have = have1;
    i1 = i2; tb1 = tb2; base1 = base2; deg1 = deg2; have1 = have2;
    sc = scN;
    parity ^= 1;
  }
  if (curb >= 0 && quad == 0) {
    float* pg = pooled + (size_t)curb * POOLW + HF + F2;
    if (u0 < F2) atomicAdd(&pg[u0], sm0);
    if (nt > 1 && u1 < F2) atomicAdd(&pg[u1], sm1);
  }
}

// ---------------------------------------------------------------------------
// mean-pool divide (counts from sorted-batch boundaries)
// ---------------------------------------------------------------------------
__global__ void k_pooldiv(float* __restrict__ pooled, const int* __restrict__ start) {
  int t = blockIdx.x * blockDim.x + threadIdx.x;
  if (t >= BATCH * POOLW) return;
  int b = t / POOLW;
  float c = (float)(start[b + 1] - start[b]);
  pooled[t] /= fmaxf(c, 1.f);
}

// ---------------------------------------------------------------------------
// Per-graph heads: block g computes all three 2-layer MLPs -> cat[g][384]
// ---------------------------------------------------------------------------
__global__ __launch_bounds__(256) void k_heads(
    const float* __restrict__ pooled,
    const float* __restrict__ fg1_w, const float* __restrict__ fg1_b,
    const float* __restrict__ fg2_w, const float* __restrict__ fg2_b,
    const float* __restrict__ fg3_w, const float* __restrict__ fg3_b,
    const float* __restrict__ fg4_w, const float* __restrict__ fg4_b,
    const float* __restrict__ fg5_w, const float* __restrict__ fg5_b,
    const float* __restrict__ fg6_w, const float* __restrict__ fg6_b,
    float* __restrict__ cat) {
  int g = blockIdx.x, t = threadIdx.x;
  __shared__ float in[POOLW];
  __shared__ float mid[256];
  for (int idx = t; idx < POOLW; idx += 256) in[idx] = pooled[(size_t)g * POOLW + idx];
  __syncthreads();
  const float* w1s[3] = {fg1_w, fg3_w, fg5_w};
  const float* b1s[3] = {fg1_b, fg3_b, fg5_b};
  const float* w2s[3] = {fg2_w, fg4_w, fg6_w};
  const float* b2s[3] = {fg2_b, fg4_b, fg6_b};
  const int off[4] = {0, HF, HF + F2, POOLW};
  for (int br = 0; br < 3; br++) {
    int kin = off[br + 1] - off[br];
    const float* iv = &in[off[br]];
    float a = b1s[br][t];
    const float* W = w1s[br];
    for (int k = 0; k < kin; k++) a += iv[k] * W[k * 256 + t];
    mid[t] = fmaxf(a, 0.f);
    __syncthreads();
    if (t < 128) {
      float b = b2s[br][t];
      const float* W2 = w2s[br];
      for (int k = 0; k < 256; k++) b += mid[k] * W2[k * 128 + t];
      cat[(size_t)g * 384 + br * 128 + t] = fmaxf(b, 0.f);
    }
    __syncthreads();
  }
}

// ---------------------------------------------------------------------------
// Final MLP: cat[384] -> 128 -> 64 -> 1 sigmoid, block per graph
// ---------------------------------------------------------------------------
__global__ __launch_bounds__(256) void k_final(
    const float* __restrict__ cat,
    const float* __restrict__ fc1_w, const float* __restrict__ fc1_b,
    const float* __restrict__ fc2_w, const float* __restrict__ fc2_b,
    const float* __restrict__ out_w, const float* __restrict__ out_b,
    float* __restrict__ out) {
  int g = blockIdx.x, t = threadIdx.x;
  __shared__ float hin[384];
  __shared__ float h1[128];
  __shared__ float h2[64];
  for (int idx = t; idx < 384; idx += 256) hin[idx] = cat[(size_t)g * 384 + idx];
  __syncthreads();
  if (t < 128) {
    float a = fc1_b[t];
    for (int k = 0; k < 384; k++) a += hin[k] * fc1_w[k * 128 + t];
    h1[t] = fmaxf(a, 0.f);
  }
  __syncthreads();
  if (t < 64) {
    float a = fc2_b[t];
    for (int k = 0; k < 128; k++) a += h1[k] * fc2_w[k * 64 + t];
    h2[t] = fmaxf(a, 0.f);
  }
  __syncthreads();
  if (t == 0) {
    float a = out_b[0];
    for (int k = 0; k < 64; k++) a += h2[k] * out_w[k];
    out[g] = 1.f / (1.f + __expf(-a));
  }
}

// ---------------------------------------------------------------------------
extern "C" void kernel_launch(void* const* d_in, const int* in_sizes, int n_in,
                              void* d_out, int out_size, void* d_ws, size_t ws_size,
                              hipStream_t stream) {
  const float* x      = (const float*)d_in[0];
  const int*   ei     = (const int*)d_in[1];
  const int*   batch  = (const int*)d_in[2];
  const float* gat_w  = (const float*)d_in[3];
  const float* asrc   = (const float*)d_in[4];
  const float* adst   = (const float*)d_in[5];
  const float* gat_b  = (const float*)d_in[6];
  const float* gin_w1 = (const float*)d_in[7];
  const float* gin_b1 = (const float*)d_in[8];
  const float* gin_w2 = (const float*)d_in[9];
  const float* gin_b2 = (const float*)d_in[10];
  const float* ec_w1  = (const float*)d_in[11];
  const float* ec_b1  = (const float*)d_in[12];
  const float* ec_w2  = (const float*)d_in[13];
  const float* ec_b2  = (const float*)d_in[14];
  const float* fg1_w = (const float*)d_in[15]; const float* fg1_b = (const float*)d_in[16];
  const float* fg2_w = (const float*)d_in[17]; const float* fg2_b = (const float*)d_in[18];
  const float* fg3_w = (const float*)d_in[19]; const float* fg3_b = (const float*)d_in[20];
  const float* fg4_w = (const float*)d_in[21]; const float* fg4_b = (const float*)d_in[22];
  const float* fg5_w = (const float*)d_in[23]; const float* fg5_b = (const float*)d_in[24];
  const float* fg6_w = (const float*)d_in[25]; const float* fg6_b = (const float*)d_in[26];
  const float* fc1_w = (const float*)d_in[27]; const float* fc1_b = (const float*)d_in[28];
  const float* fc2_w = (const float*)d_in[29]; const float* fc2_b = (const float*)d_in[30];
  const float* out_w = (const float*)d_in[31]; const float* out_b = (const float*)d_in[32];
  float* out = (float*)d_out;

  char* ws = (char*)d_ws;
  size_t off = 0;
  auto alloc = [&](size_t bytes) -> void* {
    void* p = ws + off;
    off = (off + bytes + 255) & ~(size_t)255;
    return p;
  };
  // --- zero region (one memset): histP | pooled ---
  size_t zoff0 = off;
  int*   histP  = (int*)alloc((size_t)N_NODES * PSTR * sizeof(int));  // 6.4 MB padded bins
  float* pooled = (float*)alloc((size_t)BATCH * POOLW * sizeof(float));
  size_t zbytes = off - zoff0;
  // --- rest ---
  int*   rp     = (int*)alloc((N_NODES + 1) * sizeof(int));
  int*   start  = (int*)alloc((BATCH + 1) * sizeof(int));
  int*   bsum   = (int*)alloc(256 * sizeof(int));
  int*   colidx = (int*)alloc(N_EDGES * sizeof(int));
  short* xb     = (short*)alloc((size_t)N_NODES * 64 * sizeof(short));   // bf16 x rows, 128 B
  float* alS    = (float*)alloc((size_t)N_NODES * 4 * sizeof(float));
  float* alD    = (float*)alloc((size_t)N_NODES * 4 * sizeof(float));
  short* Ubuf   = (short*)alloc((size_t)N_NODES * ECS * sizeof(short));  // bf16, 256B rows
  short* Vbuf   = (short*)alloc((size_t)N_NODES * ECS * sizeof(short));  // bf16, 256B rows
  short* agg4   = (short*)alloc((size_t)N_NODES * HF * sizeof(short));   // GAT agg (bf16)
  float* agg    = (float*)alloc((size_t)N_NODES * FDIM * sizeof(float)); // GIN aggregate
  float* cAl    = (float*)alloc(FDIM * 8 * sizeof(float));
  float* Wp     = (float*)alloc((size_t)FDIM * NPK2 * sizeof(float));
  float* bpk    = (float*)alloc(NPK2 * sizeof(float));
  float* cat    = (float*)alloc((size_t)BATCH * 384 * sizeof(float));
  (void)ws_size; (void)in_sizes; (void)n_in; (void)out_size;
  // h1g (50000*106 f32 = 21.2 MB) aliases Ubuf+Vbuf (25.6 MB contiguous,
  // dead after k_ec; stream order serializes).
  float* h1g = (float*)Ubuf;

  hipMemsetAsync(ws + zoff0, 0, zbytes, stream);

  k_cal<<<1, 448, 0, stream>>>(gat_w, asrc, adst, cAl);
  k_prep<<<(FDIM * NPK2 + 255) / 256, 256, 0, stream>>>(ec_w1, ec_b1, cAl, Wp, bpk);
  k_gemm<<<((N_NODES + GM - 1) / GM) * 2, 256, 0, stream>>>(x, Wp, bpk,
                                                            xb, Ubuf, Vbuf, alS, alD);
  k_hist<<<(N_EDGES + 255) / 256, 256, 0, stream>>>(ei, histP);
  k_bnd<<<(N_NODES + 255) / 256, 256, 0, stream>>>(batch, start);
  k_scan1<<<SCAN_BLOCKS, 256, 0, stream>>>(histP, rp, bsum);
  k_scan2<<<1, 256, 0, stream>>>(bsum);
  k_scan3<<<SCAN_BLOCKS, 256, 0, stream>>>(bsum, rp, histP);
  k_scatter<<<(N_EDGES + 255) / 256, 256, 0, stream>>>(ei, histP, colidx);

  // fused GAT-aggregate + GIN-sum over one L2-resident bf16 x table
  k_gatgin<<<(N_NODES + GCH - 1) / GCH, 256, 0, stream>>>(xb, alS, alD, rp, colidx,
                                                          agg4, agg);
  k_ec<<<(N_NODES + ECH - 1) / ECH, 256, 0, stream>>>(Ubuf, Vbuf, ec_w2, ec_b2, rp, colidx, batch, pooled);
  // GAT per-head transform + relu + pool
  k_gtrans<<<(N_NODES + 63) / 64, 256, 0, stream>>>(agg4, gat_w, gat_b, batch, pooled);
  // GIN MLP (h1g aliases U/V, dead after k_ec)
  k_gin1<<<(N_NODES + 63) / 64, 256, 0, stream>>>(agg, gin_w1, gin_b1, h1g);
  k_gin2<<<(N_NODES + 63) / 64, 256, 0, stream>>>(h1g, gin_w2, gin_b2, batch, pooled);

  k_pooldiv<<<(BATCH * POOLW + 255) / 256, 256, 0, stream>>>(pooled, start);

  k_heads<<<BATCH, 256, 0, stream>>>(pooled, fg1_w, fg1_b, fg2_w, fg2_b, fg3_w, fg3_b,
                                     fg4_w, fg4_b, fg5_w, fg5_b, fg6_w, fg6_b, cat);
  k_final<<<BATCH, 256, 0, stream>>>(cat, fc1_w, fc1_b, fc2_w, fc2_b, out_w, out_b, out);
}

// Round 10
// 723.201 us; speedup vs baseline: 1.0425x; 1.0425x over previous
//
#include <hip/hip_runtime.h>
#include <hip/hip_bf16.h>
#include <math.h>

#define N_NODES 50000
#define N_EDGES 800000
#define FDIM 53
#define BATCH 128
#define HF 212   /* H*F */
#define F2 106   /* 2F  */
#define POOLW 424 /* 212+106+106 */
#define NPK2 220 /* 106 + 106 + 8: U | V | alS | alD */
#define PSTR 32  /* padded bin stride (ints) = 128 B: one L2 line per node */
#define ECS 128  /* U/V bf16 row stride (shorts) = 256 B = 4 L2 lines */

typedef __attribute__((ext_vector_type(8))) short short8;
typedef __attribute__((ext_vector_type(4))) float f32x4;

__device__ __forceinline__ float leaky02(float x){ return x >= 0.f ? x : 0.2f * x; }

__device__ __forceinline__ short f2bf(float x) {
  unsigned u = __float_as_uint(x);
  unsigned r = (u + 0x7fffu + ((u >> 16) & 1u)) >> 16;
  return (short)r;
}
__device__ __forceinline__ float bf2f(short b) {
  return __uint_as_float(((unsigned)(unsigned short)b) << 16);
}
// packed pair f32x2 -> bf16x2 (v_cvt_pk_bf16_f32, RNE)
__device__ __forceinline__ unsigned pk2(float a, float b) {
  union { __hip_bfloat162 h; unsigned u; } c;
  c.h = __float22bfloat162_rn(make_float2(a, b));
  return c.u;
}
// LDS-only barrier: waits lgkmcnt(0) (ds ops) but leaves global loads in flight
__device__ __forceinline__ void ldsbar() {
  __builtin_amdgcn_s_waitcnt(0xC07F);   // vmcnt(63) expcnt(7) lgkmcnt(0)
  __builtin_amdgcn_s_barrier();
}

// ---------------------------------------------------------------------------
// Pack Wp[53][220] = [W1top-W1bot | W1bot | cAl] and bias bp[220].
// cAl columns (j >= 2*F2) compute their own 53-MAC dot (k_cal folded in).
// ---------------------------------------------------------------------------
__global__ void k_prep(const float* __restrict__ ec_w1, const float* __restrict__ ec_b1,
                       const float* __restrict__ gat_w, const float* __restrict__ asrc,
                       const float* __restrict__ adst,
                       float* __restrict__ Wp, float* __restrict__ bp) {
  int idx = blockIdx.x * blockDim.x + threadIdx.x;
  if (idx < FDIM * NPK2) {
    int k = idx / NPK2, j = idx % NPK2;
    float v;
    if (j < F2)            v = ec_w1[k * F2 + j] - ec_w1[(FDIM + k) * F2 + j];
    else if (j < 2 * F2)   v = ec_w1[(FDIM + k) * F2 + (j - F2)];
    else {
      int r = j - 2 * F2;              // 0..7 = sd*4 + h
      int sd = r >> 2, h = r & 3;
      const float* av = sd ? adst : asrc;
      float acc = 0.f;
      for (int f = 0; f < FDIM; ++f)
        acc += gat_w[k * HF + h * FDIM + f] * av[h * FDIM + f];
      v = acc;
    }
    Wp[idx] = v;
  }
  if (idx < NPK2) {
    bp[idx] = (idx < F2) ? ec_b1[idx] : 0.f;
  }
}

// ---------------------------------------------------------------------------
// Node-linear GEMM: x[50000x53] @ Wp[53x220] + bp -> U | V | alS | alD.
// Also emits xb (bf16 x rows, 64-short stride) during A-tile staging.
// ---------------------------------------------------------------------------
#define GM 64
#define GN 110
#define GNP 112
#define APAD 57
__global__ __launch_bounds__(256) void k_gemm(
    const float* __restrict__ x, const float* __restrict__ Wp, const float* __restrict__ bp,
    short* __restrict__ xb, short* __restrict__ Ub, short* __restrict__ Vb,
    float* __restrict__ alS, float* __restrict__ alD) {
  __shared__ float As[GM * APAD];
  __shared__ float Ws[FDIM * GNP];
  int mb = blockIdx.x >> 1, nc = blockIdx.x & 1;
  int m0 = mb * GM, n0 = nc * GN;
  int t = threadIdx.x;
  for (int idx = t; idx < GM * FDIM; idx += 256) {
    int m = idx / FDIM, k = idx % FDIM;
    int gm = m0 + m;
    float v = (gm < N_NODES) ? x[(size_t)gm * FDIM + k] : 0.f;
    As[m * APAD + k] = v;
    if (nc == 0 && gm < N_NODES) xb[(size_t)gm * 64 + k] = f2bf(v);
  }
  for (int idx = t; idx < FDIM * GNP; idx += 256) {
    int k = idx / GNP, n = idx % GNP;
    Ws[idx] = (n < GN) ? Wp[k * NPK2 + n0 + n] : 0.f;
  }
  __syncthreads();
  int tx = t & 15, ty = t >> 4;
  int ms = tx * 4, ns = ty * 7;
  float acc[4][7];
#pragma unroll
  for (int i = 0; i < 4; i++)
#pragma unroll
    for (int j = 0; j < 7; j++) acc[i][j] = 0.f;
  for (int k = 0; k < FDIM; k++) {
    float a0 = As[(ms + 0) * APAD + k];
    float a1 = As[(ms + 1) * APAD + k];
    float a2 = As[(ms + 2) * APAD + k];
    float a3 = As[(ms + 3) * APAD + k];
    float b[7];
#pragma unroll
    for (int j = 0; j < 7; j++) b[j] = Ws[k * GNP + ns + j];
#pragma unroll
    for (int j = 0; j < 7; j++) {
      acc[0][j] += a0 * b[j];
      acc[1][j] += a1 * b[j];
      acc[2][j] += a2 * b[j];
      acc[3][j] += a3 * b[j];
    }
  }
  float bj[7];
#pragma unroll
  for (int j = 0; j < 7; j++) {
    int g = n0 + ns + j;
    bj[j] = (g < NPK2) ? bp[g] : 0.f;
  }
#pragma unroll
  for (int i = 0; i < 4; i++) {
    int gm = m0 + ms + i;
    if (gm >= N_NODES) break;
#pragma unroll
    for (int j = 0; j < 7; j++) {
      int g = n0 + ns + j;
      float v = acc[i][j] + bj[j];
      if (g < F2)             Ub[(size_t)gm * ECS + g] = f2bf(v);
      else if (g < 2 * F2)    Vb[(size_t)gm * ECS + (g - F2)] = f2bf(v);
      else if (g < 2 * F2 + 4) alS[gm * 4 + (g - 2 * F2)] = v;
      else if (g < NPK2)      alD[gm * 4 + (g - 2 * F2 - 4)] = v;
    }
  }
}

// ---------------------------------------------------------------------------
// CSR build with L2-line-padded bins: hist -> scan (compacts to rp, turns
// padded slot into scatter cursor) -> scatter. Graph counts via sorted-batch
// boundary detection (fused into scan1).
// ---------------------------------------------------------------------------
#define SCAN_BLOCKS ((N_NODES + 255) / 256)

__global__ void k_hist(const int* __restrict__ ei, int* __restrict__ histP) {
  int t = blockIdx.x * blockDim.x + threadIdx.x;
  if (t < N_EDGES) atomicAdd(&histP[ei[N_EDGES + t] << 5], 1);
}

__global__ __launch_bounds__(256) void k_scan1(const int* __restrict__ histP,
                                               const int* __restrict__ batch,
                                               int* __restrict__ rp, int* __restrict__ bsum,
                                               int* __restrict__ start) {
  __shared__ int buf[256];
  int tid = threadIdx.x;
  int idx = blockIdx.x * 256 + tid;
  int v = (idx < N_NODES) ? histP[idx << 5] : 0;
  buf[tid] = v;
  __syncthreads();
  for (int off = 1; off < 256; off <<= 1) {
    int t2 = (tid >= off) ? buf[tid - off] : 0;
    __syncthreads();
    buf[tid] += t2;
    __syncthreads();
  }
  if (idx < N_NODES) rp[idx] = buf[tid] - v;
  if (tid == 255) bsum[blockIdx.x] = buf[255];
  // fused batch-boundary detection (was k_bnd)
  if (idx < N_NODES) {
    int b = batch[idx];
    if (idx == 0)
      for (int g = 0; g <= b; g++) start[g] = 0;
    int bn = (idx + 1 < N_NODES) ? batch[idx + 1] : BATCH;
    for (int g = b + 1; g <= bn; g++) start[g] = idx + 1;
  }
}

__global__ __launch_bounds__(256) void k_scan2(int* __restrict__ bsum) {
  __shared__ int buf[256];
  int tid = threadIdx.x;
  int v = (tid < SCAN_BLOCKS) ? bsum[tid] : 0;
  buf[tid] = v;
  __syncthreads();
  for (int off = 1; off < 256; off <<= 1) {
    int t2 = (tid >= off) ? buf[tid - off] : 0;
    __syncthreads();
    buf[tid] += t2;
    __syncthreads();
  }
  if (tid < SCAN_BLOCKS) bsum[tid] = buf[tid] - v;
}

__global__ __launch_bounds__(256) void k_scan3(const int* __restrict__ bsum,
                                               int* __restrict__ rp, int* __restrict__ histP) {
  int idx = blockIdx.x * 256 + threadIdx.x;
  if (idx < N_NODES) {
    int o = rp[idx] + bsum[blockIdx.x];
    rp[idx] = o;
    histP[idx << 5] = o;   // becomes the (padded) scatter cursor
  }
  if (idx == 0) rp[N_NODES] = N_EDGES;
}

__global__ void k_scatter(const int* __restrict__ ei, int* __restrict__ histP,
                          int* __restrict__ colidx) {
  int e = blockIdx.x * blockDim.x + threadIdx.x;
  if (e >= N_EDGES) return;
  int d = ei[N_EDGES + e];
  int pos = atomicAdd(&histP[d << 5], 1);
  colidx[pos] = ei[e];
}

// ---------------------------------------------------------------------------
// Fused GAT-aggregate + GIN-sum: one edge walk gathering bf16 x rows (128 B
// line each, 6.4 MB table -> L2-resident). GAT uses aggregate-then-transform.
// ---------------------------------------------------------------------------
#define GCH 20
__global__ __launch_bounds__(256) void k_gatgin(
    const short* __restrict__ xb, const float* __restrict__ alS, const float* __restrict__ alD,
    const int* __restrict__ rp, const int* __restrict__ colidx,
    short* __restrict__ agg4, float* __restrict__ agg) {
  int wid = threadIdx.x >> 6, lane = threadIdx.x & 63;
  bool fa = lane < FDIM;
  int i0 = blockIdx.x * GCH;
  int iend = min(i0 + GCH, N_NODES);
  __shared__ int rpG[GCH + 1];
  {
    int t = threadIdx.x, nn = iend - i0;
    if (t <= nn) rpG[t] = rp[i0 + t];
  }
  __syncthreads();
  for (int i = i0 + wid; i < iend; i += 4) {
    int base = rpG[i - i0], deg = rpG[i - i0 + 1] - base;
    float aldi[4], exs[4];
#pragma unroll
    for (int h = 0; h < 4; h++) {
      aldi[h] = alD[i * 4 + h];
      exs[h] = __expf(leaky02(alS[i * 4 + h] + aldi[h]));   // self-loop term
    }
    float xiv = fa ? bf2f(xb[(size_t)i * 64 + lane]) : 0.f;
    float ag0 = exs[0] * xiv, ag1 = exs[1] * xiv, ag2 = exs[2] * xiv, ag3 = exs[3] * xiv;
    float ax = xiv;
    float zl[4] = {0.f, 0.f, 0.f, 0.f};

    for (int c0 = 0; c0 < deg; c0 += 64) {
      int cn = min(64, deg - c0);
      int s = 0;
      float ex0 = 0.f, ex1 = 0.f, ex2 = 0.f, ex3 = 0.f;
      if (lane < cn) {
        s = colidx[base + c0 + lane];
        ex0 = __expf(leaky02(alS[s * 4 + 0] + aldi[0]));
        ex1 = __expf(leaky02(alS[s * 4 + 1] + aldi[1]));
        ex2 = __expf(leaky02(alS[s * 4 + 2] + aldi[2]));
        ex3 = __expf(leaky02(alS[s * 4 + 3] + aldi[3]));
        zl[0] += ex0; zl[1] += ex1; zl[2] += ex2; zl[3] += ex3;
      }
      for (int jj = 0; jj < cn; jj += 4) {
        int sj[4]; float a0[4], a1[4], a2[4], a3[4]; bool vq[4];
#pragma unroll
        for (int q = 0; q < 4; q++) {
          int j2 = jj + q;
          int jc = (j2 < cn) ? j2 : (cn - 1);
          vq[q] = j2 < cn;
          sj[q] = __shfl(s, jc);
          a0[q] = vq[q] ? __shfl(ex0, jc) : 0.f;
          a1[q] = vq[q] ? __shfl(ex1, jc) : 0.f;
          a2[q] = vq[q] ? __shfl(ex2, jc) : 0.f;
          a3[q] = vq[q] ? __shfl(ex3, jc) : 0.f;
        }
        float xg[4];
#pragma unroll
        for (int q = 0; q < 4; q++)
          xg[q] = fa ? bf2f(xb[(size_t)sj[q] * 64 + lane]) : 0.f;
#pragma unroll
        for (int q = 0; q < 4; q++) {
          ag0 += a0[q] * xg[q];
          ag1 += a1[q] * xg[q];
          ag2 += a2[q] * xg[q];
          ag3 += a3[q] * xg[q];
          ax += vq[q] ? xg[q] : 0.f;
        }
      }
    }
#pragma unroll
    for (int off = 32; off >= 1; off >>= 1)
#pragma unroll
      for (int h = 0; h < 4; h++) zl[h] += __shfl_xor(zl[h], off);
    if (fa) {
      float z0 = zl[0] + exs[0] + 1e-16f;
      float z1 = zl[1] + exs[1] + 1e-16f;
      float z2 = zl[2] + exs[2] + 1e-16f;
      float z3 = zl[3] + exs[3] + 1e-16f;
      short* ar = agg4 + (size_t)i * HF;
      ar[0 * FDIM + lane] = f2bf(ag0 / z0);
      ar[1 * FDIM + lane] = f2bf(ag1 / z1);
      ar[2 * FDIM + lane] = f2bf(ag2 / z2);
      ar[3 * FDIM + lane] = f2bf(ag3 / z3);
      agg[(size_t)i * FDIM + lane] = ax;
    }
  }
}

// ---------------------------------------------------------------------------
// GAT transform: grouped (per-head 53x53) GEMM + relu + pooled accumulation
// ---------------------------------------------------------------------------
#define TCOLS 224   /* 4 heads x 56 padded cols */
#define A4S 217     /* As row stride in shorts (odd -> conflict-free) */
__global__ __launch_bounds__(256) void k_gtrans(
    const short* __restrict__ agg4, const float* __restrict__ gat_w,
    const float* __restrict__ bias, const int* __restrict__ batch,
    float* __restrict__ pooled) {
  __shared__ short As[64 * A4S];
  __shared__ float Bs[FDIM * TCOLS];
  __shared__ float psum[4 * TCOLS];
  int m0 = blockIdx.x * 64;
  int t = threadIdx.x;
  for (int idx = t; idx < 4 * TCOLS; idx += 256) psum[idx] = 0.f;
  for (int idx = t; idx < 64 * HF; idx += 256) {
    int m = idx / HF, c = idx % HF;
    int gm = m0 + m;
    As[m * A4S + c] = (gm < N_NODES) ? agg4[(size_t)gm * HF + c] : (short)0;
  }
  for (int idx = t; idx < FDIM * TCOLS; idx += 256) {
    int k = idx / TCOLS, c = idx % TCOLS;
    int h = c / 56, jn = c % 56;
    Bs[idx] = (jn < FDIM) ? gat_w[k * HF + h * FDIM + jn] : 0.f;
  }
  __syncthreads();
  int tx = t & 15, ty = t >> 4;
  int ms = tx * 4, ns = ty * 14;
  int hh = ty >> 2;
  int jnb = (ty & 3) * 14;
  float acc[4][14];
#pragma unroll
  for (int i = 0; i < 4; i++)
#pragma unroll
    for (int j = 0; j < 14; j++) acc[i][j] = 0.f;
  for (int k = 0; k < FDIM; k++) {
    float a0 = bf2f(As[(ms + 0) * A4S + hh * FDIM + k]);
    float a1 = bf2f(As[(ms + 1) * A4S + hh * FDIM + k]);
    float a2 = bf2f(As[(ms + 2) * A4S + hh * FDIM + k]);
    float a3 = bf2f(As[(ms + 3) * A4S + hh * FDIM + k]);
    float b[14];
#pragma unroll
    for (int j = 0; j < 14; j++) b[j] = Bs[k * TCOLS + ns + j];
#pragma unroll
    for (int j = 0; j < 14; j++) {
      acc[0][j] += a0 * b[j];
      acc[1][j] += a1 * b[j];
      acc[2][j] += a2 * b[j];
      acc[3][j] += a3 * b[j];
    }
  }
  float bj[14]; bool jv[14];
#pragma unroll
  for (int j = 0; j < 14; j++) {
    jv[j] = (jnb + j) < FDIM;
    bj[j] = jv[j] ? bias[hh * FDIM + jnb + j] : 0.f;
  }
  int bmin = batch[m0];
  float pj[14];
#pragma unroll
  for (int j = 0; j < 14; j++) pj[j] = 0.f;
  int curb = -1;
#pragma unroll
  for (int i = 0; i < 4; i++) {
    int gm = m0 + ms + i;
    if (gm >= N_NODES) break;
    int b = batch[gm];
    if (b != curb) {
      if (curb >= 0) {
        int slot = curb - bmin;
        if (slot >= 0 && slot < 4) {
#pragma unroll
          for (int j = 0; j < 14; j++)
            if (jv[j]) atomicAdd(&psum[slot * TCOLS + ns + j], pj[j]);
        } else {
          float* pg = pooled + (size_t)curb * POOLW;
#pragma unroll
          for (int j = 0; j < 14; j++)
            if (jv[j]) atomicAdd(&pg[hh * FDIM + jnb + j], pj[j]);
        }
      }
      curb = b;
#pragma unroll
      for (int j = 0; j < 14; j++)
        pj[j] = jv[j] ? fmaxf(acc[i][j] + bj[j], 0.f) : 0.f;
    } else {
#pragma unroll
      for (int j = 0; j < 14; j++)
        if (jv[j]) pj[j] += fmaxf(acc[i][j] + bj[j], 0.f);
    }
  }
  if (curb >= 0) {
    int slot = curb - bmin;
    if (slot >= 0 && slot < 4) {
#pragma unroll
      for (int j = 0; j < 14; j++)
        if (jv[j]) atomicAdd(&psum[slot * TCOLS + ns + j], pj[j]);
    } else {
      float* pg = pooled + (size_t)curb * POOLW;
#pragma unroll
      for (int j = 0; j < 14; j++)
        if (jv[j]) atomicAdd(&pg[hh * FDIM + jnb + j], pj[j]);
    }
  }
  __syncthreads();
  for (int idx = t; idx < 4 * TCOLS; idx += 256) {
    int slot = idx / TCOLS, c = idx % TCOLS;
    int h = c / 56, jn = c % 56;
    float v = psum[idx];
    int b = bmin + slot;
    if (jn < FDIM && b < BATCH && v != 0.f)
      atomicAdd(&pooled[(size_t)b * POOLW + h * FDIM + jn], v);
  }
}

// ---------------------------------------------------------------------------
// Fused GIN MLP: h1 = relu(agg @ w1 + b1) kept in LDS; h2 = relu(h1 @ w2 + b2)
// + pooled accumulation. Eliminates the 21 MB h1g intermediate entirely.
// LDS: B1 (As|Ws1 then Ws2, 46.4KB) + Hs (27.8KB) + psum = 77.7KB.
// ---------------------------------------------------------------------------
#define A2PAD 111
__global__ __launch_bounds__(256) void k_gin(
    const float* __restrict__ agg,
    const float* __restrict__ w1, const float* __restrict__ b1,
    const float* __restrict__ w2, const float* __restrict__ b2,
    const int* __restrict__ batch, float* __restrict__ pooled) {
  __shared__ float B1[F2 * 112];       // phase A: As | Ws1; phase B: Ws2
  __shared__ float Hs[64 * A2PAD];
  __shared__ float psum[4 * 112];
  float* As = B1;                      // 64*APAD = 3648 floats
  float* Ws1 = B1 + 64 * APAD;         // 53*112 = 5936 floats (total 9584 < 11872)
  int m0 = blockIdx.x * 64;
  int t = threadIdx.x;
  for (int idx = t; idx < 4 * 112; idx += 256) psum[idx] = 0.f;
  for (int idx = t; idx < 64 * FDIM; idx += 256) {
    int m = idx / FDIM, k = idx % FDIM;
    int gm = m0 + m;
    As[m * APAD + k] = (gm < N_NODES) ? agg[(size_t)gm * FDIM + k] : 0.f;
  }
  for (int idx = t; idx < FDIM * 112; idx += 256) {
    int k = idx / 112, n = idx % 112;
    Ws1[idx] = (n < F2) ? w1[k * F2 + n] : 0.f;
  }
  __syncthreads();
  int tx = t & 15, ty = t >> 4;
  int ms = tx * 4, ns = ty * 7;
  // ---- phase A: h1 = relu(agg @ w1 + b1) -> Hs ----
  {
    float acc[4][7];
#pragma unroll
    for (int i = 0; i < 4; i++)
#pragma unroll
      for (int j = 0; j < 7; j++) acc[i][j] = 0.f;
    for (int k = 0; k < FDIM; k++) {
      float a0 = As[(ms + 0) * APAD + k];
      float a1 = As[(ms + 1) * APAD + k];
      float a2 = As[(ms + 2) * APAD + k];
      float a3 = As[(ms + 3) * APAD + k];
      float b[7];
#pragma unroll
      for (int j = 0; j < 7; j++) b[j] = Ws1[k * 112 + ns + j];
#pragma unroll
      for (int j = 0; j < 7; j++) {
        acc[0][j] += a0 * b[j];
        acc[1][j] += a1 * b[j];
        acc[2][j] += a2 * b[j];
        acc[3][j] += a3 * b[j];
      }
    }
#pragma unroll
    for (int i = 0; i < 4; i++) {
#pragma unroll
      for (int j = 0; j < 7; j++) {
        int n = ns + j;
        if (n < F2) Hs[(ms + i) * A2PAD + n] = fmaxf(acc[i][j] + b1[n], 0.f);
      }
    }
  }
  __syncthreads();   // all As/Ws1 reads done; Hs complete
  // ---- phase B: stage w2 over B1, then h2 = relu(Hs @ w2 + b2) + pool ----
  for (int idx = t; idx < F2 * 112; idx += 256) {
    int k = idx / 112, n = idx % 112;
    B1[idx] = (n < F2) ? w2[k * F2 + n] : 0.f;
  }
  __syncthreads();
  float acc[4][7];
#pragma unroll
  for (int i = 0; i < 4; i++)
#pragma unroll
    for (int j = 0; j < 7; j++) acc[i][j] = 0.f;
  for (int k = 0; k < F2; k++) {
    float a0 = Hs[(ms + 0) * A2PAD + k];
    float a1 = Hs[(ms + 1) * A2PAD + k];
    float a2 = Hs[(ms + 2) * A2PAD + k];
    float a3 = Hs[(ms + 3) * A2PAD + k];
    float b[7];
#pragma unroll
    for (int j = 0; j < 7; j++) b[j] = B1[k * 112 + ns + j];
#pragma unroll
    for (int j = 0; j < 7; j++) {
      acc[0][j] += a0 * b[j];
      acc[1][j] += a1 * b[j];
      acc[2][j] += a2 * b[j];
      acc[3][j] += a3 * b[j];
    }
  }
  float b2n[7];
#pragma unroll
  for (int j = 0; j < 7; j++) {
    int n = ns + j;
    b2n[j] = (n < F2) ? b2[n] : 0.f;
  }
  int bmin = batch[m0];
  float pj[7];
#pragma unroll
  for (int j = 0; j < 7; j++) pj[j] = 0.f;
  int curb = -1;
#pragma unroll
  for (int i = 0; i < 4; i++) {
    int gm = m0 + ms + i;
    if (gm >= N_NODES) break;
    int b = batch[gm];
    if (b != curb) {
      if (curb >= 0) {
        int slot = curb - bmin;
        if (slot >= 0 && slot < 4) {
#pragma unroll
          for (int j = 0; j < 7; j++)
            if (ns + j < F2) atomicAdd(&psum[slot * 112 + ns + j], pj[j]);
        } else {
          float* pg = pooled + (size_t)curb * POOLW + HF;
#pragma unroll
          for (int j = 0; j < 7; j++)
            if (ns + j < F2) atomicAdd(&pg[ns + j], pj[j]);
        }
      }
      curb = b;
#pragma unroll
      for (int j = 0; j < 7; j++)
        pj[j] = (ns + j < F2) ? fmaxf(acc[i][j] + b2n[j], 0.f) : 0.f;
    } else {
#pragma unroll
      for (int j = 0; j < 7; j++)
        if (ns + j < F2) pj[j] += fmaxf(acc[i][j] + b2n[j], 0.f);
    }
  }
  if (curb >= 0) {
    int slot = curb - bmin;
    if (slot >= 0 && slot < 4) {
#pragma unroll
      for (int j = 0; j < 7; j++)
        if (ns + j < F2) atomicAdd(&psum[slot * 112 + ns + j], pj[j]);
    } else {
      float* pg = pooled + (size_t)curb * POOLW + HF;
#pragma unroll
      for (int j = 0; j < 7; j++)
        if (ns + j < F2) atomicAdd(&pg[ns + j], pj[j]);
    }
  }
  __syncthreads();
  for (int idx = t; idx < 4 * 112; idx += 256) {
    int slot = idx / 112, n = idx % 112;
    float v = psum[idx];
    int b = bmin + slot;
    if (n < F2 && b < BATCH && v != 0.f)
      atomicAdd(&pooled[(size_t)b * POOLW + HF + n], v);
  }
}

// ---------------------------------------------------------------------------
// EdgeConv v8 (round-5 best): bf16 U/V, rp/batch in LDS, colidx prefetched
// 2 tiles ahead / V 1 tile ahead, deferred cross-quad max reduction,
// double-buffered LDS, lgkmcnt-only barrier.
// ---------------------------------------------------------------------------
#define ECH 25
__global__ __launch_bounds__(256) void k_ec(
    const short* __restrict__ Ub, const short* __restrict__ Vb,
    const float* __restrict__ w2, const float* __restrict__ b2,
    const int* __restrict__ rp, const int* __restrict__ colidx,
    const int* __restrict__ batch, float* __restrict__ pooled) {
  const int t = threadIdx.x;
  const int lane = t & 63, wid = t >> 6;
  const int n16 = lane & 15, quad = lane >> 4;
  const int nt = (wid == 3) ? 1 : 2;   // u-tile 7 is all-pad

  const int i0 = blockIdx.x * ECH;
  const int iend = min(i0 + ECH, N_NODES);
  const int nn = iend - i0;

  __shared__ int rpL[ECH + 1];
  __shared__ int batL[ECH];

  short8 Bh[2][4];
  for (int tt = 0; tt < 2; tt++) {
    int ucol = (wid * 2 + tt) * 16 + n16;
    for (int kc = 0; kc < 4; kc++) {
      short8 vh;
#pragma unroll
      for (int jv = 0; jv < 8; jv++) {
        int kk = kc * 32 + quad * 8 + jv;
        float w = (ucol < F2 && kk < F2) ? w2[kk * F2 + ucol] : 0.f;
        vh[jv] = f2bf(w);
      }
      Bh[tt][kc] = vh;
    }
  }
  float b2v[2];
#pragma unroll
  for (int tt = 0; tt < 2; tt++) {
    int u = (wid * 2 + tt) * 16 + n16;
    b2v[tt] = (u < F2) ? b2[u] : 0.f;
  }

  if (t <= nn) rpL[t] = rp[i0 + t];
  if (t < nn) batL[t] = batch[i0 + t];
  __syncthreads();

  __shared__ short hs[2][16 * 16 * 8];
  union SU { short8 s; unsigned u[4]; };
  const int es = t & 15, kg = t >> 4;
  const int k0 = kg * 8;

  float sm0 = 0.f, sm1 = 0.f;
  int curb = -1;
  const int u0 = (wid * 2) * 16 + n16;
  const int u1 = (wid * 2 + 1) * 16 + n16;

  // tile walk: (node, tile-in-node, base, deg) -> next
  auto advance = [&](int& ii, int& ttb, int& bb, int& dd) -> bool {
    ttb++;
    if (ttb * 16 < dd) return true;
    ttb = 0;
    for (ii = ii + 1; ii < iend; ii++) {
      bb = rpL[ii - i0]; dd = rpL[ii - i0 + 1] - bb;
      if (dd > 0) return true;
    }
    return false;
  };

  // current tile T
  int i = i0, tb = 0, base = 0, deg = 0;
  bool have = false;
  for (; i < iend; i++) {
    base = rpL[i - i0]; deg = rpL[i - i0 + 1] - base;
    if (deg > 0) { have = true; break; }
  }
  short8 pu8{}, pv8{};
  // tile T+1 coords + its colidx value (sc) already fetched
  int i1 = i, tb1 = 0, base1 = base, deg1 = deg;
  bool have1 = false;
  int sc = 0;
  if (have) {
    pu8 = *(const short8*)(Ub + (size_t)i * ECS + k0);
    int s0 = colidx[base + ((es < deg) ? es : 0)];
    pv8 = *(const short8*)(Vb + (size_t)s0 * ECS + k0);
    have1 = advance(i1, tb1, base1, deg1);
    if (have1) {
      int eg = tb1 * 16 + es;
      sc = colidx[base1 + ((eg < deg1) ? eg : 0)];
    }
  }

  float Uc[8];
  float vmax0 = -1e30f, vmax1 = -1e30f;
  int parity = 0;
  while (have) {
    if (tb == 0) {
#pragma unroll
      for (int j = 0; j < 8; j++) Uc[j] = bf2f(pu8[j]);
    }
    SU w;
#pragma unroll
    for (int p = 0; p < 4; p++) {
      bool kv = (k0 + 2 * p) < F2;
      float h0 = kv ? fmaxf(Uc[2 * p]     + bf2f(pv8[2 * p]),     0.f) : 0.f;
      float h1 = kv ? fmaxf(Uc[2 * p + 1] + bf2f(pv8[2 * p + 1]), 0.f) : 0.f;
      w.u[p] = pk2(h0, h1);
    }
    *(short8*)&hs[parity][(kg * 16 + es) * 8] = w.s;

    // prefetch: V (and U) for tile T+1 using sc fetched last iter; colidx for T+2
    int i2 = i1, tb2 = tb1, base2 = base1, deg2 = deg1;
    bool have2 = false;
    int scN = 0;
    if (have1) {
      if (tb1 == 0) pu8 = *(const short8*)(Ub + (size_t)i1 * ECS + k0);
      pv8 = *(const short8*)(Vb + (size_t)sc * ECS + k0);
      have2 = advance(i2, tb2, base2, deg2);
      if (have2) {
        int eg2 = tb2 * 16 + es;
        scN = colidx[base2 + ((eg2 < deg2) ? eg2 : 0)];
      }
    }

    ldsbar();
    f32x4 a0 = {0.f, 0.f, 0.f, 0.f}, a1 = {0.f, 0.f, 0.f, 0.f};
#pragma unroll
    for (int kc = 0; kc < 4; kc++) {
      short8 af = *(const short8*)&hs[parity][((kc * 4 + quad) * 16 + n16) * 8];
      a0 = __builtin_amdgcn_mfma_f32_16x16x32_bf16(af, Bh[0][kc], a0, 0, 0, 0);
      if (nt > 1)
        a1 = __builtin_amdgcn_mfma_f32_16x16x32_bf16(af, Bh[1][kc], a1, 0, 0, 0);
    }
#pragma unroll
    for (int r = 0; r < 4; r++) {
      int er = tb * 16 + quad * 4 + r;
      if (er < deg) { vmax0 = fmaxf(vmax0, a0[r]); vmax1 = fmaxf(vmax1, a1[r]); }
    }
    if (!have1 || i1 != i) {
      // node i finishes with this tile: cross-quad reduce deferred to here
      vmax0 = fmaxf(vmax0, __shfl_xor(vmax0, 16));
      vmax0 = fmaxf(vmax0, __shfl_xor(vmax0, 32));
      vmax1 = fmaxf(vmax1, __shfl_xor(vmax1, 16));
      vmax1 = fmaxf(vmax1, __shfl_xor(vmax1, 32));
      float o0 = fmaxf(vmax0 + b2v[0], 0.f);
      float o1 = fmaxf(vmax1 + b2v[1], 0.f);
      int b = batL[i - i0];
      if (b != curb) {
        if (curb >= 0 && quad == 0) {
          float* pg = pooled + (size_t)curb * POOLW + HF + F2;
          if (u0 < F2) atomicAdd(&pg[u0], sm0);
          if (nt > 1 && u1 < F2) atomicAdd(&pg[u1], sm1);
        }
        curb = b; sm0 = o0; sm1 = o1;
      } else {
        sm0 += o0; sm1 += o1;
      }
      vmax0 = -1e30f; vmax1 = -1e30f;
    }
    i = i1; tb = tb1; base = base1; deg = deg1; have = have1;
    i1 = i2; tb1 = tb2; base1 = base2; deg1 = deg2; have1 = have2;
    sc = scN;
    parity ^= 1;
  }
  if (curb >= 0 && quad == 0) {
    float* pg = pooled + (size_t)curb * POOLW + HF + F2;
    if (u0 < F2) atomicAdd(&pg[u0], sm0);
    if (nt > 1 && u1 < F2) atomicAdd(&pg[u1], sm1);
  }
}

// ---------------------------------------------------------------------------
// mean-pool divide (counts from sorted-batch boundaries)
// ---------------------------------------------------------------------------
__global__ void k_pooldiv(float* __restrict__ pooled, const int* __restrict__ start) {
  int t = blockIdx.x * blockDim.x + threadIdx.x;
  if (t >= BATCH * POOLW) return;
  int b = t / POOLW;
  float c = (float)(start[b + 1] - start[b]);
  pooled[t] /= fmaxf(c, 1.f);
}

// ---------------------------------------------------------------------------
// Per-graph heads + final MLP fused: block g computes the three 2-layer MLPs
// into cat[384] (LDS), then 384->128->64->1 sigmoid. No global cat buffer.
// ---------------------------------------------------------------------------
__global__ __launch_bounds__(256) void k_heads(
    const float* __restrict__ pooled,
    const float* __restrict__ fg1_w, const float* __restrict__ fg1_b,
    const float* __restrict__ fg2_w, const float* __restrict__ fg2_b,
    const float* __restrict__ fg3_w, const float* __restrict__ fg3_b,
    const float* __restrict__ fg4_w, const float* __restrict__ fg4_b,
    const float* __restrict__ fg5_w, const float* __restrict__ fg5_b,
    const float* __restrict__ fg6_w, const float* __restrict__ fg6_b,
    const float* __restrict__ fc1_w, const float* __restrict__ fc1_b,
    const float* __restrict__ fc2_w, const float* __restrict__ fc2_b,
    const float* __restrict__ out_w, const float* __restrict__ out_b,
    float* __restrict__ out) {
  int g = blockIdx.x, t = threadIdx.x;
  __shared__ float in[POOLW];
  __shared__ float mid[256];
  __shared__ float cat[384];
  __shared__ float h1[128];
  __shared__ float h2[64];
  for (int idx = t; idx < POOLW; idx += 256) in[idx] = pooled[(size_t)g * POOLW + idx];
  __syncthreads();
  const float* w1s[3] = {fg1_w, fg3_w, fg5_w};
  const float* b1s[3] = {fg1_b, fg3_b, fg5_b};
  const float* w2s[3] = {fg2_w, fg4_w, fg6_w};
  const float* b2s[3] = {fg2_b, fg4_b, fg6_b};
  const int off[4] = {0, HF, HF + F2, POOLW};
  for (int br = 0; br < 3; br++) {
    int kin = off[br + 1] - off[br];
    const float* iv = &in[off[br]];
    float a = b1s[br][t];
    const float* W = w1s[br];
    for (int k = 0; k < kin; k++) a += iv[k] * W[k * 256 + t];
    mid[t] = fmaxf(a, 0.f);
    __syncthreads();
    if (t < 128) {
      float b = b2s[br][t];
      const float* W2 = w2s[br];
      for (int k = 0; k < 256; k++) b += mid[k] * W2[k * 128 + t];
      cat[br * 128 + t] = fmaxf(b, 0.f);
    }
    __syncthreads();
  }
  if (t < 128) {
    float a = fc1_b[t];
    for (int k = 0; k < 384; k++) a += cat[k] * fc1_w[k * 128 + t];
    h1[t] = fmaxf(a, 0.f);
  }
  __syncthreads();
  if (t < 64) {
    float a = fc2_b[t];
    for (int k = 0; k < 128; k++) a += h1[k] * fc2_w[k * 64 + t];
    h2[t] = fmaxf(a, 0.f);
  }
  __syncthreads();
  if (t == 0) {
    float a = out_b[0];
    for (int k = 0; k < 64; k++) a += h2[k] * out_w[k];
    out[g] = 1.f / (1.f + __expf(-a));
  }
}

// ---------------------------------------------------------------------------
extern "C" void kernel_launch(void* const* d_in, const int* in_sizes, int n_in,
                              void* d_out, int out_size, void* d_ws, size_t ws_size,
                              hipStream_t stream) {
  const float* x      = (const float*)d_in[0];
  const int*   ei     = (const int*)d_in[1];
  const int*   batch  = (const int*)d_in[2];
  const float* gat_w  = (const float*)d_in[3];
  const float* asrc   = (const float*)d_in[4];
  const float* adst   = (const float*)d_in[5];
  const float* gat_b  = (const float*)d_in[6];
  const float* gin_w1 = (const float*)d_in[7];
  const float* gin_b1 = (const float*)d_in[8];
  const float* gin_w2 = (const float*)d_in[9];
  const float* gin_b2 = (const float*)d_in[10];
  const float* ec_w1  = (const float*)d_in[11];
  const float* ec_b1  = (const float*)d_in[12];
  const float* ec_w2  = (const float*)d_in[13];
  const float* ec_b2  = (const float*)d_in[14];
  const float* fg1_w = (const float*)d_in[15]; const float* fg1_b = (const float*)d_in[16];
  const float* fg2_w = (const float*)d_in[17]; const float* fg2_b = (const float*)d_in[18];
  const float* fg3_w = (const float*)d_in[19]; const float* fg3_b = (const float*)d_in[20];
  const float* fg4_w = (const float*)d_in[21]; const float* fg4_b = (const float*)d_in[22];
  const float* fg5_w = (const float*)d_in[23]; const float* fg5_b = (const float*)d_in[24];
  const float* fg6_w = (const float*)d_in[25]; const float* fg6_b = (const float*)d_in[26];
  const float* fc1_w = (const float*)d_in[27]; const float* fc1_b = (const float*)d_in[28];
  const float* fc2_w = (const float*)d_in[29]; const float* fc2_b = (const float*)d_in[30];
  const float* out_w = (const float*)d_in[31]; const float* out_b = (const float*)d_in[32];
  float* out = (float*)d_out;

  char* ws = (char*)d_ws;
  size_t off = 0;
  auto alloc = [&](size_t bytes) -> void* {
    void* p = ws + off;
    off = (off + bytes + 255) & ~(size_t)255;
    return p;
  };
  // --- zero region (one memset): histP | pooled ---
  size_t zoff0 = off;
  int*   histP  = (int*)alloc((size_t)N_NODES * PSTR * sizeof(int));  // 6.4 MB padded bins
  float* pooled = (float*)alloc((size_t)BATCH * POOLW * sizeof(float));
  size_t zbytes = off - zoff0;
  // --- rest ---
  int*   rp     = (int*)alloc((N_NODES + 1) * sizeof(int));
  int*   start  = (int*)alloc((BATCH + 1) * sizeof(int));
  int*   bsum   = (int*)alloc(256 * sizeof(int));
  int*   colidx = (int*)alloc(N_EDGES * sizeof(int));
  short* xb     = (short*)alloc((size_t)N_NODES * 64 * sizeof(short));   // bf16 x rows, 128 B
  float* alS    = (float*)alloc((size_t)N_NODES * 4 * sizeof(float));
  float* alD    = (float*)alloc((size_t)N_NODES * 4 * sizeof(float));
  short* Ubuf   = (short*)alloc((size_t)N_NODES * ECS * sizeof(short));  // bf16, 256B rows
  short* Vbuf   = (short*)alloc((size_t)N_NODES * ECS * sizeof(short));  // bf16, 256B rows
  short* agg4   = (short*)alloc((size_t)N_NODES * HF * sizeof(short));   // GAT agg (bf16)
  float* agg    = (float*)alloc((size_t)N_NODES * FDIM * sizeof(float)); // GIN aggregate
  float* Wp     = (float*)alloc((size_t)FDIM * NPK2 * sizeof(float));
  float* bpk    = (float*)alloc(NPK2 * sizeof(float));
  (void)ws_size; (void)in_sizes; (void)n_in; (void)out_size;

  hipMemsetAsync(ws + zoff0, 0, zbytes, stream);

  k_prep<<<(FDIM * NPK2 + 255) / 256, 256, 0, stream>>>(ec_w1, ec_b1, gat_w, asrc, adst,
                                                        Wp, bpk);
  k_gemm<<<((N_NODES + GM - 1) / GM) * 2, 256, 0, stream>>>(x, Wp, bpk,
                                                            xb, Ubuf, Vbuf, alS, alD);
  k_hist<<<(N_EDGES + 255) / 256, 256, 0, stream>>>(ei, histP);
  k_scan1<<<SCAN_BLOCKS, 256, 0, stream>>>(histP, batch, rp, bsum, start);
  k_scan2<<<1, 256, 0, stream>>>(bsum);
  k_scan3<<<SCAN_BLOCKS, 256, 0, stream>>>(bsum, rp, histP);
  k_scatter<<<(N_EDGES + 255) / 256, 256, 0, stream>>>(ei, histP, colidx);

  // fused GAT-aggregate + GIN-sum over one L2-resident bf16 x table
  k_gatgin<<<(N_NODES + GCH - 1) / GCH, 256, 0, stream>>>(xb, alS, alD, rp, colidx,
                                                          agg4, agg);
  k_ec<<<(N_NODES + ECH - 1) / ECH, 256, 0, stream>>>(Ubuf, Vbuf, ec_w2, ec_b2, rp, colidx, batch, pooled);
  // GAT per-head transform + relu + pool
  k_gtrans<<<(N_NODES + 63) / 64, 256, 0, stream>>>(agg4, gat_w, gat_b, batch, pooled);
  // fused GIN MLP (h1 in LDS, no h1g intermediate)
  k_gin<<<(N_NODES + 63) / 64, 256, 0, stream>>>(agg, gin_w1, gin_b1, gin_w2, gin_b2,
                                                 batch, pooled);

  k_pooldiv<<<(BATCH * POOLW + 255) / 256, 256, 0, stream>>>(pooled, start);

  k_heads<<<BATCH, 256, 0, stream>>>(pooled, fg1_w, fg1_b, fg2_w, fg2_b, fg3_w, fg3_b,
                                     fg4_w, fg4_b, fg5_w, fg5_b, fg6_w, fg6_b,
                                     fc1_w, fc1_b, fc2_w, fc2_b, out_w, out_b, out);
}

// Round 11
// 711.985 us; speedup vs baseline: 1.0590x; 1.0158x over previous
//
#include <hip/hip_runtime.h>
#include <hip/hip_bf16.h>
#include <math.h>

#define N_NODES 50000
#define N_EDGES 800000
#define FDIM 53
#define BATCH 128
#define HF 212   /* H*F */
#define F2 106   /* 2F  */
#define POOLW 424 /* 212+106+106 */
#define NPK2 220 /* 106 + 106 + 8: U | V | alS | alD */
#define PSTR 32  /* padded bin stride (ints) = 128 B: one L2 line per node */
#define ECS 128  /* U/V bf16 row stride (shorts) = 256 B = 4 L2 lines */

typedef __attribute__((ext_vector_type(8))) short short8;
typedef __attribute__((ext_vector_type(4))) float f32x4;

__device__ __forceinline__ float leaky02(float x){ return x >= 0.f ? x : 0.2f * x; }

__device__ __forceinline__ short f2bf(float x) {
  unsigned u = __float_as_uint(x);
  unsigned r = (u + 0x7fffu + ((u >> 16) & 1u)) >> 16;
  return (short)r;
}
__device__ __forceinline__ float bf2f(short b) {
  return __uint_as_float(((unsigned)(unsigned short)b) << 16);
}
// packed pair f32x2 -> bf16x2 (v_cvt_pk_bf16_f32, RNE)
__device__ __forceinline__ unsigned pk2(float a, float b) {
  union { __hip_bfloat162 h; unsigned u; } c;
  c.h = __float22bfloat162_rn(make_float2(a, b));
  return c.u;
}
// LDS-only barrier: waits lgkmcnt(0) (ds ops) but leaves global loads in flight
__device__ __forceinline__ void ldsbar() {
  __builtin_amdgcn_s_waitcnt(0xC07F);   // vmcnt(63) expcnt(7) lgkmcnt(0)
  __builtin_amdgcn_s_barrier();
}

// ---------------------------------------------------------------------------
// Pack Wp[53][220] = [W1top-W1bot | W1bot | cAl] and bias bp[220].
// cAl columns (j >= 2*F2) compute their own 53-MAC dot (k_cal folded in).
// ---------------------------------------------------------------------------
__global__ void k_prep(const float* __restrict__ ec_w1, const float* __restrict__ ec_b1,
                       const float* __restrict__ gat_w, const float* __restrict__ asrc,
                       const float* __restrict__ adst,
                       float* __restrict__ Wp, float* __restrict__ bp) {
  int idx = blockIdx.x * blockDim.x + threadIdx.x;
  if (idx < FDIM * NPK2) {
    int k = idx / NPK2, j = idx % NPK2;
    float v;
    if (j < F2)            v = ec_w1[k * F2 + j] - ec_w1[(FDIM + k) * F2 + j];
    else if (j < 2 * F2)   v = ec_w1[(FDIM + k) * F2 + (j - F2)];
    else {
      int r = j - 2 * F2;              // 0..7 = sd*4 + h
      int sd = r >> 2, h = r & 3;
      const float* av = sd ? adst : asrc;
      float acc = 0.f;
      for (int f = 0; f < FDIM; ++f)
        acc += gat_w[k * HF + h * FDIM + f] * av[h * FDIM + f];
      v = acc;
    }
    Wp[idx] = v;
  }
  if (idx < NPK2) {
    bp[idx] = (idx < F2) ? ec_b1[idx] : 0.f;
  }
}

// ---------------------------------------------------------------------------
// Node-linear GEMM: x[50000x53] @ Wp[53x220] + bp -> U | V | alS | alD.
// Also emits xb (bf16 x rows, 64-short stride) during A-tile staging.
// ---------------------------------------------------------------------------
#define GM 64
#define GN 110
#define GNP 112
#define APAD 57
__global__ __launch_bounds__(256) void k_gemm(
    const float* __restrict__ x, const float* __restrict__ Wp, const float* __restrict__ bp,
    short* __restrict__ xb, short* __restrict__ Ub, short* __restrict__ Vb,
    float* __restrict__ alS, float* __restrict__ alD) {
  __shared__ float As[GM * APAD];
  __shared__ float Ws[FDIM * GNP];
  int mb = blockIdx.x >> 1, nc = blockIdx.x & 1;
  int m0 = mb * GM, n0 = nc * GN;
  int t = threadIdx.x;
  for (int idx = t; idx < GM * FDIM; idx += 256) {
    int m = idx / FDIM, k = idx % FDIM;
    int gm = m0 + m;
    float v = (gm < N_NODES) ? x[(size_t)gm * FDIM + k] : 0.f;
    As[m * APAD + k] = v;
    if (nc == 0 && gm < N_NODES) xb[(size_t)gm * 64 + k] = f2bf(v);
  }
  for (int idx = t; idx < FDIM * GNP; idx += 256) {
    int k = idx / GNP, n = idx % GNP;
    Ws[idx] = (n < GN) ? Wp[k * NPK2 + n0 + n] : 0.f;
  }
  __syncthreads();
  int tx = t & 15, ty = t >> 4;
  int ms = tx * 4, ns = ty * 7;
  float acc[4][7];
#pragma unroll
  for (int i = 0; i < 4; i++)
#pragma unroll
    for (int j = 0; j < 7; j++) acc[i][j] = 0.f;
  for (int k = 0; k < FDIM; k++) {
    float a0 = As[(ms + 0) * APAD + k];
    float a1 = As[(ms + 1) * APAD + k];
    float a2 = As[(ms + 2) * APAD + k];
    float a3 = As[(ms + 3) * APAD + k];
    float b[7];
#pragma unroll
    for (int j = 0; j < 7; j++) b[j] = Ws[k * GNP + ns + j];
#pragma unroll
    for (int j = 0; j < 7; j++) {
      acc[0][j] += a0 * b[j];
      acc[1][j] += a1 * b[j];
      acc[2][j] += a2 * b[j];
      acc[3][j] += a3 * b[j];
    }
  }
  float bj[7];
#pragma unroll
  for (int j = 0; j < 7; j++) {
    int g = n0 + ns + j;
    bj[j] = (g < NPK2) ? bp[g] : 0.f;
  }
#pragma unroll
  for (int i = 0; i < 4; i++) {
    int gm = m0 + ms + i;
    if (gm >= N_NODES) break;
#pragma unroll
    for (int j = 0; j < 7; j++) {
      int g = n0 + ns + j;
      float v = acc[i][j] + bj[j];
      if (g < F2)             Ub[(size_t)gm * ECS + g] = f2bf(v);
      else if (g < 2 * F2)    Vb[(size_t)gm * ECS + (g - F2)] = f2bf(v);
      else if (g < 2 * F2 + 4) alS[gm * 4 + (g - 2 * F2)] = v;
      else if (g < NPK2)      alD[gm * 4 + (g - 2 * F2 - 4)] = v;
    }
  }
}

// ---------------------------------------------------------------------------
// CSR build with L2-line-padded bins: hist -> scan (compacts to rp, turns
// padded slot into scatter cursor) -> scatter. Graph counts via sorted-batch
// boundary detection (fused into scan1).
// ---------------------------------------------------------------------------
#define SCAN_BLOCKS ((N_NODES + 255) / 256)

__global__ void k_hist(const int* __restrict__ ei, int* __restrict__ histP) {
  int t = blockIdx.x * blockDim.x + threadIdx.x;
  if (t < N_EDGES) atomicAdd(&histP[ei[N_EDGES + t] << 5], 1);
}

__global__ __launch_bounds__(256) void k_scan1(const int* __restrict__ histP,
                                               const int* __restrict__ batch,
                                               int* __restrict__ rp, int* __restrict__ bsum,
                                               int* __restrict__ start) {
  __shared__ int buf[256];
  int tid = threadIdx.x;
  int idx = blockIdx.x * 256 + tid;
  int v = (idx < N_NODES) ? histP[idx << 5] : 0;
  buf[tid] = v;
  __syncthreads();
  for (int off = 1; off < 256; off <<= 1) {
    int t2 = (tid >= off) ? buf[tid - off] : 0;
    __syncthreads();
    buf[tid] += t2;
    __syncthreads();
  }
  if (idx < N_NODES) rp[idx] = buf[tid] - v;
  if (tid == 255) bsum[blockIdx.x] = buf[255];
  // fused batch-boundary detection (was k_bnd)
  if (idx < N_NODES) {
    int b = batch[idx];
    if (idx == 0)
      for (int g = 0; g <= b; g++) start[g] = 0;
    int bn = (idx + 1 < N_NODES) ? batch[idx + 1] : BATCH;
    for (int g = b + 1; g <= bn; g++) start[g] = idx + 1;
  }
}

__global__ __launch_bounds__(256) void k_scan2(int* __restrict__ bsum) {
  __shared__ int buf[256];
  int tid = threadIdx.x;
  int v = (tid < SCAN_BLOCKS) ? bsum[tid] : 0;
  buf[tid] = v;
  __syncthreads();
  for (int off = 1; off < 256; off <<= 1) {
    int t2 = (tid >= off) ? buf[tid - off] : 0;
    __syncthreads();
    buf[tid] += t2;
    __syncthreads();
  }
  if (tid < SCAN_BLOCKS) bsum[tid] = buf[tid] - v;
}

__global__ __launch_bounds__(256) void k_scan3(const int* __restrict__ bsum,
                                               int* __restrict__ rp, int* __restrict__ histP) {
  int idx = blockIdx.x * 256 + threadIdx.x;
  if (idx < N_NODES) {
    int o = rp[idx] + bsum[blockIdx.x];
    rp[idx] = o;
    histP[idx << 5] = o;   // becomes the (padded) scatter cursor
  }
  if (idx == 0) rp[N_NODES] = N_EDGES;
}

__global__ void k_scatter(const int* __restrict__ ei, int* __restrict__ histP,
                          int* __restrict__ colidx) {
  int e = blockIdx.x * blockDim.x + threadIdx.x;
  if (e >= N_EDGES) return;
  int d = ei[N_EDGES + e];
  int pos = atomicAdd(&histP[d << 5], 1);
  colidx[pos] = ei[e];
}

// ---------------------------------------------------------------------------
// Fused GAT-aggregate + GIN-sum: one edge walk gathering bf16 x rows (128 B
// line each). Per-edge (s, alpha) distributed via wave-local LDS staging
// (broadcast reads) instead of 20 ds_bpermute shuffles per 4-edge group.
// ---------------------------------------------------------------------------
#define GCH 20
__global__ __launch_bounds__(256) void k_gatgin(
    const short* __restrict__ xb, const float* __restrict__ alS, const float* __restrict__ alD,
    const int* __restrict__ rp, const int* __restrict__ colidx,
    short* __restrict__ agg4, float* __restrict__ agg) {
  int wid = threadIdx.x >> 6, lane = threadIdx.x & 63;
  bool fa = lane < FDIM;
  int i0 = blockIdx.x * GCH;
  int iend = min(i0 + GCH, N_NODES);
  __shared__ int rpG[GCH + 1];
  __shared__ int sL[4][64];        // per-wave edge src ids
  __shared__ float4 eL[4][64];     // per-wave edge alphas (4 heads)
  {
    int t = threadIdx.x, nn = iend - i0;
    if (t <= nn) rpG[t] = rp[i0 + t];
  }
  __syncthreads();
  for (int i = i0 + wid; i < iend; i += 4) {
    int base = rpG[i - i0], deg = rpG[i - i0 + 1] - base;
    float4 adv = *(const float4*)(alD + (size_t)i * 4);
    float4 asv = *(const float4*)(alS + (size_t)i * 4);
    float aldi[4] = {adv.x, adv.y, adv.z, adv.w};
    float exs[4];
    exs[0] = __expf(leaky02(asv.x + aldi[0]));   // self-loop term
    exs[1] = __expf(leaky02(asv.y + aldi[1]));
    exs[2] = __expf(leaky02(asv.z + aldi[2]));
    exs[3] = __expf(leaky02(asv.w + aldi[3]));
    float xiv = fa ? bf2f(xb[(size_t)i * 64 + lane]) : 0.f;
    float ag0 = exs[0] * xiv, ag1 = exs[1] * xiv, ag2 = exs[2] * xiv, ag3 = exs[3] * xiv;
    float ax = xiv;
    float zl[4] = {0.f, 0.f, 0.f, 0.f};

    for (int c0 = 0; c0 < deg; c0 += 64) {
      int cn = min(64, deg - c0);
      int s = 0;
      float ex0 = 0.f, ex1 = 0.f, ex2 = 0.f, ex3 = 0.f;
      if (lane < cn) {
        s = colidx[base + c0 + lane];
        float4 av = *(const float4*)(alS + (size_t)s * 4);
        ex0 = __expf(leaky02(av.x + aldi[0]));
        ex1 = __expf(leaky02(av.y + aldi[1]));
        ex2 = __expf(leaky02(av.z + aldi[2]));
        ex3 = __expf(leaky02(av.w + aldi[3]));
        zl[0] += ex0; zl[1] += ex1; zl[2] += ex2; zl[3] += ex3;
      }
      // wave-local LDS stage (s=0 / e=0 for inactive lanes); wave64 lockstep,
      // no barrier needed — compiler orders via lgkmcnt.
      sL[wid][lane] = s;
      eL[wid][lane] = make_float4(ex0, ex1, ex2, ex3);
      for (int jj = 0; jj < cn; jj += 4) {
        int4 s4 = *(const int4*)&sL[wid][jj];          // 4 edge ids, broadcast
        int sj[4] = {s4.x, s4.y, s4.z, s4.w};
        float4 e0 = eL[wid][jj + 0];
        float4 e1 = eL[wid][jj + 1];
        float4 e2 = eL[wid][jj + 2];
        float4 e3 = eL[wid][jj + 3];
        float xg[4];
#pragma unroll
        for (int q = 0; q < 4; q++)
          xg[q] = fa ? bf2f(xb[(size_t)sj[q] * 64 + lane]) : 0.f;
        ag0 += e0.x * xg[0] + e1.x * xg[1] + e2.x * xg[2] + e3.x * xg[3];
        ag1 += e0.y * xg[0] + e1.y * xg[1] + e2.y * xg[2] + e3.y * xg[3];
        ag2 += e0.z * xg[0] + e1.z * xg[1] + e2.z * xg[2] + e3.z * xg[3];
        ag3 += e0.w * xg[0] + e1.w * xg[1] + e2.w * xg[2] + e3.w * xg[3];
#pragma unroll
        for (int q = 0; q < 4; q++)
          if (jj + q < cn) ax += xg[q];                // uniform guard
      }
    }
#pragma unroll
    for (int off = 32; off >= 1; off >>= 1)
#pragma unroll
      for (int h = 0; h < 4; h++) zl[h] += __shfl_xor(zl[h], off);
    if (fa) {
      float z0 = zl[0] + exs[0] + 1e-16f;
      float z1 = zl[1] + exs[1] + 1e-16f;
      float z2 = zl[2] + exs[2] + 1e-16f;
      float z3 = zl[3] + exs[3] + 1e-16f;
      short* ar = agg4 + (size_t)i * HF;
      ar[0 * FDIM + lane] = f2bf(ag0 / z0);
      ar[1 * FDIM + lane] = f2bf(ag1 / z1);
      ar[2 * FDIM + lane] = f2bf(ag2 / z2);
      ar[3 * FDIM + lane] = f2bf(ag3 / z3);
      agg[(size_t)i * FDIM + lane] = ax;
    }
  }
}

// ---------------------------------------------------------------------------
// GAT transform: grouped (per-head 53x53) GEMM + relu + pooled accumulation
// ---------------------------------------------------------------------------
#define TCOLS 224   /* 4 heads x 56 padded cols */
#define A4S 217     /* As row stride in shorts (odd -> conflict-free) */
__global__ __launch_bounds__(256) void k_gtrans(
    const short* __restrict__ agg4, const float* __restrict__ gat_w,
    const float* __restrict__ bias, const int* __restrict__ batch,
    float* __restrict__ pooled) {
  __shared__ short As[64 * A4S];
  __shared__ float Bs[FDIM * TCOLS];
  __shared__ float psum[4 * TCOLS];
  int m0 = blockIdx.x * 64;
  int t = threadIdx.x;
  for (int idx = t; idx < 4 * TCOLS; idx += 256) psum[idx] = 0.f;
  for (int idx = t; idx < 64 * HF; idx += 256) {
    int m = idx / HF, c = idx % HF;
    int gm = m0 + m;
    As[m * A4S + c] = (gm < N_NODES) ? agg4[(size_t)gm * HF + c] : (short)0;
  }
  for (int idx = t; idx < FDIM * TCOLS; idx += 256) {
    int k = idx / TCOLS, c = idx % TCOLS;
    int h = c / 56, jn = c % 56;
    Bs[idx] = (jn < FDIM) ? gat_w[k * HF + h * FDIM + jn] : 0.f;
  }
  __syncthreads();
  int tx = t & 15, ty = t >> 4;
  int ms = tx * 4, ns = ty * 14;
  int hh = ty >> 2;
  int jnb = (ty & 3) * 14;
  float acc[4][14];
#pragma unroll
  for (int i = 0; i < 4; i++)
#pragma unroll
    for (int j = 0; j < 14; j++) acc[i][j] = 0.f;
  for (int k = 0; k < FDIM; k++) {
    float a0 = bf2f(As[(ms + 0) * A4S + hh * FDIM + k]);
    float a1 = bf2f(As[(ms + 1) * A4S + hh * FDIM + k]);
    float a2 = bf2f(As[(ms + 2) * A4S + hh * FDIM + k]);
    float a3 = bf2f(As[(ms + 3) * A4S + hh * FDIM + k]);
    float b[14];
#pragma unroll
    for (int j = 0; j < 14; j++) b[j] = Bs[k * TCOLS + ns + j];
#pragma unroll
    for (int j = 0; j < 14; j++) {
      acc[0][j] += a0 * b[j];
      acc[1][j] += a1 * b[j];
      acc[2][j] += a2 * b[j];
      acc[3][j] += a3 * b[j];
    }
  }
  float bj[14]; bool jv[14];
#pragma unroll
  for (int j = 0; j < 14; j++) {
    jv[j] = (jnb + j) < FDIM;
    bj[j] = jv[j] ? bias[hh * FDIM + jnb + j] : 0.f;
  }
  int bmin = batch[m0];
  float pj[14];
#pragma unroll
  for (int j = 0; j < 14; j++) pj[j] = 0.f;
  int curb = -1;
#pragma unroll
  for (int i = 0; i < 4; i++) {
    int gm = m0 + ms + i;
    if (gm >= N_NODES) break;
    int b = batch[gm];
    if (b != curb) {
      if (curb >= 0) {
        int slot = curb - bmin;
        if (slot >= 0 && slot < 4) {
#pragma unroll
          for (int j = 0; j < 14; j++)
            if (jv[j]) atomicAdd(&psum[slot * TCOLS + ns + j], pj[j]);
        } else {
          float* pg = pooled + (size_t)curb * POOLW;
#pragma unroll
          for (int j = 0; j < 14; j++)
            if (jv[j]) atomicAdd(&pg[hh * FDIM + jnb + j], pj[j]);
        }
      }
      curb = b;
#pragma unroll
      for (int j = 0; j < 14; j++)
        pj[j] = jv[j] ? fmaxf(acc[i][j] + bj[j], 0.f) : 0.f;
    } else {
#pragma unroll
      for (int j = 0; j < 14; j++)
        if (jv[j]) pj[j] += fmaxf(acc[i][j] + bj[j], 0.f);
    }
  }
  if (curb >= 0) {
    int slot = curb - bmin;
    if (slot >= 0 && slot < 4) {
#pragma unroll
      for (int j = 0; j < 14; j++)
        if (jv[j]) atomicAdd(&psum[slot * TCOLS + ns + j], pj[j]);
    } else {
      float* pg = pooled + (size_t)curb * POOLW;
#pragma unroll
      for (int j = 0; j < 14; j++)
        if (jv[j]) atomicAdd(&pg[hh * FDIM + jnb + j], pj[j]);
    }
  }
  __syncthreads();
  for (int idx = t; idx < 4 * TCOLS; idx += 256) {
    int slot = idx / TCOLS, c = idx % TCOLS;
    int h = c / 56, jn = c % 56;
    float v = psum[idx];
    int b = bmin + slot;
    if (jn < FDIM && b < BATCH && v != 0.f)
      atomicAdd(&pooled[(size_t)b * POOLW + h * FDIM + jn], v);
  }
}

// ---------------------------------------------------------------------------
// Fused GIN MLP: h1 = relu(agg @ w1 + b1) kept in LDS; h2 = relu(h1 @ w2 + b2)
// + pooled accumulation. Eliminates the 21 MB h1g intermediate entirely.
// ---------------------------------------------------------------------------
#define A2PAD 111
__global__ __launch_bounds__(256) void k_gin(
    const float* __restrict__ agg,
    const float* __restrict__ w1, const float* __restrict__ b1,
    const float* __restrict__ w2, const float* __restrict__ b2,
    const int* __restrict__ batch, float* __restrict__ pooled) {
  __shared__ float B1[F2 * 112];       // phase A: As | Ws1; phase B: Ws2
  __shared__ float Hs[64 * A2PAD];
  __shared__ float psum[4 * 112];
  float* As = B1;                      // 64*APAD = 3648 floats
  float* Ws1 = B1 + 64 * APAD;         // 53*112 = 5936 floats (total 9584 < 11872)
  int m0 = blockIdx.x * 64;
  int t = threadIdx.x;
  for (int idx = t; idx < 4 * 112; idx += 256) psum[idx] = 0.f;
  for (int idx = t; idx < 64 * FDIM; idx += 256) {
    int m = idx / FDIM, k = idx % FDIM;
    int gm = m0 + m;
    As[m * APAD + k] = (gm < N_NODES) ? agg[(size_t)gm * FDIM + k] : 0.f;
  }
  for (int idx = t; idx < FDIM * 112; idx += 256) {
    int k = idx / 112, n = idx % 112;
    Ws1[idx] = (n < F2) ? w1[k * F2 + n] : 0.f;
  }
  __syncthreads();
  int tx = t & 15, ty = t >> 4;
  int ms = tx * 4, ns = ty * 7;
  // ---- phase A: h1 = relu(agg @ w1 + b1) -> Hs ----
  {
    float acc[4][7];
#pragma unroll
    for (int i = 0; i < 4; i++)
#pragma unroll
      for (int j = 0; j < 7; j++) acc[i][j] = 0.f;
    for (int k = 0; k < FDIM; k++) {
      float a0 = As[(ms + 0) * APAD + k];
      float a1 = As[(ms + 1) * APAD + k];
      float a2 = As[(ms + 2) * APAD + k];
      float a3 = As[(ms + 3) * APAD + k];
      float b[7];
#pragma unroll
      for (int j = 0; j < 7; j++) b[j] = Ws1[k * 112 + ns + j];
#pragma unroll
      for (int j = 0; j < 7; j++) {
        acc[0][j] += a0 * b[j];
        acc[1][j] += a1 * b[j];
        acc[2][j] += a2 * b[j];
        acc[3][j] += a3 * b[j];
      }
    }
#pragma unroll
    for (int i = 0; i < 4; i++) {
#pragma unroll
      for (int j = 0; j < 7; j++) {
        int n = ns + j;
        if (n < F2) Hs[(ms + i) * A2PAD + n] = fmaxf(acc[i][j] + b1[n], 0.f);
      }
    }
  }
  __syncthreads();   // all As/Ws1 reads done; Hs complete
  // ---- phase B: stage w2 over B1, then h2 = relu(Hs @ w2 + b2) + pool ----
  for (int idx = t; idx < F2 * 112; idx += 256) {
    int k = idx / 112, n = idx % 112;
    B1[idx] = (n < F2) ? w2[k * F2 + n] : 0.f;
  }
  __syncthreads();
  float acc[4][7];
#pragma unroll
  for (int i = 0; i < 4; i++)
#pragma unroll
    for (int j = 0; j < 7; j++) acc[i][j] = 0.f;
  for (int k = 0; k < F2; k++) {
    float a0 = Hs[(ms + 0) * A2PAD + k];
    float a1 = Hs[(ms + 1) * A2PAD + k];
    float a2 = Hs[(ms + 2) * A2PAD + k];
    float a3 = Hs[(ms + 3) * A2PAD + k];
    float b[7];
#pragma unroll
    for (int j = 0; j < 7; j++) b[j] = B1[k * 112 + ns + j];
#pragma unroll
    for (int j = 0; j < 7; j++) {
      acc[0][j] += a0 * b[j];
      acc[1][j] += a1 * b[j];
      acc[2][j] += a2 * b[j];
      acc[3][j] += a3 * b[j];
    }
  }
  float b2n[7];
#pragma unroll
  for (int j = 0; j < 7; j++) {
    int n = ns + j;
    b2n[j] = (n < F2) ? b2[n] : 0.f;
  }
  int bmin = batch[m0];
  float pj[7];
#pragma unroll
  for (int j = 0; j < 7; j++) pj[j] = 0.f;
  int curb = -1;
#pragma unroll
  for (int i = 0; i < 4; i++) {
    int gm = m0 + ms + i;
    if (gm >= N_NODES) break;
    int b = batch[gm];
    if (b != curb) {
      if (curb >= 0) {
        int slot = curb - bmin;
        if (slot >= 0 && slot < 4) {
#pragma unroll
          for (int j = 0; j < 7; j++)
            if (ns + j < F2) atomicAdd(&psum[slot * 112 + ns + j], pj[j]);
        } else {
          float* pg = pooled + (size_t)curb * POOLW + HF;
#pragma unroll
          for (int j = 0; j < 7; j++)
            if (ns + j < F2) atomicAdd(&pg[ns + j], pj[j]);
        }
      }
      curb = b;
#pragma unroll
      for (int j = 0; j < 7; j++)
        pj[j] = (ns + j < F2) ? fmaxf(acc[i][j] + b2n[j], 0.f) : 0.f;
    } else {
#pragma unroll
      for (int j = 0; j < 7; j++)
        if (ns + j < F2) pj[j] += fmaxf(acc[i][j] + b2n[j], 0.f);
    }
  }
  if (curb >= 0) {
    int slot = curb - bmin;
    if (slot >= 0 && slot < 4) {
#pragma unroll
      for (int j = 0; j < 7; j++)
        if (ns + j < F2) atomicAdd(&psum[slot * 112 + ns + j], pj[j]);
    } else {
      float* pg = pooled + (size_t)curb * POOLW + HF;
#pragma unroll
      for (int j = 0; j < 7; j++)
        if (ns + j < F2) atomicAdd(&pg[ns + j], pj[j]);
    }
  }
  __syncthreads();
  for (int idx = t; idx < 4 * 112; idx += 256) {
    int slot = idx / 112, n = idx % 112;
    float v = psum[idx];
    int b = bmin + slot;
    if (n < F2 && b < BATCH && v != 0.f)
      atomicAdd(&pooled[(size_t)b * POOLW + HF + n], v);
  }
}

// ---------------------------------------------------------------------------
// EdgeConv v8 (round-5 best): bf16 U/V, rp/batch in LDS, colidx prefetched
// 2 tiles ahead / V 1 tile ahead, deferred cross-quad max reduction,
// double-buffered LDS, lgkmcnt-only barrier.
// ---------------------------------------------------------------------------
#define ECH 25
__global__ __launch_bounds__(256) void k_ec(
    const short* __restrict__ Ub, const short* __restrict__ Vb,
    const float* __restrict__ w2, const float* __restrict__ b2,
    const int* __restrict__ rp, const int* __restrict__ colidx,
    const int* __restrict__ batch, float* __restrict__ pooled) {
  const int t = threadIdx.x;
  const int lane = t & 63, wid = t >> 6;
  const int n16 = lane & 15, quad = lane >> 4;
  const int nt = (wid == 3) ? 1 : 2;   // u-tile 7 is all-pad

  const int i0 = blockIdx.x * ECH;
  const int iend = min(i0 + ECH, N_NODES);
  const int nn = iend - i0;

  __shared__ int rpL[ECH + 1];
  __shared__ int batL[ECH];

  short8 Bh[2][4];
  for (int tt = 0; tt < 2; tt++) {
    int ucol = (wid * 2 + tt) * 16 + n16;
    for (int kc = 0; kc < 4; kc++) {
      short8 vh;
#pragma unroll
      for (int jv = 0; jv < 8; jv++) {
        int kk = kc * 32 + quad * 8 + jv;
        float w = (ucol < F2 && kk < F2) ? w2[kk * F2 + ucol] : 0.f;
        vh[jv] = f2bf(w);
      }
      Bh[tt][kc] = vh;
    }
  }
  float b2v[2];
#pragma unroll
  for (int tt = 0; tt < 2; tt++) {
    int u = (wid * 2 + tt) * 16 + n16;
    b2v[tt] = (u < F2) ? b2[u] : 0.f;
  }

  if (t <= nn) rpL[t] = rp[i0 + t];
  if (t < nn) batL[t] = batch[i0 + t];
  __syncthreads();

  __shared__ short hs[2][16 * 16 * 8];
  union SU { short8 s; unsigned u[4]; };
  const int es = t & 15, kg = t >> 4;
  const int k0 = kg * 8;

  float sm0 = 0.f, sm1 = 0.f;
  int curb = -1;
  const int u0 = (wid * 2) * 16 + n16;
  const int u1 = (wid * 2 + 1) * 16 + n16;

  // tile walk: (node, tile-in-node, base, deg) -> next
  auto advance = [&](int& ii, int& ttb, int& bb, int& dd) -> bool {
    ttb++;
    if (ttb * 16 < dd) return true;
    ttb = 0;
    for (ii = ii + 1; ii < iend; ii++) {
      bb = rpL[ii - i0]; dd = rpL[ii - i0 + 1] - bb;
      if (dd > 0) return true;
    }
    return false;
  };

  // current tile T
  int i = i0, tb = 0, base = 0, deg = 0;
  bool have = false;
  for (; i < iend; i++) {
    base = rpL[i - i0]; deg = rpL[i - i0 + 1] - base;
    if (deg > 0) { have = true; break; }
  }
  short8 pu8{}, pv8{};
  // tile T+1 coords + its colidx value (sc) already fetched
  int i1 = i, tb1 = 0, base1 = base, deg1 = deg;
  bool have1 = false;
  int sc = 0;
  if (have) {
    pu8 = *(const short8*)(Ub + (size_t)i * ECS + k0);
    int s0 = colidx[base + ((es < deg) ? es : 0)];
    pv8 = *(const short8*)(Vb + (size_t)s0 * ECS + k0);
    have1 = advance(i1, tb1, base1, deg1);
    if (have1) {
      int eg = tb1 * 16 + es;
      sc = colidx[base1 + ((eg < deg1) ? eg : 0)];
    }
  }

  float Uc[8];
  float vmax0 = -1e30f, vmax1 = -1e30f;
  int parity = 0;
  while (have) {
    if (tb == 0) {
#pragma unroll
      for (int j = 0; j < 8; j++) Uc[j] = bf2f(pu8[j]);
    }
    SU w;
#pragma unroll
    for (int p = 0; p < 4; p++) {
      bool kv = (k0 + 2 * p) < F2;
      float h0 = kv ? fmaxf(Uc[2 * p]     + bf2f(pv8[2 * p]),     0.f) : 0.f;
      float h1 = kv ? fmaxf(Uc[2 * p + 1] + bf2f(pv8[2 * p + 1]), 0.f) : 0.f;
      w.u[p] = pk2(h0, h1);
    }
    *(short8*)&hs[parity][(kg * 16 + es) * 8] = w.s;

    // prefetch: V (and U) for tile T+1 using sc fetched last iter; colidx for T+2
    int i2 = i1, tb2 = tb1, base2 = base1, deg2 = deg1;
    bool have2 = false;
    int scN = 0;
    if (have1) {
      if (tb1 == 0) pu8 = *(const short8*)(Ub + (size_t)i1 * ECS + k0);
      pv8 = *(const short8*)(Vb + (size_t)sc * ECS + k0);
      have2 = advance(i2, tb2, base2, deg2);
      if (have2) {
        int eg2 = tb2 * 16 + es;
        scN = colidx[base2 + ((eg2 < deg2) ? eg2 : 0)];
      }
    }

    ldsbar();
    f32x4 a0 = {0.f, 0.f, 0.f, 0.f}, a1 = {0.f, 0.f, 0.f, 0.f};
#pragma unroll
    for (int kc = 0; kc < 4; kc++) {
      short8 af = *(const short8*)&hs[parity][((kc * 4 + quad) * 16 + n16) * 8];
      a0 = __builtin_amdgcn_mfma_f32_16x16x32_bf16(af, Bh[0][kc], a0, 0, 0, 0);
      if (nt > 1)
        a1 = __builtin_amdgcn_mfma_f32_16x16x32_bf16(af, Bh[1][kc], a1, 0, 0, 0);
    }
#pragma unroll
    for (int r = 0; r < 4; r++) {
      int er = tb * 16 + quad * 4 + r;
      if (er < deg) { vmax0 = fmaxf(vmax0, a0[r]); vmax1 = fmaxf(vmax1, a1[r]); }
    }
    if (!have1 || i1 != i) {
      // node i finishes with this tile: cross-quad reduce deferred to here
      vmax0 = fmaxf(vmax0, __shfl_xor(vmax0, 16));
      vmax0 = fmaxf(vmax0, __shfl_xor(vmax0, 32));
      vmax1 = fmaxf(vmax1, __shfl_xor(vmax1, 16));
      vmax1 = fmaxf(vmax1, __shfl_xor(vmax1, 32));
      float o0 = fmaxf(vmax0 + b2v[0], 0.f);
      float o1 = fmaxf(vmax1 + b2v[1], 0.f);
      int b = batL[i - i0];
      if (b != curb) {
        if (curb >= 0 && quad == 0) {
          float* pg = pooled + (size_t)curb * POOLW + HF + F2;
          if (u0 < F2) atomicAdd(&pg[u0], sm0);
          if (nt > 1 && u1 < F2) atomicAdd(&pg[u1], sm1);
        }
        curb = b; sm0 = o0; sm1 = o1;
      } else {
        sm0 += o0; sm1 += o1;
      }
      vmax0 = -1e30f; vmax1 = -1e30f;
    }
    i = i1; tb = tb1; base = base1; deg = deg1; have = have1;
    i1 = i2; tb1 = tb2; base1 = base2; deg1 = deg2; have1 = have2;
    sc = scN;
    parity ^= 1;
  }
  if (curb >= 0 && quad == 0) {
    float* pg = pooled + (size_t)curb * POOLW + HF + F2;
    if (u0 < F2) atomicAdd(&pg[u0], sm0);
    if (nt > 1 && u1 < F2) atomicAdd(&pg[u1], sm1);
  }
}

// ---------------------------------------------------------------------------
// mean-pool divide (counts from sorted-batch boundaries)
// ---------------------------------------------------------------------------
__global__ void k_pooldiv(float* __restrict__ pooled, const int* __restrict__ start) {
  int t = blockIdx.x * blockDim.x + threadIdx.x;
  if (t >= BATCH * POOLW) return;
  int b = t / POOLW;
  float c = (float)(start[b + 1] - start[b]);
  pooled[t] /= fmaxf(c, 1.f);
}

// ---------------------------------------------------------------------------
// Per-graph heads + final MLP fused: block g computes the three 2-layer MLPs
// into cat[384] (LDS), then 384->128->64->1 sigmoid. No global cat buffer.
// ---------------------------------------------------------------------------
__global__ __launch_bounds__(256) void k_heads(
    const float* __restrict__ pooled,
    const float* __restrict__ fg1_w, const float* __restrict__ fg1_b,
    const float* __restrict__ fg2_w, const float* __restrict__ fg2_b,
    const float* __restrict__ fg3_w, const float* __restrict__ fg3_b,
    const float* __restrict__ fg4_w, const float* __restrict__ fg4_b,
    const float* __restrict__ fg5_w, const float* __restrict__ fg5_b,
    const float* __restrict__ fg6_w, const float* __restrict__ fg6_b,
    const float* __restrict__ fc1_w, const float* __restrict__ fc1_b,
    const float* __restrict__ fc2_w, const float* __restrict__ fc2_b,
    const float* __restrict__ out_w, const float* __restrict__ out_b,
    float* __restrict__ out) {
  int g = blockIdx.x, t = threadIdx.x;
  __shared__ float in[POOLW];
  __shared__ float mid[256];
  __shared__ float cat[384];
  __shared__ float h1[128];
  __shared__ float h2[64];
  for (int idx = t; idx < POOLW; idx += 256) in[idx] = pooled[(size_t)g * POOLW + idx];
  __syncthreads();
  const float* w1s[3] = {fg1_w, fg3_w, fg5_w};
  const float* b1s[3] = {fg1_b, fg3_b, fg5_b};
  const float* w2s[3] = {fg2_w, fg4_w, fg6_w};
  const float* b2s[3] = {fg2_b, fg4_b, fg6_b};
  const int off[4] = {0, HF, HF + F2, POOLW};
  for (int br = 0; br < 3; br++) {
    int kin = off[br + 1] - off[br];
    const float* iv = &in[off[br]];
    float a = b1s[br][t];
    const float* W = w1s[br];
    for (int k = 0; k < kin; k++) a += iv[k] * W[k * 256 + t];
    mid[t] = fmaxf(a, 0.f);
    __syncthreads();
    if (t < 128) {
      float b = b2s[br][t];
      const float* W2 = w2s[br];
      for (int k = 0; k < 256; k++) b += mid[k] * W2[k * 128 + t];
      cat[br * 128 + t] = fmaxf(b, 0.f);
    }
    __syncthreads();
  }
  if (t < 128) {
    float a = fc1_b[t];
    for (int k = 0; k < 384; k++) a += cat[k] * fc1_w[k * 128 + t];
    h1[t] = fmaxf(a, 0.f);
  }
  __syncthreads();
  if (t < 64) {
    float a = fc2_b[t];
    for (int k = 0; k < 128; k++) a += h1[k] * fc2_w[k * 64 + t];
    h2[t] = fmaxf(a, 0.f);
  }
  __syncthreads();
  if (t == 0) {
    float a = out_b[0];
    for (int k = 0; k < 64; k++) a += h2[k] * out_w[k];
    out[g] = 1.f / (1.f + __expf(-a));
  }
}

// ---------------------------------------------------------------------------
extern "C" void kernel_launch(void* const* d_in, const int* in_sizes, int n_in,
                              void* d_out, int out_size, void* d_ws, size_t ws_size,
                              hipStream_t stream) {
  const float* x      = (const float*)d_in[0];
  const int*   ei     = (const int*)d_in[1];
  const int*   batch  = (const int*)d_in[2];
  const float* gat_w  = (const float*)d_in[3];
  const float* asrc   = (const float*)d_in[4];
  const float* adst   = (const float*)d_in[5];
  const float* gat_b  = (const float*)d_in[6];
  const float* gin_w1 = (const float*)d_in[7];
  const float* gin_b1 = (const float*)d_in[8];
  const float* gin_w2 = (const float*)d_in[9];
  const float* gin_b2 = (const float*)d_in[10];
  const float* ec_w1  = (const float*)d_in[11];
  const float* ec_b1  = (const float*)d_in[12];
  const float* ec_w2  = (const float*)d_in[13];
  const float* ec_b2  = (const float*)d_in[14];
  const float* fg1_w = (const float*)d_in[15]; const float* fg1_b = (const float*)d_in[16];
  const float* fg2_w = (const float*)d_in[17]; const float* fg2_b = (const float*)d_in[18];
  const float* fg3_w = (const float*)d_in[19]; const float* fg3_b = (const float*)d_in[20];
  const float* fg4_w = (const float*)d_in[21]; const float* fg4_b = (const float*)d_in[22];
  const float* fg5_w = (const float*)d_in[23]; const float* fg5_b = (const float*)d_in[24];
  const float* fg6_w = (const float*)d_in[25]; const float* fg6_b = (const float*)d_in[26];
  const float* fc1_w = (const float*)d_in[27]; const float* fc1_b = (const float*)d_in[28];
  const float* fc2_w = (const float*)d_in[29]; const float* fc2_b = (const float*)d_in[30];
  const float* out_w = (const float*)d_in[31]; const float* out_b = (const float*)d_in[32];
  float* out = (float*)d_out;

  char* ws = (char*)d_ws;
  size_t off = 0;
  auto alloc = [&](size_t bytes) -> void* {
    void* p = ws + off;
    off = (off + bytes + 255) & ~(size_t)255;
    return p;
  };
  // --- zero region (one memset): histP | pooled ---
  size_t zoff0 = off;
  int*   histP  = (int*)alloc((size_t)N_NODES * PSTR * sizeof(int));  // 6.4 MB padded bins
  float* pooled = (float*)alloc((size_t)BATCH * POOLW * sizeof(float));
  size_t zbytes = off - zoff0;
  // --- rest ---
  int*   rp     = (int*)alloc((N_NODES + 1) * sizeof(int));
  int*   start  = (int*)alloc((BATCH + 1) * sizeof(int));
  int*   bsum   = (int*)alloc(256 * sizeof(int));
  int*   colidx = (int*)alloc(N_EDGES * sizeof(int));
  short* xb     = (short*)alloc((size_t)N_NODES * 64 * sizeof(short));   // bf16 x rows, 128 B
  float* alS    = (float*)alloc((size_t)N_NODES * 4 * sizeof(float));
  float* alD    = (float*)alloc((size_t)N_NODES * 4 * sizeof(float));
  short* Ubuf   = (short*)alloc((size_t)N_NODES * ECS * sizeof(short));  // bf16, 256B rows
  short* Vbuf   = (short*)alloc((size_t)N_NODES * ECS * sizeof(short));  // bf16, 256B rows
  short* agg4   = (short*)alloc((size_t)N_NODES * HF * sizeof(short));   // GAT agg (bf16)
  float* agg    = (float*)alloc((size_t)N_NODES * FDIM * sizeof(float)); // GIN aggregate
  float* Wp     = (float*)alloc((size_t)FDIM * NPK2 * sizeof(float));
  float* bpk    = (float*)alloc(NPK2 * sizeof(float));
  (void)ws_size; (void)in_sizes; (void)n_in; (void)out_size;

  hipMemsetAsync(ws + zoff0, 0, zbytes, stream);

  k_prep<<<(FDIM * NPK2 + 255) / 256, 256, 0, stream>>>(ec_w1, ec_b1, gat_w, asrc, adst,
                                                        Wp, bpk);
  k_gemm<<<((N_NODES + GM - 1) / GM) * 2, 256, 0, stream>>>(x, Wp, bpk,
                                                            xb, Ubuf, Vbuf, alS, alD);
  k_hist<<<(N_EDGES + 255) / 256, 256, 0, stream>>>(ei, histP);
  k_scan1<<<SCAN_BLOCKS, 256, 0, stream>>>(histP, batch, rp, bsum, start);
  k_scan2<<<1, 256, 0, stream>>>(bsum);
  k_scan3<<<SCAN_BLOCKS, 256, 0, stream>>>(bsum, rp, histP);
  k_scatter<<<(N_EDGES + 255) / 256, 256, 0, stream>>>(ei, histP, colidx);

  // fused GAT-aggregate + GIN-sum over one L2-resident bf16 x table
  k_gatgin<<<(N_NODES + GCH - 1) / GCH, 256, 0, stream>>>(xb, alS, alD, rp, colidx,
                                                          agg4, agg);
  k_ec<<<(N_NODES + ECH - 1) / ECH, 256, 0, stream>>>(Ubuf, Vbuf, ec_w2, ec_b2, rp, colidx, batch, pooled);
  // GAT per-head transform + relu + pool
  k_gtrans<<<(N_NODES + 63) / 64, 256, 0, stream>>>(agg4, gat_w, gat_b, batch, pooled);
  // fused GIN MLP (h1 in LDS, no h1g intermediate)
  k_gin<<<(N_NODES + 63) / 64, 256, 0, stream>>>(agg, gin_w1, gin_b1, gin_w2, gin_b2,
                                                 batch, pooled);

  k_pooldiv<<<(BATCH * POOLW + 255) / 256, 256, 0, stream>>>(pooled, start);

  k_heads<<<BATCH, 256, 0, stream>>>(pooled, fg1_w, fg1_b, fg2_w, fg2_b, fg3_w, fg3_b,
                                     fg4_w, fg4_b, fg5_w, fg5_b, fg6_w, fg6_b,
                                     fc1_w, fc1_b, fc2_w, fc2_b, out_w, out_b, out);
}

// Round 12
// 705.242 us; speedup vs baseline: 1.0691x; 1.0096x over previous
//
#include <hip/hip_runtime.h>
#include <hip/hip_bf16.h>
#include <math.h>

#define N_NODES 50000
#define N_EDGES 800000
#define FDIM 53
#define BATCH 128
#define HF 212   /* H*F */
#define F2 106   /* 2F  */
#define POOLW 424 /* 212+106+106 */
#define NPK2 220 /* 106 + 106 + 8: U | V | alS | alD */
#define PSTR 32  /* padded bin stride (ints) = 128 B: one L2 line per node */
#define ECS 128  /* U/V bf16 row stride (shorts) = 256 B = 4 L2 lines */

typedef __attribute__((ext_vector_type(8))) short short8;
typedef __attribute__((ext_vector_type(4))) float f32x4;

__device__ __forceinline__ float leaky02(float x){ return x >= 0.f ? x : 0.2f * x; }

__device__ __forceinline__ short f2bf(float x) {
  unsigned u = __float_as_uint(x);
  unsigned r = (u + 0x7fffu + ((u >> 16) & 1u)) >> 16;
  return (short)r;
}
__device__ __forceinline__ float bf2f(short b) {
  return __uint_as_float(((unsigned)(unsigned short)b) << 16);
}
// packed pair f32x2 -> bf16x2 (v_cvt_pk_bf16_f32, RNE)
__device__ __forceinline__ unsigned pk2(float a, float b) {
  union { __hip_bfloat162 h; unsigned u; } c;
  c.h = __float22bfloat162_rn(make_float2(a, b));
  return c.u;
}
// LDS-only barrier: waits lgkmcnt(0) (ds ops) but leaves global loads in flight
__device__ __forceinline__ void ldsbar() {
  __builtin_amdgcn_s_waitcnt(0xC07F);   // vmcnt(63) expcnt(7) lgkmcnt(0)
  __builtin_amdgcn_s_barrier();
}

// ---------------------------------------------------------------------------
// Pack Wp[53][220] = [W1top-W1bot | W1bot | cAl] and bias bp[220].
// cAl columns (j >= 2*F2) compute their own 53-MAC dot (k_cal folded in).
// ---------------------------------------------------------------------------
__global__ void k_prep(const float* __restrict__ ec_w1, const float* __restrict__ ec_b1,
                       const float* __restrict__ gat_w, const float* __restrict__ asrc,
                       const float* __restrict__ adst,
                       float* __restrict__ Wp, float* __restrict__ bp) {
  int idx = blockIdx.x * blockDim.x + threadIdx.x;
  if (idx < FDIM * NPK2) {
    int k = idx / NPK2, j = idx % NPK2;
    float v;
    if (j < F2)            v = ec_w1[k * F2 + j] - ec_w1[(FDIM + k) * F2 + j];
    else if (j < 2 * F2)   v = ec_w1[(FDIM + k) * F2 + (j - F2)];
    else {
      int r = j - 2 * F2;              // 0..7 = sd*4 + h
      int sd = r >> 2, h = r & 3;
      const float* av = sd ? adst : asrc;
      float acc = 0.f;
      for (int f = 0; f < FDIM; ++f)
        acc += gat_w[k * HF + h * FDIM + f] * av[h * FDIM + f];
      v = acc;
    }
    Wp[idx] = v;
  }
  if (idx < NPK2) {
    bp[idx] = (idx < F2) ? ec_b1[idx] : 0.f;
  }
}

// ---------------------------------------------------------------------------
// Node-linear GEMM: x[50000x53] @ Wp[53x220] + bp -> U | V | alS | alD.
// Also emits xb (bf16 x rows, 64-short stride) during A-tile staging.
// ---------------------------------------------------------------------------
#define GM 64
#define GN 110
#define GNP 112
#define APAD 57
__global__ __launch_bounds__(256) void k_gemm(
    const float* __restrict__ x, const float* __restrict__ Wp, const float* __restrict__ bp,
    short* __restrict__ xb, short* __restrict__ Ub, short* __restrict__ Vb,
    float* __restrict__ alS, float* __restrict__ alD) {
  __shared__ float As[GM * APAD];
  __shared__ float Ws[FDIM * GNP];
  int mb = blockIdx.x >> 1, nc = blockIdx.x & 1;
  int m0 = mb * GM, n0 = nc * GN;
  int t = threadIdx.x;
  for (int idx = t; idx < GM * FDIM; idx += 256) {
    int m = idx / FDIM, k = idx % FDIM;
    int gm = m0 + m;
    float v = (gm < N_NODES) ? x[(size_t)gm * FDIM + k] : 0.f;
    As[m * APAD + k] = v;
    if (nc == 0 && gm < N_NODES) xb[(size_t)gm * 64 + k] = f2bf(v);
  }
  for (int idx = t; idx < FDIM * GNP; idx += 256) {
    int k = idx / GNP, n = idx % GNP;
    Ws[idx] = (n < GN) ? Wp[k * NPK2 + n0 + n] : 0.f;
  }
  __syncthreads();
  int tx = t & 15, ty = t >> 4;
  int ms = tx * 4, ns = ty * 7;
  float acc[4][7];
#pragma unroll
  for (int i = 0; i < 4; i++)
#pragma unroll
    for (int j = 0; j < 7; j++) acc[i][j] = 0.f;
  for (int k = 0; k < FDIM; k++) {
    float a0 = As[(ms + 0) * APAD + k];
    float a1 = As[(ms + 1) * APAD + k];
    float a2 = As[(ms + 2) * APAD + k];
    float a3 = As[(ms + 3) * APAD + k];
    float b[7];
#pragma unroll
    for (int j = 0; j < 7; j++) b[j] = Ws[k * GNP + ns + j];
#pragma unroll
    for (int j = 0; j < 7; j++) {
      acc[0][j] += a0 * b[j];
      acc[1][j] += a1 * b[j];
      acc[2][j] += a2 * b[j];
      acc[3][j] += a3 * b[j];
    }
  }
  float bj[7];
#pragma unroll
  for (int j = 0; j < 7; j++) {
    int g = n0 + ns + j;
    bj[j] = (g < NPK2) ? bp[g] : 0.f;
  }
#pragma unroll
  for (int i = 0; i < 4; i++) {
    int gm = m0 + ms + i;
    if (gm >= N_NODES) break;
#pragma unroll
    for (int j = 0; j < 7; j++) {
      int g = n0 + ns + j;
      float v = acc[i][j] + bj[j];
      if (g < F2)             Ub[(size_t)gm * ECS + g] = f2bf(v);
      else if (g < 2 * F2)    Vb[(size_t)gm * ECS + (g - F2)] = f2bf(v);
      else if (g < 2 * F2 + 4) alS[gm * 4 + (g - 2 * F2)] = v;
      else if (g < NPK2)      alD[gm * 4 + (g - 2 * F2 - 4)] = v;
    }
  }
}

// ---------------------------------------------------------------------------
// CSR build with L2-line-padded bins: hist -> scan (compacts to rp, turns
// padded slot into scatter cursor) -> scatter. Graph counts via sorted-batch
// boundary detection (fused into scan1).
// ---------------------------------------------------------------------------
#define SCAN_BLOCKS ((N_NODES + 255) / 256)

__global__ void k_hist(const int* __restrict__ ei, int* __restrict__ histP) {
  int t = blockIdx.x * blockDim.x + threadIdx.x;
  if (t < N_EDGES) atomicAdd(&histP[ei[N_EDGES + t] << 5], 1);
}

__global__ __launch_bounds__(256) void k_scan1(const int* __restrict__ histP,
                                               const int* __restrict__ batch,
                                               int* __restrict__ rp, int* __restrict__ bsum,
                                               int* __restrict__ start) {
  __shared__ int buf[256];
  int tid = threadIdx.x;
  int idx = blockIdx.x * 256 + tid;
  int v = (idx < N_NODES) ? histP[idx << 5] : 0;
  buf[tid] = v;
  __syncthreads();
  for (int off = 1; off < 256; off <<= 1) {
    int t2 = (tid >= off) ? buf[tid - off] : 0;
    __syncthreads();
    buf[tid] += t2;
    __syncthreads();
  }
  if (idx < N_NODES) rp[idx] = buf[tid] - v;
  if (tid == 255) bsum[blockIdx.x] = buf[255];
  // fused batch-boundary detection (was k_bnd)
  if (idx < N_NODES) {
    int b = batch[idx];
    if (idx == 0)
      for (int g = 0; g <= b; g++) start[g] = 0;
    int bn = (idx + 1 < N_NODES) ? batch[idx + 1] : BATCH;
    for (int g = b + 1; g <= bn; g++) start[g] = idx + 1;
  }
}

__global__ __launch_bounds__(256) void k_scan2(int* __restrict__ bsum) {
  __shared__ int buf[256];
  int tid = threadIdx.x;
  int v = (tid < SCAN_BLOCKS) ? bsum[tid] : 0;
  buf[tid] = v;
  __syncthreads();
  for (int off = 1; off < 256; off <<= 1) {
    int t2 = (tid >= off) ? buf[tid - off] : 0;
    __syncthreads();
    buf[tid] += t2;
    __syncthreads();
  }
  if (tid < SCAN_BLOCKS) bsum[tid] = buf[tid] - v;
}

__global__ __launch_bounds__(256) void k_scan3(const int* __restrict__ bsum,
                                               int* __restrict__ rp, int* __restrict__ histP) {
  int idx = blockIdx.x * 256 + threadIdx.x;
  if (idx < N_NODES) {
    int o = rp[idx] + bsum[blockIdx.x];
    rp[idx] = o;
    histP[idx << 5] = o;   // becomes the (padded) scatter cursor
  }
  if (idx == 0) rp[N_NODES] = N_EDGES;
}

__global__ void k_scatter(const int* __restrict__ ei, int* __restrict__ histP,
                          int* __restrict__ colidx) {
  int e = blockIdx.x * blockDim.x + threadIdx.x;
  if (e >= N_EDGES) return;
  int d = ei[N_EDGES + e];
  int pos = atomicAdd(&histP[d << 5], 1);
  colidx[pos] = ei[e];
}

// ---------------------------------------------------------------------------
// Fused GAT-aggregate + GIN-sum: one edge walk gathering bf16 x rows (128 B
// line each). Per-edge (s, alpha) distributed via wave-local LDS staging
// (broadcast reads) instead of 20 ds_bpermute shuffles per 4-edge group.
// ---------------------------------------------------------------------------
#define GCH 20
__global__ __launch_bounds__(256) void k_gatgin(
    const short* __restrict__ xb, const float* __restrict__ alS, const float* __restrict__ alD,
    const int* __restrict__ rp, const int* __restrict__ colidx,
    short* __restrict__ agg4, float* __restrict__ agg) {
  int wid = threadIdx.x >> 6, lane = threadIdx.x & 63;
  bool fa = lane < FDIM;
  int i0 = blockIdx.x * GCH;
  int iend = min(i0 + GCH, N_NODES);
  __shared__ int rpG[GCH + 1];
  __shared__ int sL[4][64];        // per-wave edge src ids
  __shared__ float4 eL[4][64];     // per-wave edge alphas (4 heads)
  {
    int t = threadIdx.x, nn = iend - i0;
    if (t <= nn) rpG[t] = rp[i0 + t];
  }
  __syncthreads();
  for (int i = i0 + wid; i < iend; i += 4) {
    int base = rpG[i - i0], deg = rpG[i - i0 + 1] - base;
    float4 adv = *(const float4*)(alD + (size_t)i * 4);
    float4 asv = *(const float4*)(alS + (size_t)i * 4);
    float aldi[4] = {adv.x, adv.y, adv.z, adv.w};
    float exs[4];
    exs[0] = __expf(leaky02(asv.x + aldi[0]));   // self-loop term
    exs[1] = __expf(leaky02(asv.y + aldi[1]));
    exs[2] = __expf(leaky02(asv.z + aldi[2]));
    exs[3] = __expf(leaky02(asv.w + aldi[3]));
    float xiv = fa ? bf2f(xb[(size_t)i * 64 + lane]) : 0.f;
    float ag0 = exs[0] * xiv, ag1 = exs[1] * xiv, ag2 = exs[2] * xiv, ag3 = exs[3] * xiv;
    float ax = xiv;
    float zl[4] = {0.f, 0.f, 0.f, 0.f};

    for (int c0 = 0; c0 < deg; c0 += 64) {
      int cn = min(64, deg - c0);
      int s = 0;
      float ex0 = 0.f, ex1 = 0.f, ex2 = 0.f, ex3 = 0.f;
      if (lane < cn) {
        s = colidx[base + c0 + lane];
        float4 av = *(const float4*)(alS + (size_t)s * 4);
        ex0 = __expf(leaky02(av.x + aldi[0]));
        ex1 = __expf(leaky02(av.y + aldi[1]));
        ex2 = __expf(leaky02(av.z + aldi[2]));
        ex3 = __expf(leaky02(av.w + aldi[3]));
        zl[0] += ex0; zl[1] += ex1; zl[2] += ex2; zl[3] += ex3;
      }
      // wave-local LDS stage (s=0 / e=0 for inactive lanes); wave64 lockstep,
      // no barrier needed — compiler orders via lgkmcnt.
      sL[wid][lane] = s;
      eL[wid][lane] = make_float4(ex0, ex1, ex2, ex3);
      for (int jj = 0; jj < cn; jj += 4) {
        int4 s4 = *(const int4*)&sL[wid][jj];          // 4 edge ids, broadcast
        int sj[4] = {s4.x, s4.y, s4.z, s4.w};
        float4 e0 = eL[wid][jj + 0];
        float4 e1 = eL[wid][jj + 1];
        float4 e2 = eL[wid][jj + 2];
        float4 e3 = eL[wid][jj + 3];
        float xg[4];
#pragma unroll
        for (int q = 0; q < 4; q++)
          xg[q] = fa ? bf2f(xb[(size_t)sj[q] * 64 + lane]) : 0.f;
        ag0 += e0.x * xg[0] + e1.x * xg[1] + e2.x * xg[2] + e3.x * xg[3];
        ag1 += e0.y * xg[0] + e1.y * xg[1] + e2.y * xg[2] + e3.y * xg[3];
        ag2 += e0.z * xg[0] + e1.z * xg[1] + e2.z * xg[2] + e3.z * xg[3];
        ag3 += e0.w * xg[0] + e1.w * xg[1] + e2.w * xg[2] + e3.w * xg[3];
#pragma unroll
        for (int q = 0; q < 4; q++)
          if (jj + q < cn) ax += xg[q];                // uniform guard
      }
    }
#pragma unroll
    for (int off = 32; off >= 1; off >>= 1)
#pragma unroll
      for (int h = 0; h < 4; h++) zl[h] += __shfl_xor(zl[h], off);
    if (fa) {
      float z0 = zl[0] + exs[0] + 1e-16f;
      float z1 = zl[1] + exs[1] + 1e-16f;
      float z2 = zl[2] + exs[2] + 1e-16f;
      float z3 = zl[3] + exs[3] + 1e-16f;
      short* ar = agg4 + (size_t)i * HF;
      ar[0 * FDIM + lane] = f2bf(ag0 / z0);
      ar[1 * FDIM + lane] = f2bf(ag1 / z1);
      ar[2 * FDIM + lane] = f2bf(ag2 / z2);
      ar[3 * FDIM + lane] = f2bf(ag3 / z3);
      agg[(size_t)i * FDIM + lane] = ax;
    }
  }
}

// ---------------------------------------------------------------------------
// GAT transform v2 (MFMA): per-head 53x53 GEMM on matrix cores.
// Block = 64 nodes, 4 waves x one 16-node m-tile. A staged head-padded
// (64 x [4][64] bf16, stride 264 shorts -> 2-way banks); B transposed
// (4 x 56 x 72). Per wave: 4 heads x {2 A-frags + 4 n-tiles x (2 B-frags +
// 2 mfma_f32_16x16x32_bf16)}. K pad (53..63) zeroed in A -> inert.
// Same batch-slot psum pooling epilogue.
// ---------------------------------------------------------------------------
#define AHS 264   /* Ah row stride in shorts: 132 words = 4 mod 32 -> 2-way */
#define BTS 72    /* Bt row stride in shorts: 36 words = 4 mod 32 -> 2-way */
__global__ __launch_bounds__(256) void k_gtrans(
    const short* __restrict__ agg4, const float* __restrict__ gat_w,
    const float* __restrict__ bias, const int* __restrict__ batch,
    float* __restrict__ pooled) {
  __shared__ short Ah[64 * AHS];        // 33.8 KB
  __shared__ short Bt[4 * 56 * BTS];    // 32.3 KB
  __shared__ float psum[4 * 224];       // 3.6 KB, col = h*56 + jn
  __shared__ int batL[64];
  int m0 = blockIdx.x * 64;
  int t = threadIdx.x;
  for (int idx = t; idx < 4 * 224; idx += 256) psum[idx] = 0.f;
  if (t < 64) batL[t] = (m0 + t < N_NODES) ? batch[m0 + t] : 0;
  for (int idx = t; idx < 64 * 256; idx += 256) {
    int node = idx >> 8, rem = idx & 255;
    int h = rem >> 6, k = rem & 63;
    int gm = m0 + node;
    short v = (k < FDIM && gm < N_NODES) ? agg4[(size_t)gm * HF + h * FDIM + k] : (short)0;
    Ah[node * AHS + h * 64 + k] = v;
  }
  for (int idx = t; idx < 4 * 56 * 64; idx += 256) {
    int h = idx / (56 * 64), rem = idx % (56 * 64);
    int n = rem >> 6, k = rem & 63;
    short v = (k < FDIM && n < FDIM) ? f2bf(gat_w[k * HF + h * FDIM + n]) : (short)0;
    Bt[(h * 56 + n) * BTS + k] = v;
  }
  __syncthreads();
  const int lane = t & 63, wid = t >> 6;
  const int n16 = lane & 15, quad = lane >> 4;
  const int mrow0 = wid * 16;
  const int bmin = batL[0];
#pragma unroll
  for (int h = 0; h < 4; h++) {
    short8 af0 = *(const short8*)&Ah[(mrow0 + n16) * AHS + h * 64 + quad * 8];
    short8 af1 = *(const short8*)&Ah[(mrow0 + n16) * AHS + h * 64 + 32 + quad * 8];
#pragma unroll
    for (int nt = 0; nt < 4; nt++) {
      short8 b0 = *(const short8*)&Bt[(h * 56 + nt * 16 + n16) * BTS + quad * 8];
      short8 b1 = *(const short8*)&Bt[(h * 56 + nt * 16 + n16) * BTS + 32 + quad * 8];
      f32x4 acc = {0.f, 0.f, 0.f, 0.f};
      acc = __builtin_amdgcn_mfma_f32_16x16x32_bf16(af0, b0, acc, 0, 0, 0);
      acc = __builtin_amdgcn_mfma_f32_16x16x32_bf16(af1, b1, acc, 0, 0, 0);
      int jn = nt * 16 + n16;
      bool jv = jn < FDIM;
      float bj = jv ? bias[h * FDIM + jn] : 0.f;
      // rows quad*4+r: accumulate over batch runs, flush on change
      float pj = 0.f; int curb = -1;
#pragma unroll
      for (int r = 0; r < 4; r++) {
        int lm = mrow0 + quad * 4 + r;
        int gm = m0 + lm;
        if (gm < N_NODES) {
          float o = fmaxf(acc[r] + bj, 0.f);
          int b = batL[lm];
          if (b != curb) {
            if (curb >= 0 && jv) {
              int slot = curb - bmin;
              if (slot >= 0 && slot < 4) atomicAdd(&psum[slot * 224 + h * 56 + jn], pj);
              else atomicAdd(&pooled[(size_t)curb * POOLW + h * FDIM + jn], pj);
            }
            curb = b; pj = o;
          } else {
            pj += o;
          }
        }
      }
      if (curb >= 0 && jv) {
        int slot = curb - bmin;
        if (slot >= 0 && slot < 4) atomicAdd(&psum[slot * 224 + h * 56 + jn], pj);
        else atomicAdd(&pooled[(size_t)curb * POOLW + h * FDIM + jn], pj);
      }
    }
  }
  __syncthreads();
  for (int idx = t; idx < 4 * 224; idx += 256) {
    int slot = idx / 224, c = idx % 224;
    int h = c / 56, jn = c % 56;
    float v = psum[idx];
    int b = bmin + slot;
    if (jn < FDIM && b < BATCH && v != 0.f)
      atomicAdd(&pooled[(size_t)b * POOLW + h * FDIM + jn], v);
  }
}

// ---------------------------------------------------------------------------
// Fused GIN MLP: h1 = relu(agg @ w1 + b1) kept in LDS; h2 = relu(h1 @ w2 + b2)
// + pooled accumulation. Eliminates the 21 MB h1g intermediate entirely.
// ---------------------------------------------------------------------------
#define A2PAD 111
__global__ __launch_bounds__(256) void k_gin(
    const float* __restrict__ agg,
    const float* __restrict__ w1, const float* __restrict__ b1,
    const float* __restrict__ w2, const float* __restrict__ b2,
    const int* __restrict__ batch, float* __restrict__ pooled) {
  __shared__ float B1[F2 * 112];       // phase A: As | Ws1; phase B: Ws2
  __shared__ float Hs[64 * A2PAD];
  __shared__ float psum[4 * 112];
  float* As = B1;                      // 64*APAD = 3648 floats
  float* Ws1 = B1 + 64 * APAD;         // 53*112 = 5936 floats (total 9584 < 11872)
  int m0 = blockIdx.x * 64;
  int t = threadIdx.x;
  for (int idx = t; idx < 4 * 112; idx += 256) psum[idx] = 0.f;
  for (int idx = t; idx < 64 * FDIM; idx += 256) {
    int m = idx / FDIM, k = idx % FDIM;
    int gm = m0 + m;
    As[m * APAD + k] = (gm < N_NODES) ? agg[(size_t)gm * FDIM + k] : 0.f;
  }
  for (int idx = t; idx < FDIM * 112; idx += 256) {
    int k = idx / 112, n = idx % 112;
    Ws1[idx] = (n < F2) ? w1[k * F2 + n] : 0.f;
  }
  __syncthreads();
  int tx = t & 15, ty = t >> 4;
  int ms = tx * 4, ns = ty * 7;
  // ---- phase A: h1 = relu(agg @ w1 + b1) -> Hs ----
  {
    float acc[4][7];
#pragma unroll
    for (int i = 0; i < 4; i++)
#pragma unroll
      for (int j = 0; j < 7; j++) acc[i][j] = 0.f;
    for (int k = 0; k < FDIM; k++) {
      float a0 = As[(ms + 0) * APAD + k];
      float a1 = As[(ms + 1) * APAD + k];
      float a2 = As[(ms + 2) * APAD + k];
      float a3 = As[(ms + 3) * APAD + k];
      float b[7];
#pragma unroll
      for (int j = 0; j < 7; j++) b[j] = Ws1[k * 112 + ns + j];
#pragma unroll
      for (int j = 0; j < 7; j++) {
        acc[0][j] += a0 * b[j];
        acc[1][j] += a1 * b[j];
        acc[2][j] += a2 * b[j];
        acc[3][j] += a3 * b[j];
      }
    }
#pragma unroll
    for (int i = 0; i < 4; i++) {
#pragma unroll
      for (int j = 0; j < 7; j++) {
        int n = ns + j;
        if (n < F2) Hs[(ms + i) * A2PAD + n] = fmaxf(acc[i][j] + b1[n], 0.f);
      }
    }
  }
  __syncthreads();   // all As/Ws1 reads done; Hs complete
  // ---- phase B: stage w2 over B1, then h2 = relu(Hs @ w2 + b2) + pool ----
  for (int idx = t; idx < F2 * 112; idx += 256) {
    int k = idx / 112, n = idx % 112;
    B1[idx] = (n < F2) ? w2[k * F2 + n] : 0.f;
  }
  __syncthreads();
  float acc[4][7];
#pragma unroll
  for (int i = 0; i < 4; i++)
#pragma unroll
    for (int j = 0; j < 7; j++) acc[i][j] = 0.f;
  for (int k = 0; k < F2; k++) {
    float a0 = Hs[(ms + 0) * A2PAD + k];
    float a1 = Hs[(ms + 1) * A2PAD + k];
    float a2 = Hs[(ms + 2) * A2PAD + k];
    float a3 = Hs[(ms + 3) * A2PAD + k];
    float b[7];
#pragma unroll
    for (int j = 0; j < 7; j++) b[j] = B1[k * 112 + ns + j];
#pragma unroll
    for (int j = 0; j < 7; j++) {
      acc[0][j] += a0 * b[j];
      acc[1][j] += a1 * b[j];
      acc[2][j] += a2 * b[j];
      acc[3][j] += a3 * b[j];
    }
  }
  float b2n[7];
#pragma unroll
  for (int j = 0; j < 7; j++) {
    int n = ns + j;
    b2n[j] = (n < F2) ? b2[n] : 0.f;
  }
  int bmin = batch[m0];
  float pj[7];
#pragma unroll
  for (int j = 0; j < 7; j++) pj[j] = 0.f;
  int curb = -1;
#pragma unroll
  for (int i = 0; i < 4; i++) {
    int gm = m0 + ms + i;
    if (gm >= N_NODES) break;
    int b = batch[gm];
    if (b != curb) {
      if (curb >= 0) {
        int slot = curb - bmin;
        if (slot >= 0 && slot < 4) {
#pragma unroll
          for (int j = 0; j < 7; j++)
            if (ns + j < F2) atomicAdd(&psum[slot * 112 + ns + j], pj[j]);
        } else {
          float* pg = pooled + (size_t)curb * POOLW + HF;
#pragma unroll
          for (int j = 0; j < 7; j++)
            if (ns + j < F2) atomicAdd(&pg[ns + j], pj[j]);
        }
      }
      curb = b;
#pragma unroll
      for (int j = 0; j < 7; j++)
        pj[j] = (ns + j < F2) ? fmaxf(acc[i][j] + b2n[j], 0.f) : 0.f;
    } else {
#pragma unroll
      for (int j = 0; j < 7; j++)
        if (ns + j < F2) pj[j] += fmaxf(acc[i][j] + b2n[j], 0.f);
    }
  }
  if (curb >= 0) {
    int slot = curb - bmin;
    if (slot >= 0 && slot < 4) {
#pragma unroll
      for (int j = 0; j < 7; j++)
        if (ns + j < F2) atomicAdd(&psum[slot * 112 + ns + j], pj[j]);
    } else {
      float* pg = pooled + (size_t)curb * POOLW + HF;
#pragma unroll
      for (int j = 0; j < 7; j++)
        if (ns + j < F2) atomicAdd(&pg[ns + j], pj[j]);
    }
  }
  __syncthreads();
  for (int idx = t; idx < 4 * 112; idx += 256) {
    int slot = idx / 112, n = idx % 112;
    float v = psum[idx];
    int b = bmin + slot;
    if (n < F2 && b < BATCH && v != 0.f)
      atomicAdd(&pooled[(size_t)b * POOLW + HF + n], v);
  }
}

// ---------------------------------------------------------------------------
// EdgeConv v8 (round-5 best): bf16 U/V, rp/batch in LDS, colidx prefetched
// 2 tiles ahead / V 1 tile ahead, deferred cross-quad max reduction,
// double-buffered LDS, lgkmcnt-only barrier.
// ---------------------------------------------------------------------------
#define ECH 25
__global__ __launch_bounds__(256) void k_ec(
    const short* __restrict__ Ub, const short* __restrict__ Vb,
    const float* __restrict__ w2, const float* __restrict__ b2,
    const int* __restrict__ rp, const int* __restrict__ colidx,
    const int* __restrict__ batch, float* __restrict__ pooled) {
  const int t = threadIdx.x;
  const int lane = t & 63, wid = t >> 6;
  const int n16 = lane & 15, quad = lane >> 4;
  const int nt = (wid == 3) ? 1 : 2;   // u-tile 7 is all-pad

  const int i0 = blockIdx.x * ECH;
  const int iend = min(i0 + ECH, N_NODES);
  const int nn = iend - i0;

  __shared__ int rpL[ECH + 1];
  __shared__ int batL[ECH];

  short8 Bh[2][4];
  for (int tt = 0; tt < 2; tt++) {
    int ucol = (wid * 2 + tt) * 16 + n16;
    for (int kc = 0; kc < 4; kc++) {
      short8 vh;
#pragma unroll
      for (int jv = 0; jv < 8; jv++) {
        int kk = kc * 32 + quad * 8 + jv;
        float w = (ucol < F2 && kk < F2) ? w2[kk * F2 + ucol] : 0.f;
        vh[jv] = f2bf(w);
      }
      Bh[tt][kc] = vh;
    }
  }
  float b2v[2];
#pragma unroll
  for (int tt = 0; tt < 2; tt++) {
    int u = (wid * 2 + tt) * 16 + n16;
    b2v[tt] = (u < F2) ? b2[u] : 0.f;
  }

  if (t <= nn) rpL[t] = rp[i0 + t];
  if (t < nn) batL[t] = batch[i0 + t];
  __syncthreads();

  __shared__ short hs[2][16 * 16 * 8];
  union SU { short8 s; unsigned u[4]; };
  const int es = t & 15, kg = t >> 4;
  const int k0 = kg * 8;

  float sm0 = 0.f, sm1 = 0.f;
  int curb = -1;
  const int u0 = (wid * 2) * 16 + n16;
  const int u1 = (wid * 2 + 1) * 16 + n16;

  // tile walk: (node, tile-in-node, base, deg) -> next
  auto advance = [&](int& ii, int& ttb, int& bb, int& dd) -> bool {
    ttb++;
    if (ttb * 16 < dd) return true;
    ttb = 0;
    for (ii = ii + 1; ii < iend; ii++) {
      bb = rpL[ii - i0]; dd = rpL[ii - i0 + 1] - bb;
      if (dd > 0) return true;
    }
    return false;
  };

  // current tile T
  int i = i0, tb = 0, base = 0, deg = 0;
  bool have = false;
  for (; i < iend; i++) {
    base = rpL[i - i0]; deg = rpL[i - i0 + 1] - base;
    if (deg > 0) { have = true; break; }
  }
  short8 pu8{}, pv8{};
  // tile T+1 coords + its colidx value (sc) already fetched
  int i1 = i, tb1 = 0, base1 = base, deg1 = deg;
  bool have1 = false;
  int sc = 0;
  if (have) {
    pu8 = *(const short8*)(Ub + (size_t)i * ECS + k0);
    int s0 = colidx[base + ((es < deg) ? es : 0)];
    pv8 = *(const short8*)(Vb + (size_t)s0 * ECS + k0);
    have1 = advance(i1, tb1, base1, deg1);
    if (have1) {
      int eg = tb1 * 16 + es;
      sc = colidx[base1 + ((eg < deg1) ? eg : 0)];
    }
  }

  float Uc[8];
  float vmax0 = -1e30f, vmax1 = -1e30f;
  int parity = 0;
  while (have) {
    if (tb == 0) {
#pragma unroll
      for (int j = 0; j < 8; j++) Uc[j] = bf2f(pu8[j]);
    }
    SU w;
#pragma unroll
    for (int p = 0; p < 4; p++) {
      bool kv = (k0 + 2 * p) < F2;
      float h0 = kv ? fmaxf(Uc[2 * p]     + bf2f(pv8[2 * p]),     0.f) : 0.f;
      float h1 = kv ? fmaxf(Uc[2 * p + 1] + bf2f(pv8[2 * p + 1]), 0.f) : 0.f;
      w.u[p] = pk2(h0, h1);
    }
    *(short8*)&hs[parity][(kg * 16 + es) * 8] = w.s;

    // prefetch: V (and U) for tile T+1 using sc fetched last iter; colidx for T+2
    int i2 = i1, tb2 = tb1, base2 = base1, deg2 = deg1;
    bool have2 = false;
    int scN = 0;
    if (have1) {
      if (tb1 == 0) pu8 = *(const short8*)(Ub + (size_t)i1 * ECS + k0);
      pv8 = *(const short8*)(Vb + (size_t)sc * ECS + k0);
      have2 = advance(i2, tb2, base2, deg2);
      if (have2) {
        int eg2 = tb2 * 16 + es;
        scN = colidx[base2 + ((eg2 < deg2) ? eg2 : 0)];
      }
    }

    ldsbar();
    f32x4 a0 = {0.f, 0.f, 0.f, 0.f}, a1 = {0.f, 0.f, 0.f, 0.f};
#pragma unroll
    for (int kc = 0; kc < 4; kc++) {
      short8 af = *(const short8*)&hs[parity][((kc * 4 + quad) * 16 + n16) * 8];
      a0 = __builtin_amdgcn_mfma_f32_16x16x32_bf16(af, Bh[0][kc], a0, 0, 0, 0);
      if (nt > 1)
        a1 = __builtin_amdgcn_mfma_f32_16x16x32_bf16(af, Bh[1][kc], a1, 0, 0, 0);
    }
#pragma unroll
    for (int r = 0; r < 4; r++) {
      int er = tb * 16 + quad * 4 + r;
      if (er < deg) { vmax0 = fmaxf(vmax0, a0[r]); vmax1 = fmaxf(vmax1, a1[r]); }
    }
    if (!have1 || i1 != i) {
      // node i finishes with this tile: cross-quad reduce deferred to here
      vmax0 = fmaxf(vmax0, __shfl_xor(vmax0, 16));
      vmax0 = fmaxf(vmax0, __shfl_xor(vmax0, 32));
      vmax1 = fmaxf(vmax1, __shfl_xor(vmax1, 16));
      vmax1 = fmaxf(vmax1, __shfl_xor(vmax1, 32));
      float o0 = fmaxf(vmax0 + b2v[0], 0.f);
      float o1 = fmaxf(vmax1 + b2v[1], 0.f);
      int b = batL[i - i0];
      if (b != curb) {
        if (curb >= 0 && quad == 0) {
          float* pg = pooled + (size_t)curb * POOLW + HF + F2;
          if (u0 < F2) atomicAdd(&pg[u0], sm0);
          if (nt > 1 && u1 < F2) atomicAdd(&pg[u1], sm1);
        }
        curb = b; sm0 = o0; sm1 = o1;
      } else {
        sm0 += o0; sm1 += o1;
      }
      vmax0 = -1e30f; vmax1 = -1e30f;
    }
    i = i1; tb = tb1; base = base1; deg = deg1; have = have1;
    i1 = i2; tb1 = tb2; base1 = base2; deg1 = deg2; have1 = have2;
    sc = scN;
    parity ^= 1;
  }
  if (curb >= 0 && quad == 0) {
    float* pg = pooled + (size_t)curb * POOLW + HF + F2;
    if (u0 < F2) atomicAdd(&pg[u0], sm0);
    if (nt > 1 && u1 < F2) atomicAdd(&pg[u1], sm1);
  }
}

// ---------------------------------------------------------------------------
// mean-pool divide (counts from sorted-batch boundaries)
// ---------------------------------------------------------------------------
__global__ void k_pooldiv(float* __restrict__ pooled, const int* __restrict__ start) {
  int t = blockIdx.x * blockDim.x + threadIdx.x;
  if (t >= BATCH * POOLW) return;
  int b = t / POOLW;
  float c = (float)(start[b + 1] - start[b]);
  pooled[t] /= fmaxf(c, 1.f);
}

// ---------------------------------------------------------------------------
// Per-graph heads + final MLP fused: block g computes the three 2-layer MLPs
// into cat[384] (LDS), then 384->128->64->1 sigmoid. No global cat buffer.
// ---------------------------------------------------------------------------
__global__ __launch_bounds__(256) void k_heads(
    const float* __restrict__ pooled,
    const float* __restrict__ fg1_w, const float* __restrict__ fg1_b,
    const float* __restrict__ fg2_w, const float* __restrict__ fg2_b,
    const float* __restrict__ fg3_w, const float* __restrict__ fg3_b,
    const float* __restrict__ fg4_w, const float* __restrict__ fg4_b,
    const float* __restrict__ fg5_w, const float* __restrict__ fg5_b,
    const float* __restrict__ fg6_w, const float* __restrict__ fg6_b,
    const float* __restrict__ fc1_w, const float* __restrict__ fc1_b,
    const float* __restrict__ fc2_w, const float* __restrict__ fc2_b,
    const float* __restrict__ out_w, const float* __restrict__ out_b,
    float* __restrict__ out) {
  int g = blockIdx.x, t = threadIdx.x;
  __shared__ float in[POOLW];
  __shared__ float mid[256];
  __shared__ float cat[384];
  __shared__ float h1[128];
  __shared__ float h2[64];
  for (int idx = t; idx < POOLW; idx += 256) in[idx] = pooled[(size_t)g * POOLW + idx];
  __syncthreads();
  const float* w1s[3] = {fg1_w, fg3_w, fg5_w};
  const float* b1s[3] = {fg1_b, fg3_b, fg5_b};
  const float* w2s[3] = {fg2_w, fg4_w, fg6_w};
  const float* b2s[3] = {fg2_b, fg4_b, fg6_b};
  const int off[4] = {0, HF, HF + F2, POOLW};
  for (int br = 0; br < 3; br++) {
    int kin = off[br + 1] - off[br];
    const float* iv = &in[off[br]];
    float a = b1s[br][t];
    const float* W = w1s[br];
    for (int k = 0; k < kin; k++) a += iv[k] * W[k * 256 + t];
    mid[t] = fmaxf(a, 0.f);
    __syncthreads();
    if (t < 128) {
      float b = b2s[br][t];
      const float* W2 = w2s[br];
      for (int k = 0; k < 256; k++) b += mid[k] * W2[k * 128 + t];
      cat[br * 128 + t] = fmaxf(b, 0.f);
    }
    __syncthreads();
  }
  if (t < 128) {
    float a = fc1_b[t];
    for (int k = 0; k < 384; k++) a += cat[k] * fc1_w[k * 128 + t];
    h1[t] = fmaxf(a, 0.f);
  }
  __syncthreads();
  if (t < 64) {
    float a = fc2_b[t];
    for (int k = 0; k < 128; k++) a += h1[k] * fc2_w[k * 64 + t];
    h2[t] = fmaxf(a, 0.f);
  }
  __syncthreads();
  if (t == 0) {
    float a = out_b[0];
    for (int k = 0; k < 64; k++) a += h2[k] * out_w[k];
    out[g] = 1.f / (1.f + __expf(-a));
  }
}

// ---------------------------------------------------------------------------
extern "C" void kernel_launch(void* const* d_in, const int* in_sizes, int n_in,
                              void* d_out, int out_size, void* d_ws, size_t ws_size,
                              hipStream_t stream) {
  const float* x      = (const float*)d_in[0];
  const int*   ei     = (const int*)d_in[1];
  const int*   batch  = (const int*)d_in[2];
  const float* gat_w  = (const float*)d_in[3];
  const float* asrc   = (const float*)d_in[4];
  const float* adst   = (const float*)d_in[5];
  const float* gat_b  = (const float*)d_in[6];
  const float* gin_w1 = (const float*)d_in[7];
  const float* gin_b1 = (const float*)d_in[8];
  const float* gin_w2 = (const float*)d_in[9];
  const float* gin_b2 = (const float*)d_in[10];
  const float* ec_w1  = (const float*)d_in[11];
  const float* ec_b1  = (const float*)d_in[12];
  const float* ec_w2  = (const float*)d_in[13];
  const float* ec_b2  = (const float*)d_in[14];
  const float* fg1_w = (const float*)d_in[15]; const float* fg1_b = (const float*)d_in[16];
  const float* fg2_w = (const float*)d_in[17]; const float* fg2_b = (const float*)d_in[18];
  const float* fg3_w = (const float*)d_in[19]; const float* fg3_b = (const float*)d_in[20];
  const float* fg4_w = (const float*)d_in[21]; const float* fg4_b = (const float*)d_in[22];
  const float* fg5_w = (const float*)d_in[23]; const float* fg5_b = (const float*)d_in[24];
  const float* fg6_w = (const float*)d_in[25]; const float* fg6_b = (const float*)d_in[26];
  const float* fc1_w = (const float*)d_in[27]; const float* fc1_b = (const float*)d_in[28];
  const float* fc2_w = (const float*)d_in[29]; const float* fc2_b = (const float*)d_in[30];
  const float* out_w = (const float*)d_in[31]; const float* out_b = (const float*)d_in[32];
  float* out = (float*)d_out;

  char* ws = (char*)d_ws;
  size_t off = 0;
  auto alloc = [&](size_t bytes) -> void* {
    void* p = ws + off;
    off = (off + bytes + 255) & ~(size_t)255;
    return p;
  };
  // --- zero region (one memset): histP | pooled ---
  size_t zoff0 = off;
  int*   histP  = (int*)alloc((size_t)N_NODES * PSTR * sizeof(int));  // 6.4 MB padded bins
  float* pooled = (float*)alloc((size_t)BATCH * POOLW * sizeof(float));
  size_t zbytes = off - zoff0;
  // --- rest ---
  int*   rp     = (int*)alloc((N_NODES + 1) * sizeof(int));
  int*   start  = (int*)alloc((BATCH + 1) * sizeof(int));
  int*   bsum   = (int*)alloc(256 * sizeof(int));
  int*   colidx = (int*)alloc(N_EDGES * sizeof(int));
  short* xb     = (short*)alloc((size_t)N_NODES * 64 * sizeof(short));   // bf16 x rows, 128 B
  float* alS    = (float*)alloc((size_t)N_NODES * 4 * sizeof(float));
  float* alD    = (float*)alloc((size_t)N_NODES * 4 * sizeof(float));
  short* Ubuf   = (short*)alloc((size_t)N_NODES * ECS * sizeof(short));  // bf16, 256B rows
  short* Vbuf   = (short*)alloc((size_t)N_NODES * ECS * sizeof(short));  // bf16, 256B rows
  short* agg4   = (short*)alloc((size_t)N_NODES * HF * sizeof(short));   // GAT agg (bf16)
  float* agg    = (float*)alloc((size_t)N_NODES * FDIM * sizeof(float)); // GIN aggregate
  float* Wp     = (float*)alloc((size_t)FDIM * NPK2 * sizeof(float));
  float* bpk    = (float*)alloc(NPK2 * sizeof(float));
  (void)ws_size; (void)in_sizes; (void)n_in; (void)out_size;

  hipMemsetAsync(ws + zoff0, 0, zbytes, stream);

  k_prep<<<(FDIM * NPK2 + 255) / 256, 256, 0, stream>>>(ec_w1, ec_b1, gat_w, asrc, adst,
                                                        Wp, bpk);
  k_gemm<<<((N_NODES + GM - 1) / GM) * 2, 256, 0, stream>>>(x, Wp, bpk,
                                                            xb, Ubuf, Vbuf, alS, alD);
  k_hist<<<(N_EDGES + 255) / 256, 256, 0, stream>>>(ei, histP);
  k_scan1<<<SCAN_BLOCKS, 256, 0, stream>>>(histP, batch, rp, bsum, start);
  k_scan2<<<1, 256, 0, stream>>>(bsum);
  k_scan3<<<SCAN_BLOCKS, 256, 0, stream>>>(bsum, rp, histP);
  k_scatter<<<(N_EDGES + 255) / 256, 256, 0, stream>>>(ei, histP, colidx);

  // fused GAT-aggregate + GIN-sum over one L2-resident bf16 x table
  k_gatgin<<<(N_NODES + GCH - 1) / GCH, 256, 0, stream>>>(xb, alS, alD, rp, colidx,
                                                          agg4, agg);
  k_ec<<<(N_NODES + ECH - 1) / ECH, 256, 0, stream>>>(Ubuf, Vbuf, ec_w2, ec_b2, rp, colidx, batch, pooled);
  // GAT per-head transform + relu + pool (MFMA)
  k_gtrans<<<(N_NODES + 63) / 64, 256, 0, stream>>>(agg4, gat_w, gat_b, batch, pooled);
  // fused GIN MLP (h1 in LDS, no h1g intermediate)
  k_gin<<<(N_NODES + 63) / 64, 256, 0, stream>>>(agg, gin_w1, gin_b1, gin_w2, gin_b2,
                                                 batch, pooled);

  k_pooldiv<<<(BATCH * POOLW + 255) / 256, 256, 0, stream>>>(pooled, start);

  k_heads<<<BATCH, 256, 0, stream>>>(pooled, fg1_w, fg1_b, fg2_w, fg2_b, fg3_w, fg3_b,
                                     fg4_w, fg4_b, fg5_w, fg5_b, fg6_w, fg6_b,
                                     fc1_w, fc1_b, fc2_w, fc2_b, out_w, out_b, out);
}

// Round 13
// 701.278 us; speedup vs baseline: 1.0751x; 1.0057x over previous
//
#include <hip/hip_runtime.h>
#include <hip/hip_bf16.h>
#include <math.h>

#define N_NODES 50000
#define N_EDGES 800000
#define FDIM 53
#define BATCH 128
#define HF 212   /* H*F */
#define F2 106   /* 2F  */
#define POOLW 424 /* 212+106+106 */
#define NPK2 220 /* 106 + 106 + 8: U | V | alS | alD */
#define PSTR 32  /* padded bin stride (ints) = 128 B: one L2 line per node */
#define ECS 128  /* U/V bf16 row stride (shorts) = 256 B = 4 L2 lines */

typedef __attribute__((ext_vector_type(8))) short short8;
typedef __attribute__((ext_vector_type(4))) float f32x4;

__device__ __forceinline__ float leaky02(float x){ return x >= 0.f ? x : 0.2f * x; }

__device__ __forceinline__ short f2bf(float x) {
  unsigned u = __float_as_uint(x);
  unsigned r = (u + 0x7fffu + ((u >> 16) & 1u)) >> 16;
  return (short)r;
}
__device__ __forceinline__ float bf2f(short b) {
  return __uint_as_float(((unsigned)(unsigned short)b) << 16);
}
// packed pair f32x2 -> bf16x2 (v_cvt_pk_bf16_f32, RNE)
__device__ __forceinline__ unsigned pk2(float a, float b) {
  union { __hip_bfloat162 h; unsigned u; } c;
  c.h = __float22bfloat162_rn(make_float2(a, b));
  return c.u;
}
// LDS-only barrier: waits lgkmcnt(0) (ds ops) but leaves global loads in flight
__device__ __forceinline__ void ldsbar() {
  __builtin_amdgcn_s_waitcnt(0xC07F);   // vmcnt(63) expcnt(7) lgkmcnt(0)
  __builtin_amdgcn_s_barrier();
}

// ---------------------------------------------------------------------------
// Pack Wp[53][220] = [W1top-W1bot | W1bot | cAl] and bias bp[220].
// cAl columns (j >= 2*F2) compute their own 53-MAC dot (k_cal folded in).
// ---------------------------------------------------------------------------
__global__ void k_prep(const float* __restrict__ ec_w1, const float* __restrict__ ec_b1,
                       const float* __restrict__ gat_w, const float* __restrict__ asrc,
                       const float* __restrict__ adst,
                       float* __restrict__ Wp, float* __restrict__ bp) {
  int idx = blockIdx.x * blockDim.x + threadIdx.x;
  if (idx < FDIM * NPK2) {
    int k = idx / NPK2, j = idx % NPK2;
    float v;
    if (j < F2)            v = ec_w1[k * F2 + j] - ec_w1[(FDIM + k) * F2 + j];
    else if (j < 2 * F2)   v = ec_w1[(FDIM + k) * F2 + (j - F2)];
    else {
      int r = j - 2 * F2;              // 0..7 = sd*4 + h
      int sd = r >> 2, h = r & 3;
      const float* av = sd ? adst : asrc;
      float acc = 0.f;
      for (int f = 0; f < FDIM; ++f)
        acc += gat_w[k * HF + h * FDIM + f] * av[h * FDIM + f];
      v = acc;
    }
    Wp[idx] = v;
  }
  if (idx < NPK2) {
    bp[idx] = (idx < F2) ? ec_b1[idx] : 0.f;
  }
}

// ---------------------------------------------------------------------------
// Node-linear GEMM: x[50000x53] @ Wp[53x220] + bp -> U | V | alS | alD.
// Also emits xb (bf16 x rows, 64-short stride) during A-tile staging.
// ---------------------------------------------------------------------------
#define GM 64
#define GN 110
#define GNP 112
#define APAD 57
__global__ __launch_bounds__(256) void k_gemm(
    const float* __restrict__ x, const float* __restrict__ Wp, const float* __restrict__ bp,
    short* __restrict__ xb, short* __restrict__ Ub, short* __restrict__ Vb,
    float* __restrict__ alS, float* __restrict__ alD) {
  __shared__ float As[GM * APAD];
  __shared__ float Ws[FDIM * GNP];
  int mb = blockIdx.x >> 1, nc = blockIdx.x & 1;
  int m0 = mb * GM, n0 = nc * GN;
  int t = threadIdx.x;
  for (int idx = t; idx < GM * FDIM; idx += 256) {
    int m = idx / FDIM, k = idx % FDIM;
    int gm = m0 + m;
    float v = (gm < N_NODES) ? x[(size_t)gm * FDIM + k] : 0.f;
    As[m * APAD + k] = v;
    if (nc == 0 && gm < N_NODES) xb[(size_t)gm * 64 + k] = f2bf(v);
  }
  for (int idx = t; idx < FDIM * GNP; idx += 256) {
    int k = idx / GNP, n = idx % GNP;
    Ws[idx] = (n < GN) ? Wp[k * NPK2 + n0 + n] : 0.f;
  }
  __syncthreads();
  int tx = t & 15, ty = t >> 4;
  int ms = tx * 4, ns = ty * 7;
  float acc[4][7];
#pragma unroll
  for (int i = 0; i < 4; i++)
#pragma unroll
    for (int j = 0; j < 7; j++) acc[i][j] = 0.f;
  for (int k = 0; k < FDIM; k++) {
    float a0 = As[(ms + 0) * APAD + k];
    float a1 = As[(ms + 1) * APAD + k];
    float a2 = As[(ms + 2) * APAD + k];
    float a3 = As[(ms + 3) * APAD + k];
    float b[7];
#pragma unroll
    for (int j = 0; j < 7; j++) b[j] = Ws[k * GNP + ns + j];
#pragma unroll
    for (int j = 0; j < 7; j++) {
      acc[0][j] += a0 * b[j];
      acc[1][j] += a1 * b[j];
      acc[2][j] += a2 * b[j];
      acc[3][j] += a3 * b[j];
    }
  }
  float bj[7];
#pragma unroll
  for (int j = 0; j < 7; j++) {
    int g = n0 + ns + j;
    bj[j] = (g < NPK2) ? bp[g] : 0.f;
  }
#pragma unroll
  for (int i = 0; i < 4; i++) {
    int gm = m0 + ms + i;
    if (gm >= N_NODES) break;
#pragma unroll
    for (int j = 0; j < 7; j++) {
      int g = n0 + ns + j;
      float v = acc[i][j] + bj[j];
      if (g < F2)             Ub[(size_t)gm * ECS + g] = f2bf(v);
      else if (g < 2 * F2)    Vb[(size_t)gm * ECS + (g - F2)] = f2bf(v);
      else if (g < 2 * F2 + 4) alS[gm * 4 + (g - 2 * F2)] = v;
      else if (g < NPK2)      alD[gm * 4 + (g - 2 * F2 - 4)] = v;
    }
  }
}

// ---------------------------------------------------------------------------
// CSR build with L2-line-padded bins: hist -> scan (compacts to rp, turns
// padded slot into scatter cursor) -> scatter. Graph counts via sorted-batch
// boundary detection (fused into scan1). scan2 folded into scan3 (each block
// redundantly prefix-scans the 196-entry bsum in LDS; bsum stays read-only).
// ---------------------------------------------------------------------------
#define SCAN_BLOCKS ((N_NODES + 255) / 256)

__global__ void k_hist(const int* __restrict__ ei, int* __restrict__ histP) {
  int t = blockIdx.x * blockDim.x + threadIdx.x;
  if (t < N_EDGES) atomicAdd(&histP[ei[N_EDGES + t] << 5], 1);
}

__global__ __launch_bounds__(256) void k_scan1(const int* __restrict__ histP,
                                               const int* __restrict__ batch,
                                               int* __restrict__ rp, int* __restrict__ bsum,
                                               int* __restrict__ start) {
  __shared__ int buf[256];
  int tid = threadIdx.x;
  int idx = blockIdx.x * 256 + tid;
  int v = (idx < N_NODES) ? histP[idx << 5] : 0;
  buf[tid] = v;
  __syncthreads();
  for (int off = 1; off < 256; off <<= 1) {
    int t2 = (tid >= off) ? buf[tid - off] : 0;
    __syncthreads();
    buf[tid] += t2;
    __syncthreads();
  }
  if (idx < N_NODES) rp[idx] = buf[tid] - v;
  if (tid == 255) bsum[blockIdx.x] = buf[255];
  // fused batch-boundary detection (was k_bnd)
  if (idx < N_NODES) {
    int b = batch[idx];
    if (idx == 0)
      for (int g = 0; g <= b; g++) start[g] = 0;
    int bn = (idx + 1 < N_NODES) ? batch[idx + 1] : BATCH;
    for (int g = b + 1; g <= bn; g++) start[g] = idx + 1;
  }
}

__global__ __launch_bounds__(256) void k_scan3(const int* __restrict__ bsum,
                                               int* __restrict__ rp, int* __restrict__ histP) {
  __shared__ int buf[256];
  int tid = threadIdx.x;
  int v = (tid < SCAN_BLOCKS) ? bsum[tid] : 0;
  buf[tid] = v;
  __syncthreads();
  for (int off = 1; off < 256; off <<= 1) {
    int t2 = (tid >= off) ? buf[tid - off] : 0;
    __syncthreads();
    buf[tid] += t2;
    __syncthreads();
  }
  int boff = (blockIdx.x == 0) ? 0 : buf[blockIdx.x - 1];   // exclusive offset
  int idx = blockIdx.x * 256 + tid;
  if (idx < N_NODES) {
    int o = rp[idx] + boff;
    rp[idx] = o;
    histP[idx << 5] = o;   // becomes the (padded) scatter cursor
  }
  if (idx == 0) rp[N_NODES] = N_EDGES;
}

__global__ void k_scatter(const int* __restrict__ ei, int* __restrict__ histP,
                          int* __restrict__ colidx) {
  int e = blockIdx.x * blockDim.x + threadIdx.x;
  if (e >= N_EDGES) return;
  int d = ei[N_EDGES + e];
  int pos = atomicAdd(&histP[d << 5], 1);
  colidx[pos] = ei[e];
}

// ---------------------------------------------------------------------------
// Fused GAT-aggregate + GIN-sum: one edge walk gathering bf16 x rows (128 B
// line each). Per-edge (s, alpha) distributed via wave-local LDS staging
// (broadcast reads) instead of 20 ds_bpermute shuffles per 4-edge group.
// ---------------------------------------------------------------------------
#define GCH 20
__global__ __launch_bounds__(256) void k_gatgin(
    const short* __restrict__ xb, const float* __restrict__ alS, const float* __restrict__ alD,
    const int* __restrict__ rp, const int* __restrict__ colidx,
    short* __restrict__ agg4, float* __restrict__ agg) {
  int wid = threadIdx.x >> 6, lane = threadIdx.x & 63;
  bool fa = lane < FDIM;
  int i0 = blockIdx.x * GCH;
  int iend = min(i0 + GCH, N_NODES);
  __shared__ int rpG[GCH + 1];
  __shared__ int sL[4][64];        // per-wave edge src ids
  __shared__ float4 eL[4][64];     // per-wave edge alphas (4 heads)
  {
    int t = threadIdx.x, nn = iend - i0;
    if (t <= nn) rpG[t] = rp[i0 + t];
  }
  __syncthreads();
  for (int i = i0 + wid; i < iend; i += 4) {
    int base = rpG[i - i0], deg = rpG[i - i0 + 1] - base;
    float4 adv = *(const float4*)(alD + (size_t)i * 4);
    float4 asv = *(const float4*)(alS + (size_t)i * 4);
    float aldi[4] = {adv.x, adv.y, adv.z, adv.w};
    float exs[4];
    exs[0] = __expf(leaky02(asv.x + aldi[0]));   // self-loop term
    exs[1] = __expf(leaky02(asv.y + aldi[1]));
    exs[2] = __expf(leaky02(asv.z + aldi[2]));
    exs[3] = __expf(leaky02(asv.w + aldi[3]));
    float xiv = fa ? bf2f(xb[(size_t)i * 64 + lane]) : 0.f;
    float ag0 = exs[0] * xiv, ag1 = exs[1] * xiv, ag2 = exs[2] * xiv, ag3 = exs[3] * xiv;
    float ax = xiv;
    float zl[4] = {0.f, 0.f, 0.f, 0.f};

    for (int c0 = 0; c0 < deg; c0 += 64) {
      int cn = min(64, deg - c0);
      int s = 0;
      float ex0 = 0.f, ex1 = 0.f, ex2 = 0.f, ex3 = 0.f;
      if (lane < cn) {
        s = colidx[base + c0 + lane];
        float4 av = *(const float4*)(alS + (size_t)s * 4);
        ex0 = __expf(leaky02(av.x + aldi[0]));
        ex1 = __expf(leaky02(av.y + aldi[1]));
        ex2 = __expf(leaky02(av.z + aldi[2]));
        ex3 = __expf(leaky02(av.w + aldi[3]));
        zl[0] += ex0; zl[1] += ex1; zl[2] += ex2; zl[3] += ex3;
      }
      // wave-local LDS stage (s=0 / e=0 for inactive lanes); wave64 lockstep,
      // no barrier needed — compiler orders via lgkmcnt.
      sL[wid][lane] = s;
      eL[wid][lane] = make_float4(ex0, ex1, ex2, ex3);
      for (int jj = 0; jj < cn; jj += 4) {
        int4 s4 = *(const int4*)&sL[wid][jj];          // 4 edge ids, broadcast
        int sj[4] = {s4.x, s4.y, s4.z, s4.w};
        float4 e0 = eL[wid][jj + 0];
        float4 e1 = eL[wid][jj + 1];
        float4 e2 = eL[wid][jj + 2];
        float4 e3 = eL[wid][jj + 3];
        float xg[4];
#pragma unroll
        for (int q = 0; q < 4; q++)
          xg[q] = fa ? bf2f(xb[(size_t)sj[q] * 64 + lane]) : 0.f;
        ag0 += e0.x * xg[0] + e1.x * xg[1] + e2.x * xg[2] + e3.x * xg[3];
        ag1 += e0.y * xg[0] + e1.y * xg[1] + e2.y * xg[2] + e3.y * xg[3];
        ag2 += e0.z * xg[0] + e1.z * xg[1] + e2.z * xg[2] + e3.z * xg[3];
        ag3 += e0.w * xg[0] + e1.w * xg[1] + e2.w * xg[2] + e3.w * xg[3];
#pragma unroll
        for (int q = 0; q < 4; q++)
          if (jj + q < cn) ax += xg[q];                // uniform guard
      }
    }
#pragma unroll
    for (int off = 32; off >= 1; off >>= 1)
#pragma unroll
      for (int h = 0; h < 4; h++) zl[h] += __shfl_xor(zl[h], off);
    if (fa) {
      float z0 = zl[0] + exs[0] + 1e-16f;
      float z1 = zl[1] + exs[1] + 1e-16f;
      float z2 = zl[2] + exs[2] + 1e-16f;
      float z3 = zl[3] + exs[3] + 1e-16f;
      short* ar = agg4 + (size_t)i * HF;
      ar[0 * FDIM + lane] = f2bf(ag0 / z0);
      ar[1 * FDIM + lane] = f2bf(ag1 / z1);
      ar[2 * FDIM + lane] = f2bf(ag2 / z2);
      ar[3 * FDIM + lane] = f2bf(ag3 / z3);
      agg[(size_t)i * FDIM + lane] = ax;
    }
  }
}

// ---------------------------------------------------------------------------
// Fused post-aggregation: phase 1 = GAT per-head 53x53 transform on MFMA
// (round-12 k_gtrans), phase 2 = GIN 2-layer MLP with h1 in LDS (round-12
// k_gin). One 64-node block, shared LDS arena; psum flushed between phases.
// ---------------------------------------------------------------------------
#define AHS 264   /* Ah row stride in shorts: 2-way banks only */
#define BTS 72    /* Bt row stride in shorts */
#define A2PAD 111
#define SMBYTES 75904   /* max(p1 = 66048, p2 = 75904) */
__global__ __launch_bounds__(256) void k_post(
    const short* __restrict__ agg4, const float* __restrict__ gat_w,
    const float* __restrict__ gat_b,
    const float* __restrict__ agg,
    const float* __restrict__ w1, const float* __restrict__ b1,
    const float* __restrict__ w2, const float* __restrict__ b2,
    const int* __restrict__ batch, float* __restrict__ pooled) {
  __shared__ __align__(16) char smraw[SMBYTES];
  __shared__ float psum[4 * 224];
  __shared__ int batL[64];
  int m0 = blockIdx.x * 64;
  int t = threadIdx.x;
  const int lane = t & 63, wid = t >> 6;
  const int n16 = lane & 15, quad = lane >> 4;

  // ======================= phase 1: GAT transform =======================
  {
    short* Ah = (short*)smraw;                                 // 64 x AHS
    short* Bt = (short*)(smraw + (size_t)64 * AHS * 2);        // 4*56 x BTS
    for (int idx = t; idx < 4 * 224; idx += 256) psum[idx] = 0.f;
    if (t < 64) batL[t] = (m0 + t < N_NODES) ? batch[m0 + t] : 0;
    for (int idx = t; idx < 64 * 256; idx += 256) {
      int node = idx >> 8, rem = idx & 255;
      int h = rem >> 6, k = rem & 63;
      int gm = m0 + node;
      short v = (k < FDIM && gm < N_NODES) ? agg4[(size_t)gm * HF + h * FDIM + k] : (short)0;
      Ah[node * AHS + h * 64 + k] = v;
    }
    for (int idx = t; idx < 4 * 56 * 64; idx += 256) {
      int h = idx / (56 * 64), rem = idx % (56 * 64);
      int n = rem >> 6, k = rem & 63;
      short v = (k < FDIM && n < FDIM) ? f2bf(gat_w[k * HF + h * FDIM + n]) : (short)0;
      Bt[(h * 56 + n) * BTS + k] = v;
    }
    __syncthreads();
    const int mrow0 = wid * 16;
    const int bmin = batL[0];
#pragma unroll
    for (int h = 0; h < 4; h++) {
      short8 af0 = *(const short8*)&Ah[(mrow0 + n16) * AHS + h * 64 + quad * 8];
      short8 af1 = *(const short8*)&Ah[(mrow0 + n16) * AHS + h * 64 + 32 + quad * 8];
#pragma unroll
      for (int nt = 0; nt < 4; nt++) {
        short8 b0 = *(const short8*)&Bt[(h * 56 + nt * 16 + n16) * BTS + quad * 8];
        short8 b1 = *(const short8*)&Bt[(h * 56 + nt * 16 + n16) * BTS + 32 + quad * 8];
        f32x4 acc = {0.f, 0.f, 0.f, 0.f};
        acc = __builtin_amdgcn_mfma_f32_16x16x32_bf16(af0, b0, acc, 0, 0, 0);
        acc = __builtin_amdgcn_mfma_f32_16x16x32_bf16(af1, b1, acc, 0, 0, 0);
        int jn = nt * 16 + n16;
        bool jv = jn < FDIM;
        float bj = jv ? gat_b[h * FDIM + jn] : 0.f;
        float pj = 0.f; int curb = -1;
#pragma unroll
        for (int r = 0; r < 4; r++) {
          int lm = mrow0 + quad * 4 + r;
          int gm = m0 + lm;
          if (gm < N_NODES) {
            float o = fmaxf(acc[r] + bj, 0.f);
            int b = batL[lm];
            if (b != curb) {
              if (curb >= 0 && jv) {
                int slot = curb - bmin;
                if (slot >= 0 && slot < 4) atomicAdd(&psum[slot * 224 + h * 56 + jn], pj);
                else atomicAdd(&pooled[(size_t)curb * POOLW + h * FDIM + jn], pj);
              }
              curb = b; pj = o;
            } else {
              pj += o;
            }
          }
        }
        if (curb >= 0 && jv) {
          int slot = curb - bmin;
          if (slot >= 0 && slot < 4) atomicAdd(&psum[slot * 224 + h * 56 + jn], pj);
          else atomicAdd(&pooled[(size_t)curb * POOLW + h * FDIM + jn], pj);
        }
      }
    }
    __syncthreads();
    for (int idx = t; idx < 4 * 224; idx += 256) {
      int slot = idx / 224, c = idx % 224;
      int h = c / 56, jn = c % 56;
      float v = psum[idx];
      int b = bmin + slot;
      if (jn < FDIM && b < BATCH && v != 0.f)
        atomicAdd(&pooled[(size_t)b * POOLW + h * FDIM + jn], v);
    }
    __syncthreads();   // psum reads done; LDS arena free for phase 2
  }

  // ======================= phase 2: GIN MLP =======================
  {
    float* B1 = (float*)smraw;                    // phase A: As|Ws1; phase B: Ws2
    float* Hs = (float*)(smraw + (size_t)F2 * 112 * 4);
    float* As = B1;
    float* Ws1 = B1 + 64 * APAD;
    for (int idx = t; idx < 4 * 112; idx += 256) psum[idx] = 0.f;
    for (int idx = t; idx < 64 * FDIM; idx += 256) {
      int m = idx / FDIM, k = idx % FDIM;
      int gm = m0 + m;
      As[m * APAD + k] = (gm < N_NODES) ? agg[(size_t)gm * FDIM + k] : 0.f;
    }
    for (int idx = t; idx < FDIM * 112; idx += 256) {
      int k = idx / 112, n = idx % 112;
      Ws1[idx] = (n < F2) ? w1[k * F2 + n] : 0.f;
    }
    __syncthreads();
    int tx = t & 15, ty = t >> 4;
    int ms = tx * 4, ns = ty * 7;
    // ---- h1 = relu(agg @ w1 + b1) -> Hs ----
    {
      float acc[4][7];
#pragma unroll
      for (int i = 0; i < 4; i++)
#pragma unroll
        for (int j = 0; j < 7; j++) acc[i][j] = 0.f;
      for (int k = 0; k < FDIM; k++) {
        float a0 = As[(ms + 0) * APAD + k];
        float a1 = As[(ms + 1) * APAD + k];
        float a2 = As[(ms + 2) * APAD + k];
        float a3 = As[(ms + 3) * APAD + k];
        float b[7];
#pragma unroll
        for (int j = 0; j < 7; j++) b[j] = Ws1[k * 112 + ns + j];
#pragma unroll
        for (int j = 0; j < 7; j++) {
          acc[0][j] += a0 * b[j];
          acc[1][j] += a1 * b[j];
          acc[2][j] += a2 * b[j];
          acc[3][j] += a3 * b[j];
        }
      }
#pragma unroll
      for (int i = 0; i < 4; i++) {
#pragma unroll
        for (int j = 0; j < 7; j++) {
          int n = ns + j;
          if (n < F2) Hs[(ms + i) * A2PAD + n] = fmaxf(acc[i][j] + b1[n], 0.f);
        }
      }
    }
    __syncthreads();
    // ---- stage w2 over B1, then h2 = relu(Hs @ w2 + b2) + pool ----
    for (int idx = t; idx < F2 * 112; idx += 256) {
      int k = idx / 112, n = idx % 112;
      B1[idx] = (n < F2) ? w2[k * F2 + n] : 0.f;
    }
    __syncthreads();
    float acc[4][7];
#pragma unroll
    for (int i = 0; i < 4; i++)
#pragma unroll
      for (int j = 0; j < 7; j++) acc[i][j] = 0.f;
    for (int k = 0; k < F2; k++) {
      float a0 = Hs[(ms + 0) * A2PAD + k];
      float a1 = Hs[(ms + 1) * A2PAD + k];
      float a2 = Hs[(ms + 2) * A2PAD + k];
      float a3 = Hs[(ms + 3) * A2PAD + k];
      float b[7];
#pragma unroll
      for (int j = 0; j < 7; j++) b[j] = B1[k * 112 + ns + j];
#pragma unroll
      for (int j = 0; j < 7; j++) {
        acc[0][j] += a0 * b[j];
        acc[1][j] += a1 * b[j];
        acc[2][j] += a2 * b[j];
        acc[3][j] += a3 * b[j];
      }
    }
    float b2n[7];
#pragma unroll
    for (int j = 0; j < 7; j++) {
      int n = ns + j;
      b2n[j] = (n < F2) ? b2[n] : 0.f;
    }
    int bmin = batL[0];
    float pj[7];
#pragma unroll
    for (int j = 0; j < 7; j++) pj[j] = 0.f;
    int curb = -1;
#pragma unroll
    for (int i = 0; i < 4; i++) {
      int gm = m0 + ms + i;
      if (gm >= N_NODES) break;
      int b = batL[ms + i];
      if (b != curb) {
        if (curb >= 0) {
          int slot = curb - bmin;
          if (slot >= 0 && slot < 4) {
#pragma unroll
            for (int j = 0; j < 7; j++)
              if (ns + j < F2) atomicAdd(&psum[slot * 112 + ns + j], pj[j]);
          } else {
            float* pg = pooled + (size_t)curb * POOLW + HF;
#pragma unroll
            for (int j = 0; j < 7; j++)
              if (ns + j < F2) atomicAdd(&pg[ns + j], pj[j]);
          }
        }
        curb = b;
#pragma unroll
        for (int j = 0; j < 7; j++)
          pj[j] = (ns + j < F2) ? fmaxf(acc[i][j] + b2n[j], 0.f) : 0.f;
      } else {
#pragma unroll
        for (int j = 0; j < 7; j++)
          if (ns + j < F2) pj[j] += fmaxf(acc[i][j] + b2n[j], 0.f);
      }
    }
    if (curb >= 0) {
      int slot = curb - bmin;
      if (slot >= 0 && slot < 4) {
#pragma unroll
        for (int j = 0; j < 7; j++)
          if (ns + j < F2) atomicAdd(&psum[slot * 112 + ns + j], pj[j]);
      } else {
        float* pg = pooled + (size_t)curb * POOLW + HF;
#pragma unroll
        for (int j = 0; j < 7; j++)
          if (ns + j < F2) atomicAdd(&pg[ns + j], pj[j]);
      }
    }
    __syncthreads();
    for (int idx = t; idx < 4 * 112; idx += 256) {
      int slot = idx / 112, n = idx % 112;
      float v = psum[idx];
      int b = bmin + slot;
      if (n < F2 && b < BATCH && v != 0.f)
        atomicAdd(&pooled[(size_t)b * POOLW + HF + n], v);
    }
  }
}

// ---------------------------------------------------------------------------
// EdgeConv v8 (round-5 best): bf16 U/V, rp/batch in LDS, colidx prefetched
// 2 tiles ahead / V 1 tile ahead, deferred cross-quad max reduction,
// double-buffered LDS, lgkmcnt-only barrier.
// ---------------------------------------------------------------------------
#define ECH 25
__global__ __launch_bounds__(256) void k_ec(
    const short* __restrict__ Ub, const short* __restrict__ Vb,
    const float* __restrict__ w2, const float* __restrict__ b2,
    const int* __restrict__ rp, const int* __restrict__ colidx,
    const int* __restrict__ batch, float* __restrict__ pooled) {
  const int t = threadIdx.x;
  const int lane = t & 63, wid = t >> 6;
  const int n16 = lane & 15, quad = lane >> 4;
  const int nt = (wid == 3) ? 1 : 2;   // u-tile 7 is all-pad

  const int i0 = blockIdx.x * ECH;
  const int iend = min(i0 + ECH, N_NODES);
  const int nn = iend - i0;

  __shared__ int rpL[ECH + 1];
  __shared__ int batL[ECH];

  short8 Bh[2][4];
  for (int tt = 0; tt < 2; tt++) {
    int ucol = (wid * 2 + tt) * 16 + n16;
    for (int kc = 0; kc < 4; kc++) {
      short8 vh;
#pragma unroll
      for (int jv = 0; jv < 8; jv++) {
        int kk = kc * 32 + quad * 8 + jv;
        float w = (ucol < F2 && kk < F2) ? w2[kk * F2 + ucol] : 0.f;
        vh[jv] = f2bf(w);
      }
      Bh[tt][kc] = vh;
    }
  }
  float b2v[2];
#pragma unroll
  for (int tt = 0; tt < 2; tt++) {
    int u = (wid * 2 + tt) * 16 + n16;
    b2v[tt] = (u < F2) ? b2[u] : 0.f;
  }

  if (t <= nn) rpL[t] = rp[i0 + t];
  if (t < nn) batL[t] = batch[i0 + t];
  __syncthreads();

  __shared__ short hs[2][16 * 16 * 8];
  union SU { short8 s; unsigned u[4]; };
  const int es = t & 15, kg = t >> 4;
  const int k0 = kg * 8;

  float sm0 = 0.f, sm1 = 0.f;
  int curb = -1;
  const int u0 = (wid * 2) * 16 + n16;
  const int u1 = (wid * 2 + 1) * 16 + n16;

  // tile walk: (node, tile-in-node, base, deg) -> next
  auto advance = [&](int& ii, int& ttb, int& bb, int& dd) -> bool {
    ttb++;
    if (ttb * 16 < dd) return true;
    ttb = 0;
    for (ii = ii + 1; ii < iend; ii++) {
      bb = rpL[ii - i0]; dd = rpL[ii - i0 + 1] - bb;
      if (dd > 0) return true;
    }
    return false;
  };

  // current tile T
  int i = i0, tb = 0, base = 0, deg = 0;
  bool have = false;
  for (; i < iend; i++) {
    base = rpL[i - i0]; deg = rpL[i - i0 + 1] - base;
    if (deg > 0) { have = true; break; }
  }
  short8 pu8{}, pv8{};
  // tile T+1 coords + its colidx value (sc) already fetched
  int i1 = i, tb1 = 0, base1 = base, deg1 = deg;
  bool have1 = false;
  int sc = 0;
  if (have) {
    pu8 = *(const short8*)(Ub + (size_t)i * ECS + k0);
    int s0 = colidx[base + ((es < deg) ? es : 0)];
    pv8 = *(const short8*)(Vb + (size_t)s0 * ECS + k0);
    have1 = advance(i1, tb1, base1, deg1);
    if (have1) {
      int eg = tb1 * 16 + es;
      sc = colidx[base1 + ((eg < deg1) ? eg : 0)];
    }
  }

  float Uc[8];
  float vmax0 = -1e30f, vmax1 = -1e30f;
  int parity = 0;
  while (have) {
    if (tb == 0) {
#pragma unroll
      for (int j = 0; j < 8; j++) Uc[j] = bf2f(pu8[j]);
    }
    SU w;
#pragma unroll
    for (int p = 0; p < 4; p++) {
      bool kv = (k0 + 2 * p) < F2;
      float h0 = kv ? fmaxf(Uc[2 * p]     + bf2f(pv8[2 * p]),     0.f) : 0.f;
      float h1 = kv ? fmaxf(Uc[2 * p + 1] + bf2f(pv8[2 * p + 1]), 0.f) : 0.f;
      w.u[p] = pk2(h0, h1);
    }
    *(short8*)&hs[parity][(kg * 16 + es) * 8] = w.s;

    // prefetch: V (and U) for tile T+1 using sc fetched last iter; colidx for T+2
    int i2 = i1, tb2 = tb1, base2 = base1, deg2 = deg1;
    bool have2 = false;
    int scN = 0;
    if (have1) {
      if (tb1 == 0) pu8 = *(const short8*)(Ub + (size_t)i1 * ECS + k0);
      pv8 = *(const short8*)(Vb + (size_t)sc * ECS + k0);
      have2 = advance(i2, tb2, base2, deg2);
      if (have2) {
        int eg2 = tb2 * 16 + es;
        scN = colidx[base2 + ((eg2 < deg2) ? eg2 : 0)];
      }
    }

    ldsbar();
    f32x4 a0 = {0.f, 0.f, 0.f, 0.f}, a1 = {0.f, 0.f, 0.f, 0.f};
#pragma unroll
    for (int kc = 0; kc < 4; kc++) {
      short8 af = *(const short8*)&hs[parity][((kc * 4 + quad) * 16 + n16) * 8];
      a0 = __builtin_amdgcn_mfma_f32_16x16x32_bf16(af, Bh[0][kc], a0, 0, 0, 0);
      if (nt > 1)
        a1 = __builtin_amdgcn_mfma_f32_16x16x32_bf16(af, Bh[1][kc], a1, 0, 0, 0);
    }
#pragma unroll
    for (int r = 0; r < 4; r++) {
      int er = tb * 16 + quad * 4 + r;
      if (er < deg) { vmax0 = fmaxf(vmax0, a0[r]); vmax1 = fmaxf(vmax1, a1[r]); }
    }
    if (!have1 || i1 != i) {
      // node i finishes with this tile: cross-quad reduce deferred to here
      vmax0 = fmaxf(vmax0, __shfl_xor(vmax0, 16));
      vmax0 = fmaxf(vmax0, __shfl_xor(vmax0, 32));
      vmax1 = fmaxf(vmax1, __shfl_xor(vmax1, 16));
      vmax1 = fmaxf(vmax1, __shfl_xor(vmax1, 32));
      float o0 = fmaxf(vmax0 + b2v[0], 0.f);
      float o1 = fmaxf(vmax1 + b2v[1], 0.f);
      int b = batL[i - i0];
      if (b != curb) {
        if (curb >= 0 && quad == 0) {
          float* pg = pooled + (size_t)curb * POOLW + HF + F2;
          if (u0 < F2) atomicAdd(&pg[u0], sm0);
          if (nt > 1 && u1 < F2) atomicAdd(&pg[u1], sm1);
        }
        curb = b; sm0 = o0; sm1 = o1;
      } else {
        sm0 += o0; sm1 += o1;
      }
      vmax0 = -1e30f; vmax1 = -1e30f;
    }
    i = i1; tb = tb1; base = base1; deg = deg1; have = have1;
    i1 = i2; tb1 = tb2; base1 = base2; deg1 = deg2; have1 = have2;
    sc = scN;
    parity ^= 1;
  }
  if (curb >= 0 && quad == 0) {
    float* pg = pooled + (size_t)curb * POOLW + HF + F2;
    if (u0 < F2) atomicAdd(&pg[u0], sm0);
    if (nt > 1 && u1 < F2) atomicAdd(&pg[u1], sm1);
  }
}

// ---------------------------------------------------------------------------
// Per-graph heads + final MLP fused; mean-pool divide folded into the load.
// ---------------------------------------------------------------------------
__global__ __launch_bounds__(256) void k_heads(
    const float* __restrict__ pooled, const int* __restrict__ start,
    const float* __restrict__ fg1_w, const float* __restrict__ fg1_b,
    const float* __restrict__ fg2_w, const float* __restrict__ fg2_b,
    const float* __restrict__ fg3_w, const float* __restrict__ fg3_b,
    const float* __restrict__ fg4_w, const float* __restrict__ fg4_b,
    const float* __restrict__ fg5_w, const float* __restrict__ fg5_b,
    const float* __restrict__ fg6_w, const float* __restrict__ fg6_b,
    const float* __restrict__ fc1_w, const float* __restrict__ fc1_b,
    const float* __restrict__ fc2_w, const float* __restrict__ fc2_b,
    const float* __restrict__ out_w, const float* __restrict__ out_b,
    float* __restrict__ out) {
  int g = blockIdx.x, t = threadIdx.x;
  __shared__ float in[POOLW];
  __shared__ float mid[256];
  __shared__ float cat[384];
  __shared__ float h1[128];
  __shared__ float h2[64];
  float c = fmaxf((float)(start[g + 1] - start[g]), 1.f);
  for (int idx = t; idx < POOLW; idx += 256)
    in[idx] = pooled[(size_t)g * POOLW + idx] / c;
  __syncthreads();
  const float* w1s[3] = {fg1_w, fg3_w, fg5_w};
  const float* b1s[3] = {fg1_b, fg3_b, fg5_b};
  const float* w2s[3] = {fg2_w, fg4_w, fg6_w};
  const float* b2s[3] = {fg2_b, fg4_b, fg6_b};
  const int off[4] = {0, HF, HF + F2, POOLW};
  for (int br = 0; br < 3; br++) {
    int kin = off[br + 1] - off[br];
    const float* iv = &in[off[br]];
    float a = b1s[br][t];
    const float* W = w1s[br];
    for (int k = 0; k < kin; k++) a += iv[k] * W[k * 256 + t];
    mid[t] = fmaxf(a, 0.f);
    __syncthreads();
    if (t < 128) {
      float b = b2s[br][t];
      const float* W2 = w2s[br];
      for (int k = 0; k < 256; k++) b += mid[k] * W2[k * 128 + t];
      cat[br * 128 + t] = fmaxf(b, 0.f);
    }
    __syncthreads();
  }
  if (t < 128) {
    float a = fc1_b[t];
    for (int k = 0; k < 384; k++) a += cat[k] * fc1_w[k * 128 + t];
    h1[t] = fmaxf(a, 0.f);
  }
  __syncthreads();
  if (t < 64) {
    float a = fc2_b[t];
    for (int k = 0; k < 128; k++) a += h1[k] * fc2_w[k * 64 + t];
    h2[t] = fmaxf(a, 0.f);
  }
  __syncthreads();
  if (t == 0) {
    float a = out_b[0];
    for (int k = 0; k < 64; k++) a += h2[k] * out_w[k];
    out[g] = 1.f / (1.f + __expf(-a));
  }
}

// ---------------------------------------------------------------------------
extern "C" void kernel_launch(void* const* d_in, const int* in_sizes, int n_in,
                              void* d_out, int out_size, void* d_ws, size_t ws_size,
                              hipStream_t stream) {
  const float* x      = (const float*)d_in[0];
  const int*   ei     = (const int*)d_in[1];
  const int*   batch  = (const int*)d_in[2];
  const float* gat_w  = (const float*)d_in[3];
  const float* asrc   = (const float*)d_in[4];
  const float* adst   = (const float*)d_in[5];
  const float* gat_b  = (const float*)d_in[6];
  const float* gin_w1 = (const float*)d_in[7];
  const float* gin_b1 = (const float*)d_in[8];
  const float* gin_w2 = (const float*)d_in[9];
  const float* gin_b2 = (const float*)d_in[10];
  const float* ec_w1  = (const float*)d_in[11];
  const float* ec_b1  = (const float*)d_in[12];
  const float* ec_w2  = (const float*)d_in[13];
  const float* ec_b2  = (const float*)d_in[14];
  const float* fg1_w = (const float*)d_in[15]; const float* fg1_b = (const float*)d_in[16];
  const float* fg2_w = (const float*)d_in[17]; const float* fg2_b = (const float*)d_in[18];
  const float* fg3_w = (const float*)d_in[19]; const float* fg3_b = (const float*)d_in[20];
  const float* fg4_w = (const float*)d_in[21]; const float* fg4_b = (const float*)d_in[22];
  const float* fg5_w = (const float*)d_in[23]; const float* fg5_b = (const float*)d_in[24];
  const float* fg6_w = (const float*)d_in[25]; const float* fg6_b = (const float*)d_in[26];
  const float* fc1_w = (const float*)d_in[27]; const float* fc1_b = (const float*)d_in[28];
  const float* fc2_w = (const float*)d_in[29]; const float* fc2_b = (const float*)d_in[30];
  const float* out_w = (const float*)d_in[31]; const float* out_b = (const float*)d_in[32];
  float* out = (float*)d_out;

  char* ws = (char*)d_ws;
  size_t off = 0;
  auto alloc = [&](size_t bytes) -> void* {
    void* p = ws + off;
    off = (off + bytes + 255) & ~(size_t)255;
    return p;
  };
  // --- zero region (one memset): histP | pooled ---
  size_t zoff0 = off;
  int*   histP  = (int*)alloc((size_t)N_NODES * PSTR * sizeof(int));  // 6.4 MB padded bins
  float* pooled = (float*)alloc((size_t)BATCH * POOLW * sizeof(float));
  size_t zbytes = off - zoff0;
  // --- rest ---
  int*   rp     = (int*)alloc((N_NODES + 1) * sizeof(int));
  int*   start  = (int*)alloc((BATCH + 1) * sizeof(int));
  int*   bsum   = (int*)alloc(256 * sizeof(int));
  int*   colidx = (int*)alloc(N_EDGES * sizeof(int));
  short* xb     = (short*)alloc((size_t)N_NODES * 64 * sizeof(short));   // bf16 x rows, 128 B
  float* alS    = (float*)alloc((size_t)N_NODES * 4 * sizeof(float));
  float* alD    = (float*)alloc((size_t)N_NODES * 4 * sizeof(float));
  short* Ubuf   = (short*)alloc((size_t)N_NODES * ECS * sizeof(short));  // bf16, 256B rows
  short* Vbuf   = (short*)alloc((size_t)N_NODES * ECS * sizeof(short));  // bf16, 256B rows
  short* agg4   = (short*)alloc((size_t)N_NODES * HF * sizeof(short));   // GAT agg (bf16)
  float* agg    = (float*)alloc((size_t)N_NODES * FDIM * sizeof(float)); // GIN aggregate
  float* Wp     = (float*)alloc((size_t)FDIM * NPK2 * sizeof(float));
  float* bpk    = (float*)alloc(NPK2 * sizeof(float));
  (void)ws_size; (void)in_sizes; (void)n_in; (void)out_size;

  hipMemsetAsync(ws + zoff0, 0, zbytes, stream);

  k_prep<<<(FDIM * NPK2 + 255) / 256, 256, 0, stream>>>(ec_w1, ec_b1, gat_w, asrc, adst,
                                                        Wp, bpk);
  k_gemm<<<((N_NODES + GM - 1) / GM) * 2, 256, 0, stream>>>(x, Wp, bpk,
                                                            xb, Ubuf, Vbuf, alS, alD);
  k_hist<<<(N_EDGES + 255) / 256, 256, 0, stream>>>(ei, histP);
  k_scan1<<<SCAN_BLOCKS, 256, 0, stream>>>(histP, batch, rp, bsum, start);
  k_scan3<<<SCAN_BLOCKS, 256, 0, stream>>>(bsum, rp, histP);
  k_scatter<<<(N_EDGES + 255) / 256, 256, 0, stream>>>(ei, histP, colidx);

  // fused GAT-aggregate + GIN-sum over one L2-resident bf16 x table
  k_gatgin<<<(N_NODES + GCH - 1) / GCH, 256, 0, stream>>>(xb, alS, alD, rp, colidx,
                                                          agg4, agg);
  k_ec<<<(N_NODES + ECH - 1) / ECH, 256, 0, stream>>>(Ubuf, Vbuf, ec_w2, ec_b2, rp, colidx, batch, pooled);
  // fused GAT transform (MFMA) + GIN MLP
  k_post<<<(N_NODES + 63) / 64, 256, 0, stream>>>(agg4, gat_w, gat_b, agg,
                                                  gin_w1, gin_b1, gin_w2, gin_b2,
                                                  batch, pooled);

  k_heads<<<BATCH, 256, 0, stream>>>(pooled, start,
                                     fg1_w, fg1_b, fg2_w, fg2_b, fg3_w, fg3_b,
                                     fg4_w, fg4_b, fg5_w, fg5_b, fg6_w, fg6_b,
                                     fc1_w, fc1_b, fc2_w, fc2_b, out_w, out_b, out);
}

// Round 15
// 648.987 us; speedup vs baseline: 1.1618x; 1.0806x over previous
//
#include <hip/hip_runtime.h>
#include <hip/hip_bf16.h>
#include <math.h>

#define N_NODES 50000
#define N_EDGES 800000
#define FDIM 53
#define BATCH 128
#define HF 212   /* H*F */
#define F2 106   /* 2F  */
#define POOLW 424 /* 212+106+106 */
#define NPK2 220 /* 106 + 106 + 8: U | V | alS | alD */
#define PSTR 32  /* padded bin stride (ints) = 128 B: one L2 line per node */
#define ECS 128  /* U/V bf16 row stride (shorts) = 256 B = 4 L2 lines */
#define A4P 256  /* agg4 padded row stride (shorts): [node][4][64], 16B aligned */

typedef __attribute__((ext_vector_type(8))) short short8;
typedef __attribute__((ext_vector_type(4))) float f32x4;

__device__ __forceinline__ float leaky02(float x){ return x >= 0.f ? x : 0.2f * x; }

__device__ __forceinline__ short f2bf(float x) {
  unsigned u = __float_as_uint(x);
  unsigned r = (u + 0x7fffu + ((u >> 16) & 1u)) >> 16;
  return (short)r;
}
__device__ __forceinline__ float bf2f(short b) {
  return __uint_as_float(((unsigned)(unsigned short)b) << 16);
}
// packed pair f32x2 -> bf16x2 (v_cvt_pk_bf16_f32, RNE)
__device__ __forceinline__ unsigned pk2(float a, float b) {
  union { __hip_bfloat162 h; unsigned u; } c;
  c.h = __float22bfloat162_rn(make_float2(a, b));
  return c.u;
}
// LDS-only barrier: waits lgkmcnt(0) (ds ops) but leaves global loads in flight
__device__ __forceinline__ void ldsbar() {
  __builtin_amdgcn_s_waitcnt(0xC07F);   // vmcnt(63) expcnt(7) lgkmcnt(0)
  __builtin_amdgcn_s_barrier();
}

// ---------------------------------------------------------------------------
// Pack Wp[53][220] = [W1top-W1bot | W1bot | cAl] and bias bp[220].
// cAl columns (j >= 2*F2) compute their own 53-MAC dot (k_cal folded in).
// ---------------------------------------------------------------------------
__global__ void k_prep(const float* __restrict__ ec_w1, const float* __restrict__ ec_b1,
                       const float* __restrict__ gat_w, const float* __restrict__ asrc,
                       const float* __restrict__ adst,
                       float* __restrict__ Wp, float* __restrict__ bp) {
  int idx = blockIdx.x * blockDim.x + threadIdx.x;
  if (idx < FDIM * NPK2) {
    int k = idx / NPK2, j = idx % NPK2;
    float v;
    if (j < F2)            v = ec_w1[k * F2 + j] - ec_w1[(FDIM + k) * F2 + j];
    else if (j < 2 * F2)   v = ec_w1[(FDIM + k) * F2 + (j - F2)];
    else {
      int r = j - 2 * F2;              // 0..7 = sd*4 + h
      int sd = r >> 2, h = r & 3;
      const float* av = sd ? adst : asrc;
      float acc = 0.f;
      for (int f = 0; f < FDIM; ++f)
        acc += gat_w[k * HF + h * FDIM + f] * av[h * FDIM + f];
      v = acc;
    }
    Wp[idx] = v;
  }
  if (idx < NPK2) {
    bp[idx] = (idx < F2) ? ec_b1[idx] : 0.f;
  }
}

// ---------------------------------------------------------------------------
// Node-linear GEMM: x[50000x53] @ Wp[53x220] + bp -> U | V | alS | alD.
// Also emits xb (bf16 x rows, 64-short stride) during A-tile staging.
// ---------------------------------------------------------------------------
#define GM 64
#define GN 110
#define GNP 112
#define APAD 57
__global__ __launch_bounds__(256) void k_gemm(
    const float* __restrict__ x, const float* __restrict__ Wp, const float* __restrict__ bp,
    short* __restrict__ xb, short* __restrict__ Ub, short* __restrict__ Vb,
    float* __restrict__ alS, float* __restrict__ alD) {
  __shared__ float As[GM * APAD];
  __shared__ float Ws[FDIM * GNP];
  int mb = blockIdx.x >> 1, nc = blockIdx.x & 1;
  int m0 = mb * GM, n0 = nc * GN;
  int t = threadIdx.x;
  for (int idx = t; idx < GM * FDIM; idx += 256) {
    int m = idx / FDIM, k = idx % FDIM;
    int gm = m0 + m;
    float v = (gm < N_NODES) ? x[(size_t)gm * FDIM + k] : 0.f;
    As[m * APAD + k] = v;
    if (nc == 0 && gm < N_NODES) xb[(size_t)gm * 64 + k] = f2bf(v);
  }
  for (int idx = t; idx < FDIM * GNP; idx += 256) {
    int k = idx / GNP, n = idx % GNP;
    Ws[idx] = (n < GN) ? Wp[k * NPK2 + n0 + n] : 0.f;
  }
  __syncthreads();
  int tx = t & 15, ty = t >> 4;
  int ms = tx * 4, ns = ty * 7;
  float acc[4][7];
#pragma unroll
  for (int i = 0; i < 4; i++)
#pragma unroll
    for (int j = 0; j < 7; j++) acc[i][j] = 0.f;
  for (int k = 0; k < FDIM; k++) {
    float a0 = As[(ms + 0) * APAD + k];
    float a1 = As[(ms + 1) * APAD + k];
    float a2 = As[(ms + 2) * APAD + k];
    float a3 = As[(ms + 3) * APAD + k];
    float b[7];
#pragma unroll
    for (int j = 0; j < 7; j++) b[j] = Ws[k * GNP + ns + j];
#pragma unroll
    for (int j = 0; j < 7; j++) {
      acc[0][j] += a0 * b[j];
      acc[1][j] += a1 * b[j];
      acc[2][j] += a2 * b[j];
      acc[3][j] += a3 * b[j];
    }
  }
  float bj[7];
#pragma unroll
  for (int j = 0; j < 7; j++) {
    int g = n0 + ns + j;
    bj[j] = (g < NPK2) ? bp[g] : 0.f;
  }
#pragma unroll
  for (int i = 0; i < 4; i++) {
    int gm = m0 + ms + i;
    if (gm >= N_NODES) break;
#pragma unroll
    for (int j = 0; j < 7; j++) {
      int g = n0 + ns + j;
      float v = acc[i][j] + bj[j];
      if (g < F2)             Ub[(size_t)gm * ECS + g] = f2bf(v);
      else if (g < 2 * F2)    Vb[(size_t)gm * ECS + (g - F2)] = f2bf(v);
      else if (g < 2 * F2 + 4) alS[gm * 4 + (g - 2 * F2)] = v;
      else if (g < NPK2)      alD[gm * 4 + (g - 2 * F2 - 4)] = v;
    }
  }
}

// ---------------------------------------------------------------------------
// CSR build: hist -> scan1 (block scan + batch boundaries) -> scan3 (folds
// the bsum prefix scan) -> scatter.
// ---------------------------------------------------------------------------
#define SCAN_BLOCKS ((N_NODES + 255) / 256)

__global__ void k_hist(const int* __restrict__ ei, int* __restrict__ histP) {
  int t = blockIdx.x * blockDim.x + threadIdx.x;
  if (t < N_EDGES) atomicAdd(&histP[ei[N_EDGES + t] << 5], 1);
}

__global__ __launch_bounds__(256) void k_scan1(const int* __restrict__ histP,
                                               const int* __restrict__ batch,
                                               int* __restrict__ rp, int* __restrict__ bsum,
                                               int* __restrict__ start) {
  __shared__ int buf[256];
  int tid = threadIdx.x;
  int idx = blockIdx.x * 256 + tid;
  int v = (idx < N_NODES) ? histP[idx << 5] : 0;
  buf[tid] = v;
  __syncthreads();
  for (int off = 1; off < 256; off <<= 1) {
    int t2 = (tid >= off) ? buf[tid - off] : 0;
    __syncthreads();
    buf[tid] += t2;
    __syncthreads();
  }
  if (idx < N_NODES) rp[idx] = buf[tid] - v;
  if (tid == 255) bsum[blockIdx.x] = buf[255];
  // fused batch-boundary detection (was k_bnd)
  if (idx < N_NODES) {
    int b = batch[idx];
    if (idx == 0)
      for (int g = 0; g <= b; g++) start[g] = 0;
    int bn = (idx + 1 < N_NODES) ? batch[idx + 1] : BATCH;
    for (int g = b + 1; g <= bn; g++) start[g] = idx + 1;
  }
}

__global__ __launch_bounds__(256) void k_scan3(const int* __restrict__ bsum,
                                               int* __restrict__ rp, int* __restrict__ histP) {
  __shared__ int buf[256];
  int tid = threadIdx.x;
  int v = (tid < SCAN_BLOCKS) ? bsum[tid] : 0;
  buf[tid] = v;
  __syncthreads();
  for (int off = 1; off < 256; off <<= 1) {
    int t2 = (tid >= off) ? buf[tid - off] : 0;
    __syncthreads();
    buf[tid] += t2;
    __syncthreads();
  }
  int boff = (blockIdx.x == 0) ? 0 : buf[blockIdx.x - 1];   // exclusive offset
  int idx = blockIdx.x * 256 + tid;
  if (idx < N_NODES) {
    int o = rp[idx] + boff;
    rp[idx] = o;
    histP[idx << 5] = o;   // becomes the (padded) scatter cursor
  }
  if (idx == 0) rp[N_NODES] = N_EDGES;
}

__global__ void k_scatter(const int* __restrict__ ei, int* __restrict__ histP,
                          int* __restrict__ colidx) {
  int e = blockIdx.x * blockDim.x + threadIdx.x;
  if (e >= N_EDGES) return;
  int d = ei[N_EDGES + e];
  int pos = atomicAdd(&histP[d << 5], 1);
  colidx[pos] = ei[e];
}

// ---------------------------------------------------------------------------
// Fused GAT-aggregate + GIN-sum. agg4 written in padded [node][4][64] bf16
// layout (zeros in k=53..63) so k_gt can load MFMA A-frags straight from
// global (16B aligned).
// ---------------------------------------------------------------------------
#define GCH 20
__global__ __launch_bounds__(256) void k_gatgin(
    const short* __restrict__ xb, const float* __restrict__ alS, const float* __restrict__ alD,
    const int* __restrict__ rp, const int* __restrict__ colidx,
    short* __restrict__ agg4, float* __restrict__ agg) {
  int wid = threadIdx.x >> 6, lane = threadIdx.x & 63;
  bool fa = lane < FDIM;
  int i0 = blockIdx.x * GCH;
  int iend = min(i0 + GCH, N_NODES);
  __shared__ int rpG[GCH + 1];
  __shared__ int sL[4][64];        // per-wave edge src ids
  __shared__ float4 eL[4][64];     // per-wave edge alphas (4 heads)
  {
    int t = threadIdx.x, nn = iend - i0;
    if (t <= nn) rpG[t] = rp[i0 + t];
  }
  __syncthreads();
  for (int i = i0 + wid; i < iend; i += 4) {
    int base = rpG[i - i0], deg = rpG[i - i0 + 1] - base;
    float4 adv = *(const float4*)(alD + (size_t)i * 4);
    float4 asv = *(const float4*)(alS + (size_t)i * 4);
    float aldi[4] = {adv.x, adv.y, adv.z, adv.w};
    float exs[4];
    exs[0] = __expf(leaky02(asv.x + aldi[0]));   // self-loop term
    exs[1] = __expf(leaky02(asv.y + aldi[1]));
    exs[2] = __expf(leaky02(asv.z + aldi[2]));
    exs[3] = __expf(leaky02(asv.w + aldi[3]));
    float xiv = fa ? bf2f(xb[(size_t)i * 64 + lane]) : 0.f;
    float ag0 = exs[0] * xiv, ag1 = exs[1] * xiv, ag2 = exs[2] * xiv, ag3 = exs[3] * xiv;
    float ax = xiv;
    float zl[4] = {0.f, 0.f, 0.f, 0.f};

    for (int c0 = 0; c0 < deg; c0 += 64) {
      int cn = min(64, deg - c0);
      int s = 0;
      float ex0 = 0.f, ex1 = 0.f, ex2 = 0.f, ex3 = 0.f;
      if (lane < cn) {
        s = colidx[base + c0 + lane];
        float4 av = *(const float4*)(alS + (size_t)s * 4);
        ex0 = __expf(leaky02(av.x + aldi[0]));
        ex1 = __expf(leaky02(av.y + aldi[1]));
        ex2 = __expf(leaky02(av.z + aldi[2]));
        ex3 = __expf(leaky02(av.w + aldi[3]));
        zl[0] += ex0; zl[1] += ex1; zl[2] += ex2; zl[3] += ex3;
      }
      // wave-local LDS stage; wave64 lockstep, no barrier needed.
      sL[wid][lane] = s;
      eL[wid][lane] = make_float4(ex0, ex1, ex2, ex3);
      for (int jj = 0; jj < cn; jj += 4) {
        int4 s4 = *(const int4*)&sL[wid][jj];          // 4 edge ids, broadcast
        int sj[4] = {s4.x, s4.y, s4.z, s4.w};
        float4 e0 = eL[wid][jj + 0];
        float4 e1 = eL[wid][jj + 1];
        float4 e2 = eL[wid][jj + 2];
        float4 e3 = eL[wid][jj + 3];
        float xg[4];
#pragma unroll
        for (int q = 0; q < 4; q++)
          xg[q] = fa ? bf2f(xb[(size_t)sj[q] * 64 + lane]) : 0.f;
        ag0 += e0.x * xg[0] + e1.x * xg[1] + e2.x * xg[2] + e3.x * xg[3];
        ag1 += e0.y * xg[0] + e1.y * xg[1] + e2.y * xg[2] + e3.y * xg[3];
        ag2 += e0.z * xg[0] + e1.z * xg[1] + e2.z * xg[2] + e3.z * xg[3];
        ag3 += e0.w * xg[0] + e1.w * xg[1] + e2.w * xg[2] + e3.w * xg[3];
#pragma unroll
        for (int q = 0; q < 4; q++)
          if (jj + q < cn) ax += xg[q];                // uniform guard
      }
    }
#pragma unroll
    for (int off = 32; off >= 1; off >>= 1)
#pragma unroll
      for (int h = 0; h < 4; h++) zl[h] += __shfl_xor(zl[h], off);
    {
      float z0 = zl[0] + exs[0] + 1e-16f;
      float z1 = zl[1] + exs[1] + 1e-16f;
      float z2 = zl[2] + exs[2] + 1e-16f;
      float z3 = zl[3] + exs[3] + 1e-16f;
      short* ar = agg4 + (size_t)i * A4P;
      ar[0 * 64 + lane] = fa ? f2bf(ag0 / z0) : (short)0;
      ar[1 * 64 + lane] = fa ? f2bf(ag1 / z1) : (short)0;
      ar[2 * 64 + lane] = fa ? f2bf(ag2 / z2) : (short)0;
      ar[3 * 64 + lane] = fa ? f2bf(ag3 / z3) : (short)0;
      if (fa) agg[(size_t)i * FDIM + lane] = ax;
    }
  }
}

// ---------------------------------------------------------------------------
// GAT transform v3 (MFMA, light): A-frags loaded directly from padded agg4
// in global (no LDS A staging). LDS = Bt (32.2KB) + psum -> 4 blocks/CU.
// Uniform-batch fast path: quad-reduce via 2 shuffles, one LDS atomic per
// column; slow path = run-flush (boundary blocks only, ~13%).
// ---------------------------------------------------------------------------
#define BTS 72    /* Bt row stride in shorts */
__global__ __launch_bounds__(256) void k_gt(
    const short* __restrict__ agg4, const float* __restrict__ gat_w,
    const float* __restrict__ gat_b, const int* __restrict__ batch,
    float* __restrict__ pooled) {
  __shared__ short Bt[4 * 56 * BTS];    // 32.2 KB
  __shared__ float psum[4 * 224];
  __shared__ int batL[64];
  int m0 = blockIdx.x * 64;
  int t = threadIdx.x;
  for (int idx = t; idx < 4 * 224; idx += 256) psum[idx] = 0.f;
  if (t < 64) batL[t] = batch[min(m0 + t, N_NODES - 1)];
  for (int idx = t; idx < 4 * 64 * 56; idx += 256) {
    int n = idx % 56, kk = (idx / 56) & 63, h = idx / (56 * 64);
    short v = (kk < FDIM && n < FDIM) ? f2bf(gat_w[kk * HF + h * FDIM + n]) : (short)0;
    Bt[(h * 56 + n) * BTS + kk] = v;
  }
  __syncthreads();
  const int lane = t & 63, wid = t >> 6;
  const int n16 = lane & 15, quad = lane >> 4;
  const int mrow0 = wid * 16;
  const int bmin = batL[0];
  const bool uni = (batL[0] == batL[63]);
  const size_t abase = (size_t)(m0 + mrow0 + n16) * A4P;   // pad rows read workspace, masked below
#pragma unroll
  for (int h = 0; h < 4; h++) {
    short8 af0 = *(const short8*)(agg4 + abase + h * 64 + quad * 8);
    short8 af1 = *(const short8*)(agg4 + abase + h * 64 + 32 + quad * 8);
#pragma unroll
    for (int nt = 0; nt < 4; nt++) {
      short8 b0 = *(const short8*)&Bt[(h * 56 + nt * 16 + n16) * BTS + quad * 8];
      short8 b1 = *(const short8*)&Bt[(h * 56 + nt * 16 + n16) * BTS + 32 + quad * 8];
      f32x4 acc = {0.f, 0.f, 0.f, 0.f};
      acc = __builtin_amdgcn_mfma_f32_16x16x32_bf16(af0, b0, acc, 0, 0, 0);
      acc = __builtin_amdgcn_mfma_f32_16x16x32_bf16(af1, b1, acc, 0, 0, 0);
      int jn = nt * 16 + n16;
      bool jv = jn < FDIM;
      float bj = jv ? gat_b[h * FDIM + jn] : 0.f;
      if (uni) {
        float s = 0.f;
#pragma unroll
        for (int r = 0; r < 4; r++) {
          int gm = m0 + mrow0 + quad * 4 + r;
          if (gm < N_NODES) s += fmaxf(acc[r] + bj, 0.f);
        }
        s += __shfl_xor(s, 16);
        s += __shfl_xor(s, 32);
        if (quad == 0 && jv && s != 0.f) atomicAdd(&psum[h * 56 + jn], s);
      } else {
        float pj = 0.f; int curb = -1;
#pragma unroll
        for (int r = 0; r < 4; r++) {
          int lm = mrow0 + quad * 4 + r;
          int gm = m0 + lm;
          if (gm < N_NODES) {
            float o = fmaxf(acc[r] + bj, 0.f);
            int b = batL[lm];
            if (b != curb) {
              if (curb >= 0 && jv) {
                int slot = curb - bmin;
                if (slot >= 0 && slot < 4) atomicAdd(&psum[slot * 224 + h * 56 + jn], pj);
                else atomicAdd(&pooled[(size_t)curb * POOLW + h * FDIM + jn], pj);
              }
              curb = b; pj = o;
            } else {
              pj += o;
            }
          }
        }
        if (curb >= 0 && jv) {
          int slot = curb - bmin;
          if (slot >= 0 && slot < 4) atomicAdd(&psum[slot * 224 + h * 56 + jn], pj);
          else atomicAdd(&pooled[(size_t)curb * POOLW + h * FDIM + jn], pj);
        }
      }
    }
  }
  __syncthreads();
  for (int idx = t; idx < 4 * 224; idx += 256) {
    int slot = idx / 224, c = idx % 224;
    int h = c / 56, jn = c % 56;
    float v = psum[idx];
    int b = bmin + slot;
    if (jn < FDIM && b < BATCH && v != 0.f)
      atomicAdd(&pooled[(size_t)b * POOLW + h * FDIM + jn], v);
  }
}

// ---------------------------------------------------------------------------
// Fused GIN MLP (round-12 standalone): h1 = relu(agg @ w1 + b1) in LDS;
// h2 = relu(h1 @ w2 + b2) + pooled accumulation.
// ---------------------------------------------------------------------------
#define A2PAD 111
__global__ __launch_bounds__(256) void k_gin(
    const float* __restrict__ agg,
    const float* __restrict__ w1, const float* __restrict__ b1,
    const float* __restrict__ w2, const float* __restrict__ b2,
    const int* __restrict__ batch, float* __restrict__ pooled) {
  __shared__ float B1[F2 * 112];       // phase A: As | Ws1; phase B: Ws2
  __shared__ float Hs[64 * A2PAD];
  __shared__ float psum[4 * 112];
  float* As = B1;                      // 64*APAD = 3648 floats
  float* Ws1 = B1 + 64 * APAD;         // 53*112 = 5936 floats (total 9584 < 11872)
  int m0 = blockIdx.x * 64;
  int t = threadIdx.x;
  for (int idx = t; idx < 4 * 112; idx += 256) psum[idx] = 0.f;
  for (int idx = t; idx < 64 * FDIM; idx += 256) {
    int m = idx / FDIM, k = idx % FDIM;
    int gm = m0 + m;
    As[m * APAD + k] = (gm < N_NODES) ? agg[(size_t)gm * FDIM + k] : 0.f;
  }
  for (int idx = t; idx < FDIM * 112; idx += 256) {
    int k = idx / 112, n = idx % 112;
    Ws1[idx] = (n < F2) ? w1[k * F2 + n] : 0.f;
  }
  __syncthreads();
  int tx = t & 15, ty = t >> 4;
  int ms = tx * 4, ns = ty * 7;
  // ---- phase A: h1 = relu(agg @ w1 + b1) -> Hs ----
  {
    float acc[4][7];
#pragma unroll
    for (int i = 0; i < 4; i++)
#pragma unroll
      for (int j = 0; j < 7; j++) acc[i][j] = 0.f;
    for (int k = 0; k < FDIM; k++) {
      float a0 = As[(ms + 0) * APAD + k];
      float a1 = As[(ms + 1) * APAD + k];
      float a2 = As[(ms + 2) * APAD + k];
      float a3 = As[(ms + 3) * APAD + k];
      float b[7];
#pragma unroll
      for (int j = 0; j < 7; j++) b[j] = Ws1[k * 112 + ns + j];
#pragma unroll
      for (int j = 0; j < 7; j++) {
        acc[0][j] += a0 * b[j];
        acc[1][j] += a1 * b[j];
        acc[2][j] += a2 * b[j];
        acc[3][j] += a3 * b[j];
      }
    }
#pragma unroll
    for (int i = 0; i < 4; i++) {
#pragma unroll
      for (int j = 0; j < 7; j++) {
        int n = ns + j;
        if (n < F2) Hs[(ms + i) * A2PAD + n] = fmaxf(acc[i][j] + b1[n], 0.f);
      }
    }
  }
  __syncthreads();   // all As/Ws1 reads done; Hs complete
  // ---- phase B: stage w2 over B1, then h2 = relu(Hs @ w2 + b2) + pool ----
  for (int idx = t; idx < F2 * 112; idx += 256) {
    int k = idx / 112, n = idx % 112;
    B1[idx] = (n < F2) ? w2[k * F2 + n] : 0.f;
  }
  __syncthreads();
  float acc[4][7];
#pragma unroll
  for (int i = 0; i < 4; i++)
#pragma unroll
    for (int j = 0; j < 7; j++) acc[i][j] = 0.f;
  for (int k = 0; k < F2; k++) {
    float a0 = Hs[(ms + 0) * A2PAD + k];
    float a1 = Hs[(ms + 1) * A2PAD + k];
    float a2 = Hs[(ms + 2) * A2PAD + k];
    float a3 = Hs[(ms + 3) * A2PAD + k];
    float b[7];
#pragma unroll
    for (int j = 0; j < 7; j++) b[j] = B1[k * 112 + ns + j];
#pragma unroll
    for (int j = 0; j < 7; j++) {
      acc[0][j] += a0 * b[j];
      acc[1][j] += a1 * b[j];
      acc[2][j] += a2 * b[j];
      acc[3][j] += a3 * b[j];
    }
  }
  float b2n[7];
#pragma unroll
  for (int j = 0; j < 7; j++) {
    int n = ns + j;
    b2n[j] = (n < F2) ? b2[n] : 0.f;
  }
  int bmin = batch[m0];
  float pj[7];
#pragma unroll
  for (int j = 0; j < 7; j++) pj[j] = 0.f;
  int curb = -1;
#pragma unroll
  for (int i = 0; i < 4; i++) {
    int gm = m0 + ms + i;
    if (gm >= N_NODES) break;
    int b = batch[gm];
    if (b != curb) {
      if (curb >= 0) {
        int slot = curb - bmin;
        if (slot >= 0 && slot < 4) {
#pragma unroll
          for (int j = 0; j < 7; j++)
            if (ns + j < F2) atomicAdd(&psum[slot * 112 + ns + j], pj[j]);
        } else {
          float* pg = pooled + (size_t)curb * POOLW + HF;
#pragma unroll
          for (int j = 0; j < 7; j++)
            if (ns + j < F2) atomicAdd(&pg[ns + j], pj[j]);
        }
      }
      curb = b;
#pragma unroll
      for (int j = 0; j < 7; j++)
        pj[j] = (ns + j < F2) ? fmaxf(acc[i][j] + b2n[j], 0.f) : 0.f;
    } else {
#pragma unroll
      for (int j = 0; j < 7; j++)
        if (ns + j < F2) pj[j] += fmaxf(acc[i][j] + b2n[j], 0.f);
    }
  }
  if (curb >= 0) {
    int slot = curb - bmin;
    if (slot >= 0 && slot < 4) {
#pragma unroll
      for (int j = 0; j < 7; j++)
        if (ns + j < F2) atomicAdd(&psum[slot * 112 + ns + j], pj[j]);
    } else {
      float* pg = pooled + (size_t)curb * POOLW + HF;
#pragma unroll
      for (int j = 0; j < 7; j++)
        if (ns + j < F2) atomicAdd(&pg[ns + j], pj[j]);
    }
  }
  __syncthreads();
  for (int idx = t; idx < 4 * 112; idx += 256) {
    int slot = idx / 112, n = idx % 112;
    float v = psum[idx];
    int b = bmin + slot;
    if (n < F2 && b < BATCH && v != 0.f)
      atomicAdd(&pooled[(size_t)b * POOLW + HF + n], v);
  }
}

// ---------------------------------------------------------------------------
// EdgeConv v8 (round-5 best): bf16 U/V, rp/batch in LDS, colidx prefetched
// 2 tiles ahead / V 1 tile ahead, deferred cross-quad max reduction,
// double-buffered LDS, lgkmcnt-only barrier.
// ---------------------------------------------------------------------------
#define ECH 25
__global__ __launch_bounds__(256) void k_ec(
    const short* __restrict__ Ub, const short* __restrict__ Vb,
    const float* __restrict__ w2, const float* __restrict__ b2,
    const int* __restrict__ rp, const int* __restrict__ colidx,
    const int* __restrict__ batch, float* __restrict__ pooled) {
  const int t = threadIdx.x;
  const int lane = t & 63, wid = t >> 6;
  const int n16 = lane & 15, quad = lane >> 4;
  const int nt = (wid == 3) ? 1 : 2;   // u-tile 7 is all-pad

  const int i0 = blockIdx.x * ECH;
  const int iend = min(i0 + ECH, N_NODES);
  const int nn = iend - i0;

  __shared__ int rpL[ECH + 1];
  __shared__ int batL[ECH];

  short8 Bh[2][4];
  for (int tt = 0; tt < 2; tt++) {
    int ucol = (wid * 2 + tt) * 16 + n16;
    for (int kc = 0; kc < 4; kc++) {
      short8 vh;
#pragma unroll
      for (int jv = 0; jv < 8; jv++) {
        int kk = kc * 32 + quad * 8 + jv;
        float w = (ucol < F2 && kk < F2) ? w2[kk * F2 + ucol] : 0.f;
        vh[jv] = f2bf(w);
      }
      Bh[tt][kc] = vh;
    }
  }
  float b2v[2];
#pragma unroll
  for (int tt = 0; tt < 2; tt++) {
    int u = (wid * 2 + tt) * 16 + n16;
    b2v[tt] = (u < F2) ? b2[u] : 0.f;
  }

  if (t <= nn) rpL[t] = rp[i0 + t];
  if (t < nn) batL[t] = batch[i0 + t];
  __syncthreads();

  __shared__ short hs[2][16 * 16 * 8];
  union SU { short8 s; unsigned u[4]; };
  const int es = t & 15, kg = t >> 4;
  const int k0 = kg * 8;

  float sm0 = 0.f, sm1 = 0.f;
  int curb = -1;
  const int u0 = (wid * 2) * 16 + n16;
  const int u1 = (wid * 2 + 1) * 16 + n16;

  // tile walk: (node, tile-in-node, base, deg) -> next
  auto advance = [&](int& ii, int& ttb, int& bb, int& dd) -> bool {
    ttb++;
    if (ttb * 16 < dd) return true;
    ttb = 0;
    for (ii = ii + 1; ii < iend; ii++) {
      bb = rpL[ii - i0]; dd = rpL[ii - i0 + 1] - bb;
      if (dd > 0) return true;
    }
    return false;
  };

  // current tile T
  int i = i0, tb = 0, base = 0, deg = 0;
  bool have = false;
  for (; i < iend; i++) {
    base = rpL[i - i0]; deg = rpL[i - i0 + 1] - base;
    if (deg > 0) { have = true; break; }
  }
  short8 pu8{}, pv8{};
  // tile T+1 coords + its colidx value (sc) already fetched
  int i1 = i, tb1 = 0, base1 = base, deg1 = deg;
  bool have1 = false;
  int sc = 0;
  if (have) {
    pu8 = *(const short8*)(Ub + (size_t)i * ECS + k0);
    int s0 = colidx[base + ((es < deg) ? es : 0)];
    pv8 = *(const short8*)(Vb + (size_t)s0 * ECS + k0);
    have1 = advance(i1, tb1, base1, deg1);
    if (have1) {
      int eg = tb1 * 16 + es;
      sc = colidx[base1 + ((eg < deg1) ? eg : 0)];
    }
  }

  float Uc[8];
  float vmax0 = -1e30f, vmax1 = -1e30f;
  int parity = 0;
  while (have) {
    if (tb == 0) {
#pragma unroll
      for (int j = 0; j < 8; j++) Uc[j] = bf2f(pu8[j]);
    }
    SU w;
#pragma unroll
    for (int p = 0; p < 4; p++) {
      bool kv = (k0 + 2 * p) < F2;
      float h0 = kv ? fmaxf(Uc[2 * p]     + bf2f(pv8[2 * p]),     0.f) : 0.f;
      float h1 = kv ? fmaxf(Uc[2 * p + 1] + bf2f(pv8[2 * p + 1]), 0.f) : 0.f;
      w.u[p] = pk2(h0, h1);
    }
    *(short8*)&hs[parity][(kg * 16 + es) * 8] = w.s;

    // prefetch: V (and U) for tile T+1 using sc fetched last iter; colidx for T+2
    int i2 = i1, tb2 = tb1, base2 = base1, deg2 = deg1;
    bool have2 = false;
    int scN = 0;
    if (have1) {
      if (tb1 == 0) pu8 = *(const short8*)(Ub + (size_t)i1 * ECS + k0);
      pv8 = *(const short8*)(Vb + (size_t)sc * ECS + k0);
      have2 = advance(i2, tb2, base2, deg2);
      if (have2) {
        int eg2 = tb2 * 16 + es;
        scN = colidx[base2 + ((eg2 < deg2) ? eg2 : 0)];
      }
    }

    ldsbar();
    f32x4 a0 = {0.f, 0.f, 0.f, 0.f}, a1 = {0.f, 0.f, 0.f, 0.f};
#pragma unroll
    for (int kc = 0; kc < 4; kc++) {
      short8 af = *(const short8*)&hs[parity][((kc * 4 + quad) * 16 + n16) * 8];
      a0 = __builtin_amdgcn_mfma_f32_16x16x32_bf16(af, Bh[0][kc], a0, 0, 0, 0);
      if (nt > 1)
        a1 = __builtin_amdgcn_mfma_f32_16x16x32_bf16(af, Bh[1][kc], a1, 0, 0, 0);
    }
#pragma unroll
    for (int r = 0; r < 4; r++) {
      int er = tb * 16 + quad * 4 + r;
      if (er < deg) { vmax0 = fmaxf(vmax0, a0[r]); vmax1 = fmaxf(vmax1, a1[r]); }
    }
    if (!have1 || i1 != i) {
      // node i finishes with this tile: cross-quad reduce deferred to here
      vmax0 = fmaxf(vmax0, __shfl_xor(vmax0, 16));
      vmax0 = fmaxf(vmax0, __shfl_xor(vmax0, 32));
      vmax1 = fmaxf(vmax1, __shfl_xor(vmax1, 16));
      vmax1 = fmaxf(vmax1, __shfl_xor(vmax1, 32));
      float o0 = fmaxf(vmax0 + b2v[0], 0.f);
      float o1 = fmaxf(vmax1 + b2v[1], 0.f);
      int b = batL[i - i0];
      if (b != curb) {
        if (curb >= 0 && quad == 0) {
          float* pg = pooled + (size_t)curb * POOLW + HF + F2;
          if (u0 < F2) atomicAdd(&pg[u0], sm0);
          if (nt > 1 && u1 < F2) atomicAdd(&pg[u1], sm1);
        }
        curb = b; sm0 = o0; sm1 = o1;
      } else {
        sm0 += o0; sm1 += o1;
      }
      vmax0 = -1e30f; vmax1 = -1e30f;
    }
    i = i1; tb = tb1; base = base1; deg = deg1; have = have1;
    i1 = i2; tb1 = tb2; base1 = base2; deg1 = deg2; have1 = have2;
    sc = scN;
    parity ^= 1;
  }
  if (curb >= 0 && quad == 0) {
    float* pg = pooled + (size_t)curb * POOLW + HF + F2;
    if (u0 < F2) atomicAdd(&pg[u0], sm0);
    if (nt > 1 && u1 < F2) atomicAdd(&pg[u1], sm1);
  }
}

// ---------------------------------------------------------------------------
// Per-graph heads + final MLP fused; mean-pool divide folded into the load.
// ---------------------------------------------------------------------------
__global__ __launch_bounds__(256) void k_heads(
    const float* __restrict__ pooled, const int* __restrict__ start,
    const float* __restrict__ fg1_w, const float* __restrict__ fg1_b,
    const float* __restrict__ fg2_w, const float* __restrict__ fg2_b,
    const float* __restrict__ fg3_w, const float* __restrict__ fg3_b,
    const float* __restrict__ fg4_w, const float* __restrict__ fg4_b,
    const float* __restrict__ fg5_w, const float* __restrict__ fg5_b,
    const float* __restrict__ fg6_w, const float* __restrict__ fg6_b,
    const float* __restrict__ fc1_w, const float* __restrict__ fc1_b,
    const float* __restrict__ fc2_w, const float* __restrict__ fc2_b,
    const float* __restrict__ out_w, const float* __restrict__ out_b,
    float* __restrict__ out) {
  int g = blockIdx.x, t = threadIdx.x;
  __shared__ float in[POOLW];
  __shared__ float mid[256];
  __shared__ float cat[384];
  __shared__ float h1[128];
  __shared__ float h2[64];
  float c = fmaxf((float)(start[g + 1] - start[g]), 1.f);
  for (int idx = t; idx < POOLW; idx += 256)
    in[idx] = pooled[(size_t)g * POOLW + idx] / c;
  __syncthreads();
  const float* w1s[3] = {fg1_w, fg3_w, fg5_w};
  const float* b1s[3] = {fg1_b, fg3_b, fg5_b};
  const float* w2s[3] = {fg2_w, fg4_w, fg6_w};
  const float* b2s[3] = {fg2_b, fg4_b, fg6_b};
  const int off[4] = {0, HF, HF + F2, POOLW};
  for (int br = 0; br < 3; br++) {
    int kin = off[br + 1] - off[br];
    const float* iv = &in[off[br]];
    float a = b1s[br][t];
    const float* W = w1s[br];
    for (int k = 0; k < kin; k++) a += iv[k] * W[k * 256 + t];
    mid[t] = fmaxf(a, 0.f);
    __syncthreads();
    if (t < 128) {
      float b = b2s[br][t];
      const float* W2 = w2s[br];
      for (int k = 0; k < 256; k++) b += mid[k] * W2[k * 128 + t];
      cat[br * 128 + t] = fmaxf(b, 0.f);
    }
    __syncthreads();
  }
  if (t < 128) {
    float a = fc1_b[t];
    for (int k = 0; k < 384; k++) a += cat[k] * fc1_w[k * 128 + t];
    h1[t] = fmaxf(a, 0.f);
  }
  __syncthreads();
  if (t < 64) {
    float a = fc2_b[t];
    for (int k = 0; k < 128; k++) a += h1[k] * fc2_w[k * 64 + t];
    h2[t] = fmaxf(a, 0.f);
  }
  __syncthreads();
  if (t == 0) {
    float a = out_b[0];
    for (int k = 0; k < 64; k++) a += h2[k] * out_w[k];
    out[g] = 1.f / (1.f + __expf(-a));
  }
}

// ---------------------------------------------------------------------------
extern "C" void kernel_launch(void* const* d_in, const int* in_sizes, int n_in,
                              void* d_out, int out_size, void* d_ws, size_t ws_size,
                              hipStream_t stream) {
  const float* x      = (const float*)d_in[0];
  const int*   ei     = (const int*)d_in[1];
  const int*   batch  = (const int*)d_in[2];
  const float* gat_w  = (const float*)d_in[3];
  const float* asrc   = (const float*)d_in[4];
  const float* adst   = (const float*)d_in[5];
  const float* gat_b  = (const float*)d_in[6];
  const float* gin_w1 = (const float*)d_in[7];
  const float* gin_b1 = (const float*)d_in[8];
  const float* gin_w2 = (const float*)d_in[9];
  const float* gin_b2 = (const float*)d_in[10];
  const float* ec_w1  = (const float*)d_in[11];
  const float* ec_b1  = (const float*)d_in[12];
  const float* ec_w2  = (const float*)d_in[13];
  const float* ec_b2  = (const float*)d_in[14];
  const float* fg1_w = (const float*)d_in[15]; const float* fg1_b = (const float*)d_in[16];
  const float* fg2_w = (const float*)d_in[17]; const float* fg2_b = (const float*)d_in[18];
  const float* fg3_w = (const float*)d_in[19]; const float* fg3_b = (const float*)d_in[20];
  const float* fg4_w = (const float*)d_in[21]; const float* fg4_b = (const float*)d_in[22];
  const float* fg5_w = (const float*)d_in[23]; const float* fg5_b = (const float*)d_in[24];
  const float* fg6_w = (const float*)d_in[25]; const float* fg6_b = (const float*)d_in[26];
  const float* fc1_w = (const float*)d_in[27]; const float* fc1_b = (const float*)d_in[28];
  const float* fc2_w = (const float*)d_in[29]; const float* fc2_b = (const float*)d_in[30];
  const float* out_w = (const float*)d_in[31]; const float* out_b = (const float*)d_in[32];
  float* out = (float*)d_out;

  char* ws = (char*)d_ws;
  size_t off = 0;
  auto alloc = [&](size_t bytes) -> void* {
    void* p = ws + off;
    off = (off + bytes + 255) & ~(size_t)255;
    return p;
  };
  // --- zero region (one memset): histP | pooled ---
  size_t zoff0 = off;
  int*   histP  = (int*)alloc((size_t)N_NODES * PSTR * sizeof(int));  // 6.4 MB padded bins
  float* pooled = (float*)alloc((size_t)BATCH * POOLW * sizeof(float));
  size_t zbytes = off - zoff0;
  // --- rest ---
  int*   rp     = (int*)alloc((N_NODES + 1) * sizeof(int));
  int*   start  = (int*)alloc((BATCH + 1) * sizeof(int));
  int*   bsum   = (int*)alloc(256 * sizeof(int));
  int*   colidx = (int*)alloc(N_EDGES * sizeof(int));
  short* xb     = (short*)alloc((size_t)N_NODES * 64 * sizeof(short));   // bf16 x rows, 128 B
  float* alS    = (float*)alloc((size_t)N_NODES * 4 * sizeof(float));
  float* alD    = (float*)alloc((size_t)N_NODES * 4 * sizeof(float));
  short* Ubuf   = (short*)alloc((size_t)N_NODES * ECS * sizeof(short));  // bf16, 256B rows
  short* Vbuf   = (short*)alloc((size_t)N_NODES * ECS * sizeof(short));  // bf16, 256B rows
  short* agg4   = (short*)alloc((size_t)(N_NODES + 64) * A4P * sizeof(short)); // padded bf16
  float* agg    = (float*)alloc((size_t)N_NODES * FDIM * sizeof(float)); // GIN aggregate
  float* Wp     = (float*)alloc((size_t)FDIM * NPK2 * sizeof(float));
  float* bpk    = (float*)alloc(NPK2 * sizeof(float));
  (void)ws_size; (void)in_sizes; (void)n_in; (void)out_size;

  hipMemsetAsync(ws + zoff0, 0, zbytes, stream);

  k_prep<<<(FDIM * NPK2 + 255) / 256, 256, 0, stream>>>(ec_w1, ec_b1, gat_w, asrc, adst,
                                                        Wp, bpk);
  k_gemm<<<((N_NODES + GM - 1) / GM) * 2, 256, 0, stream>>>(x, Wp, bpk,
                                                            xb, Ubuf, Vbuf, alS, alD);
  k_hist<<<(N_EDGES + 255) / 256, 256, 0, stream>>>(ei, histP);
  k_scan1<<<SCAN_BLOCKS, 256, 0, stream>>>(histP, batch, rp, bsum, start);
  k_scan3<<<SCAN_BLOCKS, 256, 0, stream>>>(bsum, rp, histP);
  k_scatter<<<(N_EDGES + 255) / 256, 256, 0, stream>>>(ei, histP, colidx);

  // fused GAT-aggregate + GIN-sum over one L2-resident bf16 x table
  k_gatgin<<<(N_NODES + GCH - 1) / GCH, 256, 0, stream>>>(xb, alS, alD, rp, colidx,
                                                          agg4, agg);
  k_ec<<<(N_NODES + ECH - 1) / ECH, 256, 0, stream>>>(Ubuf, Vbuf, ec_w2, ec_b2, rp, colidx, batch, pooled);
  // GAT transform (MFMA, global A-frags, 4 blocks/CU)
  k_gt<<<(N_NODES + 63) / 64, 256, 0, stream>>>(agg4, gat_w, gat_b, batch, pooled);
  // GIN MLP (h1 in LDS)
  k_gin<<<(N_NODES + 63) / 64, 256, 0, stream>>>(agg, gin_w1, gin_b1, gin_w2, gin_b2,
                                                 batch, pooled);

  k_heads<<<BATCH, 256, 0, stream>>>(pooled, start,
                                     fg1_w, fg1_b, fg2_w, fg2_b, fg3_w, fg3_b,
                                     fg4_w, fg4_b, fg5_w, fg5_b, fg6_w, fg6_b,
                                     fc1_w, fc1_b, fc2_w, fc2_b, out_w, out_b, out);
}

// Round 17
// 634.697 us; speedup vs baseline: 1.1879x; 1.0225x over previous
//
#include <hip/hip_runtime.h>
#include <hip/hip_bf16.h>
#include <math.h>

#define N_NODES 50000
#define N_EDGES 800000
#define FDIM 53
#define BATCH 128
#define HF 212   /* H*F */
#define F2 106   /* 2F  */
#define POOLW 424 /* 212+106+106 */
#define NPK2 220 /* 106 + 106 + 8: U | V | alS | alD */
#define PSTR 32  /* padded bin stride (ints) = 128 B: one L2 line per node */
#define ECS 128  /* U/V bf16 row stride (shorts) = 256 B = 4 L2 lines */
#define A4P 256  /* agg4 padded row stride (shorts): [node][4][64], 16B aligned */

typedef __attribute__((ext_vector_type(8))) short short8;
typedef __attribute__((ext_vector_type(4))) float f32x4;

__device__ __forceinline__ float leaky02(float x){ return x >= 0.f ? x : 0.2f * x; }

__device__ __forceinline__ short f2bf(float x) {
  unsigned u = __float_as_uint(x);
  unsigned r = (u + 0x7fffu + ((u >> 16) & 1u)) >> 16;
  return (short)r;
}
__device__ __forceinline__ float bf2f(short b) {
  return __uint_as_float(((unsigned)(unsigned short)b) << 16);
}
// packed pair f32x2 -> bf16x2 (v_cvt_pk_bf16_f32, RNE)
__device__ __forceinline__ unsigned pk2(float a, float b) {
  union { __hip_bfloat162 h; unsigned u; } c;
  c.h = __float22bfloat162_rn(make_float2(a, b));
  return c.u;
}
// LDS-only barrier: waits lgkmcnt(0) (ds ops) but leaves global loads in flight
__device__ __forceinline__ void ldsbar() {
  __builtin_amdgcn_s_waitcnt(0xC07F);   // vmcnt(63) expcnt(7) lgkmcnt(0)
  __builtin_amdgcn_s_barrier();
}

// ---------------------------------------------------------------------------
// Pack Wp[53][220] = [W1top-W1bot | W1bot | cAl] and bias bp[220].
// cAl columns (j >= 2*F2) compute their own 53-MAC dot (k_cal folded in).
// ---------------------------------------------------------------------------
__global__ void k_prep(const float* __restrict__ ec_w1, const float* __restrict__ ec_b1,
                       const float* __restrict__ gat_w, const float* __restrict__ asrc,
                       const float* __restrict__ adst,
                       float* __restrict__ Wp, float* __restrict__ bp) {
  int idx = blockIdx.x * blockDim.x + threadIdx.x;
  if (idx < FDIM * NPK2) {
    int k = idx / NPK2, j = idx % NPK2;
    float v;
    if (j < F2)            v = ec_w1[k * F2 + j] - ec_w1[(FDIM + k) * F2 + j];
    else if (j < 2 * F2)   v = ec_w1[(FDIM + k) * F2 + (j - F2)];
    else {
      int r = j - 2 * F2;              // 0..7 = sd*4 + h
      int sd = r >> 2, h = r & 3;
      const float* av = sd ? adst : asrc;
      float acc = 0.f;
      for (int f = 0; f < FDIM; ++f)
        acc += gat_w[k * HF + h * FDIM + f] * av[h * FDIM + f];
      v = acc;
    }
    Wp[idx] = v;
  }
  if (idx < NPK2) {
    bp[idx] = (idx < F2) ? ec_b1[idx] : 0.f;
  }
}

// ---------------------------------------------------------------------------
// Node-linear GEMM: x[50000x53] @ Wp[53x220] + bp -> U | V | alS | alD.
// Also emits xb (bf16 x rows, 64-short stride) during A-tile staging.
// ---------------------------------------------------------------------------
#define GM 64
#define GN 110
#define GNP 112
#define APAD 57
__global__ __launch_bounds__(256) void k_gemm(
    const float* __restrict__ x, const float* __restrict__ Wp, const float* __restrict__ bp,
    short* __restrict__ xb, short* __restrict__ Ub, short* __restrict__ Vb,
    float* __restrict__ alS, float* __restrict__ alD) {
  __shared__ float As[GM * APAD];
  __shared__ float Ws[FDIM * GNP];
  int mb = blockIdx.x >> 1, nc = blockIdx.x & 1;
  int m0 = mb * GM, n0 = nc * GN;
  int t = threadIdx.x;
  for (int idx = t; idx < GM * FDIM; idx += 256) {
    int m = idx / FDIM, k = idx % FDIM;
    int gm = m0 + m;
    float v = (gm < N_NODES) ? x[(size_t)gm * FDIM + k] : 0.f;
    As[m * APAD + k] = v;
    if (nc == 0 && gm < N_NODES) xb[(size_t)gm * 64 + k] = f2bf(v);
  }
  for (int idx = t; idx < FDIM * GNP; idx += 256) {
    int k = idx / GNP, n = idx % GNP;
    Ws[idx] = (n < GN) ? Wp[k * NPK2 + n0 + n] : 0.f;
  }
  __syncthreads();
  int tx = t & 15, ty = t >> 4;
  int ms = tx * 4, ns = ty * 7;
  float acc[4][7];
#pragma unroll
  for (int i = 0; i < 4; i++)
#pragma unroll
    for (int j = 0; j < 7; j++) acc[i][j] = 0.f;
  for (int k = 0; k < FDIM; k++) {
    float a0 = As[(ms + 0) * APAD + k];
    float a1 = As[(ms + 1) * APAD + k];
    float a2 = As[(ms + 2) * APAD + k];
    float a3 = As[(ms + 3) * APAD + k];
    float b[7];
#pragma unroll
    for (int j = 0; j < 7; j++) b[j] = Ws[k * GNP + ns + j];
#pragma unroll
    for (int j = 0; j < 7; j++) {
      acc[0][j] += a0 * b[j];
      acc[1][j] += a1 * b[j];
      acc[2][j] += a2 * b[j];
      acc[3][j] += a3 * b[j];
    }
  }
  float bj[7];
#pragma unroll
  for (int j = 0; j < 7; j++) {
    int g = n0 + ns + j;
    bj[j] = (g < NPK2) ? bp[g] : 0.f;
  }
#pragma unroll
  for (int i = 0; i < 4; i++) {
    int gm = m0 + ms + i;
    if (gm >= N_NODES) break;
#pragma unroll
    for (int j = 0; j < 7; j++) {
      int g = n0 + ns + j;
      float v = acc[i][j] + bj[j];
      if (g < F2)             Ub[(size_t)gm * ECS + g] = f2bf(v);
      else if (g < 2 * F2)    Vb[(size_t)gm * ECS + (g - F2)] = f2bf(v);
      else if (g < 2 * F2 + 4) alS[gm * 4 + (g - 2 * F2)] = v;
      else if (g < NPK2)      alD[gm * 4 + (g - 2 * F2 - 4)] = v;
    }
  }
}

// ---------------------------------------------------------------------------
// CSR build: hist -> scan1 (block scan + batch boundaries) -> scan3 (folds
// the bsum prefix scan) -> scatter.
// ---------------------------------------------------------------------------
#define SCAN_BLOCKS ((N_NODES + 255) / 256)

__global__ void k_hist(const int* __restrict__ ei, int* __restrict__ histP) {
  int t = blockIdx.x * blockDim.x + threadIdx.x;
  if (t < N_EDGES) atomicAdd(&histP[ei[N_EDGES + t] << 5], 1);
}

__global__ __launch_bounds__(256) void k_scan1(const int* __restrict__ histP,
                                               const int* __restrict__ batch,
                                               int* __restrict__ rp, int* __restrict__ bsum,
                                               int* __restrict__ start) {
  __shared__ int buf[256];
  int tid = threadIdx.x;
  int idx = blockIdx.x * 256 + tid;
  int v = (idx < N_NODES) ? histP[idx << 5] : 0;
  buf[tid] = v;
  __syncthreads();
  for (int off = 1; off < 256; off <<= 1) {
    int t2 = (tid >= off) ? buf[tid - off] : 0;
    __syncthreads();
    buf[tid] += t2;
    __syncthreads();
  }
  if (idx < N_NODES) rp[idx] = buf[tid] - v;
  if (tid == 255) bsum[blockIdx.x] = buf[255];
  // fused batch-boundary detection (was k_bnd)
  if (idx < N_NODES) {
    int b = batch[idx];
    if (idx == 0)
      for (int g = 0; g <= b; g++) start[g] = 0;
    int bn = (idx + 1 < N_NODES) ? batch[idx + 1] : BATCH;
    for (int g = b + 1; g <= bn; g++) start[g] = idx + 1;
  }
}

__global__ __launch_bounds__(256) void k_scan3(const int* __restrict__ bsum,
                                               int* __restrict__ rp, int* __restrict__ histP) {
  __shared__ int buf[256];
  int tid = threadIdx.x;
  int v = (tid < SCAN_BLOCKS) ? bsum[tid] : 0;
  buf[tid] = v;
  __syncthreads();
  for (int off = 1; off < 256; off <<= 1) {
    int t2 = (tid >= off) ? buf[tid - off] : 0;
    __syncthreads();
    buf[tid] += t2;
    __syncthreads();
  }
  int boff = (blockIdx.x == 0) ? 0 : buf[blockIdx.x - 1];   // exclusive offset
  int idx = blockIdx.x * 256 + tid;
  if (idx < N_NODES) {
    int o = rp[idx] + boff;
    rp[idx] = o;
    histP[idx << 5] = o;   // becomes the (padded) scatter cursor
  }
  if (idx == 0) rp[N_NODES] = N_EDGES;
}

__global__ void k_scatter(const int* __restrict__ ei, int* __restrict__ histP,
                          int* __restrict__ colidx) {
  int e = blockIdx.x * blockDim.x + threadIdx.x;
  if (e >= N_EDGES) return;
  int d = ei[N_EDGES + e];
  int pos = atomicAdd(&histP[d << 5], 1);
  colidx[pos] = ei[e];
}

// ---------------------------------------------------------------------------
// Fused GAT-aggregate + GIN-sum. agg4 written in padded [node][4][64] bf16
// layout; GIN aggregate written as hi/lo bf16 pair aggb[node][128]
// (hi k0..63, lo k64..127; zeros past 53) -> layer-1 MFMA reads it with
// fp32-equivalent precision (hi+lo double-bf16 decomposition).
// ---------------------------------------------------------------------------
#define GCH 20
__global__ __launch_bounds__(256) void k_gatgin(
    const short* __restrict__ xb, const float* __restrict__ alS, const float* __restrict__ alD,
    const int* __restrict__ rp, const int* __restrict__ colidx,
    short* __restrict__ agg4, short* __restrict__ aggb) {
  int wid = threadIdx.x >> 6, lane = threadIdx.x & 63;
  bool fa = lane < FDIM;
  int i0 = blockIdx.x * GCH;
  int iend = min(i0 + GCH, N_NODES);
  __shared__ int rpG[GCH + 1];
  __shared__ int sL[4][64];        // per-wave edge src ids
  __shared__ float4 eL[4][64];     // per-wave edge alphas (4 heads)
  {
    int t = threadIdx.x, nn = iend - i0;
    if (t <= nn) rpG[t] = rp[i0 + t];
  }
  __syncthreads();
  for (int i = i0 + wid; i < iend; i += 4) {
    int base = rpG[i - i0], deg = rpG[i - i0 + 1] - base;
    float4 adv = *(const float4*)(alD + (size_t)i * 4);
    float4 asv = *(const float4*)(alS + (size_t)i * 4);
    float aldi[4] = {adv.x, adv.y, adv.z, adv.w};
    float exs[4];
    exs[0] = __expf(leaky02(asv.x + aldi[0]));   // self-loop term
    exs[1] = __expf(leaky02(asv.y + aldi[1]));
    exs[2] = __expf(leaky02(asv.z + aldi[2]));
    exs[3] = __expf(leaky02(asv.w + aldi[3]));
    float xiv = fa ? bf2f(xb[(size_t)i * 64 + lane]) : 0.f;
    float ag0 = exs[0] * xiv, ag1 = exs[1] * xiv, ag2 = exs[2] * xiv, ag3 = exs[3] * xiv;
    float ax = xiv;
    float zl[4] = {0.f, 0.f, 0.f, 0.f};

    for (int c0 = 0; c0 < deg; c0 += 64) {
      int cn = min(64, deg - c0);
      int s = 0;
      float ex0 = 0.f, ex1 = 0.f, ex2 = 0.f, ex3 = 0.f;
      if (lane < cn) {
        s = colidx[base + c0 + lane];
        float4 av = *(const float4*)(alS + (size_t)s * 4);
        ex0 = __expf(leaky02(av.x + aldi[0]));
        ex1 = __expf(leaky02(av.y + aldi[1]));
        ex2 = __expf(leaky02(av.z + aldi[2]));
        ex3 = __expf(leaky02(av.w + aldi[3]));
        zl[0] += ex0; zl[1] += ex1; zl[2] += ex2; zl[3] += ex3;
      }
      // wave-local LDS stage; wave64 lockstep, no barrier needed.
      sL[wid][lane] = s;
      eL[wid][lane] = make_float4(ex0, ex1, ex2, ex3);
      for (int jj = 0; jj < cn; jj += 4) {
        int4 s4 = *(const int4*)&sL[wid][jj];          // 4 edge ids, broadcast
        int sj[4] = {s4.x, s4.y, s4.z, s4.w};
        float4 e0 = eL[wid][jj + 0];
        float4 e1 = eL[wid][jj + 1];
        float4 e2 = eL[wid][jj + 2];
        float4 e3 = eL[wid][jj + 3];
        float xg[4];
#pragma unroll
        for (int q = 0; q < 4; q++)
          xg[q] = fa ? bf2f(xb[(size_t)sj[q] * 64 + lane]) : 0.f;
        ag0 += e0.x * xg[0] + e1.x * xg[1] + e2.x * xg[2] + e3.x * xg[3];
        ag1 += e0.y * xg[0] + e1.y * xg[1] + e2.y * xg[2] + e3.y * xg[3];
        ag2 += e0.z * xg[0] + e1.z * xg[1] + e2.z * xg[2] + e3.z * xg[3];
        ag3 += e0.w * xg[0] + e1.w * xg[1] + e2.w * xg[2] + e3.w * xg[3];
#pragma unroll
        for (int q = 0; q < 4; q++)
          if (jj + q < cn) ax += xg[q];                // uniform guard
      }
    }
#pragma unroll
    for (int off = 32; off >= 1; off >>= 1)
#pragma unroll
      for (int h = 0; h < 4; h++) zl[h] += __shfl_xor(zl[h], off);
    {
      float z0 = zl[0] + exs[0] + 1e-16f;
      float z1 = zl[1] + exs[1] + 1e-16f;
      float z2 = zl[2] + exs[2] + 1e-16f;
      float z3 = zl[3] + exs[3] + 1e-16f;
      short* ar = agg4 + (size_t)i * A4P;
      ar[0 * 64 + lane] = fa ? f2bf(ag0 / z0) : (short)0;
      ar[1 * 64 + lane] = fa ? f2bf(ag1 / z1) : (short)0;
      ar[2 * 64 + lane] = fa ? f2bf(ag2 / z2) : (short)0;
      ar[3 * 64 + lane] = fa ? f2bf(ag3 / z3) : (short)0;
      // GIN aggregate: hi/lo double-bf16 (fp32-equivalent through MFMA)
      float axv = fa ? ax : 0.f;
      short hi = f2bf(axv);
      float lov = axv - bf2f(hi);
      short* br = aggb + (size_t)i * 128;
      br[lane]      = fa ? hi : (short)0;
      br[64 + lane] = fa ? f2bf(lov) : (short)0;
    }
  }
}

// ---------------------------------------------------------------------------
// GAT transform v3 (MFMA, light): A-frags loaded directly from padded agg4
// in global (no LDS A staging). LDS = Bt (32.2KB) + psum -> 4 blocks/CU.
// Uniform-batch fast path: quad-reduce via 2 shuffles, one LDS atomic per
// column; slow path = run-flush (boundary blocks only, ~13%).
// ---------------------------------------------------------------------------
#define BTS 72    /* Bt row stride in shorts */
__global__ __launch_bounds__(256) void k_gt(
    const short* __restrict__ agg4, const float* __restrict__ gat_w,
    const float* __restrict__ gat_b, const int* __restrict__ batch,
    float* __restrict__ pooled) {
  __shared__ short Bt[4 * 56 * BTS];    // 32.2 KB
  __shared__ float psum[4 * 224];
  __shared__ int batL[64];
  int m0 = blockIdx.x * 64;
  int t = threadIdx.x;
  for (int idx = t; idx < 4 * 224; idx += 256) psum[idx] = 0.f;
  if (t < 64) batL[t] = batch[min(m0 + t, N_NODES - 1)];
  for (int idx = t; idx < 4 * 64 * 56; idx += 256) {
    int n = idx % 56, kk = (idx / 56) & 63, h = idx / (56 * 64);
    short v = (kk < FDIM && n < FDIM) ? f2bf(gat_w[kk * HF + h * FDIM + n]) : (short)0;
    Bt[(h * 56 + n) * BTS + kk] = v;
  }
  __syncthreads();
  const int lane = t & 63, wid = t >> 6;
  const int n16 = lane & 15, quad = lane >> 4;
  const int mrow0 = wid * 16;
  const int bmin = batL[0];
  const bool uni = (batL[0] == batL[63]);
  const size_t abase = (size_t)(m0 + mrow0 + n16) * A4P;   // pad rows read workspace, masked below
#pragma unroll
  for (int h = 0; h < 4; h++) {
    short8 af0 = *(const short8*)(agg4 + abase + h * 64 + quad * 8);
    short8 af1 = *(const short8*)(agg4 + abase + h * 64 + 32 + quad * 8);
#pragma unroll
    for (int nt = 0; nt < 4; nt++) {
      short8 b0 = *(const short8*)&Bt[(h * 56 + nt * 16 + n16) * BTS + quad * 8];
      short8 b1 = *(const short8*)&Bt[(h * 56 + nt * 16 + n16) * BTS + 32 + quad * 8];
      f32x4 acc = {0.f, 0.f, 0.f, 0.f};
      acc = __builtin_amdgcn_mfma_f32_16x16x32_bf16(af0, b0, acc, 0, 0, 0);
      acc = __builtin_amdgcn_mfma_f32_16x16x32_bf16(af1, b1, acc, 0, 0, 0);
      int jn = nt * 16 + n16;
      bool jv = jn < FDIM;
      float bj = jv ? gat_b[h * FDIM + jn] : 0.f;
      if (uni) {
        float s = 0.f;
#pragma unroll
        for (int r = 0; r < 4; r++) {
          int gm = m0 + mrow0 + quad * 4 + r;
          if (gm < N_NODES) s += fmaxf(acc[r] + bj, 0.f);
        }
        s += __shfl_xor(s, 16);
        s += __shfl_xor(s, 32);
        if (quad == 0 && jv && s != 0.f) atomicAdd(&psum[h * 56 + jn], s);
      } else {
        float pj = 0.f; int curb = -1;
#pragma unroll
        for (int r = 0; r < 4; r++) {
          int lm = mrow0 + quad * 4 + r;
          int gm = m0 + lm;
          if (gm < N_NODES) {
            float o = fmaxf(acc[r] + bj, 0.f);
            int b = batL[lm];
            if (b != curb) {
              if (curb >= 0 && jv) {
                int slot = curb - bmin;
                if (slot >= 0 && slot < 4) atomicAdd(&psum[slot * 224 + h * 56 + jn], pj);
                else atomicAdd(&pooled[(size_t)curb * POOLW + h * FDIM + jn], pj);
              }
              curb = b; pj = o;
            } else {
              pj += o;
            }
          }
        }
        if (curb >= 0 && jv) {
          int slot = curb - bmin;
          if (slot >= 0 && slot < 4) atomicAdd(&psum[slot * 224 + h * 56 + jn], pj);
          else atomicAdd(&pooled[(size_t)curb * POOLW + h * FDIM + jn], pj);
        }
      }
    }
  }
  __syncthreads();
  for (int idx = t; idx < 4 * 224; idx += 256) {
    int slot = idx / 224, c = idx % 224;
    int h = c / 56, jn = c % 56;
    float v = psum[idx];
    int b = bmin + slot;
    if (jn < FDIM && b < BATCH && v != 0.f)
      atomicAdd(&pooled[(size_t)b * POOLW + h * FDIM + jn], v);
  }
}

// ---------------------------------------------------------------------------
// GIN MLP v3 (MFMA, hi/lo precision): layer 1 = K=128 MFMA over [hi|lo] aggb
// with w1 duplicated in B rows 64..127 -> exact (hi+lo)*w1. h1 stored as
// hi/lo bf16 pair in LDS; layer 2 accumulates hi and lo passes over shared
// B2 fragments. Numerics ~= fp32.
// ---------------------------------------------------------------------------
#define H1S 132   /* h1 row stride in shorts: 66 words % 32 = 2 -> conflict-free */
#define BWS 132   /* B arena row stride (K=128) */
__global__ __launch_bounds__(256) void k_ginm(
    const short* __restrict__ aggb,
    const float* __restrict__ w1, const float* __restrict__ b1,
    const float* __restrict__ w2, const float* __restrict__ b2,
    const int* __restrict__ batch, float* __restrict__ pooled) {
  __shared__ short h1hi[64 * H1S];    // 16.9 KB
  __shared__ short h1lo[64 * H1S];    // 16.9 KB
  __shared__ short Btw[112 * BWS];    // 29.6 KB (B1t-dup then B2t)
  __shared__ float psum[4 * 112];
  __shared__ int batL[64];
  int m0 = blockIdx.x * 64;
  int t = threadIdx.x;
  for (int idx = t; idx < 4 * 112; idx += 256) psum[idx] = 0.f;
  if (t < 64) batL[t] = batch[min(m0 + t, N_NODES - 1)];
  for (int idx = t; idx < 64 * H1S / 2; idx += 256) {
    ((int*)h1hi)[idx] = 0;
    ((int*)h1lo)[idx] = 0;
  }
  // stage B1t duplicated: rows k 0..63 = w1[k], rows k 64..127 = w1[k-64]
  for (int idx = t; idx < 112 * 128; idx += 256) {
    int n = idx >> 7, kk = idx & 127;
    int ks = kk & 63;
    short v = (ks < FDIM && n < F2) ? f2bf(w1[ks * F2 + n]) : (short)0;
    Btw[n * BWS + kk] = v;
  }
  __syncthreads();
  const int lane = t & 63, wid = t >> 6;
  const int n16 = lane & 15, quad = lane >> 4;
  const int mrow0 = wid * 16;
  const int bmin = batL[0];
  const bool uni = (batL[0] == batL[63]);
  // ---- layer 1: h1 = relu((hi+lo) @ w1 + b1) -> h1hi/h1lo ----
  {
    const size_t abase = (size_t)(m0 + mrow0 + n16) * 128;  // pad rows: workspace, masked later
    short8 a[4];
#pragma unroll
    for (int f = 0; f < 4; f++)
      a[f] = *(const short8*)(aggb + abase + f * 32 + quad * 8);
#pragma unroll
    for (int nt = 0; nt < 7; nt++) {
      f32x4 acc = {0.f, 0.f, 0.f, 0.f};
#pragma unroll
      for (int f = 0; f < 4; f++) {
        short8 bf = *(const short8*)&Btw[(nt * 16 + n16) * BWS + f * 32 + quad * 8];
        acc = __builtin_amdgcn_mfma_f32_16x16x32_bf16(a[f], bf, acc, 0, 0, 0);
      }
      int jn = nt * 16 + n16;
      if (jn < F2) {
        float bj = b1[jn];
#pragma unroll
        for (int r = 0; r < 4; r++) {
          int row = mrow0 + quad * 4 + r;
          float v = fmaxf(acc[r] + bj, 0.f);
          short hi = f2bf(v);
          h1hi[row * H1S + jn] = hi;
          h1lo[row * H1S + jn] = f2bf(v - bf2f(hi));
        }
      }
    }
  }
  __syncthreads();   // all B1t ds_reads + h1 writes done
  // stage B2t [112 out-cols][128 k] over the same arena
  for (int idx = t; idx < 112 * 128; idx += 256) {
    int n = idx >> 7, kk = idx & 127;
    short v = (kk < F2 && n < F2) ? f2bf(w2[kk * F2 + n]) : (short)0;
    Btw[n * BWS + kk] = v;
  }
  __syncthreads();
  // ---- layer 2: h2 = relu((h1hi+h1lo) @ w2 + b2) + pooled accumulation ----
  short8 ah[4], al[4];
#pragma unroll
  for (int f = 0; f < 4; f++) {
    ah[f] = *(const short8*)&h1hi[(mrow0 + n16) * H1S + f * 32 + quad * 8];
    al[f] = *(const short8*)&h1lo[(mrow0 + n16) * H1S + f * 32 + quad * 8];
  }
#pragma unroll
  for (int nt = 0; nt < 7; nt++) {
    f32x4 acc = {0.f, 0.f, 0.f, 0.f};
#pragma unroll
    for (int f = 0; f < 4; f++) {
      short8 bf = *(const short8*)&Btw[(nt * 16 + n16) * BWS + f * 32 + quad * 8];
      acc = __builtin_amdgcn_mfma_f32_16x16x32_bf16(ah[f], bf, acc, 0, 0, 0);
      acc = __builtin_amdgcn_mfma_f32_16x16x32_bf16(al[f], bf, acc, 0, 0, 0);
    }
    int jn = nt * 16 + n16;
    bool jv = jn < F2;
    float bj = jv ? b2[jn] : 0.f;
    if (uni) {
      float s = 0.f;
#pragma unroll
      for (int r = 0; r < 4; r++) {
        int gm = m0 + mrow0 + quad * 4 + r;
        if (gm < N_NODES) s += fmaxf(acc[r] + bj, 0.f);
      }
      s += __shfl_xor(s, 16);
      s += __shfl_xor(s, 32);
      if (quad == 0 && jv && s != 0.f) atomicAdd(&psum[jn], s);
    } else {
      float pj = 0.f; int curb = -1;
#pragma unroll
      for (int r = 0; r < 4; r++) {
        int lm = mrow0 + quad * 4 + r;
        int gm = m0 + lm;
        if (gm < N_NODES) {
          float o = fmaxf(acc[r] + bj, 0.f);
          int b = batL[lm];
          if (b != curb) {
            if (curb >= 0 && jv) {
              int slot = curb - bmin;
              if (slot >= 0 && slot < 4) atomicAdd(&psum[slot * 112 + jn], pj);
              else atomicAdd(&pooled[(size_t)curb * POOLW + HF + jn], pj);
            }
            curb = b; pj = o;
          } else {
            pj += o;
          }
        }
      }
      if (curb >= 0 && jv) {
        int slot = curb - bmin;
        if (slot >= 0 && slot < 4) atomicAdd(&psum[slot * 112 + jn], pj);
        else atomicAdd(&pooled[(size_t)curb * POOLW + HF + jn], pj);
      }
    }
  }
  __syncthreads();
  for (int idx = t; idx < 4 * 112; idx += 256) {
    int slot = idx / 112, n = idx % 112;
    float v = psum[idx];
    int b = bmin + slot;
    if (n < F2 && b < BATCH && v != 0.f)
      atomicAdd(&pooled[(size_t)b * POOLW + HF + n], v);
  }
}

// ---------------------------------------------------------------------------
// EdgeConv v8 (round-5 best): bf16 U/V, rp/batch in LDS, colidx prefetched
// 2 tiles ahead / V 1 tile ahead, deferred cross-quad max reduction,
// double-buffered LDS, lgkmcnt-only barrier.
// ---------------------------------------------------------------------------
#define ECH 25
__global__ __launch_bounds__(256) void k_ec(
    const short* __restrict__ Ub, const short* __restrict__ Vb,
    const float* __restrict__ w2, const float* __restrict__ b2,
    const int* __restrict__ rp, const int* __restrict__ colidx,
    const int* __restrict__ batch, float* __restrict__ pooled) {
  const int t = threadIdx.x;
  const int lane = t & 63, wid = t >> 6;
  const int n16 = lane & 15, quad = lane >> 4;
  const int nt = (wid == 3) ? 1 : 2;   // u-tile 7 is all-pad

  const int i0 = blockIdx.x * ECH;
  const int iend = min(i0 + ECH, N_NODES);
  const int nn = iend - i0;

  __shared__ int rpL[ECH + 1];
  __shared__ int batL[ECH];

  short8 Bh[2][4];
  for (int tt = 0; tt < 2; tt++) {
    int ucol = (wid * 2 + tt) * 16 + n16;
    for (int kc = 0; kc < 4; kc++) {
      short8 vh;
#pragma unroll
      for (int jv = 0; jv < 8; jv++) {
        int kk = kc * 32 + quad * 8 + jv;
        float w = (ucol < F2 && kk < F2) ? w2[kk * F2 + ucol] : 0.f;
        vh[jv] = f2bf(w);
      }
      Bh[tt][kc] = vh;
    }
  }
  float b2v[2];
#pragma unroll
  for (int tt = 0; tt < 2; tt++) {
    int u = (wid * 2 + tt) * 16 + n16;
    b2v[tt] = (u < F2) ? b2[u] : 0.f;
  }

  if (t <= nn) rpL[t] = rp[i0 + t];
  if (t < nn) batL[t] = batch[i0 + t];
  __syncthreads();

  __shared__ short hs[2][16 * 16 * 8];
  union SU { short8 s; unsigned u[4]; };
  const int es = t & 15, kg = t >> 4;
  const int k0 = kg * 8;

  float sm0 = 0.f, sm1 = 0.f;
  int curb = -1;
  const int u0 = (wid * 2) * 16 + n16;
  const int u1 = (wid * 2 + 1) * 16 + n16;

  // tile walk: (node, tile-in-node, base, deg) -> next
  auto advance = [&](int& ii, int& ttb, int& bb, int& dd) -> bool {
    ttb++;
    if (ttb * 16 < dd) return true;
    ttb = 0;
    for (ii = ii + 1; ii < iend; ii++) {
      bb = rpL[ii - i0]; dd = rpL[ii - i0 + 1] - bb;
      if (dd > 0) return true;
    }
    return false;
  };

  // current tile T
  int i = i0, tb = 0, base = 0, deg = 0;
  bool have = false;
  for (; i < iend; i++) {
    base = rpL[i - i0]; deg = rpL[i - i0 + 1] - base;
    if (deg > 0) { have = true; break; }
  }
  short8 pu8{}, pv8{};
  // tile T+1 coords + its colidx value (sc) already fetched
  int i1 = i, tb1 = 0, base1 = base, deg1 = deg;
  bool have1 = false;
  int sc = 0;
  if (have) {
    pu8 = *(const short8*)(Ub + (size_t)i * ECS + k0);
    int s0 = colidx[base + ((es < deg) ? es : 0)];
    pv8 = *(const short8*)(Vb + (size_t)s0 * ECS + k0);
    have1 = advance(i1, tb1, base1, deg1);
    if (have1) {
      int eg = tb1 * 16 + es;
      sc = colidx[base1 + ((eg < deg1) ? eg : 0)];
    }
  }

  float Uc[8];
  float vmax0 = -1e30f, vmax1 = -1e30f;
  int parity = 0;
  while (have) {
    if (tb == 0) {
#pragma unroll
      for (int j = 0; j < 8; j++) Uc[j] = bf2f(pu8[j]);
    }
    SU w;
#pragma unroll
    for (int p = 0; p < 4; p++) {
      bool kv = (k0 + 2 * p) < F2;
      float h0 = kv ? fmaxf(Uc[2 * p]     + bf2f(pv8[2 * p]),     0.f) : 0.f;
      float h1 = kv ? fmaxf(Uc[2 * p + 1] + bf2f(pv8[2 * p + 1]), 0.f) : 0.f;
      w.u[p] = pk2(h0, h1);
    }
    *(short8*)&hs[parity][(kg * 16 + es) * 8] = w.s;

    // prefetch: V (and U) for tile T+1 using sc fetched last iter; colidx for T+2
    int i2 = i1, tb2 = tb1, base2 = base1, deg2 = deg1;
    bool have2 = false;
    int scN = 0;
    if (have1) {
      if (tb1 == 0) pu8 = *(const short8*)(Ub + (size_t)i1 * ECS + k0);
      pv8 = *(const short8*)(Vb + (size_t)sc * ECS + k0);
      have2 = advance(i2, tb2, base2, deg2);
      if (have2) {
        int eg2 = tb2 * 16 + es;
        scN = colidx[base2 + ((eg2 < deg2) ? eg2 : 0)];
      }
    }

    ldsbar();
    f32x4 a0 = {0.f, 0.f, 0.f, 0.f}, a1 = {0.f, 0.f, 0.f, 0.f};
#pragma unroll
    for (int kc = 0; kc < 4; kc++) {
      short8 af = *(const short8*)&hs[parity][((kc * 4 + quad) * 16 + n16) * 8];
      a0 = __builtin_amdgcn_mfma_f32_16x16x32_bf16(af, Bh[0][kc], a0, 0, 0, 0);
      if (nt > 1)
        a1 = __builtin_amdgcn_mfma_f32_16x16x32_bf16(af, Bh[1][kc], a1, 0, 0, 0);
    }
#pragma unroll
    for (int r = 0; r < 4; r++) {
      int er = tb * 16 + quad * 4 + r;
      if (er < deg) { vmax0 = fmaxf(vmax0, a0[r]); vmax1 = fmaxf(vmax1, a1[r]); }
    }
    if (!have1 || i1 != i) {
      // node i finishes with this tile: cross-quad reduce deferred to here
      vmax0 = fmaxf(vmax0, __shfl_xor(vmax0, 16));
      vmax0 = fmaxf(vmax0, __shfl_xor(vmax0, 32));
      vmax1 = fmaxf(vmax1, __shfl_xor(vmax1, 16));
      vmax1 = fmaxf(vmax1, __shfl_xor(vmax1, 32));
      float o0 = fmaxf(vmax0 + b2v[0], 0.f);
      float o1 = fmaxf(vmax1 + b2v[1], 0.f);
      int b = batL[i - i0];
      if (b != curb) {
        if (curb >= 0 && quad == 0) {
          float* pg = pooled + (size_t)curb * POOLW + HF + F2;
          if (u0 < F2) atomicAdd(&pg[u0], sm0);
          if (nt > 1 && u1 < F2) atomicAdd(&pg[u1], sm1);
        }
        curb = b; sm0 = o0; sm1 = o1;
      } else {
        sm0 += o0; sm1 += o1;
      }
      vmax0 = -1e30f; vmax1 = -1e30f;
    }
    i = i1; tb = tb1; base = base1; deg = deg1; have = have1;
    i1 = i2; tb1 = tb2; base1 = base2; deg1 = deg2; have1 = have2;
    sc = scN;
    parity ^= 1;
  }
  if (curb >= 0 && quad == 0) {
    float* pg = pooled + (size_t)curb * POOLW + HF + F2;
    if (u0 < F2) atomicAdd(&pg[u0], sm0);
    if (nt > 1 && u1 < F2) atomicAdd(&pg[u1], sm1);
  }
}

// ---------------------------------------------------------------------------
// Per-graph heads + final MLP fused; mean-pool divide folded into the load.
// ---------------------------------------------------------------------------
__global__ __launch_bounds__(256) void k_heads(
    const float* __restrict__ pooled, const int* __restrict__ start,
    const float* __restrict__ fg1_w, const float* __restrict__ fg1_b,
    const float* __restrict__ fg2_w, const float* __restrict__ fg2_b,
    const float* __restrict__ fg3_w, const float* __restrict__ fg3_b,
    const float* __restrict__ fg4_w, const float* __restrict__ fg4_b,
    const float* __restrict__ fg5_w, const float* __restrict__ fg5_b,
    const float* __restrict__ fg6_w, const float* __restrict__ fg6_b,
    const float* __restrict__ fc1_w, const float* __restrict__ fc1_b,
    const float* __restrict__ fc2_w, const float* __restrict__ fc2_b,
    const float* __restrict__ out_w, const float* __restrict__ out_b,
    float* __restrict__ out) {
  int g = blockIdx.x, t = threadIdx.x;
  __shared__ float in[POOLW];
  __shared__ float mid[256];
  __shared__ float cat[384];
  __shared__ float h1[128];
  __shared__ float h2[64];
  float c = fmaxf((float)(start[g + 1] - start[g]), 1.f);
  for (int idx = t; idx < POOLW; idx += 256)
    in[idx] = pooled[(size_t)g * POOLW + idx] / c;
  __syncthreads();
  const float* w1s[3] = {fg1_w, fg3_w, fg5_w};
  const float* b1s[3] = {fg1_b, fg3_b, fg5_b};
  const float* w2s[3] = {fg2_w, fg4_w, fg6_w};
  const float* b2s[3] = {fg2_b, fg4_b, fg6_b};
  const int off[4] = {0, HF, HF + F2, POOLW};
  for (int br = 0; br < 3; br++) {
    int kin = off[br + 1] - off[br];
    const float* iv = &in[off[br]];
    float a = b1s[br][t];
    const float* W = w1s[br];
    for (int k = 0; k < kin; k++) a += iv[k] * W[k * 256 + t];
    mid[t] = fmaxf(a, 0.f);
    __syncthreads();
    if (t < 128) {
      float b = b2s[br][t];
      const float* W2 = w2s[br];
      for (int k = 0; k < 256; k++) b += mid[k] * W2[k * 128 + t];
      cat[br * 128 + t] = fmaxf(b, 0.f);
    }
    __syncthreads();
  }
  if (t < 128) {
    float a = fc1_b[t];
    for (int k = 0; k < 384; k++) a += cat[k] * fc1_w[k * 128 + t];
    h1[t] = fmaxf(a, 0.f);
  }
  __syncthreads();
  if (t < 64) {
    float a = fc2_b[t];
    for (int k = 0; k < 128; k++) a += h1[k] * fc2_w[k * 64 + t];
    h2[t] = fmaxf(a, 0.f);
  }
  __syncthreads();
  if (t == 0) {
    float a = out_b[0];
    for (int k = 0; k < 64; k++) a += h2[k] * out_w[k];
    out[g] = 1.f / (1.f + __expf(-a));
  }
}

// ---------------------------------------------------------------------------
extern "C" void kernel_launch(void* const* d_in, const int* in_sizes, int n_in,
                              void* d_out, int out_size, void* d_ws, size_t ws_size,
                              hipStream_t stream) {
  const float* x      = (const float*)d_in[0];
  const int*   ei     = (const int*)d_in[1];
  const int*   batch  = (const int*)d_in[2];
  const float* gat_w  = (const float*)d_in[3];
  const float* asrc   = (const float*)d_in[4];
  const float* adst   = (const float*)d_in[5];
  const float* gat_b  = (const float*)d_in[6];
  const float* gin_w1 = (const float*)d_in[7];
  const float* gin_b1 = (const float*)d_in[8];
  const float* gin_w2 = (const float*)d_in[9];
  const float* gin_b2 = (const float*)d_in[10];
  const float* ec_w1  = (const float*)d_in[11];
  const float* ec_b1  = (const float*)d_in[12];
  const float* ec_w2  = (const float*)d_in[13];
  const float* ec_b2  = (const float*)d_in[14];
  const float* fg1_w = (const float*)d_in[15]; const float* fg1_b = (const float*)d_in[16];
  const float* fg2_w = (const float*)d_in[17]; const float* fg2_b = (const float*)d_in[18];
  const float* fg3_w = (const float*)d_in[19]; const float* fg3_b = (const float*)d_in[20];
  const float* fg4_w = (const float*)d_in[21]; const float* fg4_b = (const float*)d_in[22];
  const float* fg5_w = (const float*)d_in[23]; const float* fg5_b = (const float*)d_in[24];
  const float* fg6_w = (const float*)d_in[25]; const float* fg6_b = (const float*)d_in[26];
  const float* fc1_w = (const float*)d_in[27]; const float* fc1_b = (const float*)d_in[28];
  const float* fc2_w = (const float*)d_in[29]; const float* fc2_b = (const float*)d_in[30];
  const float* out_w = (const float*)d_in[31]; const float* out_b = (const float*)d_in[32];
  float* out = (float*)d_out;

  char* ws = (char*)d_ws;
  size_t off = 0;
  auto alloc = [&](size_t bytes) -> void* {
    void* p = ws + off;
    off = (off + bytes + 255) & ~(size_t)255;
    return p;
  };
  // --- zero region (one memset): histP | pooled ---
  size_t zoff0 = off;
  int*   histP  = (int*)alloc((size_t)N_NODES * PSTR * sizeof(int));  // 6.4 MB padded bins
  float* pooled = (float*)alloc((size_t)BATCH * POOLW * sizeof(float));
  size_t zbytes = off - zoff0;
  // --- rest ---
  int*   rp     = (int*)alloc((N_NODES + 1) * sizeof(int));
  int*   start  = (int*)alloc((BATCH + 1) * sizeof(int));
  int*   bsum   = (int*)alloc(256 * sizeof(int));
  int*   colidx = (int*)alloc(N_EDGES * sizeof(int));
  short* xb     = (short*)alloc((size_t)N_NODES * 64 * sizeof(short));   // bf16 x rows, 128 B
  float* alS    = (float*)alloc((size_t)N_NODES * 4 * sizeof(float));
  float* alD    = (float*)alloc((size_t)N_NODES * 4 * sizeof(float));
  short* Ubuf   = (short*)alloc((size_t)N_NODES * ECS * sizeof(short));  // bf16, 256B rows
  short* Vbuf   = (short*)alloc((size_t)N_NODES * ECS * sizeof(short));  // bf16, 256B rows
  short* agg4   = (short*)alloc((size_t)(N_NODES + 64) * A4P * sizeof(short)); // padded bf16
  short* aggb   = (short*)alloc((size_t)(N_NODES + 64) * 128 * sizeof(short)); // GIN hi/lo
  float* Wp     = (float*)alloc((size_t)FDIM * NPK2 * sizeof(float));
  float* bpk    = (float*)alloc(NPK2 * sizeof(float));
  (void)ws_size; (void)in_sizes; (void)n_in; (void)out_size;

  hipMemsetAsync(ws + zoff0, 0, zbytes, stream);

  k_prep<<<(FDIM * NPK2 + 255) / 256, 256, 0, stream>>>(ec_w1, ec_b1, gat_w, asrc, adst,
                                                        Wp, bpk);
  k_gemm<<<((N_NODES + GM - 1) / GM) * 2, 256, 0, stream>>>(x, Wp, bpk,
                                                            xb, Ubuf, Vbuf, alS, alD);
  k_hist<<<(N_EDGES + 255) / 256, 256, 0, stream>>>(ei, histP);
  k_scan1<<<SCAN_BLOCKS, 256, 0, stream>>>(histP, batch, rp, bsum, start);
  k_scan3<<<SCAN_BLOCKS, 256, 0, stream>>>(bsum, rp, histP);
  k_scatter<<<(N_EDGES + 255) / 256, 256, 0, stream>>>(ei, histP, colidx);

  // fused GAT-aggregate + GIN-sum over one L2-resident bf16 x table
  k_gatgin<<<(N_NODES + GCH - 1) / GCH, 256, 0, stream>>>(xb, alS, alD, rp, colidx,
                                                          agg4, aggb);
  k_ec<<<(N_NODES + ECH - 1) / ECH, 256, 0, stream>>>(Ubuf, Vbuf, ec_w2, ec_b2, rp, colidx, batch, pooled);
  // GAT transform (MFMA, global A-frags)
  k_gt<<<(N_NODES + 63) / 64, 256, 0, stream>>>(agg4, gat_w, gat_b, batch, pooled);
  // GIN MLP (MFMA, hi/lo double-bf16 precision)
  k_ginm<<<(N_NODES + 63) / 64, 256, 0, stream>>>(aggb, gin_w1, gin_b1, gin_w2, gin_b2,
                                                  batch, pooled);

  k_heads<<<BATCH, 256, 0, stream>>>(pooled, start,
                                     fg1_w, fg1_b, fg2_w, fg2_b, fg3_w, fg3_b,
                                     fg4_w, fg4_b, fg5_w, fg5_b, fg6_w, fg6_b,
                                     fc1_w, fc1_b, fc2_w, fc2_b, out_w, out_b, out);
}

// Round 18
// 614.215 us; speedup vs baseline: 1.2275x; 1.0333x over previous
//
#include <hip/hip_runtime.h>
#include <hip/hip_bf16.h>
#include <math.h>

#define N_NODES 50000
#define N_EDGES 800000
#define FDIM 53
#define BATCH 128
#define HF 212   /* H*F */
#define F2 106   /* 2F  */
#define POOLW 424 /* 212+106+106 */
#define PSTR 32  /* padded bin stride (ints) = 128 B: one L2 line per node */
#define ECS 128  /* U/V bf16 row stride (shorts) = 256 B = 4 L2 lines */
#define A4P 256  /* agg4 padded row stride (shorts): [node][4][64], 16B aligned */

typedef __attribute__((ext_vector_type(8))) short short8;
typedef __attribute__((ext_vector_type(4))) float f32x4;

__device__ __forceinline__ float leaky02(float x){ return x >= 0.f ? x : 0.2f * x; }

__device__ __forceinline__ short f2bf(float x) {
  unsigned u = __float_as_uint(x);
  unsigned r = (u + 0x7fffu + ((u >> 16) & 1u)) >> 16;
  return (short)r;
}
__device__ __forceinline__ float bf2f(short b) {
  return __uint_as_float(((unsigned)(unsigned short)b) << 16);
}
// packed pair f32x2 -> bf16x2 (v_cvt_pk_bf16_f32, RNE)
__device__ __forceinline__ unsigned pk2(float a, float b) {
  union { __hip_bfloat162 h; unsigned u; } c;
  c.h = __float22bfloat162_rn(make_float2(a, b));
  return c.u;
}
// LDS-only barrier: waits lgkmcnt(0) (ds ops) but leaves global loads in flight
__device__ __forceinline__ void ldsbar() {
  __builtin_amdgcn_s_waitcnt(0xC07F);   // vmcnt(63) expcnt(7) lgkmcnt(0)
  __builtin_amdgcn_s_barrier();
}

// ---------------------------------------------------------------------------
// Weight prep: pack all MFMA B-fragment buffers (bf16, L2-resident broadcast)
// + cAl. Segments:
//   cAl[53*8]                        : 53-MAC dots
//   Wgt[4][56][64]                   : gat_w per-head transposed, k-padded
//   Wuv[2][112][256]                 : EC U/V weights, K=256 hi/lo layout
//                                      (kk<128 -> w-hi, kk>=128 -> w-lo; ks=kk&63)
//   Wg1[112][128]                    : gin_w1 dup rows (hi/lo A), bf16
//   Wg2[112][128]                    : gin_w2 transposed, bf16
// ---------------------------------------------------------------------------
#define SEG_CAL 424
#define SEG_WGT (4*56*64)
#define SEG_WUV (2*112*256)
#define SEG_WG1 (112*128)
#define SEG_WG2 (112*128)
#define PREP_TOT (SEG_CAL + SEG_WGT + SEG_WUV + SEG_WG1 + SEG_WG2)
__global__ void k_prep(const float* __restrict__ gat_w, const float* __restrict__ asrc,
                       const float* __restrict__ adst, const float* __restrict__ ec_w1,
                       const float* __restrict__ gin_w1, const float* __restrict__ gin_w2,
                       float* __restrict__ cAl, short* __restrict__ Wgt,
                       short* __restrict__ Wuv, short* __restrict__ Wg1,
                       short* __restrict__ Wg2) {
  int idx = blockIdx.x * blockDim.x + threadIdx.x;
  if (idx < SEG_CAL) {
    int k = idx >> 3, r = idx & 7, sd = r >> 2, h = r & 3;
    const float* av = sd ? adst : asrc;
    float acc = 0.f;
    for (int f = 0; f < FDIM; ++f)
      acc += gat_w[k * HF + h * FDIM + f] * av[h * FDIM + f];
    cAl[idx] = acc;
    return;
  }
  idx -= SEG_CAL;
  if (idx < SEG_WGT) {
    int h = idx / (56 * 64), rem = idx % (56 * 64);
    int n = rem >> 6, kk = rem & 63;
    Wgt[idx] = (kk < FDIM && n < FDIM) ? f2bf(gat_w[kk * HF + h * FDIM + n]) : (short)0;
    return;
  }
  idx -= SEG_WGT;
  if (idx < SEG_WUV) {
    int c = idx / (112 * 256), rem = idx % (112 * 256);
    int n = rem >> 8, kk = rem & 255, ks = kk & 63;
    float w = 0.f;
    if (ks < FDIM && n < F2)
      w = (c == 0) ? ec_w1[ks * F2 + n] - ec_w1[(FDIM + ks) * F2 + n]
                   : ec_w1[(FDIM + ks) * F2 + n];
    short hv = f2bf(w);
    Wuv[idx] = (kk < 128) ? hv : f2bf(w - bf2f(hv));
    return;
  }
  idx -= SEG_WUV;
  if (idx < SEG_WG1) {
    int n = idx >> 7, kk = idx & 127, ks = kk & 63;
    Wg1[idx] = (ks < FDIM && n < F2) ? f2bf(gin_w1[ks * F2 + n]) : (short)0;
    return;
  }
  idx -= SEG_WG1;
  if (idx < SEG_WG2) {
    int n = idx >> 7, kk = idx & 127;
    Wg2[idx] = (kk < F2 && n < F2) ? f2bf(gin_w2[kk * F2 + n]) : (short)0;
  }
}

// ---------------------------------------------------------------------------
// x split: xbhl[node][128] = [hi(0..63) | lo(64..127)] bf16 (zeros k>=53);
// alS/alD computed via wave shuffle-reduce over cAl.
// ---------------------------------------------------------------------------
__global__ __launch_bounds__(256) void k_xsplit(
    const float* __restrict__ x, const float* __restrict__ cAl,
    short* __restrict__ xbhl, float* __restrict__ alS, float* __restrict__ alD) {
  int wid = threadIdx.x >> 6, lane = threadIdx.x & 63;
  int i = blockIdx.x * 4 + wid;
  if (i >= N_NODES) return;
  float v = (lane < FDIM) ? x[(size_t)i * FDIM + lane] : 0.f;
  short hi = f2bf(v);
  xbhl[(size_t)i * 128 + lane] = hi;
  xbhl[(size_t)i * 128 + 64 + lane] = f2bf(v - bf2f(hi));
  float out = 0.f;
#pragma unroll
  for (int j = 0; j < 8; j++) {
    float p = (lane < FDIM) ? v * cAl[lane * 8 + j] : 0.f;
#pragma unroll
    for (int off = 32; off >= 1; off >>= 1) p += __shfl_xor(p, off);
    if (lane == j) out = p;
  }
  if (lane < 4) alS[i * 4 + lane] = out;
  else if (lane < 8) alD[i * 4 + (lane - 4)] = out;
}

// ---------------------------------------------------------------------------
// U/V linear (MFMA, zero LDS): K=256 hi/lo exact product. A rows 128..255
// repeat rows 0..127 (a[f&3]); B = Wuv [wh|wh|wl|wl]. Chunk c: 0=U, 1=V.
// ---------------------------------------------------------------------------
__global__ __launch_bounds__(256) void k_uv(
    const short* __restrict__ xbhl, const short* __restrict__ Wuv,
    const float* __restrict__ ec_b1,
    short* __restrict__ Ub, short* __restrict__ Vb) {
  int bid = blockIdx.x;
  int nb = bid >> 1, c = bid & 1;
  int m0 = nb * 64;
  int t = threadIdx.x;
  const int lane = t & 63, wid = t >> 6;
  const int n16 = lane & 15, quad = lane >> 4;
  const int mrow0 = wid * 16;
  const size_t abase = (size_t)(m0 + mrow0 + n16) * 128;   // pad rows: workspace
  short8 a[4];
#pragma unroll
  for (int f = 0; f < 4; f++)
    a[f] = *(const short8*)(xbhl + abase + f * 32 + quad * 8);
  const short* Bw = Wuv + (size_t)c * 112 * 256;
  short* Ob = c ? Vb : Ub;
#pragma unroll
  for (int nt = 0; nt < 7; nt++) {
    f32x4 acc = {0.f, 0.f, 0.f, 0.f};
#pragma unroll
    for (int f = 0; f < 8; f++) {
      short8 bf = *(const short8*)(Bw + (nt * 16 + n16) * 256 + f * 32 + quad * 8);
      acc = __builtin_amdgcn_mfma_f32_16x16x32_bf16(a[f & 3], bf, acc, 0, 0, 0);
    }
    int jn = nt * 16 + n16;
    if (jn < F2) {
      float bj = c ? 0.f : ec_b1[jn];
#pragma unroll
      for (int r = 0; r < 4; r++) {
        int gm = m0 + mrow0 + quad * 4 + r;
        if (gm < N_NODES) Ob[(size_t)gm * ECS + jn] = f2bf(acc[r] + bj);
      }
    }
  }
}

// ---------------------------------------------------------------------------
// CSR build: hist -> scan1 (block scan + batch boundaries) -> scan3 (folds
// the bsum prefix scan) -> scatter.
// ---------------------------------------------------------------------------
#define SCAN_BLOCKS ((N_NODES + 255) / 256)

__global__ void k_hist(const int* __restrict__ ei, int* __restrict__ histP) {
  int t = blockIdx.x * blockDim.x + threadIdx.x;
  if (t < N_EDGES) atomicAdd(&histP[ei[N_EDGES + t] << 5], 1);
}

__global__ __launch_bounds__(256) void k_scan1(const int* __restrict__ histP,
                                               const int* __restrict__ batch,
                                               int* __restrict__ rp, int* __restrict__ bsum,
                                               int* __restrict__ start) {
  __shared__ int buf[256];
  int tid = threadIdx.x;
  int idx = blockIdx.x * 256 + tid;
  int v = (idx < N_NODES) ? histP[idx << 5] : 0;
  buf[tid] = v;
  __syncthreads();
  for (int off = 1; off < 256; off <<= 1) {
    int t2 = (tid >= off) ? buf[tid - off] : 0;
    __syncthreads();
    buf[tid] += t2;
    __syncthreads();
  }
  if (idx < N_NODES) rp[idx] = buf[tid] - v;
  if (tid == 255) bsum[blockIdx.x] = buf[255];
  // fused batch-boundary detection (was k_bnd)
  if (idx < N_NODES) {
    int b = batch[idx];
    if (idx == 0)
      for (int g = 0; g <= b; g++) start[g] = 0;
    int bn = (idx + 1 < N_NODES) ? batch[idx + 1] : BATCH;
    for (int g = b + 1; g <= bn; g++) start[g] = idx + 1;
  }
}

__global__ __launch_bounds__(256) void k_scan3(const int* __restrict__ bsum,
                                               int* __restrict__ rp, int* __restrict__ histP) {
  __shared__ int buf[256];
  int tid = threadIdx.x;
  int v = (tid < SCAN_BLOCKS) ? bsum[tid] : 0;
  buf[tid] = v;
  __syncthreads();
  for (int off = 1; off < 256; off <<= 1) {
    int t2 = (tid >= off) ? buf[tid - off] : 0;
    __syncthreads();
    buf[tid] += t2;
    __syncthreads();
  }
  int boff = (blockIdx.x == 0) ? 0 : buf[blockIdx.x - 1];   // exclusive offset
  int idx = blockIdx.x * 256 + tid;
  if (idx < N_NODES) {
    int o = rp[idx] + boff;
    rp[idx] = o;
    histP[idx << 5] = o;   // becomes the (padded) scatter cursor
  }
  if (idx == 0) rp[N_NODES] = N_EDGES;
}

__global__ void k_scatter(const int* __restrict__ ei, int* __restrict__ histP,
                          int* __restrict__ colidx) {
  int e = blockIdx.x * blockDim.x + threadIdx.x;
  if (e >= N_EDGES) return;
  int d = ei[N_EDGES + e];
  int pos = atomicAdd(&histP[d << 5], 1);
  colidx[pos] = ei[e];
}

// ---------------------------------------------------------------------------
// Fused GAT-aggregate + GIN-sum. x rows read from xbhl (hi half, stride 128).
// agg4 padded [node][4][64] bf16; GIN aggregate hi/lo pair aggb[node][128].
// ---------------------------------------------------------------------------
#define GCH 20
__global__ __launch_bounds__(256) void k_gatgin(
    const short* __restrict__ xbhl, const float* __restrict__ alS, const float* __restrict__ alD,
    const int* __restrict__ rp, const int* __restrict__ colidx,
    short* __restrict__ agg4, short* __restrict__ aggb) {
  int wid = threadIdx.x >> 6, lane = threadIdx.x & 63;
  bool fa = lane < FDIM;
  int i0 = blockIdx.x * GCH;
  int iend = min(i0 + GCH, N_NODES);
  __shared__ int rpG[GCH + 1];
  __shared__ int sL[4][64];        // per-wave edge src ids
  __shared__ float4 eL[4][64];     // per-wave edge alphas (4 heads)
  {
    int t = threadIdx.x, nn = iend - i0;
    if (t <= nn) rpG[t] = rp[i0 + t];
  }
  __syncthreads();
  for (int i = i0 + wid; i < iend; i += 4) {
    int base = rpG[i - i0], deg = rpG[i - i0 + 1] - base;
    float4 adv = *(const float4*)(alD + (size_t)i * 4);
    float4 asv = *(const float4*)(alS + (size_t)i * 4);
    float aldi[4] = {adv.x, adv.y, adv.z, adv.w};
    float exs[4];
    exs[0] = __expf(leaky02(asv.x + aldi[0]));   // self-loop term
    exs[1] = __expf(leaky02(asv.y + aldi[1]));
    exs[2] = __expf(leaky02(asv.z + aldi[2]));
    exs[3] = __expf(leaky02(asv.w + aldi[3]));
    float xiv = fa ? bf2f(xbhl[(size_t)i * 128 + lane]) : 0.f;
    float ag0 = exs[0] * xiv, ag1 = exs[1] * xiv, ag2 = exs[2] * xiv, ag3 = exs[3] * xiv;
    float ax = xiv;
    float zl[4] = {0.f, 0.f, 0.f, 0.f};

    for (int c0 = 0; c0 < deg; c0 += 64) {
      int cn = min(64, deg - c0);
      int s = 0;
      float ex0 = 0.f, ex1 = 0.f, ex2 = 0.f, ex3 = 0.f;
      if (lane < cn) {
        s = colidx[base + c0 + lane];
        float4 av = *(const float4*)(alS + (size_t)s * 4);
        ex0 = __expf(leaky02(av.x + aldi[0]));
        ex1 = __expf(leaky02(av.y + aldi[1]));
        ex2 = __expf(leaky02(av.z + aldi[2]));
        ex3 = __expf(leaky02(av.w + aldi[3]));
        zl[0] += ex0; zl[1] += ex1; zl[2] += ex2; zl[3] += ex3;
      }
      // wave-local LDS stage; wave64 lockstep, no barrier needed.
      sL[wid][lane] = s;
      eL[wid][lane] = make_float4(ex0, ex1, ex2, ex3);
      for (int jj = 0; jj < cn; jj += 4) {
        int4 s4 = *(const int4*)&sL[wid][jj];          // 4 edge ids, broadcast
        int sj[4] = {s4.x, s4.y, s4.z, s4.w};
        float4 e0 = eL[wid][jj + 0];
        float4 e1 = eL[wid][jj + 1];
        float4 e2 = eL[wid][jj + 2];
        float4 e3 = eL[wid][jj + 3];
        float xg[4];
#pragma unroll
        for (int q = 0; q < 4; q++)
          xg[q] = fa ? bf2f(xbhl[(size_t)sj[q] * 128 + lane]) : 0.f;
        ag0 += e0.x * xg[0] + e1.x * xg[1] + e2.x * xg[2] + e3.x * xg[3];
        ag1 += e0.y * xg[0] + e1.y * xg[1] + e2.y * xg[2] + e3.y * xg[3];
        ag2 += e0.z * xg[0] + e1.z * xg[1] + e2.z * xg[2] + e3.z * xg[3];
        ag3 += e0.w * xg[0] + e1.w * xg[1] + e2.w * xg[2] + e3.w * xg[3];
#pragma unroll
        for (int q = 0; q < 4; q++)
          if (jj + q < cn) ax += xg[q];                // uniform guard
      }
    }
#pragma unroll
    for (int off = 32; off >= 1; off >>= 1)
#pragma unroll
      for (int h = 0; h < 4; h++) zl[h] += __shfl_xor(zl[h], off);
    {
      float z0 = zl[0] + exs[0] + 1e-16f;
      float z1 = zl[1] + exs[1] + 1e-16f;
      float z2 = zl[2] + exs[2] + 1e-16f;
      float z3 = zl[3] + exs[3] + 1e-16f;
      short* ar = agg4 + (size_t)i * A4P;
      ar[0 * 64 + lane] = fa ? f2bf(ag0 / z0) : (short)0;
      ar[1 * 64 + lane] = fa ? f2bf(ag1 / z1) : (short)0;
      ar[2 * 64 + lane] = fa ? f2bf(ag2 / z2) : (short)0;
      ar[3 * 64 + lane] = fa ? f2bf(ag3 / z3) : (short)0;
      // GIN aggregate: hi/lo double-bf16 (fp32-equivalent through MFMA)
      float axv = fa ? ax : 0.f;
      short hi = f2bf(axv);
      float lov = axv - bf2f(hi);
      short* br = aggb + (size_t)i * 128;
      br[lane]      = fa ? hi : (short)0;
      br[64 + lane] = fa ? f2bf(lov) : (short)0;
    }
  }
}

// ---------------------------------------------------------------------------
// GAT transform v4 (MFMA, LDS-free weights): A-frags from padded agg4 global,
// B-frags from Wgt global (L2-hot broadcast). LDS = psum + batL only.
// ---------------------------------------------------------------------------
__global__ __launch_bounds__(256) void k_gt(
    const short* __restrict__ agg4, const short* __restrict__ Wgt,
    const float* __restrict__ gat_b, const int* __restrict__ batch,
    float* __restrict__ pooled) {
  __shared__ float psum[4 * 224];
  __shared__ int batL[64];
  int m0 = blockIdx.x * 64;
  int t = threadIdx.x;
  for (int idx = t; idx < 4 * 224; idx += 256) psum[idx] = 0.f;
  if (t < 64) batL[t] = batch[min(m0 + t, N_NODES - 1)];
  __syncthreads();
  const int lane = t & 63, wid = t >> 6;
  const int n16 = lane & 15, quad = lane >> 4;
  const int mrow0 = wid * 16;
  const int bmin = batL[0];
  const bool uni = (batL[0] == batL[63]);
  const size_t abase = (size_t)(m0 + mrow0 + n16) * A4P;   // pad rows read workspace, masked below
#pragma unroll
  for (int h = 0; h < 4; h++) {
    short8 af0 = *(const short8*)(agg4 + abase + h * 64 + quad * 8);
    short8 af1 = *(const short8*)(agg4 + abase + h * 64 + 32 + quad * 8);
#pragma unroll
    for (int nt = 0; nt < 4; nt++) {
      short8 b0 = *(const short8*)(Wgt + (h * 56 + nt * 16 + n16) * 64 + quad * 8);
      short8 b1 = *(const short8*)(Wgt + (h * 56 + nt * 16 + n16) * 64 + 32 + quad * 8);
      f32x4 acc = {0.f, 0.f, 0.f, 0.f};
      acc = __builtin_amdgcn_mfma_f32_16x16x32_bf16(af0, b0, acc, 0, 0, 0);
      acc = __builtin_amdgcn_mfma_f32_16x16x32_bf16(af1, b1, acc, 0, 0, 0);
      int jn = nt * 16 + n16;
      bool jv = jn < FDIM;
      float bj = jv ? gat_b[h * FDIM + jn] : 0.f;
      if (uni) {
        float s = 0.f;
#pragma unroll
        for (int r = 0; r < 4; r++) {
          int gm = m0 + mrow0 + quad * 4 + r;
          if (gm < N_NODES) s += fmaxf(acc[r] + bj, 0.f);
        }
        s += __shfl_xor(s, 16);
        s += __shfl_xor(s, 32);
        if (quad == 0 && jv && s != 0.f) atomicAdd(&psum[h * 56 + jn], s);
      } else {
        float pj = 0.f; int curb = -1;
#pragma unroll
        for (int r = 0; r < 4; r++) {
          int lm = mrow0 + quad * 4 + r;
          int gm = m0 + lm;
          if (gm < N_NODES) {
            float o = fmaxf(acc[r] + bj, 0.f);
            int b = batL[lm];
            if (b != curb) {
              if (curb >= 0 && jv) {
                int slot = curb - bmin;
                if (slot >= 0 && slot < 4) atomicAdd(&psum[slot * 224 + h * 56 + jn], pj);
                else atomicAdd(&pooled[(size_t)curb * POOLW + h * FDIM + jn], pj);
              }
              curb = b; pj = o;
            } else {
              pj += o;
            }
          }
        }
        if (curb >= 0 && jv) {
          int slot = curb - bmin;
          if (slot >= 0 && slot < 4) atomicAdd(&psum[slot * 224 + h * 56 + jn], pj);
          else atomicAdd(&pooled[(size_t)curb * POOLW + h * FDIM + jn], pj);
        }
      }
    }
  }
  __syncthreads();
  for (int idx = t; idx < 4 * 224; idx += 256) {
    int slot = idx / 224, c = idx % 224;
    int h = c / 56, jn = c % 56;
    float v = psum[idx];
    int b = bmin + slot;
    if (jn < FDIM && b < BATCH && v != 0.f)
      atomicAdd(&pooled[(size_t)b * POOLW + h * FDIM + jn], v);
  }
}

// ---------------------------------------------------------------------------
// GIN MLP v4 (MFMA, LDS-free weights): layer-1 A from aggb global (hi/lo,
// K=128, Wg1 dup rows); h1 hi/lo bf16 in LDS; layer-2 B from Wg2 global with
// dual hi/lo accumulation. LDS = h1 pair + psum -> 4 blocks/CU.
// ---------------------------------------------------------------------------
#define H1S 132   /* h1 row stride in shorts: 66 words % 32 = 2 -> conflict-free */
__global__ __launch_bounds__(256) void k_ginm(
    const short* __restrict__ aggb, const short* __restrict__ Wg1,
    const short* __restrict__ Wg2,
    const float* __restrict__ b1, const float* __restrict__ b2,
    const int* __restrict__ batch, float* __restrict__ pooled) {
  __shared__ short h1hi[64 * H1S];    // 16.9 KB
  __shared__ short h1lo[64 * H1S];    // 16.9 KB
  __shared__ float psum[4 * 112];
  __shared__ int batL[64];
  int m0 = blockIdx.x * 64;
  int t = threadIdx.x;
  for (int idx = t; idx < 4 * 112; idx += 256) psum[idx] = 0.f;
  if (t < 64) batL[t] = batch[min(m0 + t, N_NODES - 1)];
  for (int idx = t; idx < 64 * H1S / 2; idx += 256) {
    ((int*)h1hi)[idx] = 0;
    ((int*)h1lo)[idx] = 0;
  }
  __syncthreads();
  const int lane = t & 63, wid = t >> 6;
  const int n16 = lane & 15, quad = lane >> 4;
  const int mrow0 = wid * 16;
  const int bmin = batL[0];
  const bool uni = (batL[0] == batL[63]);
  // ---- layer 1: h1 = relu((hi+lo) @ w1 + b1) -> h1hi/h1lo ----
  {
    const size_t abase = (size_t)(m0 + mrow0 + n16) * 128;  // pad rows: workspace, masked later
    short8 a[4];
#pragma unroll
    for (int f = 0; f < 4; f++)
      a[f] = *(const short8*)(aggb + abase + f * 32 + quad * 8);
#pragma unroll
    for (int nt = 0; nt < 7; nt++) {
      f32x4 acc = {0.f, 0.f, 0.f, 0.f};
#pragma unroll
      for (int f = 0; f < 4; f++) {
        short8 bf = *(const short8*)(Wg1 + (nt * 16 + n16) * 128 + f * 32 + quad * 8);
        acc = __builtin_amdgcn_mfma_f32_16x16x32_bf16(a[f], bf, acc, 0, 0, 0);
      }
      int jn = nt * 16 + n16;
      if (jn < F2) {
        float bj = b1[jn];
#pragma unroll
        for (int r = 0; r < 4; r++) {
          int row = mrow0 + quad * 4 + r;
          float v = fmaxf(acc[r] + bj, 0.f);
          short hi = f2bf(v);
          h1hi[row * H1S + jn] = hi;
          h1lo[row * H1S + jn] = f2bf(v - bf2f(hi));
        }
      }
    }
  }
  __syncthreads();   // h1 writes complete
  // ---- layer 2: h2 = relu((h1hi+h1lo) @ w2 + b2) + pooled accumulation ----
  short8 ah[4], al[4];
#pragma unroll
  for (int f = 0; f < 4; f++) {
    ah[f] = *(const short8*)&h1hi[(mrow0 + n16) * H1S + f * 32 + quad * 8];
    al[f] = *(const short8*)&h1lo[(mrow0 + n16) * H1S + f * 32 + quad * 8];
  }
#pragma unroll
  for (int nt = 0; nt < 7; nt++) {
    f32x4 acc = {0.f, 0.f, 0.f, 0.f};
#pragma unroll
    for (int f = 0; f < 4; f++) {
      short8 bf = *(const short8*)(Wg2 + (nt * 16 + n16) * 128 + f * 32 + quad * 8);
      acc = __builtin_amdgcn_mfma_f32_16x16x32_bf16(ah[f], bf, acc, 0, 0, 0);
      acc = __builtin_amdgcn_mfma_f32_16x16x32_bf16(al[f], bf, acc, 0, 0, 0);
    }
    int jn = nt * 16 + n16;
    bool jv = jn < F2;
    float bj = jv ? b2[jn] : 0.f;
    if (uni) {
      float s = 0.f;
#pragma unroll
      for (int r = 0; r < 4; r++) {
        int gm = m0 + mrow0 + quad * 4 + r;
        if (gm < N_NODES) s += fmaxf(acc[r] + bj, 0.f);
      }
      s += __shfl_xor(s, 16);
      s += __shfl_xor(s, 32);
      if (quad == 0 && jv && s != 0.f) atomicAdd(&psum[jn], s);
    } else {
      float pj = 0.f; int curb = -1;
#pragma unroll
      for (int r = 0; r < 4; r++) {
        int lm = mrow0 + quad * 4 + r;
        int gm = m0 + lm;
        if (gm < N_NODES) {
          float o = fmaxf(acc[r] + bj, 0.f);
          int b = batL[lm];
          if (b != curb) {
            if (curb >= 0 && jv) {
              int slot = curb - bmin;
              if (slot >= 0 && slot < 4) atomicAdd(&psum[slot * 112 + jn], pj);
              else atomicAdd(&pooled[(size_t)curb * POOLW + HF + jn], pj);
            }
            curb = b; pj = o;
          } else {
            pj += o;
          }
        }
      }
      if (curb >= 0 && jv) {
        int slot = curb - bmin;
        if (slot >= 0 && slot < 4) atomicAdd(&psum[slot * 112 + jn], pj);
        else atomicAdd(&pooled[(size_t)curb * POOLW + HF + jn], pj);
      }
    }
  }
  __syncthreads();
  for (int idx = t; idx < 4 * 112; idx += 256) {
    int slot = idx / 112, n = idx % 112;
    float v = psum[idx];
    int b = bmin + slot;
    if (n < F2 && b < BATCH && v != 0.f)
      atomicAdd(&pooled[(size_t)b * POOLW + HF + n], v);
  }
}

// ---------------------------------------------------------------------------
// EdgeConv v8 (round-5 best): bf16 U/V, rp/batch in LDS, colidx prefetched
// 2 tiles ahead / V 1 tile ahead, deferred cross-quad max reduction,
// double-buffered LDS, lgkmcnt-only barrier.
// ---------------------------------------------------------------------------
#define ECH 25
__global__ __launch_bounds__(256) void k_ec(
    const short* __restrict__ Ub, const short* __restrict__ Vb,
    const float* __restrict__ w2, const float* __restrict__ b2,
    const int* __restrict__ rp, const int* __restrict__ colidx,
    const int* __restrict__ batch, float* __restrict__ pooled) {
  const int t = threadIdx.x;
  const int lane = t & 63, wid = t >> 6;
  const int n16 = lane & 15, quad = lane >> 4;
  const int nt = (wid == 3) ? 1 : 2;   // u-tile 7 is all-pad

  const int i0 = blockIdx.x * ECH;
  const int iend = min(i0 + ECH, N_NODES);
  const int nn = iend - i0;

  __shared__ int rpL[ECH + 1];
  __shared__ int batL[ECH];

  short8 Bh[2][4];
  for (int tt = 0; tt < 2; tt++) {
    int ucol = (wid * 2 + tt) * 16 + n16;
    for (int kc = 0; kc < 4; kc++) {
      short8 vh;
#pragma unroll
      for (int jv = 0; jv < 8; jv++) {
        int kk = kc * 32 + quad * 8 + jv;
        float w = (ucol < F2 && kk < F2) ? w2[kk * F2 + ucol] : 0.f;
        vh[jv] = f2bf(w);
      }
      Bh[tt][kc] = vh;
    }
  }
  float b2v[2];
#pragma unroll
  for (int tt = 0; tt < 2; tt++) {
    int u = (wid * 2 + tt) * 16 + n16;
    b2v[tt] = (u < F2) ? b2[u] : 0.f;
  }

  if (t <= nn) rpL[t] = rp[i0 + t];
  if (t < nn) batL[t] = batch[i0 + t];
  __syncthreads();

  __shared__ short hs[2][16 * 16 * 8];
  union SU { short8 s; unsigned u[4]; };
  const int es = t & 15, kg = t >> 4;
  const int k0 = kg * 8;

  float sm0 = 0.f, sm1 = 0.f;
  int curb = -1;
  const int u0 = (wid * 2) * 16 + n16;
  const int u1 = (wid * 2 + 1) * 16 + n16;

  // tile walk: (node, tile-in-node, base, deg) -> next
  auto advance = [&](int& ii, int& ttb, int& bb, int& dd) -> bool {
    ttb++;
    if (ttb * 16 < dd) return true;
    ttb = 0;
    for (ii = ii + 1; ii < iend; ii++) {
      bb = rpL[ii - i0]; dd = rpL[ii - i0 + 1] - bb;
      if (dd > 0) return true;
    }
    return false;
  };

  // current tile T
  int i = i0, tb = 0, base = 0, deg = 0;
  bool have = false;
  for (; i < iend; i++) {
    base = rpL[i - i0]; deg = rpL[i - i0 + 1] - base;
    if (deg > 0) { have = true; break; }
  }
  short8 pu8{}, pv8{};
  // tile T+1 coords + its colidx value (sc) already fetched
  int i1 = i, tb1 = 0, base1 = base, deg1 = deg;
  bool have1 = false;
  int sc = 0;
  if (have) {
    pu8 = *(const short8*)(Ub + (size_t)i * ECS + k0);
    int s0 = colidx[base + ((es < deg) ? es : 0)];
    pv8 = *(const short8*)(Vb + (size_t)s0 * ECS + k0);
    have1 = advance(i1, tb1, base1, deg1);
    if (have1) {
      int eg = tb1 * 16 + es;
      sc = colidx[base1 + ((eg < deg1) ? eg : 0)];
    }
  }

  float Uc[8];
  float vmax0 = -1e30f, vmax1 = -1e30f;
  int parity = 0;
  while (have) {
    if (tb == 0) {
#pragma unroll
      for (int j = 0; j < 8; j++) Uc[j] = bf2f(pu8[j]);
    }
    SU w;
#pragma unroll
    for (int p = 0; p < 4; p++) {
      bool kv = (k0 + 2 * p) < F2;
      float h0 = kv ? fmaxf(Uc[2 * p]     + bf2f(pv8[2 * p]),     0.f) : 0.f;
      float h1 = kv ? fmaxf(Uc[2 * p + 1] + bf2f(pv8[2 * p + 1]), 0.f) : 0.f;
      w.u[p] = pk2(h0, h1);
    }
    *(short8*)&hs[parity][(kg * 16 + es) * 8] = w.s;

    // prefetch: V (and U) for tile T+1 using sc fetched last iter; colidx for T+2
    int i2 = i1, tb2 = tb1, base2 = base1, deg2 = deg1;
    bool have2 = false;
    int scN = 0;
    if (have1) {
      if (tb1 == 0) pu8 = *(const short8*)(Ub + (size_t)i1 * ECS + k0);
      pv8 = *(const short8*)(Vb + (size_t)sc * ECS + k0);
      have2 = advance(i2, tb2, base2, deg2);
      if (have2) {
        int eg2 = tb2 * 16 + es;
        scN = colidx[base2 + ((eg2 < deg2) ? eg2 : 0)];
      }
    }

    ldsbar();
    f32x4 a0 = {0.f, 0.f, 0.f, 0.f}, a1 = {0.f, 0.f, 0.f, 0.f};
#pragma unroll
    for (int kc = 0; kc < 4; kc++) {
      short8 af = *(const short8*)&hs[parity][((kc * 4 + quad) * 16 + n16) * 8];
      a0 = __builtin_amdgcn_mfma_f32_16x16x32_bf16(af, Bh[0][kc], a0, 0, 0, 0);
      if (nt > 1)
        a1 = __builtin_amdgcn_mfma_f32_16x16x32_bf16(af, Bh[1][kc], a1, 0, 0, 0);
    }
#pragma unroll
    for (int r = 0; r < 4; r++) {
      int er = tb * 16 + quad * 4 + r;
      if (er < deg) { vmax0 = fmaxf(vmax0, a0[r]); vmax1 = fmaxf(vmax1, a1[r]); }
    }
    if (!have1 || i1 != i) {
      // node i finishes with this tile: cross-quad reduce deferred to here
      vmax0 = fmaxf(vmax0, __shfl_xor(vmax0, 16));
      vmax0 = fmaxf(vmax0, __shfl_xor(vmax0, 32));
      vmax1 = fmaxf(vmax1, __shfl_xor(vmax1, 16));
      vmax1 = fmaxf(vmax1, __shfl_xor(vmax1, 32));
      float o0 = fmaxf(vmax0 + b2v[0], 0.f);
      float o1 = fmaxf(vmax1 + b2v[1], 0.f);
      int b = batL[i - i0];
      if (b != curb) {
        if (curb >= 0 && quad == 0) {
          float* pg = pooled + (size_t)curb * POOLW + HF + F2;
          if (u0 < F2) atomicAdd(&pg[u0], sm0);
          if (nt > 1 && u1 < F2) atomicAdd(&pg[u1], sm1);
        }
        curb = b; sm0 = o0; sm1 = o1;
      } else {
        sm0 += o0; sm1 += o1;
      }
      vmax0 = -1e30f; vmax1 = -1e30f;
    }
    i = i1; tb = tb1; base = base1; deg = deg1; have = have1;
    i1 = i2; tb1 = tb2; base1 = base2; deg1 = deg2; have1 = have2;
    sc = scN;
    parity ^= 1;
  }
  if (curb >= 0 && quad == 0) {
    float* pg = pooled + (size_t)curb * POOLW + HF + F2;
    if (u0 < F2) atomicAdd(&pg[u0], sm0);
    if (nt > 1 && u1 < F2) atomicAdd(&pg[u1], sm1);
  }
}

// ---------------------------------------------------------------------------
// Per-graph heads + final MLP fused; mean-pool divide folded into the load.
// ---------------------------------------------------------------------------
__global__ __launch_bounds__(256) void k_heads(
    const float* __restrict__ pooled, const int* __restrict__ start,
    const float* __restrict__ fg1_w, const float* __restrict__ fg1_b,
    const float* __restrict__ fg2_w, const float* __restrict__ fg2_b,
    const float* __restrict__ fg3_w, const float* __restrict__ fg3_b,
    const float* __restrict__ fg4_w, const float* __restrict__ fg4_b,
    const float* __restrict__ fg5_w, const float* __restrict__ fg5_b,
    const float* __restrict__ fg6_w, const float* __restrict__ fg6_b,
    const float* __restrict__ fc1_w, const float* __restrict__ fc1_b,
    const float* __restrict__ fc2_w, const float* __restrict__ fc2_b,
    const float* __restrict__ out_w, const float* __restrict__ out_b,
    float* __restrict__ out) {
  int g = blockIdx.x, t = threadIdx.x;
  __shared__ float in[POOLW];
  __shared__ float mid[256];
  __shared__ float cat[384];
  __shared__ float h1[128];
  __shared__ float h2[64];
  float c = fmaxf((float)(start[g + 1] - start[g]), 1.f);
  for (int idx = t; idx < POOLW; idx += 256)
    in[idx] = pooled[(size_t)g * POOLW + idx] / c;
  __syncthreads();
  const float* w1s[3] = {fg1_w, fg3_w, fg5_w};
  const float* b1s[3] = {fg1_b, fg3_b, fg5_b};
  const float* w2s[3] = {fg2_w, fg4_w, fg6_w};
  const float* b2s[3] = {fg2_b, fg4_b, fg6_b};
  const int off[4] = {0, HF, HF + F2, POOLW};
  for (int br = 0; br < 3; br++) {
    int kin = off[br + 1] - off[br];
    const float* iv = &in[off[br]];
    float a = b1s[br][t];
    const float* W = w1s[br];
    for (int k = 0; k < kin; k++) a += iv[k] * W[k * 256 + t];
    mid[t] = fmaxf(a, 0.f);
    __syncthreads();
    if (t < 128) {
      float b = b2s[br][t];
      const float* W2 = w2s[br];
      for (int k = 0; k < 256; k++) b += mid[k] * W2[k * 128 + t];
      cat[br * 128 + t] = fmaxf(b, 0.f);
    }
    __syncthreads();
  }
  if (t < 128) {
    float a = fc1_b[t];
    for (int k = 0; k < 384; k++) a += cat[k] * fc1_w[k * 128 + t];
    h1[t] = fmaxf(a, 0.f);
  }
  __syncthreads();
  if (t < 64) {
    float a = fc2_b[t];
    for (int k = 0; k < 128; k++) a += h1[k] * fc2_w[k * 64 + t];
    h2[t] = fmaxf(a, 0.f);
  }
  __syncthreads();
  if (t == 0) {
    float a = out_b[0];
    for (int k = 0; k < 64; k++) a += h2[k] * out_w[k];
    out[g] = 1.f / (1.f + __expf(-a));
  }
}

// ---------------------------------------------------------------------------
extern "C" void kernel_launch(void* const* d_in, const int* in_sizes, int n_in,
                              void* d_out, int out_size, void* d_ws, size_t ws_size,
                              hipStream_t stream) {
  const float* x      = (const float*)d_in[0];
  const int*   ei     = (const int*)d_in[1];
  const int*   batch  = (const int*)d_in[2];
  const float* gat_w  = (const float*)d_in[3];
  const float* asrc   = (const float*)d_in[4];
  const float* adst   = (const float*)d_in[5];
  const float* gat_b  = (const float*)d_in[6];
  const float* gin_w1 = (const float*)d_in[7];
  const float* gin_b1 = (const float*)d_in[8];
  const float* gin_w2 = (const float*)d_in[9];
  const float* gin_b2 = (const float*)d_in[10];
  const float* ec_w1  = (const float*)d_in[11];
  const float* ec_b1  = (const float*)d_in[12];
  const float* ec_w2  = (const float*)d_in[13];
  const float* ec_b2  = (const float*)d_in[14];
  const float* fg1_w = (const float*)d_in[15]; const float* fg1_b = (const float*)d_in[16];
  const float* fg2_w = (const float*)d_in[17]; const float* fg2_b = (const float*)d_in[18];
  const float* fg3_w = (const float*)d_in[19]; const float* fg3_b = (const float*)d_in[20];
  const float* fg4_w = (const float*)d_in[21]; const float* fg4_b = (const float*)d_in[22];
  const float* fg5_w = (const float*)d_in[23]; const float* fg5_b = (const float*)d_in[24];
  const float* fg6_w = (const float*)d_in[25]; const float* fg6_b = (const float*)d_in[26];
  const float* fc1_w = (const float*)d_in[27]; const float* fc1_b = (const float*)d_in[28];
  const float* fc2_w = (const float*)d_in[29]; const float* fc2_b = (const float*)d_in[30];
  const float* out_w = (const float*)d_in[31]; const float* out_b = (const float*)d_in[32];
  float* out = (float*)d_out;

  char* ws = (char*)d_ws;
  size_t off = 0;
  auto alloc = [&](size_t bytes) -> void* {
    void* p = ws + off;
    off = (off + bytes + 255) & ~(size_t)255;
    return p;
  };
  // --- zero region (one memset): histP | pooled ---
  size_t zoff0 = off;
  int*   histP  = (int*)alloc((size_t)N_NODES * PSTR * sizeof(int));  // 6.4 MB padded bins
  float* pooled = (float*)alloc((size_t)BATCH * POOLW * sizeof(float));
  size_t zbytes = off - zoff0;
  // --- rest ---
  int*   rp     = (int*)alloc((N_NODES + 1) * sizeof(int));
  int*   start  = (int*)alloc((BATCH + 1) * sizeof(int));
  int*   bsum   = (int*)alloc(256 * sizeof(int));
  int*   colidx = (int*)alloc(N_EDGES * sizeof(int));
  short* xbhl   = (short*)alloc((size_t)(N_NODES + 64) * 128 * sizeof(short)); // x hi/lo
  float* alS    = (float*)alloc((size_t)N_NODES * 4 * sizeof(float));
  float* alD    = (float*)alloc((size_t)N_NODES * 4 * sizeof(float));
  short* Ubuf   = (short*)alloc((size_t)N_NODES * ECS * sizeof(short));  // bf16, 256B rows
  short* Vbuf   = (short*)alloc((size_t)N_NODES * ECS * sizeof(short));  // bf16, 256B rows
  short* agg4   = (short*)alloc((size_t)(N_NODES + 64) * A4P * sizeof(short)); // padded bf16
  short* aggb   = (short*)alloc((size_t)(N_NODES + 64) * 128 * sizeof(short)); // GIN hi/lo
  float* cAl    = (float*)alloc(SEG_CAL * sizeof(float));
  short* Wgt    = (short*)alloc(SEG_WGT * sizeof(short));
  short* Wuv    = (short*)alloc(SEG_WUV * sizeof(short));
  short* Wg1    = (short*)alloc(SEG_WG1 * sizeof(short));
  short* Wg2    = (short*)alloc(SEG_WG2 * sizeof(short));
  (void)ws_size; (void)in_sizes; (void)n_in; (void)out_size;

  hipMemsetAsync(ws + zoff0, 0, zbytes, stream);

  k_prep<<<(PREP_TOT + 255) / 256, 256, 0, stream>>>(gat_w, asrc, adst, ec_w1,
                                                     gin_w1, gin_w2,
                                                     cAl, Wgt, Wuv, Wg1, Wg2);
  k_xsplit<<<(N_NODES + 3) / 4, 256, 0, stream>>>(x, cAl, xbhl, alS, alD);
  k_uv<<<((N_NODES + 63) / 64) * 2, 256, 0, stream>>>(xbhl, Wuv, ec_b1, Ubuf, Vbuf);
  k_hist<<<(N_EDGES + 255) / 256, 256, 0, stream>>>(ei, histP);
  k_scan1<<<SCAN_BLOCKS, 256, 0, stream>>>(histP, batch, rp, bsum, start);
  k_scan3<<<SCAN_BLOCKS, 256, 0, stream>>>(bsum, rp, histP);
  k_scatter<<<(N_EDGES + 255) / 256, 256, 0, stream>>>(ei, histP, colidx);

  // fused GAT-aggregate + GIN-sum over the L2-resident bf16 x table
  k_gatgin<<<(N_NODES + GCH - 1) / GCH, 256, 0, stream>>>(xbhl, alS, alD, rp, colidx,
                                                          agg4, aggb);
  k_ec<<<(N_NODES + ECH - 1) / ECH, 256, 0, stream>>>(Ubuf, Vbuf, ec_w2, ec_b2, rp, colidx, batch, pooled);
  // GAT transform (MFMA, global A+B frags)
  k_gt<<<(N_NODES + 63) / 64, 256, 0, stream>>>(agg4, Wgt, gat_b, batch, pooled);
  // GIN MLP (MFMA, hi/lo precision, global B frags)
  k_ginm<<<(N_NODES + 63) / 64, 256, 0, stream>>>(aggb, Wg1, Wg2, gin_b1, gin_b2,
                                                  batch, pooled);

  k_heads<<<BATCH, 256, 0, stream>>>(pooled, start,
                                     fg1_w, fg1_b, fg2_w, fg2_b, fg3_w, fg3_b,
                                     fg4_w, fg4_b, fg5_w, fg5_b, fg6_w, fg6_b,
                                     fc1_w, fc1_b, fc2_w, fc2_b, out_w, out_b, out);
}

// Round 19
// 595.335 us; speedup vs baseline: 1.2665x; 1.0317x over previous
//
#include <hip/hip_runtime.h>
#include <hip/hip_bf16.h>
#include <math.h>

#define N_NODES 50000
#define N_EDGES 800000
#define FDIM 53
#define BATCH 128
#define HF 212   /* H*F */
#define F2 106   /* 2F  */
#define POOLW 424 /* 212+106+106 */
#define PSTR 32  /* padded bin stride (ints) = 128 B: one L2 line per node */
#define ECS 128  /* U/V bf16 row stride (shorts) = 256 B = 4 L2 lines */
#define A4P 256  /* agg4 padded row stride (shorts): [node][4][64], 16B aligned */

typedef __attribute__((ext_vector_type(8))) short short8;
typedef __attribute__((ext_vector_type(4))) float f32x4;

__device__ __forceinline__ float leaky02(float x){ return x >= 0.f ? x : 0.2f * x; }

__device__ __forceinline__ short f2bf(float x) {
  unsigned u = __float_as_uint(x);
  unsigned r = (u + 0x7fffu + ((u >> 16) & 1u)) >> 16;
  return (short)r;
}
__device__ __forceinline__ float bf2f(short b) {
  return __uint_as_float(((unsigned)(unsigned short)b) << 16);
}
// packed pair f32x2 -> bf16x2 (v_cvt_pk_bf16_f32, RNE)
__device__ __forceinline__ unsigned pk2(float a, float b) {
  union { __hip_bfloat162 h; unsigned u; } c;
  c.h = __float22bfloat162_rn(make_float2(a, b));
  return c.u;
}
// LDS-only barrier: waits lgkmcnt(0) (ds ops) but leaves global loads in flight
__device__ __forceinline__ void ldsbar() {
  __builtin_amdgcn_s_waitcnt(0xC07F);   // vmcnt(63) expcnt(7) lgkmcnt(0)
  __builtin_amdgcn_s_barrier();
}

// ---------------------------------------------------------------------------
// Weight prep: pack all MFMA B-fragment buffers (bf16, L2-resident broadcast).
//   Wgt[4][56][64]    : gat_w per-head transposed, k-padded
//   Wuv[2][128][256]  : EC U/V weights, K=256 hi/lo layout (kk<128 hi, else lo)
//                       chunk0 cols 112..119 = cAl columns (inline 53-MAC dot)
//   Wg1[112][128]     : gin_w1 dup rows (hi/lo A), bf16
//   Wg2[112][128]     : gin_w2 transposed, bf16
// ---------------------------------------------------------------------------
#define SEG_WGT (4*56*64)
#define SEG_WUV (2*128*256)
#define SEG_WG1 (112*128)
#define SEG_WG2 (112*128)
#define PREP_TOT (SEG_WGT + SEG_WUV + SEG_WG1 + SEG_WG2)
__global__ void k_prep(const float* __restrict__ gat_w, const float* __restrict__ asrc,
                       const float* __restrict__ adst, const float* __restrict__ ec_w1,
                       const float* __restrict__ gin_w1, const float* __restrict__ gin_w2,
                       short* __restrict__ Wgt, short* __restrict__ Wuv,
                       short* __restrict__ Wg1, short* __restrict__ Wg2) {
  int idx = blockIdx.x * blockDim.x + threadIdx.x;
  if (idx < SEG_WGT) {
    int h = idx / (56 * 64), rem = idx % (56 * 64);
    int n = rem >> 6, kk = rem & 63;
    Wgt[idx] = (kk < FDIM && n < FDIM) ? f2bf(gat_w[kk * HF + h * FDIM + n]) : (short)0;
    return;
  }
  idx -= SEG_WGT;
  if (idx < SEG_WUV) {
    int c = idx / (128 * 256), rem = idx % (128 * 256);
    int n = rem >> 8, kk = rem & 255, ks = kk & 63;
    float w = 0.f;
    if (ks < FDIM) {
      if (c == 0) {
        if (n < F2) {
          w = ec_w1[ks * F2 + n] - ec_w1[(FDIM + ks) * F2 + n];
        } else if (n >= 112 && n < 120) {
          int j = n - 112, sd = j >> 2, h = j & 3;
          const float* av = sd ? adst : asrc;
          float acc = 0.f;
          for (int f = 0; f < FDIM; ++f)
            acc += gat_w[ks * HF + h * FDIM + f] * av[h * FDIM + f];
          w = acc;
        }
      } else {
        if (n < F2) w = ec_w1[(FDIM + ks) * F2 + n];
      }
    }
    short hv = f2bf(w);
    Wuv[idx] = (kk < 128) ? hv : f2bf(w - bf2f(hv));
    return;
  }
  idx -= SEG_WUV;
  if (idx < SEG_WG1) {
    int n = idx >> 7, kk = idx & 127, ks = kk & 63;
    Wg1[idx] = (ks < FDIM && n < F2) ? f2bf(gin_w1[ks * F2 + n]) : (short)0;
    return;
  }
  idx -= SEG_WG1;
  if (idx < SEG_WG2) {
    int n = idx >> 7, kk = idx & 127;
    Wg2[idx] = (kk < F2 && n < F2) ? f2bf(gin_w2[kk * F2 + n]) : (short)0;
  }
}

// ---------------------------------------------------------------------------
// x split: xbhl[node][128] = [hi(0..63) | lo(64..127)] bf16 (zeros k>=53).
// ---------------------------------------------------------------------------
__global__ __launch_bounds__(256) void k_xsplit(
    const float* __restrict__ x, short* __restrict__ xbhl) {
  int wid = threadIdx.x >> 6, lane = threadIdx.x & 63;
  int i = blockIdx.x * 4 + wid;
  if (i >= N_NODES) return;
  float v = (lane < FDIM) ? x[(size_t)i * FDIM + lane] : 0.f;
  short hi = f2bf(v);
  xbhl[(size_t)i * 128 + lane] = hi;
  xbhl[(size_t)i * 128 + 64 + lane] = f2bf(v - bf2f(hi));
}

// ---------------------------------------------------------------------------
// U/V linear + al (MFMA, zero LDS): K=256 hi/lo exact product. Chunk c:
// 0 = U (+ al columns in n-tile 7 -> alS/alD fp32), 1 = V.
// ---------------------------------------------------------------------------
__global__ __launch_bounds__(256) void k_uv(
    const short* __restrict__ xbhl, const short* __restrict__ Wuv,
    const float* __restrict__ ec_b1,
    short* __restrict__ Ub, short* __restrict__ Vb,
    float* __restrict__ alS, float* __restrict__ alD) {
  int bid = blockIdx.x;
  int nb = bid >> 1, c = bid & 1;
  int m0 = nb * 64;
  int t = threadIdx.x;
  const int lane = t & 63, wid = t >> 6;
  const int n16 = lane & 15, quad = lane >> 4;
  const int mrow0 = wid * 16;
  const size_t abase = (size_t)(m0 + mrow0 + n16) * 128;   // pad rows: workspace
  short8 a[4];
#pragma unroll
  for (int f = 0; f < 4; f++)
    a[f] = *(const short8*)(xbhl + abase + f * 32 + quad * 8);
  const short* Bw = Wuv + (size_t)c * 128 * 256;
  short* Ob = c ? Vb : Ub;
  const int ntmax = (c == 0) ? 8 : 7;
  for (int nt = 0; nt < ntmax; nt++) {
    f32x4 acc = {0.f, 0.f, 0.f, 0.f};
#pragma unroll
    for (int f = 0; f < 8; f++) {
      short8 bf = *(const short8*)(Bw + (nt * 16 + n16) * 256 + f * 32 + quad * 8);
      acc = __builtin_amdgcn_mfma_f32_16x16x32_bf16(a[f & 3], bf, acc, 0, 0, 0);
    }
    int jn = nt * 16 + n16;
    if (nt < 7) {
      if (jn < F2) {
        float bj = c ? 0.f : ec_b1[jn];
#pragma unroll
        for (int r = 0; r < 4; r++) {
          int gm = m0 + mrow0 + quad * 4 + r;
          if (gm < N_NODES) Ob[(size_t)gm * ECS + jn] = f2bf(acc[r] + bj);
        }
      }
    } else {
      // al columns: j = n16 (0..7): 0..3 -> alS, 4..7 -> alD
      int j = n16;
      if (j < 8) {
#pragma unroll
        for (int r = 0; r < 4; r++) {
          int gm = m0 + mrow0 + quad * 4 + r;
          if (gm < N_NODES) {
            if (j < 4) alS[gm * 4 + j] = acc[r];
            else       alD[gm * 4 + (j - 4)] = acc[r];
          }
        }
      }
    }
  }
}

// ---------------------------------------------------------------------------
// CSR build: hist -> scan1 (block scan + batch boundaries) -> scan3 (folds
// the bsum prefix scan) -> scatter.
// ---------------------------------------------------------------------------
#define SCAN_BLOCKS ((N_NODES + 255) / 256)

__global__ void k_hist(const int* __restrict__ ei, int* __restrict__ histP) {
  int t = blockIdx.x * blockDim.x + threadIdx.x;
  if (t < N_EDGES) atomicAdd(&histP[ei[N_EDGES + t] << 5], 1);
}

__global__ __launch_bounds__(256) void k_scan1(const int* __restrict__ histP,
                                               const int* __restrict__ batch,
                                               int* __restrict__ rp, int* __restrict__ bsum,
                                               int* __restrict__ start) {
  __shared__ int buf[256];
  int tid = threadIdx.x;
  int idx = blockIdx.x * 256 + tid;
  int v = (idx < N_NODES) ? histP[idx << 5] : 0;
  buf[tid] = v;
  __syncthreads();
  for (int off = 1; off < 256; off <<= 1) {
    int t2 = (tid >= off) ? buf[tid - off] : 0;
    __syncthreads();
    buf[tid] += t2;
    __syncthreads();
  }
  if (idx < N_NODES) rp[idx] = buf[tid] - v;
  if (tid == 255) bsum[blockIdx.x] = buf[255];
  // fused batch-boundary detection (was k_bnd)
  if (idx < N_NODES) {
    int b = batch[idx];
    if (idx == 0)
      for (int g = 0; g <= b; g++) start[g] = 0;
    int bn = (idx + 1 < N_NODES) ? batch[idx + 1] : BATCH;
    for (int g = b + 1; g <= bn; g++) start[g] = idx + 1;
  }
}

__global__ __launch_bounds__(256) void k_scan3(const int* __restrict__ bsum,
                                               int* __restrict__ rp, int* __restrict__ histP) {
  __shared__ int buf[256];
  int tid = threadIdx.x;
  int v = (tid < SCAN_BLOCKS) ? bsum[tid] : 0;
  buf[tid] = v;
  __syncthreads();
  for (int off = 1; off < 256; off <<= 1) {
    int t2 = (tid >= off) ? buf[tid - off] : 0;
    __syncthreads();
    buf[tid] += t2;
    __syncthreads();
  }
  int boff = (blockIdx.x == 0) ? 0 : buf[blockIdx.x - 1];   // exclusive offset
  int idx = blockIdx.x * 256 + tid;
  if (idx < N_NODES) {
    int o = rp[idx] + boff;
    rp[idx] = o;
    histP[idx << 5] = o;   // becomes the (padded) scatter cursor
  }
  if (idx == 0) rp[N_NODES] = N_EDGES;
}

__global__ void k_scatter(const int* __restrict__ ei, int* __restrict__ histP,
                          int* __restrict__ colidx) {
  int e = blockIdx.x * blockDim.x + threadIdx.x;
  if (e >= N_EDGES) return;
  int d = ei[N_EDGES + e];
  int pos = atomicAdd(&histP[d << 5], 1);
  colidx[pos] = ei[e];
}

// ---------------------------------------------------------------------------
// Fused GAT-aggregate + GIN-sum. x rows read from xbhl (hi half, stride 128).
// agg4 padded [node][4][64] bf16; GIN aggregate hi/lo pair aggb[node][128].
// ---------------------------------------------------------------------------
#define GCH 20
__global__ __launch_bounds__(256) void k_gatgin(
    const short* __restrict__ xbhl, const float* __restrict__ alS, const float* __restrict__ alD,
    const int* __restrict__ rp, const int* __restrict__ colidx,
    short* __restrict__ agg4, short* __restrict__ aggb) {
  int wid = threadIdx.x >> 6, lane = threadIdx.x & 63;
  bool fa = lane < FDIM;
  int i0 = blockIdx.x * GCH;
  int iend = min(i0 + GCH, N_NODES);
  __shared__ int rpG[GCH + 1];
  __shared__ int sL[4][64];        // per-wave edge src ids
  __shared__ float4 eL[4][64];     // per-wave edge alphas (4 heads)
  {
    int t = threadIdx.x, nn = iend - i0;
    if (t <= nn) rpG[t] = rp[i0 + t];
  }
  __syncthreads();
  for (int i = i0 + wid; i < iend; i += 4) {
    int base = rpG[i - i0], deg = rpG[i - i0 + 1] - base;
    float4 adv = *(const float4*)(alD + (size_t)i * 4);
    float4 asv = *(const float4*)(alS + (size_t)i * 4);
    float aldi[4] = {adv.x, adv.y, adv.z, adv.w};
    float exs[4];
    exs[0] = __expf(leaky02(asv.x + aldi[0]));   // self-loop term
    exs[1] = __expf(leaky02(asv.y + aldi[1]));
    exs[2] = __expf(leaky02(asv.z + aldi[2]));
    exs[3] = __expf(leaky02(asv.w + aldi[3]));
    float xiv = fa ? bf2f(xbhl[(size_t)i * 128 + lane]) : 0.f;
    float ag0 = exs[0] * xiv, ag1 = exs[1] * xiv, ag2 = exs[2] * xiv, ag3 = exs[3] * xiv;
    float ax = xiv;
    float zl[4] = {0.f, 0.f, 0.f, 0.f};

    for (int c0 = 0; c0 < deg; c0 += 64) {
      int cn = min(64, deg - c0);
      int s = 0;
      float ex0 = 0.f, ex1 = 0.f, ex2 = 0.f, ex3 = 0.f;
      if (lane < cn) {
        s = colidx[base + c0 + lane];
        float4 av = *(const float4*)(alS + (size_t)s * 4);
        ex0 = __expf(leaky02(av.x + aldi[0]));
        ex1 = __expf(leaky02(av.y + aldi[1]));
        ex2 = __expf(leaky02(av.z + aldi[2]));
        ex3 = __expf(leaky02(av.w + aldi[3]));
        zl[0] += ex0; zl[1] += ex1; zl[2] += ex2; zl[3] += ex3;
      }
      // wave-local LDS stage; wave64 lockstep, no barrier needed.
      sL[wid][lane] = s;
      eL[wid][lane] = make_float4(ex0, ex1, ex2, ex3);
      for (int jj = 0; jj < cn; jj += 4) {
        int4 s4 = *(const int4*)&sL[wid][jj];          // 4 edge ids, broadcast
        int sj[4] = {s4.x, s4.y, s4.z, s4.w};
        float4 e0 = eL[wid][jj + 0];
        float4 e1 = eL[wid][jj + 1];
        float4 e2 = eL[wid][jj + 2];
        float4 e3 = eL[wid][jj + 3];
        float xg[4];
#pragma unroll
        for (int q = 0; q < 4; q++)
          xg[q] = fa ? bf2f(xbhl[(size_t)sj[q] * 128 + lane]) : 0.f;
        ag0 += e0.x * xg[0] + e1.x * xg[1] + e2.x * xg[2] + e3.x * xg[3];
        ag1 += e0.y * xg[0] + e1.y * xg[1] + e2.y * xg[2] + e3.y * xg[3];
        ag2 += e0.z * xg[0] + e1.z * xg[1] + e2.z * xg[2] + e3.z * xg[3];
        ag3 += e0.w * xg[0] + e1.w * xg[1] + e2.w * xg[2] + e3.w * xg[3];
#pragma unroll
        for (int q = 0; q < 4; q++)
          if (jj + q < cn) ax += xg[q];                // uniform guard
      }
    }
#pragma unroll
    for (int off = 32; off >= 1; off >>= 1)
#pragma unroll
      for (int h = 0; h < 4; h++) zl[h] += __shfl_xor(zl[h], off);
    {
      float z0 = zl[0] + exs[0] + 1e-16f;
      float z1 = zl[1] + exs[1] + 1e-16f;
      float z2 = zl[2] + exs[2] + 1e-16f;
      float z3 = zl[3] + exs[3] + 1e-16f;
      short* ar = agg4 + (size_t)i * A4P;
      ar[0 * 64 + lane] = fa ? f2bf(ag0 / z0) : (short)0;
      ar[1 * 64 + lane] = fa ? f2bf(ag1 / z1) : (short)0;
      ar[2 * 64 + lane] = fa ? f2bf(ag2 / z2) : (short)0;
      ar[3 * 64 + lane] = fa ? f2bf(ag3 / z3) : (short)0;
      // GIN aggregate: hi/lo double-bf16 (fp32-equivalent through MFMA)
      float axv = fa ? ax : 0.f;
      short hi = f2bf(axv);
      float lov = axv - bf2f(hi);
      short* br = aggb + (size_t)i * 128;
      br[lane]      = fa ? hi : (short)0;
      br[64 + lane] = fa ? f2bf(lov) : (short)0;
    }
  }
}

// ---------------------------------------------------------------------------
// Fused post-aggregation (light): phase 1 = GAT transform (MFMA, LDS-free
// weights), phase 2 = GIN MLP (MFMA, hi/lo). LDS union ~39KB -> 4 blocks/CU.
// ---------------------------------------------------------------------------
#define H1S 132   /* h1 row stride in shorts: 66 words % 32 = 2 -> conflict-free */
__global__ __launch_bounds__(256) void k_post2(
    const short* __restrict__ agg4, const short* __restrict__ Wgt,
    const float* __restrict__ gat_b,
    const short* __restrict__ aggb, const short* __restrict__ Wg1,
    const short* __restrict__ Wg2,
    const float* __restrict__ b1, const float* __restrict__ b2,
    const int* __restrict__ batch, float* __restrict__ pooled) {
  __shared__ float psumG[4 * 224];
  __shared__ short h1hi[64 * H1S];
  __shared__ short h1lo[64 * H1S];
  __shared__ float psumN[4 * 112];
  __shared__ int batL[64];
  int m0 = blockIdx.x * 64;
  int t = threadIdx.x;
  for (int idx = t; idx < 4 * 224; idx += 256) psumG[idx] = 0.f;
  for (int idx = t; idx < 4 * 112; idx += 256) psumN[idx] = 0.f;
  if (t < 64) batL[t] = batch[min(m0 + t, N_NODES - 1)];
  for (int idx = t; idx < 64 * H1S / 2; idx += 256) {
    ((int*)h1hi)[idx] = 0;
    ((int*)h1lo)[idx] = 0;
  }
  __syncthreads();
  const int lane = t & 63, wid = t >> 6;
  const int n16 = lane & 15, quad = lane >> 4;
  const int mrow0 = wid * 16;
  const int bmin = batL[0];
  const bool uni = (batL[0] == batL[63]);

  // =================== phase 1: GAT transform ===================
  {
    const size_t abase = (size_t)(m0 + mrow0 + n16) * A4P;   // pad rows: workspace
#pragma unroll
    for (int h = 0; h < 4; h++) {
      short8 af0 = *(const short8*)(agg4 + abase + h * 64 + quad * 8);
      short8 af1 = *(const short8*)(agg4 + abase + h * 64 + 32 + quad * 8);
#pragma unroll
      for (int nt = 0; nt < 4; nt++) {
        short8 b0 = *(const short8*)(Wgt + (h * 56 + nt * 16 + n16) * 64 + quad * 8);
        short8 b1f = *(const short8*)(Wgt + (h * 56 + nt * 16 + n16) * 64 + 32 + quad * 8);
        f32x4 acc = {0.f, 0.f, 0.f, 0.f};
        acc = __builtin_amdgcn_mfma_f32_16x16x32_bf16(af0, b0, acc, 0, 0, 0);
        acc = __builtin_amdgcn_mfma_f32_16x16x32_bf16(af1, b1f, acc, 0, 0, 0);
        int jn = nt * 16 + n16;
        bool jv = jn < FDIM;
        float bj = jv ? gat_b[h * FDIM + jn] : 0.f;
        if (uni) {
          float s = 0.f;
#pragma unroll
          for (int r = 0; r < 4; r++) {
            int gm = m0 + mrow0 + quad * 4 + r;
            if (gm < N_NODES) s += fmaxf(acc[r] + bj, 0.f);
          }
          s += __shfl_xor(s, 16);
          s += __shfl_xor(s, 32);
          if (quad == 0 && jv && s != 0.f) atomicAdd(&psumG[h * 56 + jn], s);
        } else {
          float pj = 0.f; int curb = -1;
#pragma unroll
          for (int r = 0; r < 4; r++) {
            int lm = mrow0 + quad * 4 + r;
            int gm = m0 + lm;
            if (gm < N_NODES) {
              float o = fmaxf(acc[r] + bj, 0.f);
              int b = batL[lm];
              if (b != curb) {
                if (curb >= 0 && jv) {
                  int slot = curb - bmin;
                  if (slot >= 0 && slot < 4) atomicAdd(&psumG[slot * 224 + h * 56 + jn], pj);
                  else atomicAdd(&pooled[(size_t)curb * POOLW + h * FDIM + jn], pj);
                }
                curb = b; pj = o;
              } else {
                pj += o;
              }
            }
          }
          if (curb >= 0 && jv) {
            int slot = curb - bmin;
            if (slot >= 0 && slot < 4) atomicAdd(&psumG[slot * 224 + h * 56 + jn], pj);
            else atomicAdd(&pooled[(size_t)curb * POOLW + h * FDIM + jn], pj);
          }
        }
      }
    }
  }

  // =================== phase 2, layer 1: h1 = relu((hi+lo)@w1+b1) ===================
  {
    const size_t abase = (size_t)(m0 + mrow0 + n16) * 128;  // pad rows: workspace
    short8 a[4];
#pragma unroll
    for (int f = 0; f < 4; f++)
      a[f] = *(const short8*)(aggb + abase + f * 32 + quad * 8);
#pragma unroll
    for (int nt = 0; nt < 7; nt++) {
      f32x4 acc = {0.f, 0.f, 0.f, 0.f};
#pragma unroll
      for (int f = 0; f < 4; f++) {
        short8 bf = *(const short8*)(Wg1 + (nt * 16 + n16) * 128 + f * 32 + quad * 8);
        acc = __builtin_amdgcn_mfma_f32_16x16x32_bf16(a[f], bf, acc, 0, 0, 0);
      }
      int jn = nt * 16 + n16;
      if (jn < F2) {
        float bj = b1[jn];
#pragma unroll
        for (int r = 0; r < 4; r++) {
          int row = mrow0 + quad * 4 + r;
          float v = fmaxf(acc[r] + bj, 0.f);
          short hi = f2bf(v);
          h1hi[row * H1S + jn] = hi;
          h1lo[row * H1S + jn] = f2bf(v - bf2f(hi));
        }
      }
    }
  }
  __syncthreads();   // h1 writes complete (also fences psumG phase-1 atomics)

  // flush phase-1 psum while h1 settles
  for (int idx = t; idx < 4 * 224; idx += 256) {
    int slot = idx / 224, c = idx % 224;
    int h = c / 56, jn = c % 56;
    float v = psumG[idx];
    int b = bmin + slot;
    if (jn < FDIM && b < BATCH && v != 0.f)
      atomicAdd(&pooled[(size_t)b * POOLW + h * FDIM + jn], v);
  }

  // =================== phase 2, layer 2 ===================
  short8 ah[4], al[4];
#pragma unroll
  for (int f = 0; f < 4; f++) {
    ah[f] = *(const short8*)&h1hi[(mrow0 + n16) * H1S + f * 32 + quad * 8];
    al[f] = *(const short8*)&h1lo[(mrow0 + n16) * H1S + f * 32 + quad * 8];
  }
#pragma unroll
  for (int nt = 0; nt < 7; nt++) {
    f32x4 acc = {0.f, 0.f, 0.f, 0.f};
#pragma unroll
    for (int f = 0; f < 4; f++) {
      short8 bf = *(const short8*)(Wg2 + (nt * 16 + n16) * 128 + f * 32 + quad * 8);
      acc = __builtin_amdgcn_mfma_f32_16x16x32_bf16(ah[f], bf, acc, 0, 0, 0);
      acc = __builtin_amdgcn_mfma_f32_16x16x32_bf16(al[f], bf, acc, 0, 0, 0);
    }
    int jn = nt * 16 + n16;
    bool jv = jn < F2;
    float bj = jv ? b2[jn] : 0.f;
    if (uni) {
      float s = 0.f;
#pragma unroll
      for (int r = 0; r < 4; r++) {
        int gm = m0 + mrow0 + quad * 4 + r;
        if (gm < N_NODES) s += fmaxf(acc[r] + bj, 0.f);
      }
      s += __shfl_xor(s, 16);
      s += __shfl_xor(s, 32);
      if (quad == 0 && jv && s != 0.f) atomicAdd(&psumN[jn], s);
    } else {
      float pj = 0.f; int curb = -1;
#pragma unroll
      for (int r = 0; r < 4; r++) {
        int lm = mrow0 + quad * 4 + r;
        int gm = m0 + lm;
        if (gm < N_NODES) {
          float o = fmaxf(acc[r] + bj, 0.f);
          int b = batL[lm];
          if (b != curb) {
            if (curb >= 0 && jv) {
              int slot = curb - bmin;
              if (slot >= 0 && slot < 4) atomicAdd(&psumN[slot * 112 + jn], pj);
              else atomicAdd(&pooled[(size_t)curb * POOLW + HF + jn], pj);
            }
            curb = b; pj = o;
          } else {
            pj += o;
          }
        }
      }
      if (curb >= 0 && jv) {
        int slot = curb - bmin;
        if (slot >= 0 && slot < 4) atomicAdd(&psumN[slot * 112 + jn], pj);
        else atomicAdd(&pooled[(size_t)curb * POOLW + HF + jn], pj);
      }
    }
  }
  __syncthreads();
  for (int idx = t; idx < 4 * 112; idx += 256) {
    int slot = idx / 112, n = idx % 112;
    float v = psumN[idx];
    int b = bmin + slot;
    if (n < F2 && b < BATCH && v != 0.f)
      atomicAdd(&pooled[(size_t)b * POOLW + HF + n], v);
  }
}

// ---------------------------------------------------------------------------
// EdgeConv v8 (round-5 best): bf16 U/V, rp/batch in LDS, colidx prefetched
// 2 tiles ahead / V 1 tile ahead, deferred cross-quad max reduction,
// double-buffered LDS, lgkmcnt-only barrier.
// ---------------------------------------------------------------------------
#define ECH 25
__global__ __launch_bounds__(256) void k_ec(
    const short* __restrict__ Ub, const short* __restrict__ Vb,
    const float* __restrict__ w2, const float* __restrict__ b2,
    const int* __restrict__ rp, const int* __restrict__ colidx,
    const int* __restrict__ batch, float* __restrict__ pooled) {
  const int t = threadIdx.x;
  const int lane = t & 63, wid = t >> 6;
  const int n16 = lane & 15, quad = lane >> 4;
  const int nt = (wid == 3) ? 1 : 2;   // u-tile 7 is all-pad

  const int i0 = blockIdx.x * ECH;
  const int iend = min(i0 + ECH, N_NODES);
  const int nn = iend - i0;

  __shared__ int rpL[ECH + 1];
  __shared__ int batL[ECH];

  short8 Bh[2][4];
  for (int tt = 0; tt < 2; tt++) {
    int ucol = (wid * 2 + tt) * 16 + n16;
    for (int kc = 0; kc < 4; kc++) {
      short8 vh;
#pragma unroll
      for (int jv = 0; jv < 8; jv++) {
        int kk = kc * 32 + quad * 8 + jv;
        float w = (ucol < F2 && kk < F2) ? w2[kk * F2 + ucol] : 0.f;
        vh[jv] = f2bf(w);
      }
      Bh[tt][kc] = vh;
    }
  }
  float b2v[2];
#pragma unroll
  for (int tt = 0; tt < 2; tt++) {
    int u = (wid * 2 + tt) * 16 + n16;
    b2v[tt] = (u < F2) ? b2[u] : 0.f;
  }

  if (t <= nn) rpL[t] = rp[i0 + t];
  if (t < nn) batL[t] = batch[i0 + t];
  __syncthreads();

  __shared__ short hs[2][16 * 16 * 8];
  union SU { short8 s; unsigned u[4]; };
  const int es = t & 15, kg = t >> 4;
  const int k0 = kg * 8;

  float sm0 = 0.f, sm1 = 0.f;
  int curb = -1;
  const int u0 = (wid * 2) * 16 + n16;
  const int u1 = (wid * 2 + 1) * 16 + n16;

  // tile walk: (node, tile-in-node, base, deg) -> next
  auto advance = [&](int& ii, int& ttb, int& bb, int& dd) -> bool {
    ttb++;
    if (ttb * 16 < dd) return true;
    ttb = 0;
    for (ii = ii + 1; ii < iend; ii++) {
      bb = rpL[ii - i0]; dd = rpL[ii - i0 + 1] - bb;
      if (dd > 0) return true;
    }
    return false;
  };

  // current tile T
  int i = i0, tb = 0, base = 0, deg = 0;
  bool have = false;
  for (; i < iend; i++) {
    base = rpL[i - i0]; deg = rpL[i - i0 + 1] - base;
    if (deg > 0) { have = true; break; }
  }
  short8 pu8{}, pv8{};
  // tile T+1 coords + its colidx value (sc) already fetched
  int i1 = i, tb1 = 0, base1 = base, deg1 = deg;
  bool have1 = false;
  int sc = 0;
  if (have) {
    pu8 = *(const short8*)(Ub + (size_t)i * ECS + k0);
    int s0 = colidx[base + ((es < deg) ? es : 0)];
    pv8 = *(const short8*)(Vb + (size_t)s0 * ECS + k0);
    have1 = advance(i1, tb1, base1, deg1);
    if (have1) {
      int eg = tb1 * 16 + es;
      sc = colidx[base1 + ((eg < deg1) ? eg : 0)];
    }
  }

  float Uc[8];
  float vmax0 = -1e30f, vmax1 = -1e30f;
  int parity = 0;
  while (have) {
    if (tb == 0) {
#pragma unroll
      for (int j = 0; j < 8; j++) Uc[j] = bf2f(pu8[j]);
    }
    SU w;
#pragma unroll
    for (int p = 0; p < 4; p++) {
      bool kv = (k0 + 2 * p) < F2;
      float h0 = kv ? fmaxf(Uc[2 * p]     + bf2f(pv8[2 * p]),     0.f) : 0.f;
      float h1 = kv ? fmaxf(Uc[2 * p + 1] + bf2f(pv8[2 * p + 1]), 0.f) : 0.f;
      w.u[p] = pk2(h0, h1);
    }
    *(short8*)&hs[parity][(kg * 16 + es) * 8] = w.s;

    // prefetch: V (and U) for tile T+1 using sc fetched last iter; colidx for T+2
    int i2 = i1, tb2 = tb1, base2 = base1, deg2 = deg1;
    bool have2 = false;
    int scN = 0;
    if (have1) {
      if (tb1 == 0) pu8 = *(const short8*)(Ub + (size_t)i1 * ECS + k0);
      pv8 = *(const short8*)(Vb + (size_t)sc * ECS + k0);
      have2 = advance(i2, tb2, base2, deg2);
      if (have2) {
        int eg2 = tb2 * 16 + es;
        scN = colidx[base2 + ((eg2 < deg2) ? eg2 : 0)];
      }
    }

    ldsbar();
    f32x4 a0 = {0.f, 0.f, 0.f, 0.f}, a1 = {0.f, 0.f, 0.f, 0.f};
#pragma unroll
    for (int kc = 0; kc < 4; kc++) {
      short8 af = *(const short8*)&hs[parity][((kc * 4 + quad) * 16 + n16) * 8];
      a0 = __builtin_amdgcn_mfma_f32_16x16x32_bf16(af, Bh[0][kc], a0, 0, 0, 0);
      if (nt > 1)
        a1 = __builtin_amdgcn_mfma_f32_16x16x32_bf16(af, Bh[1][kc], a1, 0, 0, 0);
    }
#pragma unroll
    for (int r = 0; r < 4; r++) {
      int er = tb * 16 + quad * 4 + r;
      if (er < deg) { vmax0 = fmaxf(vmax0, a0[r]); vmax1 = fmaxf(vmax1, a1[r]); }
    }
    if (!have1 || i1 != i) {
      // node i finishes with this tile: cross-quad reduce deferred to here
      vmax0 = fmaxf(vmax0, __shfl_xor(vmax0, 16));
      vmax0 = fmaxf(vmax0, __shfl_xor(vmax0, 32));
      vmax1 = fmaxf(vmax1, __shfl_xor(vmax1, 16));
      vmax1 = fmaxf(vmax1, __shfl_xor(vmax1, 32));
      float o0 = fmaxf(vmax0 + b2v[0], 0.f);
      float o1 = fmaxf(vmax1 + b2v[1], 0.f);
      int b = batL[i - i0];
      if (b != curb) {
        if (curb >= 0 && quad == 0) {
          float* pg = pooled + (size_t)curb * POOLW + HF + F2;
          if (u0 < F2) atomicAdd(&pg[u0], sm0);
          if (nt > 1 && u1 < F2) atomicAdd(&pg[u1], sm1);
        }
        curb = b; sm0 = o0; sm1 = o1;
      } else {
        sm0 += o0; sm1 += o1;
      }
      vmax0 = -1e30f; vmax1 = -1e30f;
    }
    i = i1; tb = tb1; base = base1; deg = deg1; have = have1;
    i1 = i2; tb1 = tb2; base1 = base2; deg1 = deg2; have1 = have2;
    sc = scN;
    parity ^= 1;
  }
  if (curb >= 0 && quad == 0) {
    float* pg = pooled + (size_t)curb * POOLW + HF + F2;
    if (u0 < F2) atomicAdd(&pg[u0], sm0);
    if (nt > 1 && u1 < F2) atomicAdd(&pg[u1], sm1);
  }
}

// ---------------------------------------------------------------------------
// Per-graph heads + final MLP fused; mean-pool divide folded into the load.
// ---------------------------------------------------------------------------
__global__ __launch_bounds__(256) void k_heads(
    const float* __restrict__ pooled, const int* __restrict__ start,
    const float* __restrict__ fg1_w, const float* __restrict__ fg1_b,
    const float* __restrict__ fg2_w, const float* __restrict__ fg2_b,
    const float* __restrict__ fg3_w, const float* __restrict__ fg3_b,
    const float* __restrict__ fg4_w, const float* __restrict__ fg4_b,
    const float* __restrict__ fg5_w, const float* __restrict__ fg5_b,
    const float* __restrict__ fg6_w, const float* __restrict__ fg6_b,
    const float* __restrict__ fc1_w, const float* __restrict__ fc1_b,
    const float* __restrict__ fc2_w, const float* __restrict__ fc2_b,
    const float* __restrict__ out_w, const float* __restrict__ out_b,
    float* __restrict__ out) {
  int g = blockIdx.x, t = threadIdx.x;
  __shared__ float in[POOLW];
  __shared__ float mid[256];
  __shared__ float cat[384];
  __shared__ float h1[128];
  __shared__ float h2[64];
  float c = fmaxf((float)(start[g + 1] - start[g]), 1.f);
  for (int idx = t; idx < POOLW; idx += 256)
    in[idx] = pooled[(size_t)g * POOLW + idx] / c;
  __syncthreads();
  const float* w1s[3] = {fg1_w, fg3_w, fg5_w};
  const float* b1s[3] = {fg1_b, fg3_b, fg5_b};
  const float* w2s[3] = {fg2_w, fg4_w, fg6_w};
  const float* b2s[3] = {fg2_b, fg4_b, fg6_b};
  const int off[4] = {0, HF, HF + F2, POOLW};
  for (int br = 0; br < 3; br++) {
    int kin = off[br + 1] - off[br];
    const float* iv = &in[off[br]];
    float a = b1s[br][t];
    const float* W = w1s[br];
    for (int k = 0; k < kin; k++) a += iv[k] * W[k * 256 + t];
    mid[t] = fmaxf(a, 0.f);
    __syncthreads();
    if (t < 128) {
      float b = b2s[br][t];
      const float* W2 = w2s[br];
      for (int k = 0; k < 256; k++) b += mid[k] * W2[k * 128 + t];
      cat[br * 128 + t] = fmaxf(b, 0.f);
    }
    __syncthreads();
  }
  if (t < 128) {
    float a = fc1_b[t];
    for (int k = 0; k < 384; k++) a += cat[k] * fc1_w[k * 128 + t];
    h1[t] = fmaxf(a, 0.f);
  }
  __syncthreads();
  if (t < 64) {
    float a = fc2_b[t];
    for (int k = 0; k < 128; k++) a += h1[k] * fc2_w[k * 64 + t];
    h2[t] = fmaxf(a, 0.f);
  }
  __syncthreads();
  if (t == 0) {
    float a = out_b[0];
    for (int k = 0; k < 64; k++) a += h2[k] * out_w[k];
    out[g] = 1.f / (1.f + __expf(-a));
  }
}

// ---------------------------------------------------------------------------
extern "C" void kernel_launch(void* const* d_in, const int* in_sizes, int n_in,
                              void* d_out, int out_size, void* d_ws, size_t ws_size,
                              hipStream_t stream) {
  const float* x      = (const float*)d_in[0];
  const int*   ei     = (const int*)d_in[1];
  const int*   batch  = (const int*)d_in[2];
  const float* gat_w  = (const float*)d_in[3];
  const float* asrc   = (const float*)d_in[4];
  const float* adst   = (const float*)d_in[5];
  const float* gat_b  = (const float*)d_in[6];
  const float* gin_w1 = (const float*)d_in[7];
  const float* gin_b1 = (const float*)d_in[8];
  const float* gin_w2 = (const float*)d_in[9];
  const float* gin_b2 = (const float*)d_in[10];
  const float* ec_w1  = (const float*)d_in[11];
  const float* ec_b1  = (const float*)d_in[12];
  const float* ec_w2  = (const float*)d_in[13];
  const float* ec_b2  = (const float*)d_in[14];
  const float* fg1_w = (const float*)d_in[15]; const float* fg1_b = (const float*)d_in[16];
  const float* fg2_w = (const float*)d_in[17]; const float* fg2_b = (const float*)d_in[18];
  const float* fg3_w = (const float*)d_in[19]; const float* fg3_b = (const float*)d_in[20];
  const float* fg4_w = (const float*)d_in[21]; const float* fg4_b = (const float*)d_in[22];
  const float* fg5_w = (const float*)d_in[23]; const float* fg5_b = (const float*)d_in[24];
  const float* fg6_w = (const float*)d_in[25]; const float* fg6_b = (const float*)d_in[26];
  const float* fc1_w = (const float*)d_in[27]; const float* fc1_b = (const float*)d_in[28];
  const float* fc2_w = (const float*)d_in[29]; const float* fc2_b = (const float*)d_in[30];
  const float* out_w = (const float*)d_in[31]; const float* out_b = (const float*)d_in[32];
  float* out = (float*)d_out;

  char* ws = (char*)d_ws;
  size_t off = 0;
  auto alloc = [&](size_t bytes) -> void* {
    void* p = ws + off;
    off = (off + bytes + 255) & ~(size_t)255;
    return p;
  };
  // --- zero region (one memset): histP | pooled ---
  size_t zoff0 = off;
  int*   histP  = (int*)alloc((size_t)N_NODES * PSTR * sizeof(int));  // 6.4 MB padded bins
  float* pooled = (float*)alloc((size_t)BATCH * POOLW * sizeof(float));
  size_t zbytes = off - zoff0;
  // --- rest ---
  int*   rp     = (int*)alloc((N_NODES + 1) * sizeof(int));
  int*   start  = (int*)alloc((BATCH + 1) * sizeof(int));
  int*   bsum   = (int*)alloc(256 * sizeof(int));
  int*   colidx = (int*)alloc(N_EDGES * sizeof(int));
  short* xbhl   = (short*)alloc((size_t)(N_NODES + 64) * 128 * sizeof(short)); // x hi/lo
  float* alS    = (float*)alloc((size_t)N_NODES * 4 * sizeof(float));
  float* alD    = (float*)alloc((size_t)N_NODES * 4 * sizeof(float));
  short* Ubuf   = (short*)alloc((size_t)N_NODES * ECS * sizeof(short));  // bf16, 256B rows
  short* Vbuf   = (short*)alloc((size_t)N_NODES * ECS * sizeof(short));  // bf16, 256B rows
  short* agg4   = (short*)alloc((size_t)(N_NODES + 64) * A4P * sizeof(short)); // padded bf16
  short* aggb   = (short*)alloc((size_t)(N_NODES + 64) * 128 * sizeof(short)); // GIN hi/lo
  short* Wgt    = (short*)alloc(SEG_WGT * sizeof(short));
  short* Wuv    = (short*)alloc(SEG_WUV * sizeof(short));
  short* Wg1    = (short*)alloc(SEG_WG1 * sizeof(short));
  short* Wg2    = (short*)alloc(SEG_WG2 * sizeof(short));
  (void)ws_size; (void)in_sizes; (void)n_in; (void)out_size;

  hipMemsetAsync(ws + zoff0, 0, zbytes, stream);

  k_prep<<<(PREP_TOT + 255) / 256, 256, 0, stream>>>(gat_w, asrc, adst, ec_w1,
                                                     gin_w1, gin_w2,
                                                     Wgt, Wuv, Wg1, Wg2);
  k_xsplit<<<(N_NODES + 3) / 4, 256, 0, stream>>>(x, xbhl);
  k_uv<<<((N_NODES + 63) / 64) * 2, 256, 0, stream>>>(xbhl, Wuv, ec_b1,
                                                      Ubuf, Vbuf, alS, alD);
  k_hist<<<(N_EDGES + 255) / 256, 256, 0, stream>>>(ei, histP);
  k_scan1<<<SCAN_BLOCKS, 256, 0, stream>>>(histP, batch, rp, bsum, start);
  k_scan3<<<SCAN_BLOCKS, 256, 0, stream>>>(bsum, rp, histP);
  k_scatter<<<(N_EDGES + 255) / 256, 256, 0, stream>>>(ei, histP, colidx);

  // fused GAT-aggregate + GIN-sum over the L2-resident bf16 x table
  k_gatgin<<<(N_NODES + GCH - 1) / GCH, 256, 0, stream>>>(xbhl, alS, alD, rp, colidx,
                                                          agg4, aggb);
  k_ec<<<(N_NODES + ECH - 1) / ECH, 256, 0, stream>>>(Ubuf, Vbuf, ec_w2, ec_b2, rp, colidx, batch, pooled);
  // fused GAT transform + GIN MLP (both MFMA, LDS-free weights)
  k_post2<<<(N_NODES + 63) / 64, 256, 0, stream>>>(agg4, Wgt, gat_b,
                                                   aggb, Wg1, Wg2, gin_b1, gin_b2,
                                                   batch, pooled);

  k_heads<<<BATCH, 256, 0, stream>>>(pooled, start,
                                     fg1_w, fg1_b, fg2_w, fg2_b, fg3_w, fg3_b,
                                     fg4_w, fg4_b, fg5_w, fg5_b, fg6_w, fg6_b,
                                     fc1_w, fc1_b, fc2_w, fc2_b, out_w, out_b, out);
}

// Round 21
// 563.683 us; speedup vs baseline: 1.3376x; 1.0562x over previous
//
#include <hip/hip_runtime.h>
#include <hip/hip_bf16.h>
#include <math.h>

#define N_NODES 50000
#define N_EDGES 800000
#define FDIM 53
#define BATCH 128
#define HF 212   /* H*F */
#define F2 106   /* 2F  */
#define POOLW 424 /* 212+106+106 */
#define PSTR 32  /* padded bin stride (ints) = 128 B: one L2 line per node */
#define ECS 128  /* U/V fp16 row stride (shorts) = 256 B = 4 L2 lines */
#define A4P 256  /* agg4 padded row stride (shorts): [node][4][64], 16B aligned */

typedef __attribute__((ext_vector_type(8))) short short8;
typedef __attribute__((ext_vector_type(8))) _Float16 half8;
typedef __attribute__((ext_vector_type(4))) float f32x4;

__device__ __forceinline__ float leaky02(float x){ return x >= 0.f ? x : 0.2f * x; }

__device__ __forceinline__ short f2bf(float x) {
  unsigned u = __float_as_uint(x);
  unsigned r = (u + 0x7fffu + ((u >> 16) & 1u)) >> 16;
  return (short)r;
}
__device__ __forceinline__ float bf2f(short b) {
  return __uint_as_float(((unsigned)(unsigned short)b) << 16);
}
__device__ __forceinline__ short f2h(float x) {
  _Float16 h = (_Float16)x;
  union { _Float16 h; short s; } c; c.h = h;
  return c.s;
}
// LDS-only barrier: waits lgkmcnt(0) (ds ops) but leaves global loads in flight
__device__ __forceinline__ void ldsbar() {
  __builtin_amdgcn_s_waitcnt(0xC07F);   // vmcnt(63) expcnt(7) lgkmcnt(0)
  __builtin_amdgcn_s_barrier();
}

// ---------------------------------------------------------------------------
// Weight prep: pack all MFMA B-fragment buffers (L2-resident broadcast).
//   Wgt[4][56][64]    : gat_w per-head transposed, k-padded (bf16)
//   Wuv[2][128][256]  : EC U/V weights, K=256 hi/lo layout (kk<128 hi, else lo)
//                       chunk0 cols 112..119 = cAl columns (inline 53-MAC dot)
//   Wg1[112][128]     : gin_w1 dup rows (hi/lo A), bf16
//   Wg2[112][128]     : gin_w2 transposed, bf16
// ---------------------------------------------------------------------------
#define SEG_WGT (4*56*64)
#define SEG_WUV (2*128*256)
#define SEG_WG1 (112*128)
#define SEG_WG2 (112*128)
#define PREP_TOT (SEG_WGT + SEG_WUV + SEG_WG1 + SEG_WG2)
__global__ void k_prep(const float* __restrict__ gat_w, const float* __restrict__ asrc,
                       const float* __restrict__ adst, const float* __restrict__ ec_w1,
                       const float* __restrict__ gin_w1, const float* __restrict__ gin_w2,
                       short* __restrict__ Wgt, short* __restrict__ Wuv,
                       short* __restrict__ Wg1, short* __restrict__ Wg2) {
  int idx = blockIdx.x * blockDim.x + threadIdx.x;
  if (idx < SEG_WGT) {
    int h = idx / (56 * 64), rem = idx % (56 * 64);
    int n = rem >> 6, kk = rem & 63;
    Wgt[idx] = (kk < FDIM && n < FDIM) ? f2bf(gat_w[kk * HF + h * FDIM + n]) : (short)0;
    return;
  }
  idx -= SEG_WGT;
  if (idx < SEG_WUV) {
    int c = idx / (128 * 256), rem = idx % (128 * 256);
    int n = rem >> 8, kk = rem & 255, ks = kk & 63;
    float w = 0.f;
    if (ks < FDIM) {
      if (c == 0) {
        if (n < F2) {
          w = ec_w1[ks * F2 + n] - ec_w1[(FDIM + ks) * F2 + n];
        } else if (n >= 112 && n < 120) {
          int j = n - 112, sd = j >> 2, h = j & 3;
          const float* av = sd ? adst : asrc;
          float acc = 0.f;
          for (int f = 0; f < FDIM; ++f)
            acc += gat_w[ks * HF + h * FDIM + f] * av[h * FDIM + f];
          w = acc;
        }
      } else {
        if (n < F2) w = ec_w1[(FDIM + ks) * F2 + n];
      }
    }
    short hv = f2bf(w);
    Wuv[idx] = (kk < 128) ? hv : f2bf(w - bf2f(hv));
    return;
  }
  idx -= SEG_WUV;
  if (idx < SEG_WG1) {
    int n = idx >> 7, kk = idx & 127, ks = kk & 63;
    Wg1[idx] = (ks < FDIM && n < F2) ? f2bf(gin_w1[ks * F2 + n]) : (short)0;
    return;
  }
  idx -= SEG_WG1;
  if (idx < SEG_WG2) {
    int n = idx >> 7, kk = idx & 127;
    Wg2[idx] = (kk < F2 && n < F2) ? f2bf(gin_w2[kk * F2 + n]) : (short)0;
  }
}

// ---------------------------------------------------------------------------
// x split: xbhl[node][128] = [hi(0..63) | lo(64..127)] bf16 (zeros k>=53).
// ---------------------------------------------------------------------------
__global__ __launch_bounds__(256) void k_xsplit(
    const float* __restrict__ x, short* __restrict__ xbhl) {
  int wid = threadIdx.x >> 6, lane = threadIdx.x & 63;
  int i = blockIdx.x * 4 + wid;
  if (i >= N_NODES) return;
  float v = (lane < FDIM) ? x[(size_t)i * FDIM + lane] : 0.f;
  short hi = f2bf(v);
  xbhl[(size_t)i * 128 + lane] = hi;
  xbhl[(size_t)i * 128 + 64 + lane] = f2bf(v - bf2f(hi));
}

// ---------------------------------------------------------------------------
// U/V linear + al (MFMA, zero LDS): K=256 hi/lo exact product. Chunk c:
// 0 = U (+ al columns in n-tile 7 -> alS/alD fp32), 1 = V.
// Output U/V in fp16 with pad columns 106..127 zero-filled (lets k_ec run
// packed f16 math with no tail guard).
// ---------------------------------------------------------------------------
__global__ __launch_bounds__(256) void k_uv(
    const short* __restrict__ xbhl, const short* __restrict__ Wuv,
    const float* __restrict__ ec_b1,
    short* __restrict__ Ub, short* __restrict__ Vb,
    float* __restrict__ alS, float* __restrict__ alD) {
  int bid = blockIdx.x;
  int nb = bid >> 1, c = bid & 1;
  int m0 = nb * 64;
  int t = threadIdx.x;
  const int lane = t & 63, wid = t >> 6;
  const int n16 = lane & 15, quad = lane >> 4;
  const int mrow0 = wid * 16;
  const size_t abase = (size_t)(m0 + mrow0 + n16) * 128;   // pad rows: workspace
  short8 a[4];
#pragma unroll
  for (int f = 0; f < 4; f++)
    a[f] = *(const short8*)(xbhl + abase + f * 32 + quad * 8);
  const short* Bw = Wuv + (size_t)c * 128 * 256;
  short* Ob = c ? Vb : Ub;
  const int ntmax = (c == 0) ? 8 : 7;
  for (int nt = 0; nt < ntmax; nt++) {
    f32x4 acc = {0.f, 0.f, 0.f, 0.f};
#pragma unroll
    for (int f = 0; f < 8; f++) {
      short8 bf = *(const short8*)(Bw + (nt * 16 + n16) * 256 + f * 32 + quad * 8);
      acc = __builtin_amdgcn_mfma_f32_16x16x32_bf16(a[f & 3], bf, acc, 0, 0, 0);
    }
    int jn = nt * 16 + n16;
    if (nt < 7) {
      float bj = (!c && jn < F2) ? ec_b1[jn] : 0.f;
#pragma unroll
      for (int r = 0; r < 4; r++) {
        int gm = m0 + mrow0 + quad * 4 + r;
        if (gm < N_NODES)
          Ob[(size_t)gm * ECS + jn] = (jn < F2) ? f2h(acc[r] + bj) : (short)0;
      }
    } else {
      // al columns: j = n16 (0..7): 0..3 -> alS, 4..7 -> alD
      int j = n16;
      if (j < 8) {
#pragma unroll
        for (int r = 0; r < 4; r++) {
          int gm = m0 + mrow0 + quad * 4 + r;
          if (gm < N_NODES) {
            if (j < 4) alS[gm * 4 + j] = acc[r];
            else       alD[gm * 4 + (j - 4)] = acc[r];
          }
        }
      }
    }
  }
  // zero-fill pad cols 112..127
  {
    int jz = 112 + n16;
#pragma unroll
    for (int r = 0; r < 4; r++) {
      int gm = m0 + mrow0 + quad * 4 + r;
      if (gm < N_NODES) Ob[(size_t)gm * ECS + jz] = 0;
    }
  }
}

// ---------------------------------------------------------------------------
// CSR build: hist -> scan1 (block scan + batch boundaries) -> scan3 (folds
// the bsum prefix scan) -> scatter.
// ---------------------------------------------------------------------------
#define SCAN_BLOCKS ((N_NODES + 255) / 256)

__global__ void k_hist(const int* __restrict__ ei, int* __restrict__ histP) {
  int t = blockIdx.x * blockDim.x + threadIdx.x;
  if (t < N_EDGES) atomicAdd(&histP[ei[N_EDGES + t] << 5], 1);
}

__global__ __launch_bounds__(256) void k_scan1(const int* __restrict__ histP,
                                               const int* __restrict__ batch,
                                               int* __restrict__ rp, int* __restrict__ bsum,
                                               int* __restrict__ start) {
  __shared__ int buf[256];
  int tid = threadIdx.x;
  int idx = blockIdx.x * 256 + tid;
  int v = (idx < N_NODES) ? histP[idx << 5] : 0;
  buf[tid] = v;
  __syncthreads();
  for (int off = 1; off < 256; off <<= 1) {
    int t2 = (tid >= off) ? buf[tid - off] : 0;
    __syncthreads();
    buf[tid] += t2;
    __syncthreads();
  }
  if (idx < N_NODES) rp[idx] = buf[tid] - v;
  if (tid == 255) bsum[blockIdx.x] = buf[255];
  // fused batch-boundary detection (was k_bnd)
  if (idx < N_NODES) {
    int b = batch[idx];
    if (idx == 0)
      for (int g = 0; g <= b; g++) start[g] = 0;
    int bn = (idx + 1 < N_NODES) ? batch[idx + 1] : BATCH;
    for (int g = b + 1; g <= bn; g++) start[g] = idx + 1;
  }
}

__global__ __launch_bounds__(256) void k_scan3(const int* __restrict__ bsum,
                                               int* __restrict__ rp, int* __restrict__ histP) {
  __shared__ int buf[256];
  int tid = threadIdx.x;
  int v = (tid < SCAN_BLOCKS) ? bsum[tid] : 0;
  buf[tid] = v;
  __syncthreads();
  for (int off = 1; off < 256; off <<= 1) {
    int t2 = (tid >= off) ? buf[tid - off] : 0;
    __syncthreads();
    buf[tid] += t2;
    __syncthreads();
  }
  int boff = (blockIdx.x == 0) ? 0 : buf[blockIdx.x - 1];   // exclusive offset
  int idx = blockIdx.x * 256 + tid;
  if (idx < N_NODES) {
    int o = rp[idx] + boff;
    rp[idx] = o;
    histP[idx << 5] = o;   // becomes the (padded) scatter cursor
  }
  if (idx == 0) rp[N_NODES] = N_EDGES;
}

__global__ void k_scatter(const int* __restrict__ ei, int* __restrict__ histP,
                          int* __restrict__ colidx) {
  int e = blockIdx.x * blockDim.x + threadIdx.x;
  if (e >= N_EDGES) return;
  int d = ei[N_EDGES + e];
  int pos = atomicAdd(&histP[d << 5], 1);
  colidx[pos] = ei[e];
}

// ---------------------------------------------------------------------------
// Fused GAT-aggregate + GIN-sum. x rows read from xbhl (hi half, stride 128).
// agg4 padded [node][4][64] bf16; GIN aggregate hi/lo pair aggb[node][128].
// ---------------------------------------------------------------------------
#define GCH 20
__global__ __launch_bounds__(256) void k_gatgin(
    const short* __restrict__ xbhl, const float* __restrict__ alS, const float* __restrict__ alD,
    const int* __restrict__ rp, const int* __restrict__ colidx,
    short* __restrict__ agg4, short* __restrict__ aggb) {
  int wid = threadIdx.x >> 6, lane = threadIdx.x & 63;
  bool fa = lane < FDIM;
  int i0 = blockIdx.x * GCH;
  int iend = min(i0 + GCH, N_NODES);
  __shared__ int rpG[GCH + 1];
  __shared__ int sL[4][64];        // per-wave edge src ids
  __shared__ float4 eL[4][64];     // per-wave edge alphas (4 heads)
  {
    int t = threadIdx.x, nn = iend - i0;
    if (t <= nn) rpG[t] = rp[i0 + t];
  }
  __syncthreads();
  for (int i = i0 + wid; i < iend; i += 4) {
    int base = rpG[i - i0], deg = rpG[i - i0 + 1] - base;
    float4 adv = *(const float4*)(alD + (size_t)i * 4);
    float4 asv = *(const float4*)(alS + (size_t)i * 4);
    float aldi[4] = {adv.x, adv.y, adv.z, adv.w};
    float exs[4];
    exs[0] = __expf(leaky02(asv.x + aldi[0]));   // self-loop term
    exs[1] = __expf(leaky02(asv.y + aldi[1]));
    exs[2] = __expf(leaky02(asv.z + aldi[2]));
    exs[3] = __expf(leaky02(asv.w + aldi[3]));
    float xiv = fa ? bf2f(xbhl[(size_t)i * 128 + lane]) : 0.f;
    float ag0 = exs[0] * xiv, ag1 = exs[1] * xiv, ag2 = exs[2] * xiv, ag3 = exs[3] * xiv;
    float ax = xiv;
    float zl[4] = {0.f, 0.f, 0.f, 0.f};

    for (int c0 = 0; c0 < deg; c0 += 64) {
      int cn = min(64, deg - c0);
      int s = 0;
      float ex0 = 0.f, ex1 = 0.f, ex2 = 0.f, ex3 = 0.f;
      if (lane < cn) {
        s = colidx[base + c0 + lane];
        float4 av = *(const float4*)(alS + (size_t)s * 4);
        ex0 = __expf(leaky02(av.x + aldi[0]));
        ex1 = __expf(leaky02(av.y + aldi[1]));
        ex2 = __expf(leaky02(av.z + aldi[2]));
        ex3 = __expf(leaky02(av.w + aldi[3]));
        zl[0] += ex0; zl[1] += ex1; zl[2] += ex2; zl[3] += ex3;
      }
      // wave-local LDS stage; wave64 lockstep, no barrier needed.
      sL[wid][lane] = s;
      eL[wid][lane] = make_float4(ex0, ex1, ex2, ex3);
      for (int jj = 0; jj < cn; jj += 4) {
        int4 s4 = *(const int4*)&sL[wid][jj];          // 4 edge ids, broadcast
        int sj[4] = {s4.x, s4.y, s4.z, s4.w};
        float4 e0 = eL[wid][jj + 0];
        float4 e1 = eL[wid][jj + 1];
        float4 e2 = eL[wid][jj + 2];
        float4 e3 = eL[wid][jj + 3];
        float xg[4];
#pragma unroll
        for (int q = 0; q < 4; q++)
          xg[q] = fa ? bf2f(xbhl[(size_t)sj[q] * 128 + lane]) : 0.f;
        ag0 += e0.x * xg[0] + e1.x * xg[1] + e2.x * xg[2] + e3.x * xg[3];
        ag1 += e0.y * xg[0] + e1.y * xg[1] + e2.y * xg[2] + e3.y * xg[3];
        ag2 += e0.z * xg[0] + e1.z * xg[1] + e2.z * xg[2] + e3.z * xg[3];
        ag3 += e0.w * xg[0] + e1.w * xg[1] + e2.w * xg[2] + e3.w * xg[3];
#pragma unroll
        for (int q = 0; q < 4; q++)
          if (jj + q < cn) ax += xg[q];                // uniform guard
      }
    }
#pragma unroll
    for (int off = 32; off >= 1; off >>= 1)
#pragma unroll
      for (int h = 0; h < 4; h++) zl[h] += __shfl_xor(zl[h], off);
    {
      float z0 = zl[0] + exs[0] + 1e-16f;
      float z1 = zl[1] + exs[1] + 1e-16f;
      float z2 = zl[2] + exs[2] + 1e-16f;
      float z3 = zl[3] + exs[3] + 1e-16f;
      short* ar = agg4 + (size_t)i * A4P;
      ar[0 * 64 + lane] = fa ? f2bf(ag0 / z0) : (short)0;
      ar[1 * 64 + lane] = fa ? f2bf(ag1 / z1) : (short)0;
      ar[2 * 64 + lane] = fa ? f2bf(ag2 / z2) : (short)0;
      ar[3 * 64 + lane] = fa ? f2bf(ag3 / z3) : (short)0;
      // GIN aggregate: hi/lo double-bf16 (fp32-equivalent through MFMA)
      float axv = fa ? ax : 0.f;
      short hi = f2bf(axv);
      float lov = axv - bf2f(hi);
      short* br = aggb + (size_t)i * 128;
      br[lane]      = fa ? hi : (short)0;
      br[64 + lane] = fa ? f2bf(lov) : (short)0;
    }
  }
}

// ---------------------------------------------------------------------------
// Fused post-aggregation (light): phase 1 = GAT transform (MFMA, LDS-free
// weights), phase 2 = GIN MLP (MFMA, hi/lo). LDS union ~39KB -> 4 blocks/CU.
// ---------------------------------------------------------------------------
#define H1S 132   /* h1 row stride in shorts: 66 words % 32 = 2 -> conflict-free */
__global__ __launch_bounds__(256) void k_post2(
    const short* __restrict__ agg4, const short* __restrict__ Wgt,
    const float* __restrict__ gat_b,
    const short* __restrict__ aggb, const short* __restrict__ Wg1,
    const short* __restrict__ Wg2,
    const float* __restrict__ b1, const float* __restrict__ b2,
    const int* __restrict__ batch, float* __restrict__ pooled) {
  __shared__ float psumG[4 * 224];
  __shared__ short h1hi[64 * H1S];
  __shared__ short h1lo[64 * H1S];
  __shared__ float psumN[4 * 112];
  __shared__ int batL[64];
  int m0 = blockIdx.x * 64;
  int t = threadIdx.x;
  for (int idx = t; idx < 4 * 224; idx += 256) psumG[idx] = 0.f;
  for (int idx = t; idx < 4 * 112; idx += 256) psumN[idx] = 0.f;
  if (t < 64) batL[t] = batch[min(m0 + t, N_NODES - 1)];
  for (int idx = t; idx < 64 * H1S / 2; idx += 256) {
    ((int*)h1hi)[idx] = 0;
    ((int*)h1lo)[idx] = 0;
  }
  __syncthreads();
  const int lane = t & 63, wid = t >> 6;
  const int n16 = lane & 15, quad = lane >> 4;
  const int mrow0 = wid * 16;
  const int bmin = batL[0];
  const bool uni = (batL[0] == batL[63]);

  // =================== phase 1: GAT transform ===================
  {
    const size_t abase = (size_t)(m0 + mrow0 + n16) * A4P;   // pad rows: workspace
#pragma unroll
    for (int h = 0; h < 4; h++) {
      short8 af0 = *(const short8*)(agg4 + abase + h * 64 + quad * 8);
      short8 af1 = *(const short8*)(agg4 + abase + h * 64 + 32 + quad * 8);
#pragma unroll
      for (int nt = 0; nt < 4; nt++) {
        short8 b0 = *(const short8*)(Wgt + (h * 56 + nt * 16 + n16) * 64 + quad * 8);
        short8 b1f = *(const short8*)(Wgt + (h * 56 + nt * 16 + n16) * 64 + 32 + quad * 8);
        f32x4 acc = {0.f, 0.f, 0.f, 0.f};
        acc = __builtin_amdgcn_mfma_f32_16x16x32_bf16(af0, b0, acc, 0, 0, 0);
        acc = __builtin_amdgcn_mfma_f32_16x16x32_bf16(af1, b1f, acc, 0, 0, 0);
        int jn = nt * 16 + n16;
        bool jv = jn < FDIM;
        float bj = jv ? gat_b[h * FDIM + jn] : 0.f;
        if (uni) {
          float s = 0.f;
#pragma unroll
          for (int r = 0; r < 4; r++) {
            int gm = m0 + mrow0 + quad * 4 + r;
            if (gm < N_NODES) s += fmaxf(acc[r] + bj, 0.f);
          }
          s += __shfl_xor(s, 16);
          s += __shfl_xor(s, 32);
          if (quad == 0 && jv && s != 0.f) atomicAdd(&psumG[h * 56 + jn], s);
        } else {
          float pj = 0.f; int curb = -1;
#pragma unroll
          for (int r = 0; r < 4; r++) {
            int lm = mrow0 + quad * 4 + r;
            int gm = m0 + lm;
            if (gm < N_NODES) {
              float o = fmaxf(acc[r] + bj, 0.f);
              int b = batL[lm];
              if (b != curb) {
                if (curb >= 0 && jv) {
                  int slot = curb - bmin;
                  if (slot >= 0 && slot < 4) atomicAdd(&psumG[slot * 224 + h * 56 + jn], pj);
                  else atomicAdd(&pooled[(size_t)curb * POOLW + h * FDIM + jn], pj);
                }
                curb = b; pj = o;
              } else {
                pj += o;
              }
            }
          }
          if (curb >= 0 && jv) {
            int slot = curb - bmin;
            if (slot >= 0 && slot < 4) atomicAdd(&psumG[slot * 224 + h * 56 + jn], pj);
            else atomicAdd(&pooled[(size_t)curb * POOLW + h * FDIM + jn], pj);
          }
        }
      }
    }
  }

  // =================== phase 2, layer 1: h1 = relu((hi+lo)@w1+b1) ===================
  {
    const size_t abase = (size_t)(m0 + mrow0 + n16) * 128;  // pad rows: workspace
    short8 a[4];
#pragma unroll
    for (int f = 0; f < 4; f++)
      a[f] = *(const short8*)(aggb + abase + f * 32 + quad * 8);
#pragma unroll
    for (int nt = 0; nt < 7; nt++) {
      f32x4 acc = {0.f, 0.f, 0.f, 0.f};
#pragma unroll
      for (int f = 0; f < 4; f++) {
        short8 bf = *(const short8*)(Wg1 + (nt * 16 + n16) * 128 + f * 32 + quad * 8);
        acc = __builtin_amdgcn_mfma_f32_16x16x32_bf16(a[f], bf, acc, 0, 0, 0);
      }
      int jn = nt * 16 + n16;
      if (jn < F2) {
        float bj = b1[jn];
#pragma unroll
        for (int r = 0; r < 4; r++) {
          int row = mrow0 + quad * 4 + r;
          float v = fmaxf(acc[r] + bj, 0.f);
          short hi = f2bf(v);
          h1hi[row * H1S + jn] = hi;
          h1lo[row * H1S + jn] = f2bf(v - bf2f(hi));
        }
      }
    }
  }
  __syncthreads();   // h1 writes complete (also fences psumG phase-1 atomics)

  // flush phase-1 psum while h1 settles
  for (int idx = t; idx < 4 * 224; idx += 256) {
    int slot = idx / 224, c = idx % 224;
    int h = c / 56, jn = c % 56;
    float v = psumG[idx];
    int b = bmin + slot;
    if (jn < FDIM && b < BATCH && v != 0.f)
      atomicAdd(&pooled[(size_t)b * POOLW + h * FDIM + jn], v);
  }

  // =================== phase 2, layer 2 ===================
  short8 ah[4], al[4];
#pragma unroll
  for (int f = 0; f < 4; f++) {
    ah[f] = *(const short8*)&h1hi[(mrow0 + n16) * H1S + f * 32 + quad * 8];
    al[f] = *(const short8*)&h1lo[(mrow0 + n16) * H1S + f * 32 + quad * 8];
  }
#pragma unroll
  for (int nt = 0; nt < 7; nt++) {
    f32x4 acc = {0.f, 0.f, 0.f, 0.f};
#pragma unroll
    for (int f = 0; f < 4; f++) {
      short8 bf = *(const short8*)(Wg2 + (nt * 16 + n16) * 128 + f * 32 + quad * 8);
      acc = __builtin_amdgcn_mfma_f32_16x16x32_bf16(ah[f], bf, acc, 0, 0, 0);
      acc = __builtin_amdgcn_mfma_f32_16x16x32_bf16(al[f], bf, acc, 0, 0, 0);
    }
    int jn = nt * 16 + n16;
    bool jv = jn < F2;
    float bj = jv ? b2[jn] : 0.f;
    if (uni) {
      float s = 0.f;
#pragma unroll
      for (int r = 0; r < 4; r++) {
        int gm = m0 + mrow0 + quad * 4 + r;
        if (gm < N_NODES) s += fmaxf(acc[r] + bj, 0.f);
      }
      s += __shfl_xor(s, 16);
      s += __shfl_xor(s, 32);
      if (quad == 0 && jv && s != 0.f) atomicAdd(&psumN[jn], s);
    } else {
      float pj = 0.f; int curb = -1;
#pragma unroll
      for (int r = 0; r < 4; r++) {
        int lm = mrow0 + quad * 4 + r;
        int gm = m0 + lm;
        if (gm < N_NODES) {
          float o = fmaxf(acc[r] + bj, 0.f);
          int b = batL[lm];
          if (b != curb) {
            if (curb >= 0 && jv) {
              int slot = curb - bmin;
              if (slot >= 0 && slot < 4) atomicAdd(&psumN[slot * 112 + jn], pj);
              else atomicAdd(&pooled[(size_t)curb * POOLW + HF + jn], pj);
            }
            curb = b; pj = o;
          } else {
            pj += o;
          }
        }
      }
      if (curb >= 0 && jv) {
        int slot = curb - bmin;
        if (slot >= 0 && slot < 4) atomicAdd(&psumN[slot * 112 + jn], pj);
        else atomicAdd(&pooled[(size_t)curb * POOLW + HF + jn], pj);
      }
    }
  }
  __syncthreads();
  for (int idx = t; idx < 4 * 112; idx += 256) {
    int slot = idx / 112, n = idx % 112;
    float v = psumN[idx];
    int b = bmin + slot;
    if (n < F2 && b < BATCH && v != 0.f)
      atomicAdd(&pooled[(size_t)b * POOLW + HF + n], v);
  }
}

// ---------------------------------------------------------------------------
// EdgeConv v9: fp16 U/V with zero pads -> h-phase is 4 packed adds + 4 packed
// maxes (native half8 vector ops -> v_pk_add_f16 / v_pk_max_f16), no
// unpack/repack, no tail guard; MFMA switched to f16. Rest identical to v8.
// ---------------------------------------------------------------------------
#define ECH 25
__global__ __launch_bounds__(256) void k_ec(
    const short* __restrict__ Ub, const short* __restrict__ Vb,
    const float* __restrict__ w2, const float* __restrict__ b2,
    const int* __restrict__ rp, const int* __restrict__ colidx,
    const int* __restrict__ batch, float* __restrict__ pooled) {
  const int t = threadIdx.x;
  const int lane = t & 63, wid = t >> 6;
  const int n16 = lane & 15, quad = lane >> 4;
  const int nt = (wid == 3) ? 1 : 2;   // u-tile 7 is all-pad

  const int i0 = blockIdx.x * ECH;
  const int iend = min(i0 + ECH, N_NODES);
  const int nn = iend - i0;

  __shared__ int rpL[ECH + 1];
  __shared__ int batL[ECH];

  half8 Bh[2][4];
  for (int tt = 0; tt < 2; tt++) {
    int ucol = (wid * 2 + tt) * 16 + n16;
    for (int kc = 0; kc < 4; kc++) {
      half8 vh;
#pragma unroll
      for (int jv = 0; jv < 8; jv++) {
        int kk = kc * 32 + quad * 8 + jv;
        float w = (ucol < F2 && kk < F2) ? w2[kk * F2 + ucol] : 0.f;
        vh[jv] = (_Float16)w;
      }
      Bh[tt][kc] = vh;
    }
  }
  float b2v[2];
#pragma unroll
  for (int tt = 0; tt < 2; tt++) {
    int u = (wid * 2 + tt) * 16 + n16;
    b2v[tt] = (u < F2) ? b2[u] : 0.f;
  }

  if (t <= nn) rpL[t] = rp[i0 + t];
  if (t < nn) batL[t] = batch[i0 + t];
  __syncthreads();

  __shared__ short hs[2][16 * 16 * 8];
  union SU { short8 s; half8 h; };
  const int es = t & 15, kg = t >> 4;
  const int k0 = kg * 8;
  const half8 zero8 = (half8)(_Float16)0.f;

  float sm0 = 0.f, sm1 = 0.f;
  int curb = -1;
  const int u0 = (wid * 2) * 16 + n16;
  const int u1 = (wid * 2 + 1) * 16 + n16;

  // tile walk: (node, tile-in-node, base, deg) -> next
  auto advance = [&](int& ii, int& ttb, int& bb, int& dd) -> bool {
    ttb++;
    if (ttb * 16 < dd) return true;
    ttb = 0;
    for (ii = ii + 1; ii < iend; ii++) {
      bb = rpL[ii - i0]; dd = rpL[ii - i0 + 1] - bb;
      if (dd > 0) return true;
    }
    return false;
  };

  // current tile T
  int i = i0, tb = 0, base = 0, deg = 0;
  bool have = false;
  for (; i < iend; i++) {
    base = rpL[i - i0]; deg = rpL[i - i0 + 1] - base;
    if (deg > 0) { have = true; break; }
  }
  short8 pu8{}, pv8{};
  // tile T+1 coords + its colidx value (sc) already fetched
  int i1 = i, tb1 = 0, base1 = base, deg1 = deg;
  bool have1 = false;
  int sc = 0;
  if (have) {
    pu8 = *(const short8*)(Ub + (size_t)i * ECS + k0);
    int s0 = colidx[base + ((es < deg) ? es : 0)];
    pv8 = *(const short8*)(Vb + (size_t)s0 * ECS + k0);
    have1 = advance(i1, tb1, base1, deg1);
    if (have1) {
      int eg = tb1 * 16 + es;
      sc = colidx[base1 + ((eg < deg1) ? eg : 0)];
    }
  }

  float vmax0 = -1e30f, vmax1 = -1e30f;
  int parity = 0;
  while (have) {
    SU uu, vv, w;
    uu.s = pu8; vv.s = pv8;
    w.h = __builtin_elementwise_max(uu.h + vv.h, zero8);
    *(short8*)&hs[parity][(kg * 16 + es) * 8] = w.s;

    // prefetch: V (and U) for tile T+1 using sc fetched last iter; colidx for T+2
    int i2 = i1, tb2 = tb1, base2 = base1, deg2 = deg1;
    bool have2 = false;
    int scN = 0;
    if (have1) {
      if (tb1 == 0) pu8 = *(const short8*)(Ub + (size_t)i1 * ECS + k0);
      pv8 = *(const short8*)(Vb + (size_t)sc * ECS + k0);
      have2 = advance(i2, tb2, base2, deg2);
      if (have2) {
        int eg2 = tb2 * 16 + es;
        scN = colidx[base2 + ((eg2 < deg2) ? eg2 : 0)];
      }
    }

    ldsbar();
    f32x4 a0 = {0.f, 0.f, 0.f, 0.f}, a1 = {0.f, 0.f, 0.f, 0.f};
#pragma unroll
    for (int kc = 0; kc < 4; kc++) {
      half8 af = *(const half8*)&hs[parity][((kc * 4 + quad) * 16 + n16) * 8];
      a0 = __builtin_amdgcn_mfma_f32_16x16x32_f16(af, Bh[0][kc], a0, 0, 0, 0);
      if (nt > 1)
        a1 = __builtin_amdgcn_mfma_f32_16x16x32_f16(af, Bh[1][kc], a1, 0, 0, 0);
    }
#pragma unroll
    for (int r = 0; r < 4; r++) {
      int er = tb * 16 + quad * 4 + r;
      if (er < deg) { vmax0 = fmaxf(vmax0, a0[r]); vmax1 = fmaxf(vmax1, a1[r]); }
    }
    if (!have1 || i1 != i) {
      // node i finishes with this tile: cross-quad reduce deferred to here
      vmax0 = fmaxf(vmax0, __shfl_xor(vmax0, 16));
      vmax0 = fmaxf(vmax0, __shfl_xor(vmax0, 32));
      vmax1 = fmaxf(vmax1, __shfl_xor(vmax1, 16));
      vmax1 = fmaxf(vmax1, __shfl_xor(vmax1, 32));
      float o0 = fmaxf(vmax0 + b2v[0], 0.f);
      float o1 = fmaxf(vmax1 + b2v[1], 0.f);
      int b = batL[i - i0];
      if (b != curb) {
        if (curb >= 0 && quad == 0) {
          float* pg = pooled + (size_t)curb * POOLW + HF + F2;
          if (u0 < F2) atomicAdd(&pg[u0], sm0);
          if (nt > 1 && u1 < F2) atomicAdd(&pg[u1], sm1);
        }
        curb = b; sm0 = o0; sm1 = o1;
      } else {
        sm0 += o0; sm1 += o1;
      }
      vmax0 = -1e30f; vmax1 = -1e30f;
    }
    i = i1; tb = tb1; base = base1; deg = deg1; have = have1;
    i1 = i2; tb1 = tb2; base1 = base2; deg1 = deg2; have1 = have2;
    sc = scN;
    parity ^= 1;
  }
  if (curb >= 0 && quad == 0) {
    float* pg = pooled + (size_t)curb * POOLW + HF + F2;
    if (u0 < F2) atomicAdd(&pg[u0], sm0);
    if (nt > 1 && u1 < F2) atomicAdd(&pg[u1], sm1);
  }
}

// ---------------------------------------------------------------------------
// Per-graph heads + final MLP fused; mean-pool divide folded into the load.
// ---------------------------------------------------------------------------
__global__ __launch_bounds__(256) void k_heads(
    const float* __restrict__ pooled, const int* __restrict__ start,
    const float* __restrict__ fg1_w, const float* __restrict__ fg1_b,
    const float* __restrict__ fg2_w, const float* __restrict__ fg2_b,
    const float* __restrict__ fg3_w, const float* __restrict__ fg3_b,
    const float* __restrict__ fg4_w, const float* __restrict__ fg4_b,
    const float* __restrict__ fg5_w, const float* __restrict__ fg5_b,
    const float* __restrict__ fg6_w, const float* __restrict__ fg6_b,
    const float* __restrict__ fc1_w, const float* __restrict__ fc1_b,
    const float* __restrict__ fc2_w, const float* __restrict__ fc2_b,
    const float* __restrict__ out_w, const float* __restrict__ out_b,
    float* __restrict__ out) {
  int g = blockIdx.x, t = threadIdx.x;
  __shared__ float in[POOLW];
  __shared__ float mid[256];
  __shared__ float cat[384];
  __shared__ float h1[128];
  __shared__ float h2[64];
  float c = fmaxf((float)(start[g + 1] - start[g]), 1.f);
  for (int idx = t; idx < POOLW; idx += 256)
    in[idx] = pooled[(size_t)g * POOLW + idx] / c;
  __syncthreads();
  const float* w1s[3] = {fg1_w, fg3_w, fg5_w};
  const float* b1s[3] = {fg1_b, fg3_b, fg5_b};
  const float* w2s[3] = {fg2_w, fg4_w, fg6_w};
  const float* b2s[3] = {fg2_b, fg4_b, fg6_b};
  const int off[4] = {0, HF, HF + F2, POOLW};
  for (int br = 0; br < 3; br++) {
    int kin = off[br + 1] - off[br];
    const float* iv = &in[off[br]];
    float a = b1s[br][t];
    const float* W = w1s[br];
    for (int k = 0; k < kin; k++) a += iv[k] * W[k * 256 + t];
    mid[t] = fmaxf(a, 0.f);
    __syncthreads();
    if (t < 128) {
      float b = b2s[br][t];
      const float* W2 = w2s[br];
      for (int k = 0; k < 256; k++) b += mid[k] * W2[k * 128 + t];
      cat[br * 128 + t] = fmaxf(b, 0.f);
    }
    __syncthreads();
  }
  if (t < 128) {
    float a = fc1_b[t];
    for (int k = 0; k < 384; k++) a += cat[k] * fc1_w[k * 128 + t];
    h1[t] = fmaxf(a, 0.f);
  }
  __syncthreads();
  if (t < 64) {
    float a = fc2_b[t];
    for (int k = 0; k < 128; k++) a += h1[k] * fc2_w[k * 64 + t];
    h2[t] = fmaxf(a, 0.f);
  }
  __syncthreads();
  if (t == 0) {
    float a = out_b[0];
    for (int k = 0; k < 64; k++) a += h2[k] * out_w[k];
    out[g] = 1.f / (1.f + __expf(-a));
  }
}

// ---------------------------------------------------------------------------
extern "C" void kernel_launch(void* const* d_in, const int* in_sizes, int n_in,
                              void* d_out, int out_size, void* d_ws, size_t ws_size,
                              hipStream_t stream) {
  const float* x      = (const float*)d_in[0];
  const int*   ei     = (const int*)d_in[1];
  const int*   batch  = (const int*)d_in[2];
  const float* gat_w  = (const float*)d_in[3];
  const float* asrc   = (const float*)d_in[4];
  const float* adst   = (const float*)d_in[5];
  const float* gat_b  = (const float*)d_in[6];
  const float* gin_w1 = (const float*)d_in[7];
  const float* gin_b1 = (const float*)d_in[8];
  const float* gin_w2 = (const float*)d_in[9];
  const float* gin_b2 = (const float*)d_in[10];
  const float* ec_w1  = (const float*)d_in[11];
  const float* ec_b1  = (const float*)d_in[12];
  const float* ec_w2  = (const float*)d_in[13];
  const float* ec_b2  = (const float*)d_in[14];
  const float* fg1_w = (const float*)d_in[15]; const float* fg1_b = (const float*)d_in[16];
  const float* fg2_w = (const float*)d_in[17]; const float* fg2_b = (const float*)d_in[18];
  const float* fg3_w = (const float*)d_in[19]; const float* fg3_b = (const float*)d_in[20];
  const float* fg4_w = (const float*)d_in[21]; const float* fg4_b = (const float*)d_in[22];
  const float* fg5_w = (const float*)d_in[23]; const float* fg5_b = (const float*)d_in[24];
  const float* fg6_w = (const float*)d_in[25]; const float* fg6_b = (const float*)d_in[26];
  const float* fc1_w = (const float*)d_in[27]; const float* fc1_b = (const float*)d_in[28];
  const float* fc2_w = (const float*)d_in[29]; const float* fc2_b = (const float*)d_in[30];
  const float* out_w = (const float*)d_in[31]; const float* out_b = (const float*)d_in[32];
  float* out = (float*)d_out;

  char* ws = (char*)d_ws;
  size_t off = 0;
  auto alloc = [&](size_t bytes) -> void* {
    void* p = ws + off;
    off = (off + bytes + 255) & ~(size_t)255;
    return p;
  };
  // --- zero region (one memset): histP | pooled ---
  size_t zoff0 = off;
  int*   histP  = (int*)alloc((size_t)N_NODES * PSTR * sizeof(int));  // 6.4 MB padded bins
  float* pooled = (float*)alloc((size_t)BATCH * POOLW * sizeof(float));
  size_t zbytes = off - zoff0;
  // --- rest ---
  int*   rp     = (int*)alloc((N_NODES + 1) * sizeof(int));
  int*   start  = (int*)alloc((BATCH + 1) * sizeof(int));
  int*   bsum   = (int*)alloc(256 * sizeof(int));
  int*   colidx = (int*)alloc(N_EDGES * sizeof(int));
  short* xbhl   = (short*)alloc((size_t)(N_NODES + 64) * 128 * sizeof(short)); // x hi/lo
  float* alS    = (float*)alloc((size_t)N_NODES * 4 * sizeof(float));
  float* alD    = (float*)alloc((size_t)N_NODES * 4 * sizeof(float));
  short* Ubuf   = (short*)alloc((size_t)N_NODES * ECS * sizeof(short));  // fp16, 256B rows
  short* Vbuf   = (short*)alloc((size_t)N_NODES * ECS * sizeof(short));  // fp16, 256B rows
  short* agg4   = (short*)alloc((size_t)(N_NODES + 64) * A4P * sizeof(short)); // padded bf16
  short* aggb   = (short*)alloc((size_t)(N_NODES + 64) * 128 * sizeof(short)); // GIN hi/lo
  short* Wgt    = (short*)alloc(SEG_WGT * sizeof(short));
  short* Wuv    = (short*)alloc(SEG_WUV * sizeof(short));
  short* Wg1    = (short*)alloc(SEG_WG1 * sizeof(short));
  short* Wg2    = (short*)alloc(SEG_WG2 * sizeof(short));
  (void)ws_size; (void)in_sizes; (void)n_in; (void)out_size;

  hipMemsetAsync(ws + zoff0, 0, zbytes, stream);

  k_prep<<<(PREP_TOT + 255) / 256, 256, 0, stream>>>(gat_w, asrc, adst, ec_w1,
                                                     gin_w1, gin_w2,
                                                     Wgt, Wuv, Wg1, Wg2);
  k_xsplit<<<(N_NODES + 3) / 4, 256, 0, stream>>>(x, xbhl);
  k_uv<<<((N_NODES + 63) / 64) * 2, 256, 0, stream>>>(xbhl, Wuv, ec_b1,
                                                      Ubuf, Vbuf, alS, alD);
  k_hist<<<(N_EDGES + 255) / 256, 256, 0, stream>>>(ei, histP);
  k_scan1<<<SCAN_BLOCKS, 256, 0, stream>>>(histP, batch, rp, bsum, start);
  k_scan3<<<SCAN_BLOCKS, 256, 0, stream>>>(bsum, rp, histP);
  k_scatter<<<(N_EDGES + 255) / 256, 256, 0, stream>>>(ei, histP, colidx);

  // fused GAT-aggregate + GIN-sum over the L2-resident bf16 x table
  k_gatgin<<<(N_NODES + GCH - 1) / GCH, 256, 0, stream>>>(xbhl, alS, alD, rp, colidx,
                                                          agg4, aggb);
  k_ec<<<(N_NODES + ECH - 1) / ECH, 256, 0, stream>>>(Ubuf, Vbuf, ec_w2, ec_b2, rp, colidx, batch, pooled);
  // fused GAT transform + GIN MLP (both MFMA, LDS-free weights)
  k_post2<<<(N_NODES + 63) / 64, 256, 0, stream>>>(agg4, Wgt, gat_b,
                                                   aggb, Wg1, Wg2, gin_b1, gin_b2,
                                                   batch, pooled);

  k_heads<<<BATCH, 256, 0, stream>>>(pooled, start,
                                     fg1_w, fg1_b, fg2_w, fg2_b, fg3_w, fg3_b,
                                     fg4_w, fg4_b, fg5_w, fg5_b, fg6_w, fg6_b,
                                     fc1_w, fc1_b, fc2_w, fc2_b, out_w, out_b, out);
}